// Round 3
// baseline (1520.642 us; speedup 1.0000x reference)
//
#include <hip/hip_runtime.h>
#include <hip/hip_bf16.h>
#include <stdint.h>

using bf16 = __hip_bfloat16;
typedef short bfrag8 __attribute__((ext_vector_type(8)));
typedef float f32x4 __attribute__((ext_vector_type(4)));

// ---------------- workspace layout (bytes) ----------------
constexpr long OFF_XT   = 0L;           // 3 x [32768][512] bf16 NHWC
constexpr long OFF_XC   = 100663296L;   // 3 x [512][32768] bf16 channel-major
constexpr long OFF_WQ   = 201326592L;   // 6 x [512][512] bf16
constexpr long OFF_WK   = 204472320L;
constexpr long OFF_WV2  = 207618048L;   // 3 x [1024][512] bf16 stacked Wv
constexpr long OFF_WO2  = 210763776L;   // 3 x [512][1024] bf16 stacked Wo
constexpr long OFF_FW   = 213909504L;   // [1536][1536] bf16
constexpr long OFF_BO2  = 218628096L;   // [3][512] f32
constexpr long OFF_BV2  = 218634240L;   // [3][1024] f32
constexpr long OFF_POOL = 218646528L;   // [3][8][512] f32   (memset from here)
constexpr long OFF_SE   = 218695680L;   // [3][8][512] f32
constexpr long OFF_QACC = 218744832L;   // [8][4] f32 (+pad to 1024)
constexpr long OFF_CS   = 218745856L;   // [3][8][512] f32 column sums (memset to here+49152)
constexpr long OFF_GB   = 218795008L;   // [3][8][512][512] bf16 Gram
constexpr long OFF_ATT  = 231377920L;   // [6][8][8][64][64] bf16
constexpr long OFF_VST  = 234523648L;   // 3 x [32768][1024] bf16 ; later cross f32 3x[32768][512]
// aliases: Ost = [0, 201326592) (3 x [32768][1024] bf16) after xT/xC dead
//          weighted = 100663296 (96 MB) after Ost dead

__device__ __forceinline__ void mfma_bf16(f32x4& c, bfrag8 a, bfrag8 b) {
  asm("v_mfma_f32_16x16x32_bf16 %0, %1, %2, %0" : "+v"(c) : "v"(a), "v"(b));
}

__device__ __forceinline__ void gload16(const void* g, void* l) {
  __builtin_amdgcn_global_load_lds(
      (__attribute__((address_space(1))) void*)(g),
      (__attribute__((address_space(3))) void*)(l), 16, 0, 0);
}

__device__ __forceinline__ float bf2f(short s) {
  union { uint32_t u; float f; } cv;
  cv.u = ((uint32_t)(unsigned short)s) << 16;
  return cv.f;
}

// XCD-chunked bijective swizzle, n-fast logical order. Requires gx*gy % 8 == 0.
__device__ __forceinline__ void swz_mn(int gy, long& m0, long& n0) {
  const int gx = gridDim.x;
  const int orig = blockIdx.y * gx + blockIdx.x;
  const int q = (gx * gy) >> 3;
  const int wgid = (orig & 7) * q + (orig >> 3);
  m0 = (long)(wgid / gy) * 128;
  n0 = (long)(wgid % gy) * 128;
}

// ============ transpose + stats: NCHW f32 -> NHWC + channel-major bf16, colsum, quality ============
__global__ __launch_bounds__(256) void transpose_kernel(
    const float* __restrict__ x0, const float* __restrict__ x1,
    const float* __restrict__ x2, bf16* __restrict__ xT, bf16* __restrict__ xC,
    float* __restrict__ cs, float* __restrict__ qacc)
{
  __shared__ float tile[32][33];
  const int zz = blockIdx.z;           // m*8 + b
  const int m = zz >> 3, b = zz & 7;
  const float* x = (m == 0) ? x0 : (m == 1) ? x1 : x2;
  bf16* y = xT + (long)m * 16777216;
  bf16* y2 = xC + (long)m * 16777216;
  const int c0 = blockIdx.y * 32;
  const int tx = threadIdx.x, ty = threadIdx.y;
  float csp[4] = {0.f, 0.f, 0.f, 0.f};
  float qa = 0.f, qb_ = 0.f;   // m==0: sum,ssq ; else: zero-count in qa
  for (int jj = 0; jj < 4; ++jj) {
    const int p0 = (blockIdx.x * 4 + jj) * 32;
    float v[4];
#pragma unroll
    for (int j = 0; j < 4; ++j) {
      v[j] = x[((long)b * 512 + c0 + ty + j * 8) * 4096 + p0 + tx];
      tile[ty + j * 8][tx] = v[j];
      y2[(long)(c0 + ty + j * 8) * 32768 + (long)b * 4096 + p0 + tx] = __float2bfloat16(v[j]);
      csp[j] += v[j];
      if (m == 0) { qa += v[j]; qb_ += v[j] * v[j]; }
      else qa += (v[j] == 0.0f) ? 1.0f : 0.0f;
    }
    __syncthreads();
#pragma unroll
    for (int j = 0; j < 4; ++j)
      y[((long)b * 4096 + p0 + ty + j * 8) * 512 + c0 + tx] =
          __float2bfloat16(tile[tx][ty + j * 8]);
    __syncthreads();
  }
  // colsum: reduce over tx (32 lanes)
#pragma unroll
  for (int j = 0; j < 4; ++j) {
    float s = csp[j];
    for (int o = 16; o; o >>= 1) s += __shfl_xor(s, o);
    if (tx == 0) atomicAdd(&cs[(m * 8 + b) * 512 + c0 + ty + j * 8], s);
  }
  // quality: full-wave reduce
  const int lane = (ty * 32 + tx) & 63;
  for (int o = 32; o; o >>= 1) { qa += __shfl_xor(qa, o); qb_ += __shfl_xor(qb_, o); }
  if (lane == 0) {
    if (m == 0) { atomicAdd(&qacc[b * 4 + 1], qa); atomicAdd(&qacc[b * 4 + 2], qb_); }
    else if (m == 1) atomicAdd(&qacc[b * 4 + 0], qa);
    else atomicAdd(&qacc[b * 4 + 3], qa);
  }
}

// =================== weight conversion / stacking ===================
__global__ void prep_weights(
    const float* __restrict__ wq, const float* __restrict__ wk,
    const float* __restrict__ wv, const float* __restrict__ wo,
    const float* __restrict__ fw, const float* __restrict__ bo,
    const float* __restrict__ bv,
    bf16* __restrict__ wqB, bf16* __restrict__ wkB, bf16* __restrict__ wv2,
    bf16* __restrict__ wo2, bf16* __restrict__ fwB,
    float* __restrict__ bo2, float* __restrict__ bv2)
{
  const int L0[3] = {2, 0, 1}, L1[3] = {4, 5, 3};
  const long stride = (long)gridDim.x * blockDim.x;
  for (long j = (long)blockIdx.x * blockDim.x + threadIdx.x; j < 2359296; j += stride) {
    fwB[j] = __float2bfloat16(fw[j]);
    if (j < 1572864) {
      wqB[j] = __float2bfloat16(wq[j]);
      wkB[j] = __float2bfloat16(wk[j]);
      const long m = j >> 19, rem = j & 524287;
      {  // wo2[m][c (512)][k (1024)], k = jj*512 + ci
        const long c = rem >> 10, k = rem & 1023, jj = k >> 9, ci = k & 511;
        wo2[j] = __float2bfloat16(wo[(((m * 2 + jj) * 512 + c) << 9) + ci]);
      }
      {  // wv2[m][row (1024)][k (512)]
        const long row = rem >> 9, k = rem & 511;
        const int im = (row < 512) ? L0[m] : L1[m];
        wv2[j] = __float2bfloat16(wv[((long)(im * 512 + (row & 511)) << 9) + k]);
      }
    }
    if (j < 1536) {
      const long m2 = j >> 9, cc = j & 511;
      bo2[j] = bo[((m2 * 2) << 9) + cc] + bo[((m2 * 2 + 1) << 9) + cc];
    }
    if (j < 3072) {
      const long m3 = j >> 10, row = j & 1023;
      const int im = (row < 512) ? L0[m3] : L1[m3];
      bv2[j] = bv[im * 512 + (row & 511)];
    }
  }
}

// =================== GEMM core: C[M,N] = A[M,K] * Bt[N,K]^T ===================
template<int BM, int BN>
__device__ __forceinline__ void gemm_core(
    const bf16* __restrict__ A, long lda,
    const bf16* __restrict__ Bt, long ldb,
    int K, long m0, long n0,
    bf16* As, bf16* Bs, f32x4 (&acc)[BM / 32][BN / 32])
{
  constexpr int WM = BM / 2, WN = BN / 2, FM = BM / 32, FN = BN / 32;
  const int t = threadIdx.x;
  const int lane = t & 63, wv = t >> 6;
  const int wr = wv >> 1, wc = wv & 1;
  const int l16 = lane & 15, lk = lane >> 4;
  const int srow = t >> 2;
  const int scol = (t & 3) * 8;
  const bf16* Ag = A + (m0 + srow) * lda + scol;
  const bf16* Bg = Bt + (n0 + srow) * ldb + scol;
  char* AsB = (char*)As;
  char* BsB = (char*)Bs;
  const int aoff = wv * 1024;
  for (int kk = 0; kk < K; kk += 32) {
#pragma unroll
    for (int it = 0; it < BM / 64; ++it)
      gload16(Ag + (long)it * 64 * lda + kk, AsB + it * 4096 + aoff);
#pragma unroll
    for (int it = 0; it < BN / 64; ++it)
      gload16(Bg + (long)it * 64 * ldb + kk, BsB + it * 4096 + aoff);
    __syncthreads();
    bfrag8 af[FM], bfr[FN];
#pragma unroll
    for (int m = 0; m < FM; ++m)
      af[m] = *(const bfrag8*)(AsB + ((wr * WM + m * 16 + l16) * 32 + lk * 8) * 2);
#pragma unroll
    for (int n = 0; n < FN; ++n)
      bfr[n] = *(const bfrag8*)(BsB + ((wc * WN + n * 16 + l16) * 32 + lk * 8) * 2);
#pragma unroll
    for (int m = 0; m < FM; ++m)
#pragma unroll
      for (int n = 0; n < FN; ++n)
        mfma_bf16(acc[m][n], af[m], bfr[n]);
    __syncthreads();
  }
}

// =================== V projection: Vst[m][pix][1024] = xT[m] * wv2[m]^T ===================
__global__ __launch_bounds__(256, 2) void v_gemm(
    const bf16* __restrict__ xT, const bf16* __restrict__ wv2,
    bf16* __restrict__ Vst, const float* __restrict__ bv2)
{
  __shared__ __align__(16) bf16 As[128 * 32];
  __shared__ __align__(16) bf16 Bs[128 * 32];
  const int z = blockIdx.z;
  const bf16* A = xT + (long)z * 16777216;
  const bf16* Bt = wv2 + (long)z * 524288;
  bf16* C = Vst + (long)z * 33554432;
  const float* bias = bv2 + z * 1024;
  f32x4 acc[4][4];
#pragma unroll
  for (int m = 0; m < 4; ++m)
#pragma unroll
    for (int n = 0; n < 4; ++n)
      acc[m][n] = f32x4{0.f, 0.f, 0.f, 0.f};
  long m0, n0;
  swz_mn(8, m0, n0);
  gemm_core<128, 128>(A, 512, Bt, 512, 512, m0, n0, As, Bs, acc);

  const int t = threadIdx.x;
  const int lane = t & 63, wv = t >> 6;
  const int wr = wv >> 1, wc = wv & 1;
  const int l16 = lane & 15, lk = lane >> 4;
#pragma unroll
  for (int m = 0; m < 4; ++m) {
    const long gr0 = m0 + wr * 64 + m * 16 + lk * 4;
#pragma unroll
    for (int n = 0; n < 4; ++n) {
      const long gc = n0 + wc * 64 + n * 16 + l16;
      const float bb = bias[gc];
#pragma unroll
      for (int i = 0; i < 4; ++i)
        C[(gr0 + i) * 1024 + gc] = __float2bfloat16(acc[m][n][i] + bb);
    }
  }
}

// ======= Wo projection: cross[z][pix][512] f32 = Ost[z]*wo2[z]^T + bias + resid; fused SE pool =======
__global__ __launch_bounds__(256, 2) void wo_gemm(
    const bf16* __restrict__ Ost, const bf16* __restrict__ wo2,
    float* __restrict__ crossB, const float* __restrict__ bo2,
    const float* __restrict__ r0, const float* __restrict__ r1,
    const float* __restrict__ r2, float* __restrict__ pooled)
{
  __shared__ __align__(16) bf16 As[128 * 32];
  __shared__ __align__(16) bf16 Bs[128 * 32];
  const int z = blockIdx.z;
  const bf16* A = Ost + (long)z * 33554432;
  const bf16* Bt = wo2 + (long)z * 524288;
  float* Cf = crossB + (long)z * 16777216;
  const float* bias = bo2 + z * 512;
  const float* resid = (z == 0) ? r0 : (z == 1) ? r1 : r2;
  f32x4 acc[4][4];
#pragma unroll
  for (int m = 0; m < 4; ++m)
#pragma unroll
    for (int n = 0; n < 4; ++n)
      acc[m][n] = f32x4{0.f, 0.f, 0.f, 0.f};
  long m0, n0;
  swz_mn(4, m0, n0);
  gemm_core<128, 128>(A, 1024, Bt, 1024, 1024, m0, n0, As, Bs, acc);

  const int t = threadIdx.x;
  const int lane = t & 63, wv = t >> 6;
  const int wr = wv >> 1, wc = wv & 1;
  const int l16 = lane & 15, lk = lane >> 4;
  const long b = m0 >> 12;
  const long p_in_b = m0 & 4095;
  float csum[4] = {0.f, 0.f, 0.f, 0.f};
#pragma unroll
  for (int m = 0; m < 4; ++m) {
    const long gr0 = m0 + wr * 64 + m * 16 + lk * 4;
    const long p = (gr0 & 4095);
#pragma unroll
    for (int n = 0; n < 4; ++n) {
      const long gc = n0 + wc * 64 + n * 16 + l16;
      const float bb = bias[gc];
      const float4 r4 = *(const float4*)(resid + b * 2097152L + gc * 4096L + p);
#pragma unroll
      for (int i = 0; i < 4; ++i) {
        const float o = acc[m][n][i] + bb + (&r4.x)[i];
        Cf[(gr0 + i) * 512 + gc] = o;
        csum[n] += o;
      }
    }
  }
  // SE pooling: reduce csum over lk lanes, atomicAdd per column
#pragma unroll
  for (int n = 0; n < 4; ++n) {
    float s = csum[n];
    s += __shfl_xor(s, 16);
    s += __shfl_xor(s, 32);
    if (lane < 16) {
      const long gc = n0 + wc * 64 + n * 16 + l16;
      atomicAdd(&pooled[((long)z * 8 + b) * 512 + gc], s);
    }
  }
  (void)p_in_b;
}

// =================== fusion GEMM: out[b][o][p] = Fw . weighted ===================
__global__ __launch_bounds__(256, 2) void fusion_gemm(
    const bf16* __restrict__ A, const bf16* __restrict__ Bt,
    float* __restrict__ Cf, const float* __restrict__ bias)
{
  __shared__ __align__(16) bf16 As[128 * 32];
  __shared__ __align__(16) bf16 Bs[128 * 32];
  f32x4 acc[4][4];
#pragma unroll
  for (int m = 0; m < 4; ++m)
#pragma unroll
    for (int n = 0; n < 4; ++n)
      acc[m][n] = f32x4{0.f, 0.f, 0.f, 0.f};
  long m0, n0;
  swz_mn(12, m0, n0);
  gemm_core<128, 128>(A, 1536, Bt, 1536, 1536, m0, n0, As, Bs, acc);

  const int t = threadIdx.x;
  const int lane = t & 63, wv = t >> 6;
  const int wr = wv >> 1, wc = wv & 1;
  const int l16 = lane & 15, lk = lane >> 4;
#pragma unroll
  for (int m = 0; m < 4; ++m) {
    const long gr0 = m0 + wr * 64 + m * 16 + lk * 4;
    const long b = gr0 >> 12, p = gr0 & 4095;
#pragma unroll
    for (int n = 0; n < 4; ++n) {
      const long gc = n0 + wc * 64 + n * 16 + l16;
      const float bb = bias[gc];
      float4 o4;
      o4.x = acc[m][n][0] + bb; o4.y = acc[m][n][1] + bb;
      o4.z = acc[m][n][2] + bb; o4.w = acc[m][n][3] + bb;
      *(float4*)(Cf + b * 6291456L + gc * 4096L + p) = o4;
    }
  }
}

// =================== Gram: G[i,j] = sum_p xA[p,i] xB[p,j], bf16 out ===================
__global__ __launch_bounds__(256, 2) void gram_kernel(
    const bf16* __restrict__ xC, bf16* __restrict__ Gb)
{
  __shared__ __align__(16) bf16 As[128 * 32];
  __shared__ __align__(16) bf16 Bs[128 * 32];
  const int z = blockIdx.z;
  const int pair = z >> 3, b = z & 7;
  const int A1[3] = {0, 0, 1}, A2[3] = {1, 2, 2};
  const bf16* A = xC + (long)A1[pair] * 16777216 + b * 4096;
  const bf16* Bt = xC + (long)A2[pair] * 16777216 + b * 4096;
  f32x4 acc[4][4];
#pragma unroll
  for (int m = 0; m < 4; ++m)
#pragma unroll
    for (int n = 0; n < 4; ++n)
      acc[m][n] = f32x4{0.f, 0.f, 0.f, 0.f};
  const long m0 = (long)blockIdx.x * 128, n0 = (long)blockIdx.y * 128;
  gemm_core<128, 128>(A, 32768, Bt, 32768, 4096, m0, n0, As, Bs, acc);
  bf16* C = Gb + (long)z * 262144;
  const int t = threadIdx.x;
  const int lane = t & 63, wv = t >> 6;
  const int wr = wv >> 1, wc = wv & 1;
  const int l16 = lane & 15, lk = lane >> 4;
#pragma unroll
  for (int m = 0; m < 4; ++m) {
    const long gr0 = m0 + wr * 64 + m * 16 + lk * 4;
#pragma unroll
    for (int n = 0; n < 4; ++n) {
      const long gc = n0 + wc * 64 + n * 16 + l16;
#pragma unroll
      for (int i = 0; i < 4; ++i)
        C[(gr0 + i) * 512 + gc] = __float2bfloat16(acc[m][n][i]);
    }
  }
}

// =================== scores+softmax: S = Wq G Wk^T (or transposed form) ===================
__global__ __launch_bounds__(256, 2) void scores_kernel(
    const bf16* __restrict__ wqB, const bf16* __restrict__ wkB,
    const bf16* __restrict__ Gb, const float* __restrict__ colsum,
    const float* __restrict__ bq, const float* __restrict__ bk,
    bf16* __restrict__ attnB)
{
  __shared__ __align__(16) bf16 RtS[64 * 520];  // R^T bf16 ; later aliased as S f32 [64][68]
  __shared__ float uv[128];
  const int h = blockIdx.x, b = blockIdx.y, i = blockIdx.z;
  const int qm = i >> 1, jj = i & 1;
  const int km = jj ? (qm == 2 ? 1 : 2) : (qm == 0 ? 1 : 0);
  const int lo = qm < km ? qm : km, hi = qm < km ? km : qm;
  const int pair = lo + hi - 1;
  const int trans = qm > km;
  const bf16* G = Gb + ((long)(pair * 8 + b)) * 262144;
  const bf16* Wq_h = wqB + (long)i * 262144 + h * 64 * 512;
  const bf16* Wk_h = wkB + (long)i * 262144 + h * 64 * 512;
  const bf16* WA = trans ? Wk_h : Wq_h;
  const bf16* WB = trans ? Wq_h : Wk_h;
  const int t = threadIdx.x, lane = t & 63, wv = t >> 6;
  const int l16 = lane & 15, lk = lane >> 4;

  if (t < 128) {
    const int d = t & 63;
    const bf16* wrow = ((t < 64) ? Wq_h : Wk_h) + d * 512;
    const float* sv = colsum + (((t < 64) ? qm : km) * 8 + b) * 512;
    float a = 0.f;
    for (int c = 0; c < 512; c += 8) {
      const bfrag8 w8 = *(const bfrag8*)(wrow + c);
#pragma unroll
      for (int e = 0; e < 8; ++e) a += bf2f(w8[e]) * sv[c + e];
    }
    uv[t] = a;
  }

  // step A: R[512,64] = G . WB^T ; wave wv owns rows [wv*128, +128)
  f32x4 acc[8][4];
#pragma unroll
  for (int m = 0; m < 8; ++m)
#pragma unroll
    for (int n = 0; n < 4; ++n)
      acc[m][n] = f32x4{0.f, 0.f, 0.f, 0.f};
  for (int kk = 0; kk < 512; kk += 32) {
    bfrag8 a[8], bb[4];
#pragma unroll
    for (int m = 0; m < 8; ++m)
      a[m] = *(const bfrag8*)(G + (wv * 128 + m * 16 + l16) * 512 + kk + lk * 8);
#pragma unroll
    for (int n = 0; n < 4; ++n)
      bb[n] = *(const bfrag8*)(WB + (n * 16 + l16) * 512 + kk + lk * 8);
#pragma unroll
    for (int m = 0; m < 8; ++m)
#pragma unroll
      for (int n = 0; n < 4; ++n)
        mfma_bf16(acc[m][n], a[m], bb[n]);
  }
#pragma unroll
  for (int m = 0; m < 8; ++m)
#pragma unroll
    for (int n = 0; n < 4; ++n)
#pragma unroll
      for (int idx = 0; idx < 4; ++idx)
        RtS[(n * 16 + l16) * 520 + wv * 128 + m * 16 + lk * 4 + idx] =
            __float2bfloat16(acc[m][n][idx]);
  __syncthreads();

  // step B: S[64,64] = WA . Rt^T
  f32x4 acc2[4];
#pragma unroll
  for (int m = 0; m < 4; ++m) acc2[m] = f32x4{0.f, 0.f, 0.f, 0.f};
  for (int kk = 0; kk < 512; kk += 32) {
    bfrag8 a2[4];
#pragma unroll
    for (int m = 0; m < 4; ++m)
      a2[m] = *(const bfrag8*)(WA + (m * 16 + l16) * 512 + kk + lk * 8);
    const bfrag8 b2 = *(const bfrag8*)(&RtS[(wv * 16 + l16) * 520 + kk + lk * 8]);
#pragma unroll
    for (int m = 0; m < 4; ++m) mfma_bf16(acc2[m], a2[m], b2);
  }
  __syncthreads();
  float* S = (float*)RtS;  // [64][68]
#pragma unroll
  for (int m = 0; m < 4; ++m)
#pragma unroll
    for (int idx = 0; idx < 4; ++idx)
      S[(m * 16 + lk * 4 + idx) * 68 + wv * 16 + l16] = acc2[m][idx];
  __syncthreads();

  const int r = t >> 2, q = t & 3;
  const float* bq_h = bq + i * 512 + h * 64;
  const float* bk_h = bk + i * 512 + h * 64;
  const float u_r = uv[r], bq_r = bq_h[r];
  float vals[16];
  float mx = -1e30f;
#pragma unroll
  for (int kq = 0; kq < 16; ++kq) {
    const int k = q * 16 + kq;
    float s = trans ? S[k * 68 + r] : S[r * 68 + k];
    s += u_r * bk_h[k] + bq_r * uv[64 + k] + 4096.0f * bq_r * bk_h[k];
    s *= 0.125f;
    vals[kq] = s;
    mx = fmaxf(mx, s);
  }
  mx = fmaxf(mx, __shfl_xor(mx, 1));
  mx = fmaxf(mx, __shfl_xor(mx, 2));
  float sum = 0.f;
#pragma unroll
  for (int kq = 0; kq < 16; ++kq) { vals[kq] = expf(vals[kq] - mx); sum += vals[kq]; }
  sum += __shfl_xor(sum, 1);
  sum += __shfl_xor(sum, 2);
  const float inv = 1.0f / sum;
  __align__(16) bf16 ob[16];
#pragma unroll
  for (int kq = 0; kq < 16; ++kq) ob[kq] = __float2bfloat16(vals[kq] * inv);
  bf16* op = attnB + (((long)(i * 8 + b) * 8 + h) * 64 + r) * 64 + q * 16;
  *(bfrag8*)(op) = *(const bfrag8*)(ob);
  *(bfrag8*)(op + 8) = *(const bfrag8*)(ob + 8);
}

// =================== PV: O'[p, d] = sum_e V'[p, e] * attn[d, e] ===================
__global__ __launch_bounds__(256, 2) void pv_kernel(
    const bf16* __restrict__ Vst, const bf16* __restrict__ attnB,
    bf16* __restrict__ Ost)
{
  __shared__ __align__(16) bf16 As[128 * 32];
  __shared__ __align__(16) bf16 Bs[64 * 32];
  const int i = blockIdx.z;
  const int qm = i >> 1, jj = i & 1;
  const int km = jj ? (qm == 2 ? 1 : 2) : (qm == 0 ? 1 : 0);
  const int slot = (i >= 3) ? 1 : 0;
  const int bh = blockIdx.y, b = bh >> 3, h = bh & 7;
  const bf16* A = Vst + (long)km * 33554432 + (long)b * 4096 * 1024 + slot * 512 + h * 64;
  const bf16* Bt = attnB + ((long)(i * 8 + b) * 8 + h) * 4096;
  f32x4 acc[4][2];
#pragma unroll
  for (int m = 0; m < 4; ++m)
#pragma unroll
    for (int n = 0; n < 2; ++n)
      acc[m][n] = f32x4{0.f, 0.f, 0.f, 0.f};
  const long m0 = (long)blockIdx.x * 128;
  gemm_core<128, 64>(A, 1024, Bt, 64, 64, m0, 0, As, Bs, acc);

  const int t = threadIdx.x;
  const int lane = t & 63, wv = t >> 6;
  const int wr = wv >> 1, wc = wv & 1;
  const int l16 = lane & 15, lk = lane >> 4;
  bf16* Cb = Ost + (long)qm * 33554432 + (long)b * 4096 * 1024 + jj * 512 + h * 64;
#pragma unroll
  for (int m = 0; m < 4; ++m) {
    const long gr0 = m0 + wr * 64 + m * 16 + lk * 4;
#pragma unroll
    for (int n = 0; n < 2; ++n) {
      const int gc = wc * 32 + n * 16 + l16;
#pragma unroll
      for (int i2 = 0; i2 < 4; ++i2)
        Cb[(gr0 + i2) * 1024 + gc] = __float2bfloat16(acc[m][n][i2]);
    }
  }
}

// =================== SE MLP ===================
__global__ __launch_bounds__(512) void se_mlp(
    const float* __restrict__ pooled,
    const float* __restrict__ W1, const float* __restrict__ b1,
    const float* __restrict__ W2, const float* __restrict__ b2,
    float* __restrict__ se)
{
  const int b = blockIdx.x, m = blockIdx.y;
  __shared__ float y[32];
  const int t = threadIdx.x;
  if (t < 32) {
    float s = b1[m * 32 + t];
    const float* w = W1 + (long)(m * 32 + t) * 512;
    const float* p = pooled + ((long)m * 8 + b) * 512;
    for (int c = 0; c < 512; ++c) s += w[c] * (p[c] * (1.0f / 4096.0f));
    y[t] = fmaxf(s, 0.0f);
  }
  __syncthreads();
  float s = b2[m * 512 + t];
  const float* w2 = W2 + (long)(m * 512 + t) * 32;
#pragma unroll
  for (int j = 0; j < 32; ++j) s += w2[j] * y[j];
  se[((long)m * 8 + b) * 512 + t] = 1.0f / (1.0f + expf(-s));
}

// ========= refined = l2norm_c(cross*se); alpha = sigmoid(gate); weighted out (fused) =========
__global__ __launch_bounds__(384) void refine_gate(
    const float* __restrict__ cr0, const float* __restrict__ cr1,
    const float* __restrict__ cr2, const float* __restrict__ se,
    const float* __restrict__ gw, const float* __restrict__ gb,
    const float* __restrict__ qacc, bf16* __restrict__ weighted)
{
  __shared__ float part[2][3][3];
  const int t = threadIdx.x, wv = t >> 6, lane = t & 63;
  const int px_i = (wv >= 3) ? 1 : 0;
  const int m = wv - px_i * 3;
  const int pix = blockIdx.x * 2 + px_i;
  const int b = pix >> 12;
  const float* cr = (m == 0) ? cr0 : (m == 1) ? cr1 : cr2;
  const int c0 = lane * 8;
  const float4 v0 = *(const float4*)(cr + (long)pix * 512 + c0);
  const float4 v1 = *(const float4*)(cr + (long)pix * 512 + c0 + 4);
  const float* sp = se + ((long)m * 8 + b) * 512 + c0;
  const float4 s0 = *(const float4*)(sp);
  const float4 s1 = *(const float4*)(sp + 4);
  float w[8] = {v0.x * s0.x, v0.y * s0.y, v0.z * s0.z, v0.w * s0.w,
                v1.x * s1.x, v1.y * s1.y, v1.z * s1.z, v1.w * s1.w};
  float ss = 0.f;
#pragma unroll
  for (int i = 0; i < 8; ++i) ss += w[i] * w[i];
  for (int o = 32; o; o >>= 1) ss += __shfl_xor(ss, o);
  const float inv = 1.0f / (sqrtf(ss) + 1e-6f);
  float rf[8];
#pragma unroll
  for (int i = 0; i < 8; ++i) rf[i] = w[i] * inv;

  float a0 = 0.f, a1 = 0.f, a2 = 0.f;
#pragma unroll
  for (int i = 0; i < 8; ++i) {
    const int c = m * 512 + c0 + i;
    a0 += gw[c] * rf[i];
    a1 += gw[1539 + c] * rf[i];
    a2 += gw[3078 + c] * rf[i];
  }
  for (int o = 32; o; o >>= 1) {
    a0 += __shfl_xor(a0, o); a1 += __shfl_xor(a1, o); a2 += __shfl_xor(a2, o);
  }
  if (lane == 0) {
    part[px_i][m][0] = a0; part[px_i][m][1] = a1; part[px_i][m][2] = a2;
  }
  __syncthreads();
  const float N = 2097152.0f;
  const float q0 = qacc[b * 4 + 0] / N;
  const float q1 = (qacc[b * 4 + 2] - qacc[b * 4 + 1] * qacc[b * 4 + 1] / N) / (N - 1.0f);
  const float q2 = qacc[b * 4 + 3] / N;
  const float sg = part[px_i][0][m] + part[px_i][1][m] + part[px_i][2][m] + gb[m] +
                   gw[m * 1539 + 1536] * q0 + gw[m * 1539 + 1537] * q1 +
                   gw[m * 1539 + 1538] * q2;
  const float al = 1.0f / (1.0f + expf(-sg));
  __align__(16) bf16 tmp[8];
#pragma unroll
  for (int i = 0; i < 8; ++i) tmp[i] = __float2bfloat16(rf[i] * al);
  *(bfrag8*)(weighted + (long)pix * 1536 + m * 512 + c0) = *(const bfrag8*)tmp;
}

// =================== host launch ===================
extern "C" void kernel_launch(void* const* d_in, const int* in_sizes, int n_in,
                              void* d_out, int out_size, void* d_ws, size_t ws_size,
                              hipStream_t stream)
{
  (void)in_sizes; (void)n_in; (void)out_size; (void)ws_size;
  const float* rgb   = (const float*)d_in[0];
  const float* depth = (const float*)d_in[1];
  const float* lidar = (const float*)d_in[2];
  const float* wq  = (const float*)d_in[3];
  const float* bq  = (const float*)d_in[4];
  const float* wk  = (const float*)d_in[5];
  const float* bk  = (const float*)d_in[6];
  const float* wvw = (const float*)d_in[7];
  const float* bv  = (const float*)d_in[8];
  const float* wo  = (const float*)d_in[9];
  const float* bo  = (const float*)d_in[10];
  const float* seW1 = (const float*)d_in[11];
  const float* seb1 = (const float*)d_in[12];
  const float* seW2 = (const float*)d_in[13];
  const float* seb2 = (const float*)d_in[14];
  const float* gw  = (const float*)d_in[15];
  const float* gb  = (const float*)d_in[16];
  const float* fw  = (const float*)d_in[17];
  const float* fb  = (const float*)d_in[18];

  char* ws = (char*)d_ws;
  bf16*  xT   = (bf16*)(ws + OFF_XT);
  bf16*  xC   = (bf16*)(ws + OFF_XC);
  bf16*  wqB  = (bf16*)(ws + OFF_WQ);
  bf16*  wkB  = (bf16*)(ws + OFF_WK);
  bf16*  wv2  = (bf16*)(ws + OFF_WV2);
  bf16*  wo2  = (bf16*)(ws + OFF_WO2);
  bf16*  fwB  = (bf16*)(ws + OFF_FW);
  float* bo2  = (float*)(ws + OFF_BO2);
  float* bv2  = (float*)(ws + OFF_BV2);
  float* pooled = (float*)(ws + OFF_POOL);
  float* seB  = (float*)(ws + OFF_SE);
  float* qacc = (float*)(ws + OFF_QACC);
  float* cs   = (float*)(ws + OFF_CS);
  bf16*  Gb   = (bf16*)(ws + OFF_GB);
  bf16*  attnB = (bf16*)(ws + OFF_ATT);
  bf16*  Vst  = (bf16*)(ws + OFF_VST);
  bf16*  Ost  = (bf16*)(ws + OFF_XT);        // alias after xT/xC dead

  // zero: pooled, se, qacc, colsum
  (void)hipMemsetAsync(ws + OFF_POOL, 0, OFF_CS + 49152 - OFF_POOL, stream);

  transpose_kernel<<<dim3(32, 16, 24), dim3(32, 8), 0, stream>>>(rgb, depth, lidar,
                                                                 xT, xC, cs, qacc);
  prep_weights<<<2048, 256, 0, stream>>>(wq, wk, wvw, wo, fw, bo, bv,
                                         wqB, wkB, wv2, wo2, fwB, bo2, bv2);

  gram_kernel<<<dim3(4, 4, 24), 256, 0, stream>>>(xC, Gb);
  scores_kernel<<<dim3(8, 8, 6), 256, 0, stream>>>(wqB, wkB, Gb, cs, bq, bk, attnB);

  v_gemm<<<dim3(256, 8, 3), 256, 0, stream>>>(xT, wv2, Vst, bv2);
  pv_kernel<<<dim3(32, 64, 6), 256, 0, stream>>>(Vst, attnB, Ost);

  float* crossB = (float*)(ws + OFF_VST);
  wo_gemm<<<dim3(256, 4, 3), 256, 0, stream>>>(Ost, wo2, crossB, bo2,
                                               rgb, depth, lidar, pooled);
  se_mlp<<<dim3(8, 3), 512, 0, stream>>>(pooled, seW1, seb1, seW2, seb2, seB);

  float* cross0 = crossB;
  float* cross1 = (float*)(ws + OFF_VST + 67108864L);
  float* cross2 = (float*)(ws + OFF_VST + 134217728L);
  bf16* weighted = (bf16*)(ws + OFF_XC);
  refine_gate<<<16384, 384, 0, stream>>>(cross0, cross1, cross2, seB, gw, gb, qacc, weighted);

  fusion_gemm<<<dim3(256, 12), 256, 0, stream>>>(weighted, fwB, (float*)d_out, fb);
}

// Round 4
// 1124.385 us; speedup vs baseline: 1.3524x; 1.3524x over previous
//
#include <hip/hip_runtime.h>
#include <hip/hip_bf16.h>
#include <stdint.h>

using bf16 = __hip_bfloat16;
typedef short bfrag8 __attribute__((ext_vector_type(8)));
typedef float f32x4 __attribute__((ext_vector_type(4)));

// ---------------- workspace layout (bytes) ----------------
constexpr long OFF_XT   = 0L;           // 3 x [32768][512] bf16 NHWC
constexpr long OFF_XC   = 100663296L;   // 3 x [512][32768] bf16 channel-major
constexpr long OFF_WQ   = 201326592L;   // 6 x [512][512] bf16
constexpr long OFF_WK   = 204472320L;
constexpr long OFF_WV2  = 207618048L;   // 3 x [1024][512] bf16 stacked Wv
constexpr long OFF_WO2  = 210763776L;   // 3 x [512][1024] bf16 stacked Wo
constexpr long OFF_FW   = 213909504L;   // [1536][1536] bf16
constexpr long OFF_BO2  = 218628096L;   // [3][512] f32
constexpr long OFF_BV2  = 218634240L;   // [3][1024] f32
constexpr long OFF_POOL = 218646528L;   // [3][8][512] f32   (memset from here)
constexpr long OFF_SE   = 218695680L;   // [3][8][512] f32
constexpr long OFF_QACC = 218744832L;   // [8][4] f32 (+pad to 1024)
constexpr long OFF_CS   = 218745856L;   // [3][8][512] f32 column sums (memset to here+49152)
constexpr long OFF_GB   = 218795008L;   // [3][8][512][512] bf16 Gram
constexpr long OFF_ATT  = 231377920L;   // [6][8][8][64][64] bf16
constexpr long OFF_VST  = 234523648L;   // 3 x [32768][1024] bf16 ; later cross f32 3x[32768][512]
constexpr long OFF_QST  = 435850240L;   // [24][2048][2] f32 quality partials (no memset needed)
// aliases: Ost = [0, 201326592) (3 x [32768][1024] bf16) after xT/xC dead
//          weighted = 100663296 (96 MB) after Ost dead

__device__ __forceinline__ void mfma_bf16(f32x4& c, bfrag8 a, bfrag8 b) {
  asm("v_mfma_f32_16x16x32_bf16 %0, %1, %2, %0" : "+v"(c) : "v"(a), "v"(b));
}

__device__ __forceinline__ void gload16(const void* g, void* l) {
  __builtin_amdgcn_global_load_lds(
      (__attribute__((address_space(1))) void*)(g),
      (__attribute__((address_space(3))) void*)(l), 16, 0, 0);
}

__device__ __forceinline__ float bf2f(short s) {
  union { uint32_t u; float f; } cv;
  cv.u = ((uint32_t)(unsigned short)s) << 16;
  return cv.f;
}

// XCD-chunked bijective swizzle, n-fast logical order. Requires gx*gy % 8 == 0.
__device__ __forceinline__ void swz_mn(int gy, long& m0, long& n0) {
  const int gx = gridDim.x;
  const int orig = blockIdx.y * gx + blockIdx.x;
  const int q = (gx * gy) >> 3;
  const int wgid = (orig & 7) * q + (orig >> 3);
  m0 = (long)(wgid / gy) * 128;
  n0 = (long)(wgid % gy) * 128;
}

// ============ transpose + stats: NCHW f32 -> NHWC + channel-major bf16, colsum, quality ============
__global__ __launch_bounds__(256) void transpose_kernel(
    const float* __restrict__ x0, const float* __restrict__ x1,
    const float* __restrict__ x2, bf16* __restrict__ xT, bf16* __restrict__ xC,
    float* __restrict__ cs, float* __restrict__ qstage)
{
  __shared__ float tile[32][33];
  __shared__ float qpart[4][2];
  const int zz = blockIdx.z;           // m*8 + b
  const int m = zz >> 3, b = zz & 7;
  const float* x = (m == 0) ? x0 : (m == 1) ? x1 : x2;
  bf16* y = xT + (long)m * 16777216;
  bf16* y2 = xC + (long)m * 16777216;
  const int p0 = blockIdx.x * 32, c0 = blockIdx.y * 32;
  const int tx = threadIdx.x, ty = threadIdx.y;
  float csp[4];
  float qa = 0.f, qb_ = 0.f;   // m==0 (rgb): sum,ssq ; else: zero-count in qa
#pragma unroll
  for (int j = 0; j < 4; ++j) {
    const float v = x[((long)b * 512 + c0 + ty + j * 8) * 4096 + p0 + tx];
    tile[ty + j * 8][tx] = v;
    y2[(long)(c0 + ty + j * 8) * 32768 + (long)b * 4096 + p0 + tx] = __float2bfloat16(v);
    csp[j] = v;
    if (m == 0) { qa += v; qb_ += v * v; }
    else qa += (v == 0.0f) ? 1.0f : 0.0f;
  }
  __syncthreads();
#pragma unroll
  for (int j = 0; j < 4; ++j)
    y[((long)b * 4096 + p0 + ty + j * 8) * 512 + c0 + tx] =
        __float2bfloat16(tile[tx][ty + j * 8]);
  // colsum: reduce over tx (32 lanes), one atomic per (c) per block (depth 128, distributed)
#pragma unroll
  for (int j = 0; j < 4; ++j) {
    float s = csp[j];
    for (int o = 16; o; o >>= 1) s += __shfl_xor(s, o);
    if (tx == 0) atomicAdd(&cs[(m * 8 + b) * 512 + c0 + ty + j * 8], s);
  }
  // quality: block-level reduce, STAGED write (no atomics)
  const int t = ty * 32 + tx;
  const int lane = t & 63;
  for (int o = 32; o; o >>= 1) { qa += __shfl_xor(qa, o); qb_ += __shfl_xor(qb_, o); }
  if (lane == 0) { qpart[t >> 6][0] = qa; qpart[t >> 6][1] = qb_; }
  __syncthreads();
  if (t == 0) {
    const float pa = qpart[0][0] + qpart[1][0] + qpart[2][0] + qpart[3][0];
    const float pb = qpart[0][1] + qpart[1][1] + qpart[2][1] + qpart[3][1];
    float* qs = qstage + ((long)zz * 2048 + blockIdx.y * 128 + blockIdx.x) * 2;
    qs[0] = pa; qs[1] = pb;
  }
}

// =================== quality partial reduce -> qacc ===================
__global__ __launch_bounds__(256) void quality_reduce(
    const float* __restrict__ qstage, float* __restrict__ qacc)
{
  __shared__ float pr[4][2];
  const int zz = blockIdx.x;  // m*8 + b
  const int m = zz >> 3, b = zz & 7;
  const int t = threadIdx.x;
  float sa = 0.f, sb = 0.f;
  for (int i = t; i < 2048; i += 256) {
    sa += qstage[((long)zz * 2048 + i) * 2];
    sb += qstage[((long)zz * 2048 + i) * 2 + 1];
  }
  for (int o = 32; o; o >>= 1) { sa += __shfl_xor(sa, o); sb += __shfl_xor(sb, o); }
  if ((t & 63) == 0) { pr[t >> 6][0] = sa; pr[t >> 6][1] = sb; }
  __syncthreads();
  if (t == 0) {
    sa = pr[0][0] + pr[1][0] + pr[2][0] + pr[3][0];
    sb = pr[0][1] + pr[1][1] + pr[2][1] + pr[3][1];
    if (m == 0) { qacc[b * 4 + 1] = sa; qacc[b * 4 + 2] = sb; }
    else if (m == 1) qacc[b * 4 + 0] = sa;
    else qacc[b * 4 + 3] = sa;
  }
}

// =================== weight conversion / stacking ===================
__global__ void prep_weights(
    const float* __restrict__ wq, const float* __restrict__ wk,
    const float* __restrict__ wv, const float* __restrict__ wo,
    const float* __restrict__ fw, const float* __restrict__ bo,
    const float* __restrict__ bv,
    bf16* __restrict__ wqB, bf16* __restrict__ wkB, bf16* __restrict__ wv2,
    bf16* __restrict__ wo2, bf16* __restrict__ fwB,
    float* __restrict__ bo2, float* __restrict__ bv2)
{
  const int L0[3] = {2, 0, 1}, L1[3] = {4, 5, 3};
  const long stride = (long)gridDim.x * blockDim.x;
  for (long j = (long)blockIdx.x * blockDim.x + threadIdx.x; j < 2359296; j += stride) {
    fwB[j] = __float2bfloat16(fw[j]);
    if (j < 1572864) {
      wqB[j] = __float2bfloat16(wq[j]);
      wkB[j] = __float2bfloat16(wk[j]);
      const long m = j >> 19, rem = j & 524287;
      {  // wo2[m][c (512)][k (1024)], k = jj*512 + ci
        const long c = rem >> 10, k = rem & 1023, jj = k >> 9, ci = k & 511;
        wo2[j] = __float2bfloat16(wo[(((m * 2 + jj) * 512 + c) << 9) + ci]);
      }
      {  // wv2[m][row (1024)][k (512)]
        const long row = rem >> 9, k = rem & 511;
        const int im = (row < 512) ? L0[m] : L1[m];
        wv2[j] = __float2bfloat16(wv[((long)(im * 512 + (row & 511)) << 9) + k]);
      }
    }
    if (j < 1536) {
      const long m2 = j >> 9, cc = j & 511;
      bo2[j] = bo[((m2 * 2) << 9) + cc] + bo[((m2 * 2 + 1) << 9) + cc];
    }
    if (j < 3072) {
      const long m3 = j >> 10, row = j & 1023;
      const int im = (row < 512) ? L0[m3] : L1[m3];
      bv2[j] = bv[im * 512 + (row & 511)];
    }
  }
}

// =================== GEMM core: C[M,N] = A[M,K] * Bt[N,K]^T ===================
template<int BM, int BN>
__device__ __forceinline__ void gemm_core(
    const bf16* __restrict__ A, long lda,
    const bf16* __restrict__ Bt, long ldb,
    int K, long m0, long n0,
    bf16* As, bf16* Bs, f32x4 (&acc)[BM / 32][BN / 32])
{
  constexpr int WM = BM / 2, WN = BN / 2, FM = BM / 32, FN = BN / 32;
  const int t = threadIdx.x;
  const int lane = t & 63, wv = t >> 6;
  const int wr = wv >> 1, wc = wv & 1;
  const int l16 = lane & 15, lk = lane >> 4;
  const int srow = t >> 2;
  const int scol = (t & 3) * 8;
  const bf16* Ag = A + (m0 + srow) * lda + scol;
  const bf16* Bg = Bt + (n0 + srow) * ldb + scol;
  char* AsB = (char*)As;
  char* BsB = (char*)Bs;
  const int aoff = wv * 1024;
  for (int kk = 0; kk < K; kk += 32) {
#pragma unroll
    for (int it = 0; it < BM / 64; ++it)
      gload16(Ag + (long)it * 64 * lda + kk, AsB + it * 4096 + aoff);
#pragma unroll
    for (int it = 0; it < BN / 64; ++it)
      gload16(Bg + (long)it * 64 * ldb + kk, BsB + it * 4096 + aoff);
    __syncthreads();
    bfrag8 af[FM], bfr[FN];
#pragma unroll
    for (int m = 0; m < FM; ++m)
      af[m] = *(const bfrag8*)(AsB + ((wr * WM + m * 16 + l16) * 32 + lk * 8) * 2);
#pragma unroll
    for (int n = 0; n < FN; ++n)
      bfr[n] = *(const bfrag8*)(BsB + ((wc * WN + n * 16 + l16) * 32 + lk * 8) * 2);
#pragma unroll
    for (int m = 0; m < FM; ++m)
#pragma unroll
      for (int n = 0; n < FN; ++n)
        mfma_bf16(acc[m][n], af[m], bfr[n]);
    __syncthreads();
  }
}

// =================== V projection: Vst[m][pix][1024] = xT[m] * wv2[m]^T ===================
__global__ __launch_bounds__(256, 2) void v_gemm(
    const bf16* __restrict__ xT, const bf16* __restrict__ wv2,
    bf16* __restrict__ Vst, const float* __restrict__ bv2)
{
  __shared__ __align__(16) bf16 As[128 * 32];
  __shared__ __align__(16) bf16 Bs[128 * 32];
  const int z = blockIdx.z;
  const bf16* A = xT + (long)z * 16777216;
  const bf16* Bt = wv2 + (long)z * 524288;
  bf16* C = Vst + (long)z * 33554432;
  const float* bias = bv2 + z * 1024;
  f32x4 acc[4][4];
#pragma unroll
  for (int m = 0; m < 4; ++m)
#pragma unroll
    for (int n = 0; n < 4; ++n)
      acc[m][n] = f32x4{0.f, 0.f, 0.f, 0.f};
  long m0, n0;
  swz_mn(8, m0, n0);
  gemm_core<128, 128>(A, 512, Bt, 512, 512, m0, n0, As, Bs, acc);

  const int t = threadIdx.x;
  const int lane = t & 63, wv = t >> 6;
  const int wr = wv >> 1, wc = wv & 1;
  const int l16 = lane & 15, lk = lane >> 4;
#pragma unroll
  for (int m = 0; m < 4; ++m) {
    const long gr0 = m0 + wr * 64 + m * 16 + lk * 4;
#pragma unroll
    for (int n = 0; n < 4; ++n) {
      const long gc = n0 + wc * 64 + n * 16 + l16;
      const float bb = bias[gc];
#pragma unroll
      for (int i = 0; i < 4; ++i)
        C[(gr0 + i) * 1024 + gc] = __float2bfloat16(acc[m][n][i] + bb);
    }
  }
}

// ======= Wo projection: cross[z][pix][512] f32 = Ost[z]*wo2[z]^T + bias + resid; fused SE pool =======
__global__ __launch_bounds__(256, 2) void wo_gemm(
    const bf16* __restrict__ Ost, const bf16* __restrict__ wo2,
    float* __restrict__ crossB, const float* __restrict__ bo2,
    const float* __restrict__ r0, const float* __restrict__ r1,
    const float* __restrict__ r2, float* __restrict__ pooled)
{
  __shared__ __align__(16) bf16 As[128 * 32];
  __shared__ __align__(16) bf16 Bs[128 * 32];
  const int z = blockIdx.z;
  const bf16* A = Ost + (long)z * 33554432;
  const bf16* Bt = wo2 + (long)z * 524288;
  float* Cf = crossB + (long)z * 16777216;
  const float* bias = bo2 + z * 512;
  const float* resid = (z == 0) ? r0 : (z == 1) ? r1 : r2;
  f32x4 acc[4][4];
#pragma unroll
  for (int m = 0; m < 4; ++m)
#pragma unroll
    for (int n = 0; n < 4; ++n)
      acc[m][n] = f32x4{0.f, 0.f, 0.f, 0.f};
  long m0, n0;
  swz_mn(4, m0, n0);
  gemm_core<128, 128>(A, 1024, Bt, 1024, 1024, m0, n0, As, Bs, acc);

  const int t = threadIdx.x;
  const int lane = t & 63, wv = t >> 6;
  const int wr = wv >> 1, wc = wv & 1;
  const int l16 = lane & 15, lk = lane >> 4;
  const long b = m0 >> 12;
  float csum[4] = {0.f, 0.f, 0.f, 0.f};
#pragma unroll
  for (int m = 0; m < 4; ++m) {
    const long gr0 = m0 + wr * 64 + m * 16 + lk * 4;
    const long p = (gr0 & 4095);
#pragma unroll
    for (int n = 0; n < 4; ++n) {
      const long gc = n0 + wc * 64 + n * 16 + l16;
      const float bb = bias[gc];
      const float4 r4 = *(const float4*)(resid + b * 2097152L + gc * 4096L + p);
#pragma unroll
      for (int i = 0; i < 4; ++i) {
        const float o = acc[m][n][i] + bb + (&r4.x)[i];
        Cf[(gr0 + i) * 512 + gc] = o;
        csum[n] += o;
      }
    }
  }
#pragma unroll
  for (int n = 0; n < 4; ++n) {
    float s = csum[n];
    s += __shfl_xor(s, 16);
    s += __shfl_xor(s, 32);
    if (lane < 16) {
      const long gc = n0 + wc * 64 + n * 16 + l16;
      atomicAdd(&pooled[((long)z * 8 + b) * 512 + gc], s);
    }
  }
}

// =================== fusion GEMM: out[b][o][p] = Fw . weighted ===================
__global__ __launch_bounds__(256, 2) void fusion_gemm(
    const bf16* __restrict__ A, const bf16* __restrict__ Bt,
    float* __restrict__ Cf, const float* __restrict__ bias)
{
  __shared__ __align__(16) bf16 As[128 * 32];
  __shared__ __align__(16) bf16 Bs[128 * 32];
  f32x4 acc[4][4];
#pragma unroll
  for (int m = 0; m < 4; ++m)
#pragma unroll
    for (int n = 0; n < 4; ++n)
      acc[m][n] = f32x4{0.f, 0.f, 0.f, 0.f};
  long m0, n0;
  swz_mn(12, m0, n0);
  gemm_core<128, 128>(A, 1536, Bt, 1536, 1536, m0, n0, As, Bs, acc);

  const int t = threadIdx.x;
  const int lane = t & 63, wv = t >> 6;
  const int wr = wv >> 1, wc = wv & 1;
  const int l16 = lane & 15, lk = lane >> 4;
#pragma unroll
  for (int m = 0; m < 4; ++m) {
    const long gr0 = m0 + wr * 64 + m * 16 + lk * 4;
    const long b = gr0 >> 12, p = gr0 & 4095;
#pragma unroll
    for (int n = 0; n < 4; ++n) {
      const long gc = n0 + wc * 64 + n * 16 + l16;
      const float bb = bias[gc];
      float4 o4;
      o4.x = acc[m][n][0] + bb; o4.y = acc[m][n][1] + bb;
      o4.z = acc[m][n][2] + bb; o4.w = acc[m][n][3] + bb;
      *(float4*)(Cf + b * 6291456L + gc * 4096L + p) = o4;
    }
  }
}

// =================== Gram: G[i,j] = sum_p xA[p,i] xB[p,j], bf16 out ===================
__global__ __launch_bounds__(256, 2) void gram_kernel(
    const bf16* __restrict__ xC, bf16* __restrict__ Gb)
{
  __shared__ __align__(16) bf16 As[128 * 32];
  __shared__ __align__(16) bf16 Bs[128 * 32];
  const int z = blockIdx.z;
  const int pair = z >> 3, b = z & 7;
  const int A1[3] = {0, 0, 1}, A2[3] = {1, 2, 2};
  const bf16* A = xC + (long)A1[pair] * 16777216 + b * 4096;
  const bf16* Bt = xC + (long)A2[pair] * 16777216 + b * 4096;
  f32x4 acc[4][4];
#pragma unroll
  for (int m = 0; m < 4; ++m)
#pragma unroll
    for (int n = 0; n < 4; ++n)
      acc[m][n] = f32x4{0.f, 0.f, 0.f, 0.f};
  const long m0 = (long)blockIdx.x * 128, n0 = (long)blockIdx.y * 128;
  gemm_core<128, 128>(A, 32768, Bt, 32768, 4096, m0, n0, As, Bs, acc);
  bf16* C = Gb + (long)z * 262144;
  const int t = threadIdx.x;
  const int lane = t & 63, wv = t >> 6;
  const int wr = wv >> 1, wc = wv & 1;
  const int l16 = lane & 15, lk = lane >> 4;
#pragma unroll
  for (int m = 0; m < 4; ++m) {
    const long gr0 = m0 + wr * 64 + m * 16 + lk * 4;
#pragma unroll
    for (int n = 0; n < 4; ++n) {
      const long gc = n0 + wc * 64 + n * 16 + l16;
#pragma unroll
      for (int i = 0; i < 4; ++i)
        C[(gr0 + i) * 512 + gc] = __float2bfloat16(acc[m][n][i]);
    }
  }
}

// =================== scores+softmax: S = Wq G Wk^T (or transposed form) ===================
__global__ __launch_bounds__(256, 2) void scores_kernel(
    const bf16* __restrict__ wqB, const bf16* __restrict__ wkB,
    const bf16* __restrict__ Gb, const float* __restrict__ colsum,
    const float* __restrict__ bq, const float* __restrict__ bk,
    bf16* __restrict__ attnB)
{
  __shared__ __align__(16) bf16 RtS[64 * 520];  // R^T bf16 ; later aliased as S f32 [64][68]
  __shared__ float uv[128];
  const int h = blockIdx.x, b = blockIdx.y, i = blockIdx.z;
  const int qm = i >> 1, jj = i & 1;
  const int km = jj ? (qm == 2 ? 1 : 2) : (qm == 0 ? 1 : 0);
  const int lo = qm < km ? qm : km, hi = qm < km ? km : qm;
  const int pair = lo + hi - 1;
  const int trans = qm > km;
  const bf16* G = Gb + ((long)(pair * 8 + b)) * 262144;
  const bf16* Wq_h = wqB + (long)i * 262144 + h * 64 * 512;
  const bf16* Wk_h = wkB + (long)i * 262144 + h * 64 * 512;
  const bf16* WA = trans ? Wk_h : Wq_h;
  const bf16* WB = trans ? Wq_h : Wk_h;
  const int t = threadIdx.x, lane = t & 63, wv = t >> 6;
  const int l16 = lane & 15, lk = lane >> 4;

  if (t < 128) {
    const int d = t & 63;
    const bf16* wrow = ((t < 64) ? Wq_h : Wk_h) + d * 512;
    const float* sv = colsum + (((t < 64) ? qm : km) * 8 + b) * 512;
    float a = 0.f;
    for (int c = 0; c < 512; c += 8) {
      const bfrag8 w8 = *(const bfrag8*)(wrow + c);
#pragma unroll
      for (int e = 0; e < 8; ++e) a += bf2f(w8[e]) * sv[c + e];
    }
    uv[t] = a;
  }

  // step A: R[512,64] = G . WB^T ; wave wv owns rows [wv*128, +128)
  f32x4 acc[8][4];
#pragma unroll
  for (int m = 0; m < 8; ++m)
#pragma unroll
    for (int n = 0; n < 4; ++n)
      acc[m][n] = f32x4{0.f, 0.f, 0.f, 0.f};
  for (int kk = 0; kk < 512; kk += 32) {
    bfrag8 a[8], bb[4];
#pragma unroll
    for (int m = 0; m < 8; ++m)
      a[m] = *(const bfrag8*)(G + (wv * 128 + m * 16 + l16) * 512 + kk + lk * 8);
#pragma unroll
    for (int n = 0; n < 4; ++n)
      bb[n] = *(const bfrag8*)(WB + (n * 16 + l16) * 512 + kk + lk * 8);
#pragma unroll
    for (int m = 0; m < 8; ++m)
#pragma unroll
      for (int n = 0; n < 4; ++n)
        mfma_bf16(acc[m][n], a[m], bb[n]);
  }
#pragma unroll
  for (int m = 0; m < 8; ++m)
#pragma unroll
    for (int n = 0; n < 4; ++n)
#pragma unroll
      for (int idx = 0; idx < 4; ++idx)
        RtS[(n * 16 + l16) * 520 + wv * 128 + m * 16 + lk * 4 + idx] =
            __float2bfloat16(acc[m][n][idx]);
  __syncthreads();

  // step B: S[64,64] = WA . Rt^T
  f32x4 acc2[4];
#pragma unroll
  for (int m = 0; m < 4; ++m) acc2[m] = f32x4{0.f, 0.f, 0.f, 0.f};
  for (int kk = 0; kk < 512; kk += 32) {
    bfrag8 a2[4];
#pragma unroll
    for (int m = 0; m < 4; ++m)
      a2[m] = *(const bfrag8*)(WA + (m * 16 + l16) * 512 + kk + lk * 8);
    const bfrag8 b2 = *(const bfrag8*)(&RtS[(wv * 16 + l16) * 520 + kk + lk * 8]);
#pragma unroll
    for (int m = 0; m < 4; ++m) mfma_bf16(acc2[m], a2[m], b2);
  }
  __syncthreads();
  float* S = (float*)RtS;  // [64][68]
#pragma unroll
  for (int m = 0; m < 4; ++m)
#pragma unroll
    for (int idx = 0; idx < 4; ++idx)
      S[(m * 16 + lk * 4 + idx) * 68 + wv * 16 + l16] = acc2[m][idx];
  __syncthreads();

  const int r = t >> 2, q = t & 3;
  const float* bq_h = bq + i * 512 + h * 64;
  const float* bk_h = bk + i * 512 + h * 64;
  const float u_r = uv[r], bq_r = bq_h[r];
  float vals[16];
  float mx = -1e30f;
#pragma unroll
  for (int kq = 0; kq < 16; ++kq) {
    const int k = q * 16 + kq;
    float s = trans ? S[k * 68 + r] : S[r * 68 + k];
    s += u_r * bk_h[k] + bq_r * uv[64 + k] + 4096.0f * bq_r * bk_h[k];
    s *= 0.125f;
    vals[kq] = s;
    mx = fmaxf(mx, s);
  }
  mx = fmaxf(mx, __shfl_xor(mx, 1));
  mx = fmaxf(mx, __shfl_xor(mx, 2));
  float sum = 0.f;
#pragma unroll
  for (int kq = 0; kq < 16; ++kq) { vals[kq] = expf(vals[kq] - mx); sum += vals[kq]; }
  sum += __shfl_xor(sum, 1);
  sum += __shfl_xor(sum, 2);
  const float inv = 1.0f / sum;
  __align__(16) bf16 ob[16];
#pragma unroll
  for (int kq = 0; kq < 16; ++kq) ob[kq] = __float2bfloat16(vals[kq] * inv);
  bf16* op = attnB + (((long)(i * 8 + b) * 8 + h) * 64 + r) * 64 + q * 16;
  *(bfrag8*)(op) = *(const bfrag8*)(ob);
  *(bfrag8*)(op + 8) = *(const bfrag8*)(ob + 8);
}

// =================== PV: O'[p, d] = sum_e V'[p, e] * attn[d, e] ===================
__global__ __launch_bounds__(256, 2) void pv_kernel(
    const bf16* __restrict__ Vst, const bf16* __restrict__ attnB,
    bf16* __restrict__ Ost)
{
  __shared__ __align__(16) bf16 As[128 * 32];
  __shared__ __align__(16) bf16 Bs[64 * 32];
  const int i = blockIdx.z;
  const int qm = i >> 1, jj = i & 1;
  const int km = jj ? (qm == 2 ? 1 : 2) : (qm == 0 ? 1 : 0);
  const int slot = (i >= 3) ? 1 : 0;
  const int bh = blockIdx.y, b = bh >> 3, h = bh & 7;
  const bf16* A = Vst + (long)km * 33554432 + (long)b * 4096 * 1024 + slot * 512 + h * 64;
  const bf16* Bt = attnB + ((long)(i * 8 + b) * 8 + h) * 4096;
  f32x4 acc[4][2];
#pragma unroll
  for (int m = 0; m < 4; ++m)
#pragma unroll
    for (int n = 0; n < 2; ++n)
      acc[m][n] = f32x4{0.f, 0.f, 0.f, 0.f};
  const long m0 = (long)blockIdx.x * 128;
  gemm_core<128, 64>(A, 1024, Bt, 64, 64, m0, 0, As, Bs, acc);

  const int t = threadIdx.x;
  const int lane = t & 63, wv = t >> 6;
  const int wr = wv >> 1, wc = wv & 1;
  const int l16 = lane & 15, lk = lane >> 4;
  bf16* Cb = Ost + (long)qm * 33554432 + (long)b * 4096 * 1024 + jj * 512 + h * 64;
#pragma unroll
  for (int m = 0; m < 4; ++m) {
    const long gr0 = m0 + wr * 64 + m * 16 + lk * 4;
#pragma unroll
    for (int n = 0; n < 2; ++n) {
      const int gc = wc * 32 + n * 16 + l16;
#pragma unroll
      for (int i2 = 0; i2 < 4; ++i2)
        Cb[(gr0 + i2) * 1024 + gc] = __float2bfloat16(acc[m][n][i2]);
    }
  }
}

// =================== SE MLP ===================
__global__ __launch_bounds__(512) void se_mlp(
    const float* __restrict__ pooled,
    const float* __restrict__ W1, const float* __restrict__ b1,
    const float* __restrict__ W2, const float* __restrict__ b2,
    float* __restrict__ se)
{
  const int b = blockIdx.x, m = blockIdx.y;
  __shared__ float y[32];
  const int t = threadIdx.x;
  if (t < 32) {
    float s = b1[m * 32 + t];
    const float* w = W1 + (long)(m * 32 + t) * 512;
    const float* p = pooled + ((long)m * 8 + b) * 512;
    for (int c = 0; c < 512; ++c) s += w[c] * (p[c] * (1.0f / 4096.0f));
    y[t] = fmaxf(s, 0.0f);
  }
  __syncthreads();
  float s = b2[m * 512 + t];
  const float* w2 = W2 + (long)(m * 512 + t) * 32;
#pragma unroll
  for (int j = 0; j < 32; ++j) s += w2[j] * y[j];
  se[((long)m * 8 + b) * 512 + t] = 1.0f / (1.0f + expf(-s));
}

// ========= refined = l2norm_c(cross*se); alpha = sigmoid(gate); weighted out (fused) =========
__global__ __launch_bounds__(384) void refine_gate(
    const float* __restrict__ cr0, const float* __restrict__ cr1,
    const float* __restrict__ cr2, const float* __restrict__ se,
    const float* __restrict__ gw, const float* __restrict__ gb,
    const float* __restrict__ qacc, bf16* __restrict__ weighted)
{
  __shared__ float part[2][3][3];
  const int t = threadIdx.x, wv = t >> 6, lane = t & 63;
  const int px_i = (wv >= 3) ? 1 : 0;
  const int m = wv - px_i * 3;
  const int pix = blockIdx.x * 2 + px_i;
  const int b = pix >> 12;
  const float* cr = (m == 0) ? cr0 : (m == 1) ? cr1 : cr2;
  const int c0 = lane * 8;
  const float4 v0 = *(const float4*)(cr + (long)pix * 512 + c0);
  const float4 v1 = *(const float4*)(cr + (long)pix * 512 + c0 + 4);
  const float* sp = se + ((long)m * 8 + b) * 512 + c0;
  const float4 s0 = *(const float4*)(sp);
  const float4 s1 = *(const float4*)(sp + 4);
  float w[8] = {v0.x * s0.x, v0.y * s0.y, v0.z * s0.z, v0.w * s0.w,
                v1.x * s1.x, v1.y * s1.y, v1.z * s1.z, v1.w * s1.w};
  float ss = 0.f;
#pragma unroll
  for (int i = 0; i < 8; ++i) ss += w[i] * w[i];
  for (int o = 32; o; o >>= 1) ss += __shfl_xor(ss, o);
  const float inv = 1.0f / (sqrtf(ss) + 1e-6f);
  float rf[8];
#pragma unroll
  for (int i = 0; i < 8; ++i) rf[i] = w[i] * inv;

  float a0 = 0.f, a1 = 0.f, a2 = 0.f;
#pragma unroll
  for (int i = 0; i < 8; ++i) {
    const int c = m * 512 + c0 + i;
    a0 += gw[c] * rf[i];
    a1 += gw[1539 + c] * rf[i];
    a2 += gw[3078 + c] * rf[i];
  }
  for (int o = 32; o; o >>= 1) {
    a0 += __shfl_xor(a0, o); a1 += __shfl_xor(a1, o); a2 += __shfl_xor(a2, o);
  }
  if (lane == 0) {
    part[px_i][m][0] = a0; part[px_i][m][1] = a1; part[px_i][m][2] = a2;
  }
  __syncthreads();
  const float N = 2097152.0f;
  const float q0 = qacc[b * 4 + 0] / N;
  const float q1 = (qacc[b * 4 + 2] - qacc[b * 4 + 1] * qacc[b * 4 + 1] / N) / (N - 1.0f);
  const float q2 = qacc[b * 4 + 3] / N;
  const float sg = part[px_i][0][m] + part[px_i][1][m] + part[px_i][2][m] + gb[m] +
                   gw[m * 1539 + 1536] * q0 + gw[m * 1539 + 1537] * q1 +
                   gw[m * 1539 + 1538] * q2;
  const float al = 1.0f / (1.0f + expf(-sg));
  __align__(16) bf16 tmp[8];
#pragma unroll
  for (int i = 0; i < 8; ++i) tmp[i] = __float2bfloat16(rf[i] * al);
  *(bfrag8*)(weighted + (long)pix * 1536 + m * 512 + c0) = *(const bfrag8*)tmp;
}

// =================== host launch ===================
extern "C" void kernel_launch(void* const* d_in, const int* in_sizes, int n_in,
                              void* d_out, int out_size, void* d_ws, size_t ws_size,
                              hipStream_t stream)
{
  (void)in_sizes; (void)n_in; (void)out_size; (void)ws_size;
  const float* rgb   = (const float*)d_in[0];
  const float* depth = (const float*)d_in[1];
  const float* lidar = (const float*)d_in[2];
  const float* wq  = (const float*)d_in[3];
  const float* bq  = (const float*)d_in[4];
  const float* wk  = (const float*)d_in[5];
  const float* bk  = (const float*)d_in[6];
  const float* wvw = (const float*)d_in[7];
  const float* bv  = (const float*)d_in[8];
  const float* wo  = (const float*)d_in[9];
  const float* bo  = (const float*)d_in[10];
  const float* seW1 = (const float*)d_in[11];
  const float* seb1 = (const float*)d_in[12];
  const float* seW2 = (const float*)d_in[13];
  const float* seb2 = (const float*)d_in[14];
  const float* gw  = (const float*)d_in[15];
  const float* gb  = (const float*)d_in[16];
  const float* fw  = (const float*)d_in[17];
  const float* fb  = (const float*)d_in[18];

  char* ws = (char*)d_ws;
  bf16*  xT   = (bf16*)(ws + OFF_XT);
  bf16*  xC   = (bf16*)(ws + OFF_XC);
  bf16*  wqB  = (bf16*)(ws + OFF_WQ);
  bf16*  wkB  = (bf16*)(ws + OFF_WK);
  bf16*  wv2  = (bf16*)(ws + OFF_WV2);
  bf16*  wo2  = (bf16*)(ws + OFF_WO2);
  bf16*  fwB  = (bf16*)(ws + OFF_FW);
  float* bo2  = (float*)(ws + OFF_BO2);
  float* bv2  = (float*)(ws + OFF_BV2);
  float* pooled = (float*)(ws + OFF_POOL);
  float* seB  = (float*)(ws + OFF_SE);
  float* qacc = (float*)(ws + OFF_QACC);
  float* cs   = (float*)(ws + OFF_CS);
  bf16*  Gb   = (bf16*)(ws + OFF_GB);
  bf16*  attnB = (bf16*)(ws + OFF_ATT);
  bf16*  Vst  = (bf16*)(ws + OFF_VST);
  float* qstage = (float*)(ws + OFF_QST);
  bf16*  Ost  = (bf16*)(ws + OFF_XT);        // alias after xT/xC dead

  // zero: pooled (+se, qacc harmlessly), colsum
  (void)hipMemsetAsync(ws + OFF_POOL, 0, OFF_CS + 49152 - OFF_POOL, stream);

  transpose_kernel<<<dim3(128, 16, 24), dim3(32, 8), 0, stream>>>(rgb, depth, lidar,
                                                                  xT, xC, cs, qstage);
  quality_reduce<<<24, 256, 0, stream>>>(qstage, qacc);
  prep_weights<<<2048, 256, 0, stream>>>(wq, wk, wvw, wo, fw, bo, bv,
                                         wqB, wkB, wv2, wo2, fwB, bo2, bv2);

  gram_kernel<<<dim3(4, 4, 24), 256, 0, stream>>>(xC, Gb);
  scores_kernel<<<dim3(8, 8, 6), 256, 0, stream>>>(wqB, wkB, Gb, cs, bq, bk, attnB);

  v_gemm<<<dim3(256, 8, 3), 256, 0, stream>>>(xT, wv2, Vst, bv2);
  pv_kernel<<<dim3(32, 64, 6), 256, 0, stream>>>(Vst, attnB, Ost);

  float* crossB = (float*)(ws + OFF_VST);
  wo_gemm<<<dim3(256, 4, 3), 256, 0, stream>>>(Ost, wo2, crossB, bo2,
                                               rgb, depth, lidar, pooled);
  se_mlp<<<dim3(8, 3), 512, 0, stream>>>(pooled, seW1, seb1, seW2, seb2, seB);

  float* cross0 = crossB;
  float* cross1 = (float*)(ws + OFF_VST + 67108864L);
  float* cross2 = (float*)(ws + OFF_VST + 134217728L);
  bf16* weighted = (bf16*)(ws + OFF_XC);
  refine_gate<<<16384, 384, 0, stream>>>(cross0, cross1, cross2, seB, gw, gb, qacc, weighted);

  fusion_gemm<<<dim3(256, 12), 256, 0, stream>>>(weighted, fwB, (float*)d_out, fb);
}

// Round 5
// 967.127 us; speedup vs baseline: 1.5723x; 1.1626x over previous
//
#include <hip/hip_runtime.h>
#include <hip/hip_bf16.h>
#include <stdint.h>

using bf16 = __hip_bfloat16;
typedef short bfrag8 __attribute__((ext_vector_type(8)));
typedef float f32x4 __attribute__((ext_vector_type(4)));

// ---------------- workspace layout (bytes) ----------------
constexpr long OFF_XT   = 0L;           // 3 x [32768][512] bf16 NHWC (live until cross_gemm)
constexpr long OFF_XC   = 100663296L;   // 3 x [512][32768] bf16 channel-major (dead after gram)
constexpr long OFF_WQ   = 201326592L;   // 6 x [512][512] bf16
constexpr long OFF_WK   = 204472320L;
constexpr long OFF_WVT  = 207618048L;   // 6 x [cin 512][ef 512] bf16 (Wv transposed)
constexpr long OFF_WOB  = 210763776L;   // 6 x [512][512] bf16 (Wo plain)
constexpr long OFF_FW   = 213909504L;   // [1536][1536] bf16
constexpr long OFF_BO2  = 218628096L;   // [3][512] f32
constexpr long OFF_POOL = 218646528L;   // [3][8][512] f32   (memset from here)
constexpr long OFF_SE   = 218695680L;   // [3][8][512] f32
constexpr long OFF_QACC = 218744832L;   // [8][4] f32 (+pad to 1024)
constexpr long OFF_CS   = 218745856L;   // [3][8][512] f32 column sums (memset to here+49152)
constexpr long OFF_GB   = 218795008L;   // [3][8][512][512] bf16 Gram
constexpr long OFF_ATT  = 231377920L;   // attnT [6][8][8][64(e)][64(d)] bf16
constexpr long OFF_VST  = 234523648L;   // cross f32 3 x [32768][512] (192 MB)
constexpr long OFF_QST  = 435850240L;   // [24][2048][2] f32 quality partials
constexpr long OFF_MVEC = 436243456L;   // [48][512] f32 (memset)
// aliases in XC region (dead after gram_kernel):
//   Mbuf = OFF_XC (+25165824), Weff = OFF_XC+25165824 (+25165824)  [dead after cross_gemm]
//   weighted = OFF_XC (96 MB) written by refine_gate after Mbuf/Weff dead

__device__ __forceinline__ void mfma_bf16(f32x4& c, bfrag8 a, bfrag8 b) {
  asm("v_mfma_f32_16x16x32_bf16 %0, %1, %2, %0" : "+v"(c) : "v"(a), "v"(b));
}

__device__ __forceinline__ void gload16(const void* g, void* l) {
  __builtin_amdgcn_global_load_lds(
      (__attribute__((address_space(1))) void*)(g),
      (__attribute__((address_space(3))) void*)(l), 16, 0, 0);
}

__device__ __forceinline__ float bf2f(short s) {
  union { uint32_t u; float f; } cv;
  cv.u = ((uint32_t)(unsigned short)s) << 16;
  return cv.f;
}

// XCD-chunked bijective swizzle, n-fast logical order. Requires gx*gy % 8 == 0.
__device__ __forceinline__ void swz_mn(int gy, long& m0, long& n0) {
  const int gx = gridDim.x;
  const int orig = blockIdx.y * gx + blockIdx.x;
  const int q = (gx * gy) >> 3;
  const int wgid = (orig & 7) * q + (orig >> 3);
  m0 = (long)(wgid / gy) * 128;
  n0 = (long)(wgid % gy) * 128;
}

// ============ transpose + stats: NCHW f32 -> NHWC + channel-major bf16, colsum, quality ============
__global__ __launch_bounds__(256) void transpose_kernel(
    const float* __restrict__ x0, const float* __restrict__ x1,
    const float* __restrict__ x2, bf16* __restrict__ xT, bf16* __restrict__ xC,
    float* __restrict__ cs, float* __restrict__ qstage)
{
  __shared__ float tile[32][33];
  __shared__ float qpart[4][2];
  const int zz = blockIdx.z;           // m*8 + b
  const int m = zz >> 3, b = zz & 7;
  const float* x = (m == 0) ? x0 : (m == 1) ? x1 : x2;
  bf16* y = xT + (long)m * 16777216;
  bf16* y2 = xC + (long)m * 16777216;
  const int p0 = blockIdx.x * 32, c0 = blockIdx.y * 32;
  const int tx = threadIdx.x, ty = threadIdx.y;
  float csp[4];
  float qa = 0.f, qb_ = 0.f;   // m==0 (rgb): sum,ssq ; else: zero-count in qa
#pragma unroll
  for (int j = 0; j < 4; ++j) {
    const float v = x[((long)b * 512 + c0 + ty + j * 8) * 4096 + p0 + tx];
    tile[ty + j * 8][tx] = v;
    y2[(long)(c0 + ty + j * 8) * 32768 + (long)b * 4096 + p0 + tx] = __float2bfloat16(v);
    csp[j] = v;
    if (m == 0) { qa += v; qb_ += v * v; }
    else qa += (v == 0.0f) ? 1.0f : 0.0f;
  }
  __syncthreads();
#pragma unroll
  for (int j = 0; j < 4; ++j)
    y[((long)b * 4096 + p0 + ty + j * 8) * 512 + c0 + tx] =
        __float2bfloat16(tile[tx][ty + j * 8]);
  // colsum: reduce over tx (32 lanes), one atomic per c per block
#pragma unroll
  for (int j = 0; j < 4; ++j) {
    float s = csp[j];
    for (int o = 16; o; o >>= 1) s += __shfl_xor(s, o);
    if (tx == 0) atomicAdd(&cs[(m * 8 + b) * 512 + c0 + ty + j * 8], s);
  }
  // quality: block-level reduce, staged write (no atomics)
  const int t = ty * 32 + tx;
  const int lane = t & 63;
  for (int o = 32; o; o >>= 1) { qa += __shfl_xor(qa, o); qb_ += __shfl_xor(qb_, o); }
  if (lane == 0) { qpart[t >> 6][0] = qa; qpart[t >> 6][1] = qb_; }
  __syncthreads();
  if (t == 0) {
    const float pa = qpart[0][0] + qpart[1][0] + qpart[2][0] + qpart[3][0];
    const float pb = qpart[0][1] + qpart[1][1] + qpart[2][1] + qpart[3][1];
    float* qs = qstage + ((long)zz * 2048 + blockIdx.y * 128 + blockIdx.x) * 2;
    qs[0] = pa; qs[1] = pb;
  }
}

// =================== quality partial reduce -> qacc ===================
__global__ __launch_bounds__(256) void quality_reduce(
    const float* __restrict__ qstage, float* __restrict__ qacc)
{
  __shared__ float pr[4][2];
  const int zz = blockIdx.x;  // m*8 + b
  const int m = zz >> 3, b = zz & 7;
  const int t = threadIdx.x;
  float sa = 0.f, sb = 0.f;
  for (int i = t; i < 2048; i += 256) {
    sa += qstage[((long)zz * 2048 + i) * 2];
    sb += qstage[((long)zz * 2048 + i) * 2 + 1];
  }
  for (int o = 32; o; o >>= 1) { sa += __shfl_xor(sa, o); sb += __shfl_xor(sb, o); }
  if ((t & 63) == 0) { pr[t >> 6][0] = sa; pr[t >> 6][1] = sb; }
  __syncthreads();
  if (t == 0) {
    sa = pr[0][0] + pr[1][0] + pr[2][0] + pr[3][0];
    sb = pr[0][1] + pr[1][1] + pr[2][1] + pr[3][1];
    if (m == 0) { qacc[b * 4 + 1] = sa; qacc[b * 4 + 2] = sb; }
    else if (m == 1) qacc[b * 4 + 0] = sa;
    else qacc[b * 4 + 3] = sa;
  }
}

// =================== weight conversion ===================
__global__ void prep_weights(
    const float* __restrict__ wq, const float* __restrict__ wk,
    const float* __restrict__ wv, const float* __restrict__ wo,
    const float* __restrict__ fw, const float* __restrict__ bo,
    bf16* __restrict__ wqB, bf16* __restrict__ wkB, bf16* __restrict__ wvT,
    bf16* __restrict__ woB, bf16* __restrict__ fwB, float* __restrict__ bo2)
{
  const long stride = (long)gridDim.x * blockDim.x;
  for (long j = (long)blockIdx.x * blockDim.x + threadIdx.x; j < 2359296; j += stride) {
    fwB[j] = __float2bfloat16(fw[j]);
    if (j < 1572864) {
      wqB[j] = __float2bfloat16(wq[j]);
      wkB[j] = __float2bfloat16(wk[j]);
      woB[j] = __float2bfloat16(wo[j]);
      const long i = j >> 18, rem = j & 262143, cin = rem >> 9, ef = rem & 511;
      wvT[j] = __float2bfloat16(wv[(i << 18) + (ef << 9) + cin]);
    }
    if (j < 1536) {
      const long m2 = j >> 9, cc = j & 511;
      bo2[j] = bo[((m2 * 2) << 9) + cc] + bo[((m2 * 2 + 1) << 9) + cc];
    }
  }
}

// =================== GEMM core: C[M,N] = A[M,K] * Bt[N,K]^T ===================
template<int BM, int BN>
__device__ __forceinline__ void gemm_core(
    const bf16* __restrict__ A, long lda,
    const bf16* __restrict__ Bt, long ldb,
    int K, long m0, long n0,
    bf16* As, bf16* Bs, f32x4 (&acc)[BM / 32][BN / 32])
{
  constexpr int WM = BM / 2, WN = BN / 2, FM = BM / 32, FN = BN / 32;
  const int t = threadIdx.x;
  const int lane = t & 63, wv = t >> 6;
  const int wr = wv >> 1, wc = wv & 1;
  const int l16 = lane & 15, lk = lane >> 4;
  const int srow = t >> 2;
  const int scol = (t & 3) * 8;
  const bf16* Ag = A + (m0 + srow) * lda + scol;
  const bf16* Bg = Bt + (n0 + srow) * ldb + scol;
  char* AsB = (char*)As;
  char* BsB = (char*)Bs;
  const int aoff = wv * 1024;
  for (int kk = 0; kk < K; kk += 32) {
#pragma unroll
    for (int it = 0; it < BM / 64; ++it)
      gload16(Ag + (long)it * 64 * lda + kk, AsB + it * 4096 + aoff);
#pragma unroll
    for (int it = 0; it < BN / 64; ++it)
      gload16(Bg + (long)it * 64 * ldb + kk, BsB + it * 4096 + aoff);
    __syncthreads();
    bfrag8 af[FM], bfr[FN];
#pragma unroll
    for (int m = 0; m < FM; ++m)
      af[m] = *(const bfrag8*)(AsB + ((wr * WM + m * 16 + l16) * 32 + lk * 8) * 2);
#pragma unroll
    for (int n = 0; n < FN; ++n)
      bfr[n] = *(const bfrag8*)(BsB + ((wc * WN + n * 16 + l16) * 32 + lk * 8) * 2);
#pragma unroll
    for (int m = 0; m < FM; ++m)
#pragma unroll
      for (int n = 0; n < FN; ++n)
        mfma_bf16(acc[m][n], af[m], bfr[n]);
    __syncthreads();
  }
}

// =================== Gram: G[i,j] = sum_p xA[p,i] xB[p,j], bf16 out ===================
__global__ __launch_bounds__(256, 2) void gram_kernel(
    const bf16* __restrict__ xC, bf16* __restrict__ Gb)
{
  __shared__ __align__(16) bf16 As[128 * 32];
  __shared__ __align__(16) bf16 Bs[128 * 32];
  const int z = blockIdx.z;
  const int pair = z >> 3, b = z & 7;
  const int A1[3] = {0, 0, 1}, A2[3] = {1, 2, 2};
  const bf16* A = xC + (long)A1[pair] * 16777216 + b * 4096;
  const bf16* Bt = xC + (long)A2[pair] * 16777216 + b * 4096;
  f32x4 acc[4][4];
#pragma unroll
  for (int m = 0; m < 4; ++m)
#pragma unroll
    for (int n = 0; n < 4; ++n)
      acc[m][n] = f32x4{0.f, 0.f, 0.f, 0.f};
  const long m0 = (long)blockIdx.x * 128, n0 = (long)blockIdx.y * 128;
  gemm_core<128, 128>(A, 32768, Bt, 32768, 4096, m0, n0, As, Bs, acc);
  bf16* C = Gb + (long)z * 262144;
  const int t = threadIdx.x;
  const int lane = t & 63, wv = t >> 6;
  const int wr = wv >> 1, wc = wv & 1;
  const int l16 = lane & 15, lk = lane >> 4;
#pragma unroll
  for (int m = 0; m < 4; ++m) {
    const long gr0 = m0 + wr * 64 + m * 16 + lk * 4;
#pragma unroll
    for (int n = 0; n < 4; ++n) {
      const long gc = n0 + wc * 64 + n * 16 + l16;
#pragma unroll
      for (int i = 0; i < 4; ++i)
        C[(gr0 + i) * 512 + gc] = __float2bfloat16(acc[m][n][i]);
    }
  }
}

// =================== scores+softmax -> attnT[e][d] ===================
__global__ __launch_bounds__(256, 2) void scores_kernel(
    const bf16* __restrict__ wqB, const bf16* __restrict__ wkB,
    const bf16* __restrict__ Gb, const float* __restrict__ colsum,
    const float* __restrict__ bq, const float* __restrict__ bk,
    bf16* __restrict__ attnT)
{
  __shared__ __align__(16) bf16 RtS[64 * 520];  // R^T bf16 ; later aliased as S f32 [64][68]
  __shared__ float uv[128];
  __shared__ __align__(16) bf16 attT[64][64];
  const int h = blockIdx.x, b = blockIdx.y, i = blockIdx.z;
  const int qm = i >> 1, jj = i & 1;
  const int km = jj ? (qm == 2 ? 1 : 2) : (qm == 0 ? 1 : 0);
  const int lo = qm < km ? qm : km, hi = qm < km ? km : qm;
  const int pair = lo + hi - 1;
  const int trans = qm > km;
  const bf16* G = Gb + ((long)(pair * 8 + b)) * 262144;
  const bf16* Wq_h = wqB + (long)i * 262144 + h * 64 * 512;
  const bf16* Wk_h = wkB + (long)i * 262144 + h * 64 * 512;
  const bf16* WA = trans ? Wk_h : Wq_h;
  const bf16* WB = trans ? Wq_h : Wk_h;
  const int t = threadIdx.x, lane = t & 63, wv = t >> 6;
  const int l16 = lane & 15, lk = lane >> 4;

  if (t < 128) {
    const int d = t & 63;
    const bf16* wrow = ((t < 64) ? Wq_h : Wk_h) + d * 512;
    const float* sv = colsum + (((t < 64) ? qm : km) * 8 + b) * 512;
    float a = 0.f;
    for (int c = 0; c < 512; c += 8) {
      const bfrag8 w8 = *(const bfrag8*)(wrow + c);
#pragma unroll
      for (int e = 0; e < 8; ++e) a += bf2f(w8[e]) * sv[c + e];
    }
    uv[t] = a;
  }

  // step A: R[512,64] = G . WB^T ; wave wv owns rows [wv*128, +128)
  f32x4 acc[8][4];
#pragma unroll
  for (int m = 0; m < 8; ++m)
#pragma unroll
    for (int n = 0; n < 4; ++n)
      acc[m][n] = f32x4{0.f, 0.f, 0.f, 0.f};
  for (int kk = 0; kk < 512; kk += 32) {
    bfrag8 a[8], bb[4];
#pragma unroll
    for (int m = 0; m < 8; ++m)
      a[m] = *(const bfrag8*)(G + (wv * 128 + m * 16 + l16) * 512 + kk + lk * 8);
#pragma unroll
    for (int n = 0; n < 4; ++n)
      bb[n] = *(const bfrag8*)(WB + (n * 16 + l16) * 512 + kk + lk * 8);
#pragma unroll
    for (int m = 0; m < 8; ++m)
#pragma unroll
      for (int n = 0; n < 4; ++n)
        mfma_bf16(acc[m][n], a[m], bb[n]);
  }
#pragma unroll
  for (int m = 0; m < 8; ++m)
#pragma unroll
    for (int n = 0; n < 4; ++n)
#pragma unroll
      for (int idx = 0; idx < 4; ++idx)
        RtS[(n * 16 + l16) * 520 + wv * 128 + m * 16 + lk * 4 + idx] =
            __float2bfloat16(acc[m][n][idx]);
  __syncthreads();

  // step B: S[64,64] = WA . Rt^T
  f32x4 acc2[4];
#pragma unroll
  for (int m = 0; m < 4; ++m) acc2[m] = f32x4{0.f, 0.f, 0.f, 0.f};
  for (int kk = 0; kk < 512; kk += 32) {
    bfrag8 a2[4];
#pragma unroll
    for (int m = 0; m < 4; ++m)
      a2[m] = *(const bfrag8*)(WA + (m * 16 + l16) * 512 + kk + lk * 8);
    const bfrag8 b2 = *(const bfrag8*)(&RtS[(wv * 16 + l16) * 520 + kk + lk * 8]);
#pragma unroll
    for (int m = 0; m < 4; ++m) mfma_bf16(acc2[m], a2[m], b2);
  }
  __syncthreads();
  float* S = (float*)RtS;  // [64][68]
#pragma unroll
  for (int m = 0; m < 4; ++m)
#pragma unroll
    for (int idx = 0; idx < 4; ++idx)
      S[(m * 16 + lk * 4 + idx) * 68 + wv * 16 + l16] = acc2[m][idx];
  __syncthreads();

  const int r = t >> 2, q = t & 3;   // r = d (query row), q*16+kq = e (key col)
  const float* bq_h = bq + i * 512 + h * 64;
  const float* bk_h = bk + i * 512 + h * 64;
  const float u_r = uv[r], bq_r = bq_h[r];
  float vals[16];
  float mx = -1e30f;
#pragma unroll
  for (int kq = 0; kq < 16; ++kq) {
    const int k = q * 16 + kq;
    float s = trans ? S[k * 68 + r] : S[r * 68 + k];
    s += u_r * bk_h[k] + bq_r * uv[64 + k] + 4096.0f * bq_r * bk_h[k];
    s *= 0.125f;
    vals[kq] = s;
    mx = fmaxf(mx, s);
  }
  mx = fmaxf(mx, __shfl_xor(mx, 1));
  mx = fmaxf(mx, __shfl_xor(mx, 2));
  float sum = 0.f;
#pragma unroll
  for (int kq = 0; kq < 16; ++kq) { vals[kq] = expf(vals[kq] - mx); sum += vals[kq]; }
  sum += __shfl_xor(sum, 1);
  sum += __shfl_xor(sum, 2);
  const float inv = 1.0f / sum;
  // transposed store into LDS: attT[e][d]
#pragma unroll
  for (int kq = 0; kq < 16; ++kq)
    attT[q * 16 + kq][r] = __float2bfloat16(vals[kq] * inv);
  __syncthreads();
  const int er = t >> 2, c16 = (t & 3) * 16;
  bf16* op = attnT + (((long)(i * 8 + b) * 8 + h) * 64 + er) * 64 + c16;
  *(bfrag8*)(op) = *(const bfrag8*)(&attT[er][c16]);
  *(bfrag8*)(op + 8) = *(const bfrag8*)(&attT[er][c16 + 8]);
}

// =================== mfold: M[c,ef] = sum_d Wo[c, h*64+d] * attnT[e,d]; mvec += M.bv ===================
__global__ __launch_bounds__(256, 2) void mfold_kernel(
    const bf16* __restrict__ woB, const bf16* __restrict__ attnT,
    const float* __restrict__ bv, bf16* __restrict__ Mbuf, float* __restrict__ mvec)
{
  __shared__ __align__(16) bf16 As[128 * 32];
  __shared__ __align__(16) bf16 Bs[64 * 32];
  const int ib = blockIdx.z;          // i*8+b
  const int i = ib >> 3;
  const int h = blockIdx.y;
  const bf16* A = woB + (long)i * 262144 + h * 64;
  const bf16* Bt = attnT + ((long)ib * 8 + h) * 4096;
  f32x4 acc[4][2];
#pragma unroll
  for (int m = 0; m < 4; ++m)
#pragma unroll
    for (int n = 0; n < 2; ++n)
      acc[m][n] = f32x4{0.f, 0.f, 0.f, 0.f};
  const long m0 = (long)blockIdx.x * 128;
  gemm_core<128, 64>(A, 512, Bt, 64, 64, m0, 0, As, Bs, acc);

  const int t = threadIdx.x;
  const int lane = t & 63, wv = t >> 6;
  const int wr = wv >> 1, wc = wv & 1;
  const int l16 = lane & 15, lk = lane >> 4;
  bf16* C = Mbuf + (long)ib * 262144;
  const float* bvp = bv + i * 512 + h * 64;
  float mp[4][4];
#pragma unroll
  for (int m = 0; m < 4; ++m)
#pragma unroll
    for (int i2 = 0; i2 < 4; ++i2) mp[m][i2] = 0.f;
#pragma unroll
  for (int m = 0; m < 4; ++m) {
    const long gr0 = m0 + wr * 64 + m * 16 + lk * 4;
#pragma unroll
    for (int n = 0; n < 2; ++n) {
      const int gc = wc * 32 + n * 16 + l16;
      const float bvv = bvp[gc];
#pragma unroll
      for (int i2 = 0; i2 < 4; ++i2) {
        C[(gr0 + i2) * 512 + h * 64 + gc] = __float2bfloat16(acc[m][n][i2]);
        mp[m][i2] += acc[m][n][i2] * bvv;
      }
    }
  }
#pragma unroll
  for (int m = 0; m < 4; ++m)
#pragma unroll
    for (int i2 = 0; i2 < 4; ++i2) {
      float v = mp[m][i2];
      v += __shfl_xor(v, 1); v += __shfl_xor(v, 2);
      v += __shfl_xor(v, 4); v += __shfl_xor(v, 8);
      if (l16 == 0)
        atomicAdd(&mvec[(long)ib * 512 + m0 + wr * 64 + m * 16 + lk * 4 + i2], v);
    }
}

// =================== weff: W_eff[c,cin] = sum_ef M[c,ef] * wvT[cin,ef] ===================
__global__ __launch_bounds__(256, 2) void weff_gemm(
    const bf16* __restrict__ Mbuf, const bf16* __restrict__ wvT,
    bf16* __restrict__ Weff)
{
  __shared__ __align__(16) bf16 As[128 * 32];
  __shared__ __align__(16) bf16 Bs[128 * 32];
  const int ib = blockIdx.z;
  const int i = ib >> 3;
  f32x4 acc[4][4];
#pragma unroll
  for (int m = 0; m < 4; ++m)
#pragma unroll
    for (int n = 0; n < 4; ++n)
      acc[m][n] = f32x4{0.f, 0.f, 0.f, 0.f};
  const long m0 = (long)blockIdx.x * 128, n0 = (long)blockIdx.y * 128;
  gemm_core<128, 128>(Mbuf + (long)ib * 262144, 512, wvT + (long)i * 262144, 512,
                      512, m0, n0, As, Bs, acc);
  bf16* C = Weff + (long)ib * 262144;
  const int t = threadIdx.x;
  const int lane = t & 63, wv = t >> 6;
  const int wr = wv >> 1, wc = wv & 1;
  const int l16 = lane & 15, lk = lane >> 4;
#pragma unroll
  for (int m = 0; m < 4; ++m) {
    const long gr0 = m0 + wr * 64 + m * 16 + lk * 4;
#pragma unroll
    for (int n = 0; n < 4; ++n) {
      const long gc = n0 + wc * 64 + n * 16 + l16;
#pragma unroll
      for (int i2 = 0; i2 < 4; ++i2)
        C[(gr0 + i2) * 512 + gc] = __float2bfloat16(acc[m][n][i2]);
    }
  }
}

// ======= cross: cross[qm][b*4096+p, c] = sum_i xT[km(i)][b] . Weff_i^T + bias + resid; SE pool =======
__global__ __launch_bounds__(256, 2) void cross_gemm(
    const bf16* __restrict__ xT, const bf16* __restrict__ Weff,
    float* __restrict__ crossB, const float* __restrict__ bo2,
    const float* __restrict__ mvec,
    const float* __restrict__ r0, const float* __restrict__ r1,
    const float* __restrict__ r2, float* __restrict__ pooled)
{
  __shared__ __align__(16) bf16 As[128 * 32];
  __shared__ __align__(16) bf16 Bs[128 * 32];
  const int z = blockIdx.z;           // qm*8 + b
  const int qm = z >> 3, b = z & 7;
  const int KM0[3] = {1, 0, 0}, KM1[3] = {2, 2, 1};
  const bf16* A0 = xT + (long)KM0[qm] * 16777216 + (long)b * 2097152;
  const bf16* A1 = xT + (long)KM1[qm] * 16777216 + (long)b * 2097152;
  const bf16* B0 = Weff + ((long)(2 * qm) * 8 + b) * 262144;
  const bf16* B1 = Weff + ((long)(2 * qm + 1) * 8 + b) * 262144;
  float* Cf = crossB + (long)qm * 16777216;
  const float* resid = (qm == 0) ? r0 : (qm == 1) ? r1 : r2;
  f32x4 acc[4][4];
#pragma unroll
  for (int m = 0; m < 4; ++m)
#pragma unroll
    for (int n = 0; n < 4; ++n)
      acc[m][n] = f32x4{0.f, 0.f, 0.f, 0.f};
  long m0, n0;
  swz_mn(4, m0, n0);
  gemm_core<128, 128>(A0, 512, B0, 512, 512, m0, n0, As, Bs, acc);
  gemm_core<128, 128>(A1, 512, B1, 512, 512, m0, n0, As, Bs, acc);

  const int t = threadIdx.x;
  const int lane = t & 63, wv = t >> 6;
  const int wr = wv >> 1, wc = wv & 1;
  const int l16 = lane & 15, lk = lane >> 4;
  const float* mv0 = mvec + ((long)(2 * qm) * 8 + b) * 512;
  const float* mv1 = mvec + ((long)(2 * qm + 1) * 8 + b) * 512;
  float csum[4] = {0.f, 0.f, 0.f, 0.f};
#pragma unroll
  for (int m = 0; m < 4; ++m) {
    const long p = m0 + wr * 64 + m * 16 + lk * 4;      // pixel within batch [0,4096)
    const long gr0 = (long)b * 4096 + p;
#pragma unroll
    for (int n = 0; n < 4; ++n) {
      const long gc = n0 + wc * 64 + n * 16 + l16;
      const float bb = bo2[qm * 512 + gc] + mv0[gc] + mv1[gc];
      const float4 r4 = *(const float4*)(resid + (long)b * 2097152 + gc * 4096L + p);
#pragma unroll
      for (int i2 = 0; i2 < 4; ++i2) {
        const float o = acc[m][n][i2] + bb + (&r4.x)[i2];
        Cf[(gr0 + i2) * 512 + gc] = o;
        csum[n] += o;
      }
    }
  }
#pragma unroll
  for (int n = 0; n < 4; ++n) {
    float s = csum[n];
    s += __shfl_xor(s, 16);
    s += __shfl_xor(s, 32);
    if (lane < 16) {
      const long gc = n0 + wc * 64 + n * 16 + l16;
      atomicAdd(&pooled[((long)qm * 8 + b) * 512 + gc], s);
    }
  }
}

// =================== fusion GEMM: out[b][o][p] = Fw . weighted ===================
__global__ __launch_bounds__(256, 2) void fusion_gemm(
    const bf16* __restrict__ A, const bf16* __restrict__ Bt,
    float* __restrict__ Cf, const float* __restrict__ bias)
{
  __shared__ __align__(16) bf16 As[128 * 32];
  __shared__ __align__(16) bf16 Bs[128 * 32];
  f32x4 acc[4][4];
#pragma unroll
  for (int m = 0; m < 4; ++m)
#pragma unroll
    for (int n = 0; n < 4; ++n)
      acc[m][n] = f32x4{0.f, 0.f, 0.f, 0.f};
  long m0, n0;
  swz_mn(12, m0, n0);
  gemm_core<128, 128>(A, 1536, Bt, 1536, 1536, m0, n0, As, Bs, acc);

  const int t = threadIdx.x;
  const int lane = t & 63, wv = t >> 6;
  const int wr = wv >> 1, wc = wv & 1;
  const int l16 = lane & 15, lk = lane >> 4;
#pragma unroll
  for (int m = 0; m < 4; ++m) {
    const long gr0 = m0 + wr * 64 + m * 16 + lk * 4;
    const long b = gr0 >> 12, p = gr0 & 4095;
#pragma unroll
    for (int n = 0; n < 4; ++n) {
      const long gc = n0 + wc * 64 + n * 16 + l16;
      const float bb = bias[gc];
      float4 o4;
      o4.x = acc[m][n][0] + bb; o4.y = acc[m][n][1] + bb;
      o4.z = acc[m][n][2] + bb; o4.w = acc[m][n][3] + bb;
      *(float4*)(Cf + b * 6291456L + gc * 4096L + p) = o4;
    }
  }
}

// =================== SE MLP ===================
__global__ __launch_bounds__(512) void se_mlp(
    const float* __restrict__ pooled,
    const float* __restrict__ W1, const float* __restrict__ b1,
    const float* __restrict__ W2, const float* __restrict__ b2,
    float* __restrict__ se)
{
  const int b = blockIdx.x, m = blockIdx.y;
  __shared__ float y[32];
  const int t = threadIdx.x;
  if (t < 32) {
    float s = b1[m * 32 + t];
    const float* w = W1 + (long)(m * 32 + t) * 512;
    const float* p = pooled + ((long)m * 8 + b) * 512;
    for (int c = 0; c < 512; ++c) s += w[c] * (p[c] * (1.0f / 4096.0f));
    y[t] = fmaxf(s, 0.0f);
  }
  __syncthreads();
  float s = b2[m * 512 + t];
  const float* w2 = W2 + (long)(m * 512 + t) * 32;
#pragma unroll
  for (int j = 0; j < 32; ++j) s += w2[j] * y[j];
  se[((long)m * 8 + b) * 512 + t] = 1.0f / (1.0f + expf(-s));
}

// ========= refined = l2norm_c(cross*se); alpha = sigmoid(gate); weighted out (fused) =========
__global__ __launch_bounds__(384) void refine_gate(
    const float* __restrict__ cr0, const float* __restrict__ cr1,
    const float* __restrict__ cr2, const float* __restrict__ se,
    const float* __restrict__ gw, const float* __restrict__ gb,
    const float* __restrict__ qacc, bf16* __restrict__ weighted)
{
  __shared__ float part[2][3][3];
  const int t = threadIdx.x, wv = t >> 6, lane = t & 63;
  const int px_i = (wv >= 3) ? 1 : 0;
  const int m = wv - px_i * 3;
  const int pix = blockIdx.x * 2 + px_i;
  const int b = pix >> 12;
  const float* cr = (m == 0) ? cr0 : (m == 1) ? cr1 : cr2;
  const int c0 = lane * 8;
  const float4 v0 = *(const float4*)(cr + (long)pix * 512 + c0);
  const float4 v1 = *(const float4*)(cr + (long)pix * 512 + c0 + 4);
  const float* sp = se + ((long)m * 8 + b) * 512 + c0;
  const float4 s0 = *(const float4*)(sp);
  const float4 s1 = *(const float4*)(sp + 4);
  float w[8] = {v0.x * s0.x, v0.y * s0.y, v0.z * s0.z, v0.w * s0.w,
                v1.x * s1.x, v1.y * s1.y, v1.z * s1.z, v1.w * s1.w};
  float ss = 0.f;
#pragma unroll
  for (int i = 0; i < 8; ++i) ss += w[i] * w[i];
  for (int o = 32; o; o >>= 1) ss += __shfl_xor(ss, o);
  const float inv = 1.0f / (sqrtf(ss) + 1e-6f);
  float rf[8];
#pragma unroll
  for (int i = 0; i < 8; ++i) rf[i] = w[i] * inv;

  float a0 = 0.f, a1 = 0.f, a2 = 0.f;
#pragma unroll
  for (int i = 0; i < 8; ++i) {
    const int c = m * 512 + c0 + i;
    a0 += gw[c] * rf[i];
    a1 += gw[1539 + c] * rf[i];
    a2 += gw[3078 + c] * rf[i];
  }
  for (int o = 32; o; o >>= 1) {
    a0 += __shfl_xor(a0, o); a1 += __shfl_xor(a1, o); a2 += __shfl_xor(a2, o);
  }
  if (lane == 0) {
    part[px_i][m][0] = a0; part[px_i][m][1] = a1; part[px_i][m][2] = a2;
  }
  __syncthreads();
  const float N = 2097152.0f;
  const float q0 = qacc[b * 4 + 0] / N;
  const float q1 = (qacc[b * 4 + 2] - qacc[b * 4 + 1] * qacc[b * 4 + 1] / N) / (N - 1.0f);
  const float q2 = qacc[b * 4 + 3] / N;
  const float sg = part[px_i][0][m] + part[px_i][1][m] + part[px_i][2][m] + gb[m] +
                   gw[m * 1539 + 1536] * q0 + gw[m * 1539 + 1537] * q1 +
                   gw[m * 1539 + 1538] * q2;
  const float al = 1.0f / (1.0f + expf(-sg));
  __align__(16) bf16 tmp[8];
#pragma unroll
  for (int i = 0; i < 8; ++i) tmp[i] = __float2bfloat16(rf[i] * al);
  *(bfrag8*)(weighted + (long)pix * 1536 + m * 512 + c0) = *(const bfrag8*)tmp;
}

// =================== host launch ===================
extern "C" void kernel_launch(void* const* d_in, const int* in_sizes, int n_in,
                              void* d_out, int out_size, void* d_ws, size_t ws_size,
                              hipStream_t stream)
{
  (void)in_sizes; (void)n_in; (void)out_size; (void)ws_size;
  const float* rgb   = (const float*)d_in[0];
  const float* depth = (const float*)d_in[1];
  const float* lidar = (const float*)d_in[2];
  const float* wq  = (const float*)d_in[3];
  const float* bq  = (const float*)d_in[4];
  const float* wk  = (const float*)d_in[5];
  const float* bk  = (const float*)d_in[6];
  const float* wvw = (const float*)d_in[7];
  const float* bv  = (const float*)d_in[8];
  const float* wo  = (const float*)d_in[9];
  const float* bo  = (const float*)d_in[10];
  const float* seW1 = (const float*)d_in[11];
  const float* seb1 = (const float*)d_in[12];
  const float* seW2 = (const float*)d_in[13];
  const float* seb2 = (const float*)d_in[14];
  const float* gw  = (const float*)d_in[15];
  const float* gb  = (const float*)d_in[16];
  const float* fw  = (const float*)d_in[17];
  const float* fb  = (const float*)d_in[18];

  char* ws = (char*)d_ws;
  bf16*  xT   = (bf16*)(ws + OFF_XT);
  bf16*  xC   = (bf16*)(ws + OFF_XC);
  bf16*  wqB  = (bf16*)(ws + OFF_WQ);
  bf16*  wkB  = (bf16*)(ws + OFF_WK);
  bf16*  wvT  = (bf16*)(ws + OFF_WVT);
  bf16*  woB  = (bf16*)(ws + OFF_WOB);
  bf16*  fwB  = (bf16*)(ws + OFF_FW);
  float* bo2  = (float*)(ws + OFF_BO2);
  float* pooled = (float*)(ws + OFF_POOL);
  float* seB  = (float*)(ws + OFF_SE);
  float* qacc = (float*)(ws + OFF_QACC);
  float* cs   = (float*)(ws + OFF_CS);
  bf16*  Gb   = (bf16*)(ws + OFF_GB);
  bf16*  attnT = (bf16*)(ws + OFF_ATT);
  float* qstage = (float*)(ws + OFF_QST);
  float* mvec = (float*)(ws + OFF_MVEC);
  bf16*  Mbuf = (bf16*)(ws + OFF_XC);              // alias, dead after weff
  bf16*  Weff = (bf16*)(ws + OFF_XC + 25165824L);  // alias, dead after cross
  float* crossB = (float*)(ws + OFF_VST);

  // zero: pooled (+se, qacc harmlessly), colsum ; mvec
  (void)hipMemsetAsync(ws + OFF_POOL, 0, OFF_CS + 49152 - OFF_POOL, stream);
  (void)hipMemsetAsync(ws + OFF_MVEC, 0, 98304, stream);

  transpose_kernel<<<dim3(128, 16, 24), dim3(32, 8), 0, stream>>>(rgb, depth, lidar,
                                                                  xT, xC, cs, qstage);
  quality_reduce<<<24, 256, 0, stream>>>(qstage, qacc);
  prep_weights<<<2048, 256, 0, stream>>>(wq, wk, wvw, wo, fw, bo,
                                         wqB, wkB, wvT, woB, fwB, bo2);

  gram_kernel<<<dim3(4, 4, 24), 256, 0, stream>>>(xC, Gb);
  scores_kernel<<<dim3(8, 8, 6), 256, 0, stream>>>(wqB, wkB, Gb, cs, bq, bk, attnT);

  mfold_kernel<<<dim3(4, 8, 48), 256, 0, stream>>>(woB, attnT, bv, Mbuf, mvec);
  weff_gemm<<<dim3(4, 4, 48), 256, 0, stream>>>(Mbuf, wvT, Weff);

  cross_gemm<<<dim3(32, 4, 24), 256, 0, stream>>>(xT, Weff, crossB, bo2, mvec,
                                                  rgb, depth, lidar, pooled);
  se_mlp<<<dim3(8, 3), 512, 0, stream>>>(pooled, seW1, seb1, seW2, seb2, seB);

  float* cross0 = crossB;
  float* cross1 = (float*)(ws + OFF_VST + 67108864L);
  float* cross2 = (float*)(ws + OFF_VST + 134217728L);
  bf16* weighted = (bf16*)(ws + OFF_XC);
  refine_gate<<<16384, 384, 0, stream>>>(cross0, cross1, cross2, seB, gw, gb, qacc, weighted);

  fusion_gemm<<<dim3(256, 12), 256, 0, stream>>>(weighted, fwB, (float*)d_out, fb);
}

// Round 6
// 934.658 us; speedup vs baseline: 1.6269x; 1.0347x over previous
//
#include <hip/hip_runtime.h>
#include <hip/hip_bf16.h>
#include <stdint.h>

using bf16 = __hip_bfloat16;
typedef short bfrag8 __attribute__((ext_vector_type(8)));
typedef float f32x4 __attribute__((ext_vector_type(4)));

// ---------------- workspace layout (bytes) ----------------
constexpr long OFF_XT   = 0L;           // 3 x [32768][512] bf16 NHWC (live until cross_gemm)
constexpr long OFF_XC   = 100663296L;   // 3 x [512][32768] bf16 channel-major (dead after gram)
constexpr long OFF_WQ   = 201326592L;   // 6 x [512][512] bf16
constexpr long OFF_WK   = 204472320L;
constexpr long OFF_WVT  = 207618048L;   // 6 x [cin 512][ef 512] bf16 (Wv transposed)
constexpr long OFF_WOB  = 210763776L;   // 6 x [512][512] bf16 (Wo plain)
constexpr long OFF_FW   = 213909504L;   // [1536][1536] bf16
constexpr long OFF_BO2  = 218628096L;   // [3][512] f32
constexpr long OFF_POOL = 218646528L;   // [3][8][512] f32   (memset from here)
constexpr long OFF_SE   = 218695680L;   // [3][8][512] f32
constexpr long OFF_QACC = 218744832L;   // [8][4] f32 (+pad to 1024)
constexpr long OFF_CS   = 218745856L;   // [3][8][512] f32 column sums (memset to here+49152)
constexpr long OFF_GB   = 218795008L;   // [3][8][512][512] bf16 Gram
constexpr long OFF_ATT  = 231377920L;   // attnT [6][8][8][64(e)][64(d)] bf16
constexpr long OFF_VST  = 234523648L;   // cross bf16 3 x [32768][512] (96 MB)
constexpr long OFF_QST  = 435850240L;   // [24][2048][2] f32 quality partials
constexpr long OFF_MVEC = 436243456L;   // [48][512] f32 (memset)
// aliases in XC region (dead after gram_kernel):
//   Mbuf = OFF_XC (+25165824), Weff = OFF_XC+25165824 (+25165824)  [dead after cross_gemm]
//   weighted = OFF_XC (96 MB) written by refine_gate after Mbuf/Weff dead

__device__ __forceinline__ void mfma_bf16(f32x4& c, bfrag8 a, bfrag8 b) {
  asm("v_mfma_f32_16x16x32_bf16 %0, %1, %2, %0" : "+v"(c) : "v"(a), "v"(b));
}

__device__ __forceinline__ void gload16(const void* g, void* l) {
  __builtin_amdgcn_global_load_lds(
      (__attribute__((address_space(1))) void*)(g),
      (__attribute__((address_space(3))) void*)(l), 16, 0, 0);
}

__device__ __forceinline__ float bf2f(short s) {
  union { uint32_t u; float f; } cv;
  cv.u = ((uint32_t)(unsigned short)s) << 16;
  return cv.f;
}

// XCD-chunked bijective swizzle, n-fast logical order. Requires gx*gy % 8 == 0.
__device__ __forceinline__ void swz_mn(int gy, long& m0, long& n0) {
  const int gx = gridDim.x;
  const int orig = blockIdx.y * gx + blockIdx.x;
  const int q = (gx * gy) >> 3;
  const int wgid = (orig & 7) * q + (orig >> 3);
  m0 = (long)(wgid / gy) * 128;
  n0 = (long)(wgid % gy) * 128;
}

// ============ transpose + stats: NCHW f32 -> NHWC + channel-major bf16, colsum, quality ============
__global__ __launch_bounds__(256) void transpose_kernel(
    const float* __restrict__ x0, const float* __restrict__ x1,
    const float* __restrict__ x2, bf16* __restrict__ xT, bf16* __restrict__ xC,
    float* __restrict__ cs, float* __restrict__ qstage)
{
  __shared__ float tile[32][33];
  __shared__ float qpart[4][2];
  const int zz = blockIdx.z;           // m*8 + b
  const int m = zz >> 3, b = zz & 7;
  const float* x = (m == 0) ? x0 : (m == 1) ? x1 : x2;
  bf16* y = xT + (long)m * 16777216;
  bf16* y2 = xC + (long)m * 16777216;
  const int p0 = blockIdx.x * 32, c0 = blockIdx.y * 32;
  const int tx = threadIdx.x, ty = threadIdx.y;
  float csp[4];
  float qa = 0.f, qb_ = 0.f;   // m==0 (rgb): sum,ssq ; else: zero-count in qa
#pragma unroll
  for (int j = 0; j < 4; ++j) {
    const float v = x[((long)b * 512 + c0 + ty + j * 8) * 4096 + p0 + tx];
    tile[ty + j * 8][tx] = v;
    y2[(long)(c0 + ty + j * 8) * 32768 + (long)b * 4096 + p0 + tx] = __float2bfloat16(v);
    csp[j] = v;
    if (m == 0) { qa += v; qb_ += v * v; }
    else qa += (v == 0.0f) ? 1.0f : 0.0f;
  }
  __syncthreads();
#pragma unroll
  for (int j = 0; j < 4; ++j)
    y[((long)b * 4096 + p0 + ty + j * 8) * 512 + c0 + tx] =
        __float2bfloat16(tile[tx][ty + j * 8]);
  // colsum: reduce over tx (32 lanes), one atomic per c per block
#pragma unroll
  for (int j = 0; j < 4; ++j) {
    float s = csp[j];
    for (int o = 16; o; o >>= 1) s += __shfl_xor(s, o);
    if (tx == 0) atomicAdd(&cs[(m * 8 + b) * 512 + c0 + ty + j * 8], s);
  }
  // quality: block-level reduce, staged write (no atomics)
  const int t = ty * 32 + tx;
  const int lane = t & 63;
  for (int o = 32; o; o >>= 1) { qa += __shfl_xor(qa, o); qb_ += __shfl_xor(qb_, o); }
  if (lane == 0) { qpart[t >> 6][0] = qa; qpart[t >> 6][1] = qb_; }
  __syncthreads();
  if (t == 0) {
    const float pa = qpart[0][0] + qpart[1][0] + qpart[2][0] + qpart[3][0];
    const float pb = qpart[0][1] + qpart[1][1] + qpart[2][1] + qpart[3][1];
    float* qs = qstage + ((long)zz * 2048 + blockIdx.y * 128 + blockIdx.x) * 2;
    qs[0] = pa; qs[1] = pb;
  }
}

// =================== quality partial reduce -> qacc ===================
__global__ __launch_bounds__(256) void quality_reduce(
    const float* __restrict__ qstage, float* __restrict__ qacc)
{
  __shared__ float pr[4][2];
  const int zz = blockIdx.x;  // m*8 + b
  const int m = zz >> 3, b = zz & 7;
  const int t = threadIdx.x;
  float sa = 0.f, sb = 0.f;
  for (int i = t; i < 2048; i += 256) {
    sa += qstage[((long)zz * 2048 + i) * 2];
    sb += qstage[((long)zz * 2048 + i) * 2 + 1];
  }
  for (int o = 32; o; o >>= 1) { sa += __shfl_xor(sa, o); sb += __shfl_xor(sb, o); }
  if ((t & 63) == 0) { pr[t >> 6][0] = sa; pr[t >> 6][1] = sb; }
  __syncthreads();
  if (t == 0) {
    sa = pr[0][0] + pr[1][0] + pr[2][0] + pr[3][0];
    sb = pr[0][1] + pr[1][1] + pr[2][1] + pr[3][1];
    if (m == 0) { qacc[b * 4 + 1] = sa; qacc[b * 4 + 2] = sb; }
    else if (m == 1) qacc[b * 4 + 0] = sa;
    else qacc[b * 4 + 3] = sa;
  }
}

// =================== weight conversion ===================
__global__ void prep_weights(
    const float* __restrict__ wq, const float* __restrict__ wk,
    const float* __restrict__ wv, const float* __restrict__ wo,
    const float* __restrict__ fw, const float* __restrict__ bo,
    bf16* __restrict__ wqB, bf16* __restrict__ wkB, bf16* __restrict__ wvT,
    bf16* __restrict__ woB, bf16* __restrict__ fwB, float* __restrict__ bo2)
{
  const long stride = (long)gridDim.x * blockDim.x;
  for (long j = (long)blockIdx.x * blockDim.x + threadIdx.x; j < 2359296; j += stride) {
    fwB[j] = __float2bfloat16(fw[j]);
    if (j < 1572864) {
      wqB[j] = __float2bfloat16(wq[j]);
      wkB[j] = __float2bfloat16(wk[j]);
      woB[j] = __float2bfloat16(wo[j]);
      const long i = j >> 18, rem = j & 262143, cin = rem >> 9, ef = rem & 511;
      wvT[j] = __float2bfloat16(wv[(i << 18) + (ef << 9) + cin]);
    }
    if (j < 1536) {
      const long m2 = j >> 9, cc = j & 511;
      bo2[j] = bo[((m2 * 2) << 9) + cc] + bo[((m2 * 2 + 1) << 9) + cc];
    }
  }
}

// =================== GEMM core: C[M,N] = A[M,K] * Bt[N,K]^T ===================
template<int BM, int BN>
__device__ __forceinline__ void gemm_core(
    const bf16* __restrict__ A, long lda,
    const bf16* __restrict__ Bt, long ldb,
    int K, long m0, long n0,
    bf16* As, bf16* Bs, f32x4 (&acc)[BM / 32][BN / 32])
{
  constexpr int WM = BM / 2, WN = BN / 2, FM = BM / 32, FN = BN / 32;
  const int t = threadIdx.x;
  const int lane = t & 63, wv = t >> 6;
  const int wr = wv >> 1, wc = wv & 1;
  const int l16 = lane & 15, lk = lane >> 4;
  const int srow = t >> 2;
  const int scol = (t & 3) * 8;
  const bf16* Ag = A + (m0 + srow) * lda + scol;
  const bf16* Bg = Bt + (n0 + srow) * ldb + scol;
  char* AsB = (char*)As;
  char* BsB = (char*)Bs;
  const int aoff = wv * 1024;
  for (int kk = 0; kk < K; kk += 32) {
#pragma unroll
    for (int it = 0; it < BM / 64; ++it)
      gload16(Ag + (long)it * 64 * lda + kk, AsB + it * 4096 + aoff);
#pragma unroll
    for (int it = 0; it < BN / 64; ++it)
      gload16(Bg + (long)it * 64 * ldb + kk, BsB + it * 4096 + aoff);
    __syncthreads();
    bfrag8 af[FM], bfr[FN];
#pragma unroll
    for (int m = 0; m < FM; ++m)
      af[m] = *(const bfrag8*)(AsB + ((wr * WM + m * 16 + l16) * 32 + lk * 8) * 2);
#pragma unroll
    for (int n = 0; n < FN; ++n)
      bfr[n] = *(const bfrag8*)(BsB + ((wc * WN + n * 16 + l16) * 32 + lk * 8) * 2);
#pragma unroll
    for (int m = 0; m < FM; ++m)
#pragma unroll
      for (int n = 0; n < FN; ++n)
        mfma_bf16(acc[m][n], af[m], bfr[n]);
    __syncthreads();
  }
}

// =================== Gram: G[i,j] = sum_p xA[p,i] xB[p,j], bf16 out ===================
__global__ __launch_bounds__(256, 2) void gram_kernel(
    const bf16* __restrict__ xC, bf16* __restrict__ Gb)
{
  __shared__ __align__(16) bf16 As[128 * 32];
  __shared__ __align__(16) bf16 Bs[128 * 32];
  const int z = blockIdx.z;
  const int pair = z >> 3, b = z & 7;
  const int A1[3] = {0, 0, 1}, A2[3] = {1, 2, 2};
  const bf16* A = xC + (long)A1[pair] * 16777216 + b * 4096;
  const bf16* Bt = xC + (long)A2[pair] * 16777216 + b * 4096;
  f32x4 acc[4][4];
#pragma unroll
  for (int m = 0; m < 4; ++m)
#pragma unroll
    for (int n = 0; n < 4; ++n)
      acc[m][n] = f32x4{0.f, 0.f, 0.f, 0.f};
  const long m0 = (long)blockIdx.x * 128, n0 = (long)blockIdx.y * 128;
  gemm_core<128, 128>(A, 32768, Bt, 32768, 4096, m0, n0, As, Bs, acc);
  bf16* C = Gb + (long)z * 262144;
  const int t = threadIdx.x;
  const int lane = t & 63, wv = t >> 6;
  const int wr = wv >> 1, wc = wv & 1;
  const int l16 = lane & 15, lk = lane >> 4;
#pragma unroll
  for (int m = 0; m < 4; ++m) {
    const long gr0 = m0 + wr * 64 + m * 16 + lk * 4;
#pragma unroll
    for (int n = 0; n < 4; ++n) {
      const long gc = n0 + wc * 64 + n * 16 + l16;
#pragma unroll
      for (int i = 0; i < 4; ++i)
        C[(gr0 + i) * 512 + gc] = __float2bfloat16(acc[m][n][i]);
    }
  }
}

// =================== scores+softmax -> attnT[e][d] ===================
__global__ __launch_bounds__(256, 2) void scores_kernel(
    const bf16* __restrict__ wqB, const bf16* __restrict__ wkB,
    const bf16* __restrict__ Gb, const float* __restrict__ colsum,
    const float* __restrict__ bq, const float* __restrict__ bk,
    bf16* __restrict__ attnT)
{
  __shared__ __align__(16) bf16 RtS[64 * 520];  // R^T bf16 ; later aliased as S f32 [64][68]
  __shared__ float uv[128];
  __shared__ __align__(16) bf16 attT[64][64];
  const int h = blockIdx.x, b = blockIdx.y, i = blockIdx.z;
  const int qm = i >> 1, jj = i & 1;
  const int km = jj ? (qm == 2 ? 1 : 2) : (qm == 0 ? 1 : 0);
  const int lo = qm < km ? qm : km, hi = qm < km ? km : qm;
  const int pair = lo + hi - 1;
  const int trans = qm > km;
  const bf16* G = Gb + ((long)(pair * 8 + b)) * 262144;
  const bf16* Wq_h = wqB + (long)i * 262144 + h * 64 * 512;
  const bf16* Wk_h = wkB + (long)i * 262144 + h * 64 * 512;
  const bf16* WA = trans ? Wk_h : Wq_h;
  const bf16* WB = trans ? Wq_h : Wk_h;
  const int t = threadIdx.x, lane = t & 63, wv = t >> 6;
  const int l16 = lane & 15, lk = lane >> 4;

  if (t < 128) {
    const int d = t & 63;
    const bf16* wrow = ((t < 64) ? Wq_h : Wk_h) + d * 512;
    const float* sv = colsum + (((t < 64) ? qm : km) * 8 + b) * 512;
    float a = 0.f;
    for (int c = 0; c < 512; c += 8) {
      const bfrag8 w8 = *(const bfrag8*)(wrow + c);
#pragma unroll
      for (int e = 0; e < 8; ++e) a += bf2f(w8[e]) * sv[c + e];
    }
    uv[t] = a;
  }

  // step A: R[512,64] = G . WB^T ; wave wv owns rows [wv*128, +128)
  f32x4 acc[8][4];
#pragma unroll
  for (int m = 0; m < 8; ++m)
#pragma unroll
    for (int n = 0; n < 4; ++n)
      acc[m][n] = f32x4{0.f, 0.f, 0.f, 0.f};
  for (int kk = 0; kk < 512; kk += 32) {
    bfrag8 a[8], bb[4];
#pragma unroll
    for (int m = 0; m < 8; ++m)
      a[m] = *(const bfrag8*)(G + (wv * 128 + m * 16 + l16) * 512 + kk + lk * 8);
#pragma unroll
    for (int n = 0; n < 4; ++n)
      bb[n] = *(const bfrag8*)(WB + (n * 16 + l16) * 512 + kk + lk * 8);
#pragma unroll
    for (int m = 0; m < 8; ++m)
#pragma unroll
      for (int n = 0; n < 4; ++n)
        mfma_bf16(acc[m][n], a[m], bb[n]);
  }
#pragma unroll
  for (int m = 0; m < 8; ++m)
#pragma unroll
    for (int n = 0; n < 4; ++n)
#pragma unroll
      for (int idx = 0; idx < 4; ++idx)
        RtS[(n * 16 + l16) * 520 + wv * 128 + m * 16 + lk * 4 + idx] =
            __float2bfloat16(acc[m][n][idx]);
  __syncthreads();

  // step B: S[64,64] = WA . Rt^T
  f32x4 acc2[4];
#pragma unroll
  for (int m = 0; m < 4; ++m) acc2[m] = f32x4{0.f, 0.f, 0.f, 0.f};
  for (int kk = 0; kk < 512; kk += 32) {
    bfrag8 a2[4];
#pragma unroll
    for (int m = 0; m < 4; ++m)
      a2[m] = *(const bfrag8*)(WA + (m * 16 + l16) * 512 + kk + lk * 8);
    const bfrag8 b2 = *(const bfrag8*)(&RtS[(wv * 16 + l16) * 520 + kk + lk * 8]);
#pragma unroll
    for (int m = 0; m < 4; ++m) mfma_bf16(acc2[m], a2[m], b2);
  }
  __syncthreads();
  float* S = (float*)RtS;  // [64][68]
#pragma unroll
  for (int m = 0; m < 4; ++m)
#pragma unroll
    for (int idx = 0; idx < 4; ++idx)
      S[(m * 16 + lk * 4 + idx) * 68 + wv * 16 + l16] = acc2[m][idx];
  __syncthreads();

  const int r = t >> 2, q = t & 3;   // r = d (query row), q*16+kq = e (key col)
  const float* bq_h = bq + i * 512 + h * 64;
  const float* bk_h = bk + i * 512 + h * 64;
  const float u_r = uv[r], bq_r = bq_h[r];
  float vals[16];
  float mx = -1e30f;
#pragma unroll
  for (int kq = 0; kq < 16; ++kq) {
    const int k = q * 16 + kq;
    float s = trans ? S[k * 68 + r] : S[r * 68 + k];
    s += u_r * bk_h[k] + bq_r * uv[64 + k] + 4096.0f * bq_r * bk_h[k];
    s *= 0.125f;
    vals[kq] = s;
    mx = fmaxf(mx, s);
  }
  mx = fmaxf(mx, __shfl_xor(mx, 1));
  mx = fmaxf(mx, __shfl_xor(mx, 2));
  float sum = 0.f;
#pragma unroll
  for (int kq = 0; kq < 16; ++kq) { vals[kq] = expf(vals[kq] - mx); sum += vals[kq]; }
  sum += __shfl_xor(sum, 1);
  sum += __shfl_xor(sum, 2);
  const float inv = 1.0f / sum;
  // transposed store into LDS: attT[e][d]
#pragma unroll
  for (int kq = 0; kq < 16; ++kq)
    attT[q * 16 + kq][r] = __float2bfloat16(vals[kq] * inv);
  __syncthreads();
  const int er = t >> 2, c16 = (t & 3) * 16;
  bf16* op = attnT + (((long)(i * 8 + b) * 8 + h) * 64 + er) * 64 + c16;
  *(bfrag8*)(op) = *(const bfrag8*)(&attT[er][c16]);
  *(bfrag8*)(op + 8) = *(const bfrag8*)(&attT[er][c16 + 8]);
}

// =================== mfold: M[c,ef] = sum_d Wo[c, h*64+d] * attnT[e,d]; mvec += M.bv ===================
__global__ __launch_bounds__(256, 2) void mfold_kernel(
    const bf16* __restrict__ woB, const bf16* __restrict__ attnT,
    const float* __restrict__ bv, bf16* __restrict__ Mbuf, float* __restrict__ mvec)
{
  __shared__ __align__(16) bf16 As[128 * 32];
  __shared__ __align__(16) bf16 Bs[64 * 32];
  const int ib = blockIdx.z;          // i*8+b
  const int i = ib >> 3;
  const int h = blockIdx.y;
  const bf16* A = woB + (long)i * 262144 + h * 64;
  const bf16* Bt = attnT + ((long)ib * 8 + h) * 4096;
  f32x4 acc[4][2];
#pragma unroll
  for (int m = 0; m < 4; ++m)
#pragma unroll
    for (int n = 0; n < 2; ++n)
      acc[m][n] = f32x4{0.f, 0.f, 0.f, 0.f};
  const long m0 = (long)blockIdx.x * 128;
  gemm_core<128, 64>(A, 512, Bt, 64, 64, m0, 0, As, Bs, acc);

  const int t = threadIdx.x;
  const int lane = t & 63, wv = t >> 6;
  const int wr = wv >> 1, wc = wv & 1;
  const int l16 = lane & 15, lk = lane >> 4;
  bf16* C = Mbuf + (long)ib * 262144;
  const float* bvp = bv + i * 512 + h * 64;
  float mp[4][4];
#pragma unroll
  for (int m = 0; m < 4; ++m)
#pragma unroll
    for (int i2 = 0; i2 < 4; ++i2) mp[m][i2] = 0.f;
#pragma unroll
  for (int m = 0; m < 4; ++m) {
    const long gr0 = m0 + wr * 64 + m * 16 + lk * 4;
#pragma unroll
    for (int n = 0; n < 2; ++n) {
      const int gc = wc * 32 + n * 16 + l16;
      const float bvv = bvp[gc];
#pragma unroll
      for (int i2 = 0; i2 < 4; ++i2) {
        C[(gr0 + i2) * 512 + h * 64 + gc] = __float2bfloat16(acc[m][n][i2]);
        mp[m][i2] += acc[m][n][i2] * bvv;
      }
    }
  }
#pragma unroll
  for (int m = 0; m < 4; ++m)
#pragma unroll
    for (int i2 = 0; i2 < 4; ++i2) {
      float v = mp[m][i2];
      v += __shfl_xor(v, 1); v += __shfl_xor(v, 2);
      v += __shfl_xor(v, 4); v += __shfl_xor(v, 8);
      if (l16 == 0)
        atomicAdd(&mvec[(long)ib * 512 + m0 + wr * 64 + m * 16 + lk * 4 + i2], v);
    }
}

// =================== weff: W_eff[c,cin] = sum_ef M[c,ef] * wvT[cin,ef] ===================
__global__ __launch_bounds__(256, 2) void weff_gemm(
    const bf16* __restrict__ Mbuf, const bf16* __restrict__ wvT,
    bf16* __restrict__ Weff)
{
  __shared__ __align__(16) bf16 As[128 * 32];
  __shared__ __align__(16) bf16 Bs[128 * 32];
  const int ib = blockIdx.z;
  const int i = ib >> 3;
  f32x4 acc[4][4];
#pragma unroll
  for (int m = 0; m < 4; ++m)
#pragma unroll
    for (int n = 0; n < 4; ++n)
      acc[m][n] = f32x4{0.f, 0.f, 0.f, 0.f};
  const long m0 = (long)blockIdx.x * 128, n0 = (long)blockIdx.y * 128;
  gemm_core<128, 128>(Mbuf + (long)ib * 262144, 512, wvT + (long)i * 262144, 512,
                      512, m0, n0, As, Bs, acc);
  bf16* C = Weff + (long)ib * 262144;
  const int t = threadIdx.x;
  const int lane = t & 63, wv = t >> 6;
  const int wr = wv >> 1, wc = wv & 1;
  const int l16 = lane & 15, lk = lane >> 4;
#pragma unroll
  for (int m = 0; m < 4; ++m) {
    const long gr0 = m0 + wr * 64 + m * 16 + lk * 4;
#pragma unroll
    for (int n = 0; n < 4; ++n) {
      const long gc = n0 + wc * 64 + n * 16 + l16;
#pragma unroll
      for (int i2 = 0; i2 < 4; ++i2)
        C[(gr0 + i2) * 512 + gc] = __float2bfloat16(acc[m][n][i2]);
    }
  }
}

// ======= cross: cross[qm][b*4096+p, c] bf16 = sum_i xT[km(i)][b].Weff_i^T + bias + residT; SE pool =======
__global__ __launch_bounds__(256, 2) void cross_gemm(
    const bf16* __restrict__ xT, const bf16* __restrict__ Weff,
    bf16* __restrict__ crossB, const float* __restrict__ bo2,
    const float* __restrict__ mvec, float* __restrict__ pooled)
{
  __shared__ __align__(16) bf16 As[128 * 32];
  __shared__ __align__(16) bf16 Bs[128 * 32];
  const int z = blockIdx.z;           // qm*8 + b
  const int qm = z >> 3, b = z & 7;
  const int KM0[3] = {1, 0, 0}, KM1[3] = {2, 2, 1};
  const bf16* A0 = xT + (long)KM0[qm] * 16777216 + (long)b * 2097152;
  const bf16* A1 = xT + (long)KM1[qm] * 16777216 + (long)b * 2097152;
  const bf16* B0 = Weff + ((long)(2 * qm) * 8 + b) * 262144;
  const bf16* B1 = Weff + ((long)(2 * qm + 1) * 8 + b) * 262144;
  const bf16* residT = xT + (long)qm * 16777216;   // bf16 NHWC residual
  bf16* Cb = crossB + (long)qm * 16777216;
  f32x4 acc[4][4];
#pragma unroll
  for (int m = 0; m < 4; ++m)
#pragma unroll
    for (int n = 0; n < 4; ++n)
      acc[m][n] = f32x4{0.f, 0.f, 0.f, 0.f};
  long m0, n0;
  swz_mn(4, m0, n0);
  gemm_core<128, 128>(A0, 512, B0, 512, 512, m0, n0, As, Bs, acc);
  gemm_core<128, 128>(A1, 512, B1, 512, 512, m0, n0, As, Bs, acc);

  const int t = threadIdx.x;
  const int lane = t & 63, wv = t >> 6;
  const int wr = wv >> 1, wc = wv & 1;
  const int l16 = lane & 15, lk = lane >> 4;
  const float* mv0 = mvec + ((long)(2 * qm) * 8 + b) * 512;
  const float* mv1 = mvec + ((long)(2 * qm + 1) * 8 + b) * 512;
  float csum[4] = {0.f, 0.f, 0.f, 0.f};
#pragma unroll
  for (int m = 0; m < 4; ++m) {
    const long p = m0 + wr * 64 + m * 16 + lk * 4;      // pixel within batch [0,4096)
    const long gr0 = (long)b * 4096 + p;
#pragma unroll
    for (int n = 0; n < 4; ++n) {
      const long gc = n0 + wc * 64 + n * 16 + l16;
      const float bb = bo2[qm * 512 + gc] + mv0[gc] + mv1[gc];
#pragma unroll
      for (int i2 = 0; i2 < 4; ++i2) {
        const float rv = __bfloat162float(residT[(gr0 + i2) * 512 + gc]);
        const float o = acc[m][n][i2] + bb + rv;
        Cb[(gr0 + i2) * 512 + gc] = __float2bfloat16(o);
        csum[n] += o;
      }
    }
  }
#pragma unroll
  for (int n = 0; n < 4; ++n) {
    float s = csum[n];
    s += __shfl_xor(s, 16);
    s += __shfl_xor(s, 32);
    if (lane < 16) {
      const long gc = n0 + wc * 64 + n * 16 + l16;
      atomicAdd(&pooled[((long)qm * 8 + b) * 512 + gc], s);
    }
  }
}

// =================== fusion GEMM: out[b][o][p] = Fw . weighted (LDS-staged coalesced write) ===================
__global__ __launch_bounds__(256, 2) void fusion_gemm(
    const bf16* __restrict__ A, const bf16* __restrict__ Bt,
    float* __restrict__ Cf, const float* __restrict__ bias)
{
  __shared__ __align__(16) bf16 As[128 * 32];
  __shared__ __align__(16) bf16 Bs[128 * 32];
  __shared__ float stg[16][132];
  f32x4 acc[4][4];
#pragma unroll
  for (int m = 0; m < 4; ++m)
#pragma unroll
    for (int n = 0; n < 4; ++n)
      acc[m][n] = f32x4{0.f, 0.f, 0.f, 0.f};
  long m0, n0;
  swz_mn(12, m0, n0);
  gemm_core<128, 128>(A, 1536, Bt, 1536, 1536, m0, n0, As, Bs, acc);

  const int t = threadIdx.x;
  const int lane = t & 63, wv = t >> 6;
  const int wr = wv >> 1, wc = wv & 1;
  const int l16 = lane & 15, lk = lane >> 4;
  const long bB = m0 >> 12;          // 4096 % 128 == 0 -> whole tile in one batch
  const long pbase = m0 & 4095;
  const int ch = t >> 4, idx = t & 15;
#pragma unroll
  for (int ci = 0; ci < 8; ++ci) {
    __syncthreads();
    if (wc == (ci >> 2)) {
      const int n = ci & 3;
      const float bb = bias[n0 + ci * 16 + l16];
#pragma unroll
      for (int m = 0; m < 4; ++m)
#pragma unroll
        for (int i = 0; i < 4; ++i)
          stg[l16][wr * 64 + m * 16 + lk * 4 + i] = acc[m][n][i] + bb;
    }
    __syncthreads();
    const long gc = n0 + ci * 16 + ch;
    float* dst = Cf + bB * 6291456L + gc * 4096L + pbase + idx * 8;
    *(float4*)(dst) = *(float4*)&stg[ch][idx * 8];
    *(float4*)(dst + 4) = *(float4*)&stg[ch][idx * 8 + 4];
  }
}

// =================== SE MLP ===================
__global__ __launch_bounds__(512) void se_mlp(
    const float* __restrict__ pooled,
    const float* __restrict__ W1, const float* __restrict__ b1,
    const float* __restrict__ W2, const float* __restrict__ b2,
    float* __restrict__ se)
{
  const int b = blockIdx.x, m = blockIdx.y;
  __shared__ float y[32];
  const int t = threadIdx.x;
  if (t < 32) {
    float s = b1[m * 32 + t];
    const float* w = W1 + (long)(m * 32 + t) * 512;
    const float* p = pooled + ((long)m * 8 + b) * 512;
    for (int c = 0; c < 512; ++c) s += w[c] * (p[c] * (1.0f / 4096.0f));
    y[t] = fmaxf(s, 0.0f);
  }
  __syncthreads();
  float s = b2[m * 512 + t];
  const float* w2 = W2 + (long)(m * 512 + t) * 32;
#pragma unroll
  for (int j = 0; j < 32; ++j) s += w2[j] * y[j];
  se[((long)m * 8 + b) * 512 + t] = 1.0f / (1.0f + expf(-s));
}

// ========= refined = l2norm_c(cross*se); alpha = sigmoid(gate); weighted out (fused) =========
__global__ __launch_bounds__(384) void refine_gate(
    const bf16* __restrict__ cr0, const bf16* __restrict__ cr1,
    const bf16* __restrict__ cr2, const float* __restrict__ se,
    const float* __restrict__ gw, const float* __restrict__ gb,
    const float* __restrict__ qacc, bf16* __restrict__ weighted)
{
  __shared__ float part[2][3][3];
  const int t = threadIdx.x, wv = t >> 6, lane = t & 63;
  const int px_i = (wv >= 3) ? 1 : 0;
  const int m = wv - px_i * 3;
  const int pix = blockIdx.x * 2 + px_i;
  const int b = pix >> 12;
  const bf16* cr = (m == 0) ? cr0 : (m == 1) ? cr1 : cr2;
  const int c0 = lane * 8;
  const bfrag8 v8 = *(const bfrag8*)(cr + (long)pix * 512 + c0);
  const float* sp = se + ((long)m * 8 + b) * 512 + c0;
  const float4 s0 = *(const float4*)(sp);
  const float4 s1 = *(const float4*)(sp + 4);
  float w[8] = {bf2f(v8[0]) * s0.x, bf2f(v8[1]) * s0.y,
                bf2f(v8[2]) * s0.z, bf2f(v8[3]) * s0.w,
                bf2f(v8[4]) * s1.x, bf2f(v8[5]) * s1.y,
                bf2f(v8[6]) * s1.z, bf2f(v8[7]) * s1.w};
  float ss = 0.f;
#pragma unroll
  for (int i = 0; i < 8; ++i) ss += w[i] * w[i];
  for (int o = 32; o; o >>= 1) ss += __shfl_xor(ss, o);
  const float inv = 1.0f / (sqrtf(ss) + 1e-6f);
  float rf[8];
#pragma unroll
  for (int i = 0; i < 8; ++i) rf[i] = w[i] * inv;

  float a0 = 0.f, a1 = 0.f, a2 = 0.f;
#pragma unroll
  for (int i = 0; i < 8; ++i) {
    const int c = m * 512 + c0 + i;
    a0 += gw[c] * rf[i];
    a1 += gw[1539 + c] * rf[i];
    a2 += gw[3078 + c] * rf[i];
  }
  for (int o = 32; o; o >>= 1) {
    a0 += __shfl_xor(a0, o); a1 += __shfl_xor(a1, o); a2 += __shfl_xor(a2, o);
  }
  if (lane == 0) {
    part[px_i][m][0] = a0; part[px_i][m][1] = a1; part[px_i][m][2] = a2;
  }
  __syncthreads();
  const float N = 2097152.0f;
  const float q0 = qacc[b * 4 + 0] / N;
  const float q1 = (qacc[b * 4 + 2] - qacc[b * 4 + 1] * qacc[b * 4 + 1] / N) / (N - 1.0f);
  const float q2 = qacc[b * 4 + 3] / N;
  const float sg = part[px_i][0][m] + part[px_i][1][m] + part[px_i][2][m] + gb[m] +
                   gw[m * 1539 + 1536] * q0 + gw[m * 1539 + 1537] * q1 +
                   gw[m * 1539 + 1538] * q2;
  const float al = 1.0f / (1.0f + expf(-sg));
  __align__(16) bf16 tmp[8];
#pragma unroll
  for (int i = 0; i < 8; ++i) tmp[i] = __float2bfloat16(rf[i] * al);
  *(bfrag8*)(weighted + (long)pix * 1536 + m * 512 + c0) = *(const bfrag8*)tmp;
}

// =================== host launch ===================
extern "C" void kernel_launch(void* const* d_in, const int* in_sizes, int n_in,
                              void* d_out, int out_size, void* d_ws, size_t ws_size,
                              hipStream_t stream)
{
  (void)in_sizes; (void)n_in; (void)out_size; (void)ws_size;
  const float* rgb   = (const float*)d_in[0];
  const float* depth = (const float*)d_in[1];
  const float* lidar = (const float*)d_in[2];
  const float* wq  = (const float*)d_in[3];
  const float* bq  = (const float*)d_in[4];
  const float* wk  = (const float*)d_in[5];
  const float* bk  = (const float*)d_in[6];
  const float* wvw = (const float*)d_in[7];
  const float* bv  = (const float*)d_in[8];
  const float* wo  = (const float*)d_in[9];
  const float* bo  = (const float*)d_in[10];
  const float* seW1 = (const float*)d_in[11];
  const float* seb1 = (const float*)d_in[12];
  const float* seW2 = (const float*)d_in[13];
  const float* seb2 = (const float*)d_in[14];
  const float* gw  = (const float*)d_in[15];
  const float* gb  = (const float*)d_in[16];
  const float* fw  = (const float*)d_in[17];
  const float* fb  = (const float*)d_in[18];

  char* ws = (char*)d_ws;
  bf16*  xT   = (bf16*)(ws + OFF_XT);
  bf16*  xC   = (bf16*)(ws + OFF_XC);
  bf16*  wqB  = (bf16*)(ws + OFF_WQ);
  bf16*  wkB  = (bf16*)(ws + OFF_WK);
  bf16*  wvT  = (bf16*)(ws + OFF_WVT);
  bf16*  woB  = (bf16*)(ws + OFF_WOB);
  bf16*  fwB  = (bf16*)(ws + OFF_FW);
  float* bo2  = (float*)(ws + OFF_BO2);
  float* pooled = (float*)(ws + OFF_POOL);
  float* seB  = (float*)(ws + OFF_SE);
  float* qacc = (float*)(ws + OFF_QACC);
  float* cs   = (float*)(ws + OFF_CS);
  bf16*  Gb   = (bf16*)(ws + OFF_GB);
  bf16*  attnT = (bf16*)(ws + OFF_ATT);
  float* qstage = (float*)(ws + OFF_QST);
  float* mvec = (float*)(ws + OFF_MVEC);
  bf16*  Mbuf = (bf16*)(ws + OFF_XC);              // alias, dead after weff
  bf16*  Weff = (bf16*)(ws + OFF_XC + 25165824L);  // alias, dead after cross
  bf16*  crossB = (bf16*)(ws + OFF_VST);

  // zero: pooled (+se, qacc harmlessly), colsum ; mvec
  (void)hipMemsetAsync(ws + OFF_POOL, 0, OFF_CS + 49152 - OFF_POOL, stream);
  (void)hipMemsetAsync(ws + OFF_MVEC, 0, 98304, stream);

  transpose_kernel<<<dim3(128, 16, 24), dim3(32, 8), 0, stream>>>(rgb, depth, lidar,
                                                                  xT, xC, cs, qstage);
  quality_reduce<<<24, 256, 0, stream>>>(qstage, qacc);
  prep_weights<<<2048, 256, 0, stream>>>(wq, wk, wvw, wo, fw, bo,
                                         wqB, wkB, wvT, woB, fwB, bo2);

  gram_kernel<<<dim3(4, 4, 24), 256, 0, stream>>>(xC, Gb);
  scores_kernel<<<dim3(8, 8, 6), 256, 0, stream>>>(wqB, wkB, Gb, cs, bq, bk, attnT);

  mfold_kernel<<<dim3(4, 8, 48), 256, 0, stream>>>(woB, attnT, bv, Mbuf, mvec);
  weff_gemm<<<dim3(4, 4, 48), 256, 0, stream>>>(Mbuf, wvT, Weff);

  cross_gemm<<<dim3(32, 4, 24), 256, 0, stream>>>(xT, Weff, crossB, bo2, mvec, pooled);
  se_mlp<<<dim3(8, 3), 512, 0, stream>>>(pooled, seW1, seb1, seW2, seb2, seB);

  bf16* cross0 = crossB;
  bf16* cross1 = (bf16*)(ws + OFF_VST + 33554432L);
  bf16* cross2 = (bf16*)(ws + OFF_VST + 67108864L);
  bf16* weighted = (bf16*)(ws + OFF_XC);
  refine_gate<<<16384, 384, 0, stream>>>(cross0, cross1, cross2, seB, gw, gb, qacc, weighted);

  fusion_gemm<<<dim3(256, 12), 256, 0, stream>>>(weighted, fwB, (float*)d_out, fb);
}

// Round 7
// 924.768 us; speedup vs baseline: 1.6444x; 1.0107x over previous
//
#include <hip/hip_runtime.h>
#include <hip/hip_bf16.h>
#include <stdint.h>

using bf16 = __hip_bfloat16;
typedef short bfrag8 __attribute__((ext_vector_type(8)));
typedef float f32x4 __attribute__((ext_vector_type(4)));

// ---------------- workspace layout (bytes) ----------------
constexpr long OFF_XT   = 0L;           // 3 x [32768][512] bf16 NHWC (live until cross_gemm)
constexpr long OFF_XC   = 100663296L;   // 3 x [512][32768] bf16 channel-major (dead after gram)
constexpr long OFF_WQ   = 201326592L;   // 6 x [512][512] bf16
constexpr long OFF_WK   = 204472320L;
constexpr long OFF_WVT  = 207618048L;   // 6 x [cin 512][ef 512] bf16 (Wv transposed)
constexpr long OFF_WOB  = 210763776L;   // 6 x [512][512] bf16 (Wo plain)
constexpr long OFF_FW   = 213909504L;   // [1536][1536] bf16
constexpr long OFF_BO2  = 218628096L;   // [3][512] f32
constexpr long OFF_POOL = 218646528L;   // [3][8][512] f32   (memset from here)
constexpr long OFF_SE   = 218695680L;   // [3][8][512] f32
constexpr long OFF_QACC = 218744832L;   // [8][4] f32 (+pad to 1024)
constexpr long OFF_CS   = 218745856L;   // [3][8][512] f32 column sums (memset to here+49152)
constexpr long OFF_GB   = 218795008L;   // [3][8][512][512] bf16 Gram
constexpr long OFF_ATT  = 231377920L;   // attnT [6][8][8][64(e)][64(d)] bf16
constexpr long OFF_VST  = 234523648L;   // cross bf16 3 x [32768][512] (96 MB)
constexpr long OFF_QST  = 435850240L;   // [24][2048][2] f32 quality partials
constexpr long OFF_MVEC = 436243456L;   // [48][512] f32 (memset)
// aliases in XC region: Mbuf = OFF_XC, Weff = OFF_XC+25165824 ; weighted = OFF_XC after dead

__device__ __forceinline__ void mfma_bf16(f32x4& c, bfrag8 a, bfrag8 b) {
  asm("v_mfma_f32_16x16x32_bf16 %0, %1, %2, %0" : "+v"(c) : "v"(a), "v"(b));
}

__device__ __forceinline__ void gload16(const void* g, void* l) {
  __builtin_amdgcn_global_load_lds(
      (__attribute__((address_space(1))) void*)(g),
      (__attribute__((address_space(3))) void*)(l), 16, 0, 0);
}

__device__ __forceinline__ float bf2f(short s) {
  union { uint32_t u; float f; } cv;
  cv.u = ((uint32_t)(unsigned short)s) << 16;
  return cv.f;
}

// ============================================================================
// 256x256 8-phase GEMM core (T2 XOR-swizzle + T3/T4 counted vmcnt + T5 setprio)
// 512 threads = 8 waves (2M x 4N). Per-wave out: 128x64 (4 quadrant strips).
// LDS: [parity2][half2][128 rows][64 k] bf16 for A (64KB) then B (64KB).
// Phase q reads halves (ah,bh): (0,1),(1,1),(1,0),(0,0).
// Stage ledger (per 8-phase iter, K-tiles e=2i, o=2i+1):
//   p0: (o).A0  p1: (o).B0  p2: (e+2).B1  p3: (e+2).A1 +vmcnt(4)
//   p4: (e+2).A0  p5: (e+2).B0  p6: (o+2).B1  p7: (o+2).A1 +vmcnt(4)
// vmcnt(4) retires everything but the newest 2 halves -> next K-tile landed.
// ============================================================================
#define SWZ_OFF(r, kb) ((kb) ^ (((r) & 7) << 4))

__device__ __forceinline__ void bar256() {
  __builtin_amdgcn_sched_barrier(0);
  __builtin_amdgcn_s_barrier();
  __builtin_amdgcn_sched_barrier(0);
}

__device__ __forceinline__ void stage_half(const bf16* __restrict__ g, long ldg,
                                           char* slot, int t) {
#pragma unroll
  for (int j = 0; j < 2; ++j) {
    const int L = t * 16 + j * 8192;
    const int r = L >> 7;
    const int kb = (L & 127) ^ ((r & 7) << 4);   // inverse-swizzled source chunk
    gload16(g + (long)r * ldg + (kb >> 1), slot + L);
  }
}

template<int NSEG, int NTSEG>
__device__ __forceinline__ void gemm256_core(
    const bf16* const* Aseg, long lda,
    const bf16* const* Bseg, long ldb,
    long m0, long n0, char* sm, f32x4 (&acc)[4][4][2])
{
  constexpr int NT = NSEG * NTSEG;
  const int t = threadIdx.x;
  const int lane = t & 63, wid = t >> 6;
  const int wm = wid >> 2, wn = wid & 3;
  const int l16 = lane & 15, lk = lane >> 4;

  auto STAGE = [&](int mat, int hf, int kt) {
    int ktw = (kt >= NT) ? kt - NT : kt;   // wrap: garbage data into dead slot, keeps vmcnt exact
    const int seg = ktw / NTSEG, ktt = ktw % NTSEG;
    const int kp = ktw & 1;
    if (mat == 0)
      stage_half(Aseg[seg] + (m0 + (long)hf * 128) * lda + ktt * 64, lda,
                 sm + (kp * 2 + hf) * 16384, t);
    else
      stage_half(Bseg[seg] + (n0 + (long)hf * 128) * ldb + ktt * 64, ldb,
                 sm + 65536 + (kp * 2 + hf) * 16384, t);
  };

  // prologue: K-tile0 all 4 halves; K-tile1 B1+A1
  STAGE(0, 0, 0); STAGE(0, 1, 0); STAGE(1, 0, 0); STAGE(1, 1, 0);
  STAGE(1, 1, 1); STAGE(0, 1, 1);
  __builtin_amdgcn_sched_barrier(0);
  asm volatile("s_waitcnt vmcnt(4)" ::: "memory");
  bar256();

  constexpr int s_ah[4] = {0, 1, 1, 0};
  constexpr int s_bh[4] = {1, 1, 0, 0};
  constexpr int s_mat[8] = {0, 1, 1, 0, 0, 1, 1, 0};
  constexpr int s_hf[8]  = {0, 0, 1, 1, 0, 0, 1, 1};
  constexpr int s_dkt[8] = {1, 1, 2, 2, 2, 2, 3, 3};

  for (int i = 0; i < NT / 2; ++i) {
#pragma unroll
    for (int p = 0; p < 8; ++p) {
      const int q = p & 3, kp = p >> 2;
      const int ah = s_ah[q], bh = s_bh[q];
      const char* Ab = sm + (kp * 2 + ah) * 16384;
      const char* Bb = sm + 65536 + (kp * 2 + bh) * 16384;
      bfrag8 af[4][2], bfr[2][2];
#pragma unroll
      for (int mf = 0; mf < 4; ++mf) {
        const int rowA = wm * 64 + mf * 16 + l16;
#pragma unroll
        for (int ks = 0; ks < 2; ++ks)
          af[mf][ks] = *(const bfrag8*)(Ab + rowA * 128 + SWZ_OFF(rowA, ks * 64 + lk * 16));
      }
#pragma unroll
      for (int nf = 0; nf < 2; ++nf) {
        const int rowB = wn * 32 + nf * 16 + l16;
#pragma unroll
        for (int ks = 0; ks < 2; ++ks)
          bfr[nf][ks] = *(const bfrag8*)(Bb + rowB * 128 + SWZ_OFF(rowB, ks * 64 + lk * 16));
      }
      STAGE(s_mat[p], s_hf[p], 2 * i + s_dkt[p]);
      bar256();
      __builtin_amdgcn_s_setprio(1);
#pragma unroll
      for (int ks = 0; ks < 2; ++ks)
#pragma unroll
        for (int mf = 0; mf < 4; ++mf)
#pragma unroll
          for (int nf = 0; nf < 2; ++nf)
            mfma_bf16(acc[q][mf][nf], af[mf][ks], bfr[nf][ks]);
      __builtin_amdgcn_s_setprio(0);
      if (p == 3 || p == 7) {
        __builtin_amdgcn_sched_barrier(0);
        asm volatile("s_waitcnt vmcnt(4)" ::: "memory");
      }
      bar256();
    }
  }
}

// =================== fusion GEMM (256² 8-phase): out f32 NCHW ===================
__global__ __launch_bounds__(512, 2) void fusion_gemm256(
    const bf16* __restrict__ A, const bf16* __restrict__ Bt,
    float* __restrict__ Cf, const float* __restrict__ bias)
{
  __shared__ __align__(16) char sm[131072];
  const int orig = blockIdx.y * 128 + blockIdx.x;     // grid (128, 6)
  const int wgid = (orig & 7) * 96 + (orig >> 3);
  const long m0 = (long)(wgid / 6) * 256;
  const long n0 = (long)(wgid % 6) * 256;
  f32x4 acc[4][4][2];
#pragma unroll
  for (int q = 0; q < 4; ++q)
#pragma unroll
    for (int mf = 0; mf < 4; ++mf)
#pragma unroll
      for (int nf = 0; nf < 2; ++nf)
        acc[q][mf][nf] = f32x4{0.f, 0.f, 0.f, 0.f};
  const bf16* Aseg[1] = {A};
  const bf16* Bseg[1] = {Bt};
  gemm256_core<1, 24>(Aseg, 1536, Bseg, 1536, m0, n0, sm, acc);

  const int t = threadIdx.x;
  const int lane = t & 63, wid = t >> 6;
  const int wm = wid >> 2, wn = wid & 3;
  const int l16 = lane & 15, lk = lane >> 4;
  constexpr int s_ah[4] = {0, 1, 1, 0};
  constexpr int s_bh[4] = {1, 1, 0, 0};
  const long b = m0 >> 12;
#pragma unroll
  for (int q = 0; q < 4; ++q) {
    const int ah = s_ah[q], bh = s_bh[q];
#pragma unroll
    for (int mf = 0; mf < 4; ++mf) {
      const long row = m0 + ah * 128 + wm * 64 + mf * 16 + lk * 4;
      const long p = row & 4095;
#pragma unroll
      for (int nf = 0; nf < 2; ++nf) {
        const long gc = n0 + bh * 128 + wn * 32 + nf * 16 + l16;
        const float bb = bias[gc];
        float4 o4;
        o4.x = acc[q][mf][nf][0] + bb; o4.y = acc[q][mf][nf][1] + bb;
        o4.z = acc[q][mf][nf][2] + bb; o4.w = acc[q][mf][nf][3] + bb;
        *(float4*)(Cf + b * 6291456L + gc * 4096L + p) = o4;
      }
    }
  }
}

// ====== cross GEMM (256² 8-phase, 2-segment K): bf16 out + resid + SE pool ======
__global__ __launch_bounds__(512, 2) void cross_gemm256(
    const bf16* __restrict__ xT, const bf16* __restrict__ Weff,
    bf16* __restrict__ crossB, const float* __restrict__ bo2,
    const float* __restrict__ mvec, float* __restrict__ pooled)
{
  __shared__ __align__(16) char sm[131072];
  const int z = blockIdx.z;             // qm*8 + b
  const int qm = z >> 3, b = z & 7;
  const int KM0[3] = {1, 0, 0}, KM1[3] = {2, 2, 1};
  const bf16* A0 = xT + (long)KM0[qm] * 16777216 + (long)b * 2097152;
  const bf16* A1 = xT + (long)KM1[qm] * 16777216 + (long)b * 2097152;
  const bf16* B0 = Weff + ((long)(2 * qm) * 8 + b) * 262144;
  const bf16* B1 = Weff + ((long)(2 * qm + 1) * 8 + b) * 262144;
  const int orig = blockIdx.y * 16 + blockIdx.x;   // grid (16, 2, 24)
  const int wgid = (orig & 7) * 4 + (orig >> 3);
  const long m0 = (long)(wgid >> 1) * 256;
  const long n0 = (long)(wgid & 1) * 256;
  f32x4 acc[4][4][2];
#pragma unroll
  for (int q = 0; q < 4; ++q)
#pragma unroll
    for (int mf = 0; mf < 4; ++mf)
#pragma unroll
      for (int nf = 0; nf < 2; ++nf)
        acc[q][mf][nf] = f32x4{0.f, 0.f, 0.f, 0.f};
  const bf16* Aseg[2] = {A0, A1};
  const bf16* Bseg[2] = {B0, B1};
  gemm256_core<2, 8>(Aseg, 512, Bseg, 512, m0, n0, sm, acc);

  const int t = threadIdx.x;
  const int lane = t & 63, wid = t >> 6;
  const int wm = wid >> 2, wn = wid & 3;
  const int l16 = lane & 15, lk = lane >> 4;
  constexpr int s_ah[4] = {0, 1, 1, 0};
  constexpr int s_bh[4] = {1, 1, 0, 0};
  const bf16* residT = xT + (long)qm * 16777216;
  bf16* Cb = crossB + (long)qm * 16777216;
  const float* mv0 = mvec + ((long)(2 * qm) * 8 + b) * 512;
  const float* mv1 = mvec + ((long)(2 * qm + 1) * 8 + b) * 512;
  float csum[2][2] = {{0.f, 0.f}, {0.f, 0.f}};
#pragma unroll
  for (int q = 0; q < 4; ++q) {
    const int ah = s_ah[q], bh = s_bh[q];
#pragma unroll
    for (int mf = 0; mf < 4; ++mf) {
      const long row = m0 + ah * 128 + wm * 64 + mf * 16 + lk * 4;
      const long gr0 = (long)b * 4096 + row;
#pragma unroll
      for (int nf = 0; nf < 2; ++nf) {
        const long gc = n0 + bh * 128 + wn * 32 + nf * 16 + l16;
        const float bb = bo2[qm * 512 + gc] + mv0[gc] + mv1[gc];
#pragma unroll
        for (int i2 = 0; i2 < 4; ++i2) {
          const float rv = __bfloat162float(residT[(gr0 + i2) * 512 + gc]);
          const float o = acc[q][mf][nf][i2] + bb + rv;
          Cb[(gr0 + i2) * 512 + gc] = __float2bfloat16(o);
          csum[bh][nf] += o;
        }
      }
    }
  }
#pragma unroll
  for (int bh = 0; bh < 2; ++bh)
#pragma unroll
    for (int nf = 0; nf < 2; ++nf) {
      float s = csum[bh][nf];
      s += __shfl_xor(s, 16);
      s += __shfl_xor(s, 32);
      if (lk == 0) {
        const long gc = n0 + bh * 128 + wn * 32 + nf * 16 + l16;
        atomicAdd(&pooled[((long)qm * 8 + b) * 512 + gc], s);
      }
    }
}

// ============ transpose + stats: NCHW f32 -> NHWC + channel-major bf16, colsum, quality ============
__global__ __launch_bounds__(256) void transpose_kernel(
    const float* __restrict__ x0, const float* __restrict__ x1,
    const float* __restrict__ x2, bf16* __restrict__ xT, bf16* __restrict__ xC,
    float* __restrict__ cs, float* __restrict__ qstage)
{
  __shared__ float tile[32][33];
  __shared__ float qpart[4][2];
  const int zz = blockIdx.z;           // m*8 + b
  const int m = zz >> 3, b = zz & 7;
  const float* x = (m == 0) ? x0 : (m == 1) ? x1 : x2;
  bf16* y = xT + (long)m * 16777216;
  bf16* y2 = xC + (long)m * 16777216;
  const int p0 = blockIdx.x * 32, c0 = blockIdx.y * 32;
  const int tx = threadIdx.x, ty = threadIdx.y;
  float csp[4];
  float qa = 0.f, qb_ = 0.f;   // m==0 (rgb): sum,ssq ; else: zero-count in qa
#pragma unroll
  for (int j = 0; j < 4; ++j) {
    const float v = x[((long)b * 512 + c0 + ty + j * 8) * 4096 + p0 + tx];
    tile[ty + j * 8][tx] = v;
    y2[(long)(c0 + ty + j * 8) * 32768 + (long)b * 4096 + p0 + tx] = __float2bfloat16(v);
    csp[j] = v;
    if (m == 0) { qa += v; qb_ += v * v; }
    else qa += (v == 0.0f) ? 1.0f : 0.0f;
  }
  __syncthreads();
#pragma unroll
  for (int j = 0; j < 4; ++j)
    y[((long)b * 4096 + p0 + ty + j * 8) * 512 + c0 + tx] =
        __float2bfloat16(tile[tx][ty + j * 8]);
#pragma unroll
  for (int j = 0; j < 4; ++j) {
    float s = csp[j];
    for (int o = 16; o; o >>= 1) s += __shfl_xor(s, o);
    if (tx == 0) atomicAdd(&cs[(m * 8 + b) * 512 + c0 + ty + j * 8], s);
  }
  const int t = ty * 32 + tx;
  const int lane = t & 63;
  for (int o = 32; o; o >>= 1) { qa += __shfl_xor(qa, o); qb_ += __shfl_xor(qb_, o); }
  if (lane == 0) { qpart[t >> 6][0] = qa; qpart[t >> 6][1] = qb_; }
  __syncthreads();
  if (t == 0) {
    const float pa = qpart[0][0] + qpart[1][0] + qpart[2][0] + qpart[3][0];
    const float pb = qpart[0][1] + qpart[1][1] + qpart[2][1] + qpart[3][1];
    float* qs = qstage + ((long)zz * 2048 + blockIdx.y * 128 + blockIdx.x) * 2;
    qs[0] = pa; qs[1] = pb;
  }
}

// =================== quality partial reduce -> qacc ===================
__global__ __launch_bounds__(256) void quality_reduce(
    const float* __restrict__ qstage, float* __restrict__ qacc)
{
  __shared__ float pr[4][2];
  const int zz = blockIdx.x;  // m*8 + b
  const int m = zz >> 3, b = zz & 7;
  const int t = threadIdx.x;
  float sa = 0.f, sb = 0.f;
  for (int i = t; i < 2048; i += 256) {
    sa += qstage[((long)zz * 2048 + i) * 2];
    sb += qstage[((long)zz * 2048 + i) * 2 + 1];
  }
  for (int o = 32; o; o >>= 1) { sa += __shfl_xor(sa, o); sb += __shfl_xor(sb, o); }
  if ((t & 63) == 0) { pr[t >> 6][0] = sa; pr[t >> 6][1] = sb; }
  __syncthreads();
  if (t == 0) {
    sa = pr[0][0] + pr[1][0] + pr[2][0] + pr[3][0];
    sb = pr[0][1] + pr[1][1] + pr[2][1] + pr[3][1];
    if (m == 0) { qacc[b * 4 + 1] = sa; qacc[b * 4 + 2] = sb; }
    else if (m == 1) qacc[b * 4 + 0] = sa;
    else qacc[b * 4 + 3] = sa;
  }
}

// =================== weight conversion ===================
__global__ void prep_weights(
    const float* __restrict__ wq, const float* __restrict__ wk,
    const float* __restrict__ wv, const float* __restrict__ wo,
    const float* __restrict__ fw, const float* __restrict__ bo,
    bf16* __restrict__ wqB, bf16* __restrict__ wkB, bf16* __restrict__ wvT,
    bf16* __restrict__ woB, bf16* __restrict__ fwB, float* __restrict__ bo2)
{
  const long stride = (long)gridDim.x * blockDim.x;
  for (long j = (long)blockIdx.x * blockDim.x + threadIdx.x; j < 2359296; j += stride) {
    fwB[j] = __float2bfloat16(fw[j]);
    if (j < 1572864) {
      wqB[j] = __float2bfloat16(wq[j]);
      wkB[j] = __float2bfloat16(wk[j]);
      woB[j] = __float2bfloat16(wo[j]);
      const long i = j >> 18, rem = j & 262143, cin = rem >> 9, ef = rem & 511;
      wvT[j] = __float2bfloat16(wv[(i << 18) + (ef << 9) + cin]);
    }
    if (j < 1536) {
      const long m2 = j >> 9, cc = j & 511;
      bo2[j] = bo[((m2 * 2) << 9) + cc] + bo[((m2 * 2 + 1) << 9) + cc];
    }
  }
}

// =================== 128² GEMM core (m97-style, for small GEMMs) ===================
template<int BM, int BN>
__device__ __forceinline__ void gemm_core(
    const bf16* __restrict__ A, long lda,
    const bf16* __restrict__ Bt, long ldb,
    int K, long m0, long n0,
    bf16* As, bf16* Bs, f32x4 (&acc)[BM / 32][BN / 32])
{
  constexpr int WM = BM / 2, WN = BN / 2, FM = BM / 32, FN = BN / 32;
  const int t = threadIdx.x;
  const int lane = t & 63, wv = t >> 6;
  const int wr = wv >> 1, wc = wv & 1;
  const int l16 = lane & 15, lk = lane >> 4;
  const int srow = t >> 2;
  const int scol = (t & 3) * 8;
  const bf16* Ag = A + (m0 + srow) * lda + scol;
  const bf16* Bg = Bt + (n0 + srow) * ldb + scol;
  char* AsB = (char*)As;
  char* BsB = (char*)Bs;
  const int aoff = wv * 1024;
  for (int kk = 0; kk < K; kk += 32) {
#pragma unroll
    for (int it = 0; it < BM / 64; ++it)
      gload16(Ag + (long)it * 64 * lda + kk, AsB + it * 4096 + aoff);
#pragma unroll
    for (int it = 0; it < BN / 64; ++it)
      gload16(Bg + (long)it * 64 * ldb + kk, BsB + it * 4096 + aoff);
    __syncthreads();
    bfrag8 af[FM], bfr[FN];
#pragma unroll
    for (int m = 0; m < FM; ++m)
      af[m] = *(const bfrag8*)(AsB + ((wr * WM + m * 16 + l16) * 32 + lk * 8) * 2);
#pragma unroll
    for (int n = 0; n < FN; ++n)
      bfr[n] = *(const bfrag8*)(BsB + ((wc * WN + n * 16 + l16) * 32 + lk * 8) * 2);
#pragma unroll
    for (int m = 0; m < FM; ++m)
#pragma unroll
      for (int n = 0; n < FN; ++n)
        mfma_bf16(acc[m][n], af[m], bfr[n]);
    __syncthreads();
  }
}

// =================== Gram: G[i,j] = sum_p xA[p,i] xB[p,j], bf16 out ===================
__global__ __launch_bounds__(256, 2) void gram_kernel(
    const bf16* __restrict__ xC, bf16* __restrict__ Gb)
{
  __shared__ __align__(16) bf16 As[128 * 32];
  __shared__ __align__(16) bf16 Bs[128 * 32];
  const int z = blockIdx.z;
  const int pair = z >> 3, b = z & 7;
  const int A1[3] = {0, 0, 1}, A2[3] = {1, 2, 2};
  const bf16* A = xC + (long)A1[pair] * 16777216 + b * 4096;
  const bf16* Bt = xC + (long)A2[pair] * 16777216 + b * 4096;
  f32x4 acc[4][4];
#pragma unroll
  for (int m = 0; m < 4; ++m)
#pragma unroll
    for (int n = 0; n < 4; ++n)
      acc[m][n] = f32x4{0.f, 0.f, 0.f, 0.f};
  const long m0 = (long)blockIdx.x * 128, n0 = (long)blockIdx.y * 128;
  gemm_core<128, 128>(A, 32768, Bt, 32768, 4096, m0, n0, As, Bs, acc);
  bf16* C = Gb + (long)z * 262144;
  const int t = threadIdx.x;
  const int lane = t & 63, wv = t >> 6;
  const int wr = wv >> 1, wc = wv & 1;
  const int l16 = lane & 15, lk = lane >> 4;
#pragma unroll
  for (int m = 0; m < 4; ++m) {
    const long gr0 = m0 + wr * 64 + m * 16 + lk * 4;
#pragma unroll
    for (int n = 0; n < 4; ++n) {
      const long gc = n0 + wc * 64 + n * 16 + l16;
#pragma unroll
      for (int i = 0; i < 4; ++i)
        C[(gr0 + i) * 512 + gc] = __float2bfloat16(acc[m][n][i]);
    }
  }
}

// =================== scores+softmax -> attnT[e][d] ===================
__global__ __launch_bounds__(256, 2) void scores_kernel(
    const bf16* __restrict__ wqB, const bf16* __restrict__ wkB,
    const bf16* __restrict__ Gb, const float* __restrict__ colsum,
    const float* __restrict__ bq, const float* __restrict__ bk,
    bf16* __restrict__ attnT)
{
  __shared__ __align__(16) bf16 RtS[64 * 520];  // R^T bf16 ; later aliased as S f32 [64][68]
  __shared__ float uv[128];
  __shared__ __align__(16) bf16 attT[64][64];
  const int h = blockIdx.x, b = blockIdx.y, i = blockIdx.z;
  const int qm = i >> 1, jj = i & 1;
  const int km = jj ? (qm == 2 ? 1 : 2) : (qm == 0 ? 1 : 0);
  const int lo = qm < km ? qm : km, hi = qm < km ? km : qm;
  const int pair = lo + hi - 1;
  const int trans = qm > km;
  const bf16* G = Gb + ((long)(pair * 8 + b)) * 262144;
  const bf16* Wq_h = wqB + (long)i * 262144 + h * 64 * 512;
  const bf16* Wk_h = wkB + (long)i * 262144 + h * 64 * 512;
  const bf16* WA = trans ? Wk_h : Wq_h;
  const bf16* WB = trans ? Wq_h : Wk_h;
  const int t = threadIdx.x, lane = t & 63, wv = t >> 6;
  const int l16 = lane & 15, lk = lane >> 4;

  if (t < 128) {
    const int d = t & 63;
    const bf16* wrow = ((t < 64) ? Wq_h : Wk_h) + d * 512;
    const float* sv = colsum + (((t < 64) ? qm : km) * 8 + b) * 512;
    float a = 0.f;
    for (int c = 0; c < 512; c += 8) {
      const bfrag8 w8 = *(const bfrag8*)(wrow + c);
#pragma unroll
      for (int e = 0; e < 8; ++e) a += bf2f(w8[e]) * sv[c + e];
    }
    uv[t] = a;
  }

  // step A: R[512,64] = G . WB^T ; wave wv owns rows [wv*128, +128)
  f32x4 acc[8][4];
#pragma unroll
  for (int m = 0; m < 8; ++m)
#pragma unroll
    for (int n = 0; n < 4; ++n)
      acc[m][n] = f32x4{0.f, 0.f, 0.f, 0.f};
  for (int kk = 0; kk < 512; kk += 32) {
    bfrag8 a[8], bb[4];
#pragma unroll
    for (int m = 0; m < 8; ++m)
      a[m] = *(const bfrag8*)(G + (wv * 128 + m * 16 + l16) * 512 + kk + lk * 8);
#pragma unroll
    for (int n = 0; n < 4; ++n)
      bb[n] = *(const bfrag8*)(WB + (n * 16 + l16) * 512 + kk + lk * 8);
#pragma unroll
    for (int m = 0; m < 8; ++m)
#pragma unroll
      for (int n = 0; n < 4; ++n)
        mfma_bf16(acc[m][n], a[m], bb[n]);
  }
#pragma unroll
  for (int m = 0; m < 8; ++m)
#pragma unroll
    for (int n = 0; n < 4; ++n)
#pragma unroll
      for (int idx = 0; idx < 4; ++idx)
        RtS[(n * 16 + l16) * 520 + wv * 128 + m * 16 + lk * 4 + idx] =
            __float2bfloat16(acc[m][n][idx]);
  __syncthreads();

  // step B: S[64,64] = WA . Rt^T
  f32x4 acc2[4];
#pragma unroll
  for (int m = 0; m < 4; ++m) acc2[m] = f32x4{0.f, 0.f, 0.f, 0.f};
  for (int kk = 0; kk < 512; kk += 32) {
    bfrag8 a2[4];
#pragma unroll
    for (int m = 0; m < 4; ++m)
      a2[m] = *(const bfrag8*)(WA + (m * 16 + l16) * 512 + kk + lk * 8);
    const bfrag8 b2 = *(const bfrag8*)(&RtS[(wv * 16 + l16) * 520 + kk + lk * 8]);
#pragma unroll
    for (int m = 0; m < 4; ++m) mfma_bf16(acc2[m], a2[m], b2);
  }
  __syncthreads();
  float* S = (float*)RtS;  // [64][68]
#pragma unroll
  for (int m = 0; m < 4; ++m)
#pragma unroll
    for (int idx = 0; idx < 4; ++idx)
      S[(m * 16 + lk * 4 + idx) * 68 + wv * 16 + l16] = acc2[m][idx];
  __syncthreads();

  const int r = t >> 2, q = t & 3;   // r = d (query row), q*16+kq = e (key col)
  const float* bq_h = bq + i * 512 + h * 64;
  const float* bk_h = bk + i * 512 + h * 64;
  const float u_r = uv[r], bq_r = bq_h[r];
  float vals[16];
  float mx = -1e30f;
#pragma unroll
  for (int kq = 0; kq < 16; ++kq) {
    const int k = q * 16 + kq;
    float s = trans ? S[k * 68 + r] : S[r * 68 + k];
    s += u_r * bk_h[k] + bq_r * uv[64 + k] + 4096.0f * bq_r * bk_h[k];
    s *= 0.125f;
    vals[kq] = s;
    mx = fmaxf(mx, s);
  }
  mx = fmaxf(mx, __shfl_xor(mx, 1));
  mx = fmaxf(mx, __shfl_xor(mx, 2));
  float sum = 0.f;
#pragma unroll
  for (int kq = 0; kq < 16; ++kq) { vals[kq] = expf(vals[kq] - mx); sum += vals[kq]; }
  sum += __shfl_xor(sum, 1);
  sum += __shfl_xor(sum, 2);
  const float inv = 1.0f / sum;
#pragma unroll
  for (int kq = 0; kq < 16; ++kq)
    attT[q * 16 + kq][r] = __float2bfloat16(vals[kq] * inv);
  __syncthreads();
  const int er = t >> 2, c16 = (t & 3) * 16;
  bf16* op = attnT + (((long)(i * 8 + b) * 8 + h) * 64 + er) * 64 + c16;
  *(bfrag8*)(op) = *(const bfrag8*)(&attT[er][c16]);
  *(bfrag8*)(op + 8) = *(const bfrag8*)(&attT[er][c16 + 8]);
}

// =================== mfold: M[c,ef] = sum_d Wo[c, h*64+d] * attnT[e,d]; mvec += M.bv ===================
__global__ __launch_bounds__(256, 2) void mfold_kernel(
    const bf16* __restrict__ woB, const bf16* __restrict__ attnT,
    const float* __restrict__ bv, bf16* __restrict__ Mbuf, float* __restrict__ mvec)
{
  __shared__ __align__(16) bf16 As[128 * 32];
  __shared__ __align__(16) bf16 Bs[64 * 32];
  const int ib = blockIdx.z;          // i*8+b
  const int i = ib >> 3;
  const int h = blockIdx.y;
  const bf16* A = woB + (long)i * 262144 + h * 64;
  const bf16* Bt = attnT + ((long)ib * 8 + h) * 4096;
  f32x4 acc[4][2];
#pragma unroll
  for (int m = 0; m < 4; ++m)
#pragma unroll
    for (int n = 0; n < 2; ++n)
      acc[m][n] = f32x4{0.f, 0.f, 0.f, 0.f};
  const long m0 = (long)blockIdx.x * 128;
  gemm_core<128, 64>(A, 512, Bt, 64, 64, m0, 0, As, Bs, acc);

  const int t = threadIdx.x;
  const int lane = t & 63, wv = t >> 6;
  const int wr = wv >> 1, wc = wv & 1;
  const int l16 = lane & 15, lk = lane >> 4;
  bf16* C = Mbuf + (long)ib * 262144;
  const float* bvp = bv + i * 512 + h * 64;
  float mp[4][4];
#pragma unroll
  for (int m = 0; m < 4; ++m)
#pragma unroll
    for (int i2 = 0; i2 < 4; ++i2) mp[m][i2] = 0.f;
#pragma unroll
  for (int m = 0; m < 4; ++m) {
    const long gr0 = m0 + wr * 64 + m * 16 + lk * 4;
#pragma unroll
    for (int n = 0; n < 2; ++n) {
      const int gc = wc * 32 + n * 16 + l16;
      const float bvv = bvp[gc];
#pragma unroll
      for (int i2 = 0; i2 < 4; ++i2) {
        C[(gr0 + i2) * 512 + h * 64 + gc] = __float2bfloat16(acc[m][n][i2]);
        mp[m][i2] += acc[m][n][i2] * bvv;
      }
    }
  }
#pragma unroll
  for (int m = 0; m < 4; ++m)
#pragma unroll
    for (int i2 = 0; i2 < 4; ++i2) {
      float v = mp[m][i2];
      v += __shfl_xor(v, 1); v += __shfl_xor(v, 2);
      v += __shfl_xor(v, 4); v += __shfl_xor(v, 8);
      if (l16 == 0)
        atomicAdd(&mvec[(long)ib * 512 + m0 + wr * 64 + m * 16 + lk * 4 + i2], v);
    }
}

// =================== weff: W_eff[c,cin] = sum_ef M[c,ef] * wvT[cin,ef] ===================
__global__ __launch_bounds__(256, 2) void weff_gemm(
    const bf16* __restrict__ Mbuf, const bf16* __restrict__ wvT,
    bf16* __restrict__ Weff)
{
  __shared__ __align__(16) bf16 As[128 * 32];
  __shared__ __align__(16) bf16 Bs[128 * 32];
  const int ib = blockIdx.z;
  const int i = ib >> 3;
  f32x4 acc[4][4];
#pragma unroll
  for (int m = 0; m < 4; ++m)
#pragma unroll
    for (int n = 0; n < 4; ++n)
      acc[m][n] = f32x4{0.f, 0.f, 0.f, 0.f};
  const long m0 = (long)blockIdx.x * 128, n0 = (long)blockIdx.y * 128;
  gemm_core<128, 128>(Mbuf + (long)ib * 262144, 512, wvT + (long)i * 262144, 512,
                      512, m0, n0, As, Bs, acc);
  bf16* C = Weff + (long)ib * 262144;
  const int t = threadIdx.x;
  const int lane = t & 63, wv = t >> 6;
  const int wr = wv >> 1, wc = wv & 1;
  const int l16 = lane & 15, lk = lane >> 4;
#pragma unroll
  for (int m = 0; m < 4; ++m) {
    const long gr0 = m0 + wr * 64 + m * 16 + lk * 4;
#pragma unroll
    for (int n = 0; n < 4; ++n) {
      const long gc = n0 + wc * 64 + n * 16 + l16;
#pragma unroll
      for (int i2 = 0; i2 < 4; ++i2)
        C[(gr0 + i2) * 512 + gc] = __float2bfloat16(acc[m][n][i2]);
    }
  }
}

// =================== SE MLP ===================
__global__ __launch_bounds__(512) void se_mlp(
    const float* __restrict__ pooled,
    const float* __restrict__ W1, const float* __restrict__ b1,
    const float* __restrict__ W2, const float* __restrict__ b2,
    float* __restrict__ se)
{
  const int b = blockIdx.x, m = blockIdx.y;
  __shared__ float y[32];
  const int t = threadIdx.x;
  if (t < 32) {
    float s = b1[m * 32 + t];
    const float* w = W1 + (long)(m * 32 + t) * 512;
    const float* p = pooled + ((long)m * 8 + b) * 512;
    for (int c = 0; c < 512; ++c) s += w[c] * (p[c] * (1.0f / 4096.0f));
    y[t] = fmaxf(s, 0.0f);
  }
  __syncthreads();
  float s = b2[m * 512 + t];
  const float* w2 = W2 + (long)(m * 512 + t) * 32;
#pragma unroll
  for (int j = 0; j < 32; ++j) s += w2[j] * y[j];
  se[((long)m * 8 + b) * 512 + t] = 1.0f / (1.0f + expf(-s));
}

// ========= refined = l2norm_c(cross*se); alpha = sigmoid(gate); weighted out (fused) =========
__global__ __launch_bounds__(384) void refine_gate(
    const bf16* __restrict__ cr0, const bf16* __restrict__ cr1,
    const bf16* __restrict__ cr2, const float* __restrict__ se,
    const float* __restrict__ gw, const float* __restrict__ gb,
    const float* __restrict__ qacc, bf16* __restrict__ weighted)
{
  __shared__ float part[2][3][3];
  const int t = threadIdx.x, wv = t >> 6, lane = t & 63;
  const int px_i = (wv >= 3) ? 1 : 0;
  const int m = wv - px_i * 3;
  const int pix = blockIdx.x * 2 + px_i;
  const int b = pix >> 12;
  const bf16* cr = (m == 0) ? cr0 : (m == 1) ? cr1 : cr2;
  const int c0 = lane * 8;
  const bfrag8 v8 = *(const bfrag8*)(cr + (long)pix * 512 + c0);
  const float* sp = se + ((long)m * 8 + b) * 512 + c0;
  const float4 s0 = *(const float4*)(sp);
  const float4 s1 = *(const float4*)(sp + 4);
  float w[8] = {bf2f(v8[0]) * s0.x, bf2f(v8[1]) * s0.y,
                bf2f(v8[2]) * s0.z, bf2f(v8[3]) * s0.w,
                bf2f(v8[4]) * s1.x, bf2f(v8[5]) * s1.y,
                bf2f(v8[6]) * s1.z, bf2f(v8[7]) * s1.w};
  float ss = 0.f;
#pragma unroll
  for (int i = 0; i < 8; ++i) ss += w[i] * w[i];
  for (int o = 32; o; o >>= 1) ss += __shfl_xor(ss, o);
  const float inv = 1.0f / (sqrtf(ss) + 1e-6f);
  float rf[8];
#pragma unroll
  for (int i = 0; i < 8; ++i) rf[i] = w[i] * inv;

  float a0 = 0.f, a1 = 0.f, a2 = 0.f;
#pragma unroll
  for (int i = 0; i < 8; ++i) {
    const int c = m * 512 + c0 + i;
    a0 += gw[c] * rf[i];
    a1 += gw[1539 + c] * rf[i];
    a2 += gw[3078 + c] * rf[i];
  }
  for (int o = 32; o; o >>= 1) {
    a0 += __shfl_xor(a0, o); a1 += __shfl_xor(a1, o); a2 += __shfl_xor(a2, o);
  }
  if (lane == 0) {
    part[px_i][m][0] = a0; part[px_i][m][1] = a1; part[px_i][m][2] = a2;
  }
  __syncthreads();
  const float N = 2097152.0f;
  const float q0 = qacc[b * 4 + 0] / N;
  const float q1 = (qacc[b * 4 + 2] - qacc[b * 4 + 1] * qacc[b * 4 + 1] / N) / (N - 1.0f);
  const float q2 = qacc[b * 4 + 3] / N;
  const float sg = part[px_i][0][m] + part[px_i][1][m] + part[px_i][2][m] + gb[m] +
                   gw[m * 1539 + 1536] * q0 + gw[m * 1539 + 1537] * q1 +
                   gw[m * 1539 + 1538] * q2;
  const float al = 1.0f / (1.0f + expf(-sg));
  __align__(16) bf16 tmp[8];
#pragma unroll
  for (int i = 0; i < 8; ++i) tmp[i] = __float2bfloat16(rf[i] * al);
  *(bfrag8*)(weighted + (long)pix * 1536 + m * 512 + c0) = *(const bfrag8*)tmp;
}

// =================== host launch ===================
extern "C" void kernel_launch(void* const* d_in, const int* in_sizes, int n_in,
                              void* d_out, int out_size, void* d_ws, size_t ws_size,
                              hipStream_t stream)
{
  (void)in_sizes; (void)n_in; (void)out_size; (void)ws_size;
  const float* rgb   = (const float*)d_in[0];
  const float* depth = (const float*)d_in[1];
  const float* lidar = (const float*)d_in[2];
  const float* wq  = (const float*)d_in[3];
  const float* bq  = (const float*)d_in[4];
  const float* wk  = (const float*)d_in[5];
  const float* bk  = (const float*)d_in[6];
  const float* wvw = (const float*)d_in[7];
  const float* bv  = (const float*)d_in[8];
  const float* wo  = (const float*)d_in[9];
  const float* bo  = (const float*)d_in[10];
  const float* seW1 = (const float*)d_in[11];
  const float* seb1 = (const float*)d_in[12];
  const float* seW2 = (const float*)d_in[13];
  const float* seb2 = (const float*)d_in[14];
  const float* gw  = (const float*)d_in[15];
  const float* gb  = (const float*)d_in[16];
  const float* fw  = (const float*)d_in[17];
  const float* fb  = (const float*)d_in[18];

  char* ws = (char*)d_ws;
  bf16*  xT   = (bf16*)(ws + OFF_XT);
  bf16*  xC   = (bf16*)(ws + OFF_XC);
  bf16*  wqB  = (bf16*)(ws + OFF_WQ);
  bf16*  wkB  = (bf16*)(ws + OFF_WK);
  bf16*  wvT  = (bf16*)(ws + OFF_WVT);
  bf16*  woB  = (bf16*)(ws + OFF_WOB);
  bf16*  fwB  = (bf16*)(ws + OFF_FW);
  float* bo2  = (float*)(ws + OFF_BO2);
  float* pooled = (float*)(ws + OFF_POOL);
  float* seB  = (float*)(ws + OFF_SE);
  float* qacc = (float*)(ws + OFF_QACC);
  float* cs   = (float*)(ws + OFF_CS);
  bf16*  Gb   = (bf16*)(ws + OFF_GB);
  bf16*  attnT = (bf16*)(ws + OFF_ATT);
  float* qstage = (float*)(ws + OFF_QST);
  float* mvec = (float*)(ws + OFF_MVEC);
  bf16*  Mbuf = (bf16*)(ws + OFF_XC);              // alias, dead after weff
  bf16*  Weff = (bf16*)(ws + OFF_XC + 25165824L);  // alias, dead after cross
  bf16*  crossB = (bf16*)(ws + OFF_VST);

  // zero: pooled (+se, qacc harmlessly), colsum ; mvec
  (void)hipMemsetAsync(ws + OFF_POOL, 0, OFF_CS + 49152 - OFF_POOL, stream);
  (void)hipMemsetAsync(ws + OFF_MVEC, 0, 98304, stream);

  transpose_kernel<<<dim3(128, 16, 24), dim3(32, 8), 0, stream>>>(rgb, depth, lidar,
                                                                  xT, xC, cs, qstage);
  quality_reduce<<<24, 256, 0, stream>>>(qstage, qacc);
  prep_weights<<<2048, 256, 0, stream>>>(wq, wk, wvw, wo, fw, bo,
                                         wqB, wkB, wvT, woB, fwB, bo2);

  gram_kernel<<<dim3(4, 4, 24), 256, 0, stream>>>(xC, Gb);
  scores_kernel<<<dim3(8, 8, 6), 256, 0, stream>>>(wqB, wkB, Gb, cs, bq, bk, attnT);

  mfold_kernel<<<dim3(4, 8, 48), 256, 0, stream>>>(woB, attnT, bv, Mbuf, mvec);
  weff_gemm<<<dim3(4, 4, 48), 256, 0, stream>>>(Mbuf, wvT, Weff);

  cross_gemm256<<<dim3(16, 2, 24), 512, 0, stream>>>(xT, Weff, crossB, bo2, mvec, pooled);
  se_mlp<<<dim3(8, 3), 512, 0, stream>>>(pooled, seW1, seb1, seW2, seb2, seB);

  bf16* cross0 = crossB;
  bf16* cross1 = (bf16*)(ws + OFF_VST + 33554432L);
  bf16* cross2 = (bf16*)(ws + OFF_VST + 67108864L);
  bf16* weighted = (bf16*)(ws + OFF_XC);
  refine_gate<<<16384, 384, 0, stream>>>(cross0, cross1, cross2, seB, gw, gb, qacc, weighted);

  fusion_gemm256<<<dim3(128, 6), 512, 0, stream>>>(weighted, fwB, (float*)d_out, fb);
}

// Round 8
// 882.944 us; speedup vs baseline: 1.7222x; 1.0474x over previous
//
#include <hip/hip_runtime.h>
#include <hip/hip_bf16.h>
#include <stdint.h>

using bf16 = __hip_bfloat16;
typedef short bfrag8 __attribute__((ext_vector_type(8)));
typedef float f32x4 __attribute__((ext_vector_type(4)));

// ---------------- workspace layout (bytes) ----------------
constexpr long OFF_XT   = 0L;           // 3 x [32768][512] bf16 NHWC (live until cross_gemm)
constexpr long OFF_XC   = 100663296L;   // 3 x [512][32768] bf16 channel-major (dead after gram)
constexpr long OFF_WQ   = 201326592L;   // 6 x [512][512] bf16
constexpr long OFF_WK   = 204472320L;
constexpr long OFF_WVT  = 207618048L;   // 6 x [cin 512][ef 512] bf16 (Wv transposed)
constexpr long OFF_WOB  = 210763776L;   // 6 x [512][512] bf16 (Wo plain)
constexpr long OFF_FW   = 213909504L;   // [1536][1536] bf16
constexpr long OFF_BO2  = 218628096L;   // [3][512] f32
constexpr long OFF_POOL = 218646528L;   // [3][8][512] f32   (memset from here)
constexpr long OFF_SE   = 218695680L;   // [3][8][512] f32
constexpr long OFF_QACC = 218744832L;   // [8][4] f32 (+pad to 1024)
constexpr long OFF_CS   = 218745856L;   // [3][8][512] f32 column sums (memset to here+49152)
constexpr long OFF_GB   = 218795008L;   // [3][8][512][512] bf16 Gram
constexpr long OFF_ATT  = 231377920L;   // attnT [6][8][8][64(e)][64(d)] bf16
constexpr long OFF_VST  = 234523648L;   // cross bf16 3 x [32768][512] (96 MB)
constexpr long OFF_QST  = 435850240L;   // [24][2048][2] f32 quality partials
constexpr long OFF_MVEC = 436243456L;   // [48][512] f32 (memset)
// aliases in XC region: Mbuf = OFF_XC, Weff = OFF_XC+25165824 ; weighted = OFF_XC after dead

__device__ __forceinline__ void mfma_bf16(f32x4& c, bfrag8 a, bfrag8 b) {
  asm("v_mfma_f32_16x16x32_bf16 %0, %1, %2, %0" : "+v"(c) : "v"(a), "v"(b));
}

__device__ __forceinline__ void gload16(const void* g, void* l) {
  __builtin_amdgcn_global_load_lds(
      (__attribute__((address_space(1))) void*)(g),
      (__attribute__((address_space(3))) void*)(l), 16, 0, 0);
}

__device__ __forceinline__ float bf2f(short s) {
  union { uint32_t u; float f; } cv;
  cv.u = ((uint32_t)(unsigned short)s) << 16;
  return cv.f;
}

// XCD-chunked bijective swizzle, n-fast logical order. Requires gx*gy % 8 == 0.
__device__ __forceinline__ void swz_mn(int gy, long& m0, long& n0) {
  const int gx = gridDim.x;
  const int orig = blockIdx.y * gx + blockIdx.x;
  const int q = (gx * gy) >> 3;
  const int wgid = (orig & 7) * q + (orig >> 3);
  m0 = (long)(wgid / gy) * 128;
  n0 = (long)(wgid % gy) * 128;
}

// ============================================================================
// 256x256 8-phase GEMM core with register-reuse phase order:
//   q0=(A0,B0) q1=(A0,B1) q2=(A1,B1) q3=(A1,B0)
// A-half loaded at q0/q2 (8 reads), B0 at q0 (4, held to q3), B1 at q1 (4,
// held to q2) -> 24 ds_read_b128 per K-tile per wave (minimal).
// Stage ledger unchanged from r7 (verified): per iter i (kt e=2i, o=2i+1):
//   p0:(o).A0 p1:(o).B0 p2:(e+2).B1 p3:(e+2).A1 +vmcnt(4)
//   p4:(e+2).A0 p5:(e+2).B0 p6:(o+2).B1 p7:(o+2).A1 +vmcnt(4)
// Wrapped (kt>=NT) stages land in a dummy 16KB slot: vmcnt counts stay exact,
// no same-phase read/write slot race.
// ============================================================================
#define SWZ_OFF(r, kb) ((kb) ^ (((r) & 7) << 4))

__device__ __forceinline__ void bar256() {
  __builtin_amdgcn_sched_barrier(0);
  __builtin_amdgcn_s_barrier();
  __builtin_amdgcn_sched_barrier(0);
}

__device__ __forceinline__ void stage_half(const bf16* __restrict__ g, long ldg,
                                           char* slot, int t) {
#pragma unroll
  for (int j = 0; j < 2; ++j) {
    const int L = t * 16 + j * 8192;
    const int r = L >> 7;
    const int kb = (L & 127) ^ ((r & 7) << 4);   // inverse-swizzled source chunk
    gload16(g + (long)r * ldg + (kb >> 1), slot + L);
  }
}

template<int NT>
__device__ __forceinline__ void gemm256_core(
    const bf16* __restrict__ A, long lda,
    const bf16* __restrict__ B, long ldb,
    long m0, long n0, char* sm, f32x4 (&acc)[4][4][2])
{
  const int t = threadIdx.x;
  const int lane = t & 63, wid = t >> 6;
  const int wm = wid >> 2, wn = wid & 3;
  const int l16 = lane & 15, lk = lane >> 4;

  auto STAGE = [&](int mat, int hf, int kt) {
    const bool wrap = (kt >= NT);
    const int ktw = wrap ? kt - NT : kt;
    const int kp = ktw & 1;
    char* slot = wrap ? (sm + 131072)
                      : (mat == 0 ? sm + (kp * 2 + hf) * 16384
                                  : sm + 65536 + (kp * 2 + hf) * 16384);
    if (mat == 0)
      stage_half(A + (m0 + (long)hf * 128) * lda + ktw * 64, lda, slot, t);
    else
      stage_half(B + (n0 + (long)hf * 128) * ldb + ktw * 64, ldb, slot, t);
  };

  // prologue: kt0 all 4 halves; kt1 B1+A1
  STAGE(0, 0, 0); STAGE(0, 1, 0); STAGE(1, 0, 0); STAGE(1, 1, 0);
  STAGE(1, 1, 1); STAGE(0, 1, 1);
  __builtin_amdgcn_sched_barrier(0);
  asm volatile("s_waitcnt vmcnt(4)" ::: "memory");
  bar256();

  constexpr int s_mat[8] = {0, 1, 1, 0, 0, 1, 1, 0};
  constexpr int s_hf[8]  = {0, 0, 1, 1, 0, 0, 1, 1};
  constexpr int s_dkt[8] = {1, 1, 2, 2, 2, 2, 3, 3};

  bfrag8 af[4][2], bfr0[2][2], bfr1[2][2];

  for (int i = 0; i < NT / 2; ++i) {
#pragma unroll
    for (int p = 0; p < 8; ++p) {
      const int q = p & 3, kp = p >> 2;
      const int ah = (q >= 2) ? 1 : 0;
      const int bh = (q == 1 || q == 2) ? 1 : 0;
      const char* Ab = sm + (kp * 2 + ah) * 16384;
      const char* Bb = sm + 65536 + (kp * 2 + bh) * 16384;
      if (q == 0 || q == 2) {
#pragma unroll
        for (int mf = 0; mf < 4; ++mf) {
          const int rowA = wm * 64 + mf * 16 + l16;
#pragma unroll
          for (int ks = 0; ks < 2; ++ks)
            af[mf][ks] = *(const bfrag8*)(Ab + rowA * 128 +
                                          SWZ_OFF(rowA, ks * 64 + lk * 16));
        }
      }
      if (q == 0) {
#pragma unroll
        for (int nf = 0; nf < 2; ++nf) {
          const int rowB = wn * 32 + nf * 16 + l16;
#pragma unroll
          for (int ks = 0; ks < 2; ++ks)
            bfr0[nf][ks] = *(const bfrag8*)(Bb + rowB * 128 +
                                            SWZ_OFF(rowB, ks * 64 + lk * 16));
        }
      }
      if (q == 1) {
#pragma unroll
        for (int nf = 0; nf < 2; ++nf) {
          const int rowB = wn * 32 + nf * 16 + l16;
#pragma unroll
          for (int ks = 0; ks < 2; ++ks)
            bfr1[nf][ks] = *(const bfrag8*)(Bb + rowB * 128 +
                                            SWZ_OFF(rowB, ks * 64 + lk * 16));
        }
      }
      STAGE(s_mat[p], s_hf[p], 2 * i + s_dkt[p]);
      bar256();
      __builtin_amdgcn_s_setprio(1);
      if (q == 0 || q == 3) {
#pragma unroll
        for (int ks = 0; ks < 2; ++ks)
#pragma unroll
          for (int mf = 0; mf < 4; ++mf)
#pragma unroll
            for (int nf = 0; nf < 2; ++nf)
              mfma_bf16(acc[q][mf][nf], af[mf][ks], bfr0[nf][ks]);
      } else {
#pragma unroll
        for (int ks = 0; ks < 2; ++ks)
#pragma unroll
          for (int mf = 0; mf < 4; ++mf)
#pragma unroll
            for (int nf = 0; nf < 2; ++nf)
              mfma_bf16(acc[q][mf][nf], af[mf][ks], bfr1[nf][ks]);
      }
      __builtin_amdgcn_s_setprio(0);
      if (p == 3 || p == 7) {
        __builtin_amdgcn_sched_barrier(0);
        asm volatile("s_waitcnt vmcnt(4)" ::: "memory");
      }
      bar256();
    }
  }
}

// =================== fusion GEMM (256² 8-phase): out f32 NCHW ===================
__global__ __launch_bounds__(512, 2) void fusion_gemm256(
    const bf16* __restrict__ A, const bf16* __restrict__ Bt,
    float* __restrict__ Cf, const float* __restrict__ bias)
{
  __shared__ __align__(16) char sm[147456];     // 128K slots + 16K dummy
  const int orig = blockIdx.y * 128 + blockIdx.x;     // grid (128, 6)
  const int wgid = (orig & 7) * 96 + (orig >> 3);
  const long m0 = (long)(wgid / 6) * 256;
  const long n0 = (long)(wgid % 6) * 256;
  f32x4 acc[4][4][2];
#pragma unroll
  for (int q = 0; q < 4; ++q)
#pragma unroll
    for (int mf = 0; mf < 4; ++mf)
#pragma unroll
      for (int nf = 0; nf < 2; ++nf)
        acc[q][mf][nf] = f32x4{0.f, 0.f, 0.f, 0.f};
  gemm256_core<24>(A, 1536, Bt, 1536, m0, n0, sm, acc);

  const int t = threadIdx.x;
  const int lane = t & 63, wid = t >> 6;
  const int wm = wid >> 2, wn = wid & 3;
  const int l16 = lane & 15, lk = lane >> 4;
  constexpr int s_ah[4] = {0, 0, 1, 1};
  constexpr int s_bh[4] = {0, 1, 1, 0};
  const long b = m0 >> 12;
#pragma unroll
  for (int q = 0; q < 4; ++q) {
    const int ah = s_ah[q], bh = s_bh[q];
#pragma unroll
    for (int mf = 0; mf < 4; ++mf) {
      const long row = m0 + ah * 128 + wm * 64 + mf * 16 + lk * 4;
      const long p = row & 4095;
#pragma unroll
      for (int nf = 0; nf < 2; ++nf) {
        const long gc = n0 + bh * 128 + wn * 32 + nf * 16 + l16;
        const float bb = bias[gc];
        float4 o4;
        o4.x = acc[q][mf][nf][0] + bb; o4.y = acc[q][mf][nf][1] + bb;
        o4.z = acc[q][mf][nf][2] + bb; o4.w = acc[q][mf][nf][3] + bb;
        *(float4*)(Cf + b * 6291456L + gc * 4096L + p) = o4;
      }
    }
  }
}

// ============ transpose + stats: NCHW f32 -> NHWC + channel-major bf16, colsum, quality ============
__global__ __launch_bounds__(256) void transpose_kernel(
    const float* __restrict__ x0, const float* __restrict__ x1,
    const float* __restrict__ x2, bf16* __restrict__ xT, bf16* __restrict__ xC,
    float* __restrict__ cs, float* __restrict__ qstage)
{
  __shared__ float tile[32][33];
  __shared__ float qpart[4][2];
  const int zz = blockIdx.z;           // m*8 + b
  const int m = zz >> 3, b = zz & 7;
  const float* x = (m == 0) ? x0 : (m == 1) ? x1 : x2;
  bf16* y = xT + (long)m * 16777216;
  bf16* y2 = xC + (long)m * 16777216;
  const int p0 = blockIdx.x * 32, c0 = blockIdx.y * 32;
  const int tx = threadIdx.x, ty = threadIdx.y;
  float csp[4];
  float qa = 0.f, qb_ = 0.f;   // m==0 (rgb): sum,ssq ; else: zero-count in qa
#pragma unroll
  for (int j = 0; j < 4; ++j) {
    const float v = x[((long)b * 512 + c0 + ty + j * 8) * 4096 + p0 + tx];
    tile[ty + j * 8][tx] = v;
    y2[(long)(c0 + ty + j * 8) * 32768 + (long)b * 4096 + p0 + tx] = __float2bfloat16(v);
    csp[j] = v;
    if (m == 0) { qa += v; qb_ += v * v; }
    else qa += (v == 0.0f) ? 1.0f : 0.0f;
  }
  __syncthreads();
#pragma unroll
  for (int j = 0; j < 4; ++j)
    y[((long)b * 4096 + p0 + ty + j * 8) * 512 + c0 + tx] =
        __float2bfloat16(tile[tx][ty + j * 8]);
#pragma unroll
  for (int j = 0; j < 4; ++j) {
    float s = csp[j];
    for (int o = 16; o; o >>= 1) s += __shfl_xor(s, o);
    if (tx == 0) atomicAdd(&cs[(m * 8 + b) * 512 + c0 + ty + j * 8], s);
  }
  const int t = ty * 32 + tx;
  const int lane = t & 63;
  for (int o = 32; o; o >>= 1) { qa += __shfl_xor(qa, o); qb_ += __shfl_xor(qb_, o); }
  if (lane == 0) { qpart[t >> 6][0] = qa; qpart[t >> 6][1] = qb_; }
  __syncthreads();
  if (t == 0) {
    const float pa = qpart[0][0] + qpart[1][0] + qpart[2][0] + qpart[3][0];
    const float pb = qpart[0][1] + qpart[1][1] + qpart[2][1] + qpart[3][1];
    float* qs = qstage + ((long)zz * 2048 + blockIdx.y * 128 + blockIdx.x) * 2;
    qs[0] = pa; qs[1] = pb;
  }
}

// =================== quality partial reduce -> qacc ===================
__global__ __launch_bounds__(256) void quality_reduce(
    const float* __restrict__ qstage, float* __restrict__ qacc)
{
  __shared__ float pr[4][2];
  const int zz = blockIdx.x;  // m*8 + b
  const int m = zz >> 3, b = zz & 7;
  const int t = threadIdx.x;
  float sa = 0.f, sb = 0.f;
  for (int i = t; i < 2048; i += 256) {
    sa += qstage[((long)zz * 2048 + i) * 2];
    sb += qstage[((long)zz * 2048 + i) * 2 + 1];
  }
  for (int o = 32; o; o >>= 1) { sa += __shfl_xor(sa, o); sb += __shfl_xor(sb, o); }
  if ((t & 63) == 0) { pr[t >> 6][0] = sa; pr[t >> 6][1] = sb; }
  __syncthreads();
  if (t == 0) {
    sa = pr[0][0] + pr[1][0] + pr[2][0] + pr[3][0];
    sb = pr[0][1] + pr[1][1] + pr[2][1] + pr[3][1];
    if (m == 0) { qacc[b * 4 + 1] = sa; qacc[b * 4 + 2] = sb; }
    else if (m == 1) qacc[b * 4 + 0] = sa;
    else qacc[b * 4 + 3] = sa;
  }
}

// =================== weight conversion ===================
__global__ void prep_weights(
    const float* __restrict__ wq, const float* __restrict__ wk,
    const float* __restrict__ wv, const float* __restrict__ wo,
    const float* __restrict__ fw, const float* __restrict__ bo,
    bf16* __restrict__ wqB, bf16* __restrict__ wkB, bf16* __restrict__ wvT,
    bf16* __restrict__ woB, bf16* __restrict__ fwB, float* __restrict__ bo2)
{
  const long stride = (long)gridDim.x * blockDim.x;
  for (long j = (long)blockIdx.x * blockDim.x + threadIdx.x; j < 2359296; j += stride) {
    fwB[j] = __float2bfloat16(fw[j]);
    if (j < 1572864) {
      wqB[j] = __float2bfloat16(wq[j]);
      wkB[j] = __float2bfloat16(wk[j]);
      woB[j] = __float2bfloat16(wo[j]);
      const long i = j >> 18, rem = j & 262143, cin = rem >> 9, ef = rem & 511;
      wvT[j] = __float2bfloat16(wv[(i << 18) + (ef << 9) + cin]);
    }
    if (j < 1536) {
      const long m2 = j >> 9, cc = j & 511;
      bo2[j] = bo[((m2 * 2) << 9) + cc] + bo[((m2 * 2 + 1) << 9) + cc];
    }
  }
}

// =================== 128² GEMM core (m97-style) ===================
template<int BM, int BN>
__device__ __forceinline__ void gemm_core(
    const bf16* __restrict__ A, long lda,
    const bf16* __restrict__ Bt, long ldb,
    int K, long m0, long n0,
    bf16* As, bf16* Bs, f32x4 (&acc)[BM / 32][BN / 32])
{
  constexpr int WM = BM / 2, WN = BN / 2, FM = BM / 32, FN = BN / 32;
  const int t = threadIdx.x;
  const int lane = t & 63, wv = t >> 6;
  const int wr = wv >> 1, wc = wv & 1;
  const int l16 = lane & 15, lk = lane >> 4;
  const int srow = t >> 2;
  const int scol = (t & 3) * 8;
  const bf16* Ag = A + (m0 + srow) * lda + scol;
  const bf16* Bg = Bt + (n0 + srow) * ldb + scol;
  char* AsB = (char*)As;
  char* BsB = (char*)Bs;
  const int aoff = wv * 1024;
  for (int kk = 0; kk < K; kk += 32) {
#pragma unroll
    for (int it = 0; it < BM / 64; ++it)
      gload16(Ag + (long)it * 64 * lda + kk, AsB + it * 4096 + aoff);
#pragma unroll
    for (int it = 0; it < BN / 64; ++it)
      gload16(Bg + (long)it * 64 * ldb + kk, BsB + it * 4096 + aoff);
    __syncthreads();
    bfrag8 af[FM], bfr[FN];
#pragma unroll
    for (int m = 0; m < FM; ++m)
      af[m] = *(const bfrag8*)(AsB + ((wr * WM + m * 16 + l16) * 32 + lk * 8) * 2);
#pragma unroll
    for (int n = 0; n < FN; ++n)
      bfr[n] = *(const bfrag8*)(BsB + ((wc * WN + n * 16 + l16) * 32 + lk * 8) * 2);
#pragma unroll
    for (int m = 0; m < FM; ++m)
#pragma unroll
      for (int n = 0; n < FN; ++n)
        mfma_bf16(acc[m][n], af[m], bfr[n]);
    __syncthreads();
  }
}

// ======= cross (128²): cross[qm][b*4096+p, c] bf16 = sum_i xT[km(i)][b].Weff_i^T + bias + residT; SE pool =======
__global__ __launch_bounds__(256, 2) void cross_gemm(
    const bf16* __restrict__ xT, const bf16* __restrict__ Weff,
    bf16* __restrict__ crossB, const float* __restrict__ bo2,
    const float* __restrict__ mvec, float* __restrict__ pooled)
{
  __shared__ __align__(16) bf16 As[128 * 32];
  __shared__ __align__(16) bf16 Bs[128 * 32];
  const int z = blockIdx.z;           // qm*8 + b
  const int qm = z >> 3, b = z & 7;
  const int KM0[3] = {1, 0, 0}, KM1[3] = {2, 2, 1};
  const bf16* A0 = xT + (long)KM0[qm] * 16777216 + (long)b * 2097152;
  const bf16* A1 = xT + (long)KM1[qm] * 16777216 + (long)b * 2097152;
  const bf16* B0 = Weff + ((long)(2 * qm) * 8 + b) * 262144;
  const bf16* B1 = Weff + ((long)(2 * qm + 1) * 8 + b) * 262144;
  const bf16* residT = xT + (long)qm * 16777216;   // bf16 NHWC residual
  bf16* Cb = crossB + (long)qm * 16777216;
  f32x4 acc[4][4];
#pragma unroll
  for (int m = 0; m < 4; ++m)
#pragma unroll
    for (int n = 0; n < 4; ++n)
      acc[m][n] = f32x4{0.f, 0.f, 0.f, 0.f};
  long m0, n0;
  swz_mn(4, m0, n0);
  gemm_core<128, 128>(A0, 512, B0, 512, 512, m0, n0, As, Bs, acc);
  gemm_core<128, 128>(A1, 512, B1, 512, 512, m0, n0, As, Bs, acc);

  const int t = threadIdx.x;
  const int lane = t & 63, wv = t >> 6;
  const int wr = wv >> 1, wc = wv & 1;
  const int l16 = lane & 15, lk = lane >> 4;
  const float* mv0 = mvec + ((long)(2 * qm) * 8 + b) * 512;
  const float* mv1 = mvec + ((long)(2 * qm + 1) * 8 + b) * 512;
  float csum[4] = {0.f, 0.f, 0.f, 0.f};
#pragma unroll
  for (int m = 0; m < 4; ++m) {
    const long p = m0 + wr * 64 + m * 16 + lk * 4;      // pixel within batch [0,4096)
    const long gr0 = (long)b * 4096 + p;
#pragma unroll
    for (int n = 0; n < 4; ++n) {
      const long gc = n0 + wc * 64 + n * 16 + l16;
      const float bb = bo2[qm * 512 + gc] + mv0[gc] + mv1[gc];
#pragma unroll
      for (int i2 = 0; i2 < 4; ++i2) {
        const float rv = __bfloat162float(residT[(gr0 + i2) * 512 + gc]);
        const float o = acc[m][n][i2] + bb + rv;
        Cb[(gr0 + i2) * 512 + gc] = __float2bfloat16(o);
        csum[n] += o;
      }
    }
  }
#pragma unroll
  for (int n = 0; n < 4; ++n) {
    float s = csum[n];
    s += __shfl_xor(s, 16);
    s += __shfl_xor(s, 32);
    if (lane < 16) {
      const long gc = n0 + wc * 64 + n * 16 + l16;
      atomicAdd(&pooled[((long)qm * 8 + b) * 512 + gc], s);
    }
  }
}

// =================== Gram: G[i,j] = sum_p xA[p,i] xB[p,j], bf16 out ===================
__global__ __launch_bounds__(256, 2) void gram_kernel(
    const bf16* __restrict__ xC, bf16* __restrict__ Gb)
{
  __shared__ __align__(16) bf16 As[128 * 32];
  __shared__ __align__(16) bf16 Bs[128 * 32];
  const int z = blockIdx.z;
  const int pair = z >> 3, b = z & 7;
  const int A1[3] = {0, 0, 1}, A2[3] = {1, 2, 2};
  const bf16* A = xC + (long)A1[pair] * 16777216 + b * 4096;
  const bf16* Bt = xC + (long)A2[pair] * 16777216 + b * 4096;
  f32x4 acc[4][4];
#pragma unroll
  for (int m = 0; m < 4; ++m)
#pragma unroll
    for (int n = 0; n < 4; ++n)
      acc[m][n] = f32x4{0.f, 0.f, 0.f, 0.f};
  const long m0 = (long)blockIdx.x * 128, n0 = (long)blockIdx.y * 128;
  gemm_core<128, 128>(A, 32768, Bt, 32768, 4096, m0, n0, As, Bs, acc);
  bf16* C = Gb + (long)z * 262144;
  const int t = threadIdx.x;
  const int lane = t & 63, wv = t >> 6;
  const int wr = wv >> 1, wc = wv & 1;
  const int l16 = lane & 15, lk = lane >> 4;
#pragma unroll
  for (int m = 0; m < 4; ++m) {
    const long gr0 = m0 + wr * 64 + m * 16 + lk * 4;
#pragma unroll
    for (int n = 0; n < 4; ++n) {
      const long gc = n0 + wc * 64 + n * 16 + l16;
#pragma unroll
      for (int i = 0; i < 4; ++i)
        C[(gr0 + i) * 512 + gc] = __float2bfloat16(acc[m][n][i]);
    }
  }
}

// =================== scores+softmax -> attnT[e][d] ===================
__global__ __launch_bounds__(256, 2) void scores_kernel(
    const bf16* __restrict__ wqB, const bf16* __restrict__ wkB,
    const bf16* __restrict__ Gb, const float* __restrict__ colsum,
    const float* __restrict__ bq, const float* __restrict__ bk,
    bf16* __restrict__ attnT)
{
  __shared__ __align__(16) bf16 RtS[64 * 520];  // R^T bf16 ; later aliased as S f32 [64][68]
  __shared__ float uv[128];
  __shared__ __align__(16) bf16 attT[64][64];
  const int h = blockIdx.x, b = blockIdx.y, i = blockIdx.z;
  const int qm = i >> 1, jj = i & 1;
  const int km = jj ? (qm == 2 ? 1 : 2) : (qm == 0 ? 1 : 0);
  const int lo = qm < km ? qm : km, hi = qm < km ? km : qm;
  const int pair = lo + hi - 1;
  const int trans = qm > km;
  const bf16* G = Gb + ((long)(pair * 8 + b)) * 262144;
  const bf16* Wq_h = wqB + (long)i * 262144 + h * 64 * 512;
  const bf16* Wk_h = wkB + (long)i * 262144 + h * 64 * 512;
  const bf16* WA = trans ? Wk_h : Wq_h;
  const bf16* WB = trans ? Wq_h : Wk_h;
  const int t = threadIdx.x, lane = t & 63, wv = t >> 6;
  const int l16 = lane & 15, lk = lane >> 4;

  if (t < 128) {
    const int d = t & 63;
    const bf16* wrow = ((t < 64) ? Wq_h : Wk_h) + d * 512;
    const float* sv = colsum + (((t < 64) ? qm : km) * 8 + b) * 512;
    float a = 0.f;
    for (int c = 0; c < 512; c += 8) {
      const bfrag8 w8 = *(const bfrag8*)(wrow + c);
#pragma unroll
      for (int e = 0; e < 8; ++e) a += bf2f(w8[e]) * sv[c + e];
    }
    uv[t] = a;
  }

  // step A: R[512,64] = G . WB^T ; wave wv owns rows [wv*128, +128)
  f32x4 acc[8][4];
#pragma unroll
  for (int m = 0; m < 8; ++m)
#pragma unroll
    for (int n = 0; n < 4; ++n)
      acc[m][n] = f32x4{0.f, 0.f, 0.f, 0.f};
  for (int kk = 0; kk < 512; kk += 32) {
    bfrag8 a[8], bb[4];
#pragma unroll
    for (int m = 0; m < 8; ++m)
      a[m] = *(const bfrag8*)(G + (wv * 128 + m * 16 + l16) * 512 + kk + lk * 8);
#pragma unroll
    for (int n = 0; n < 4; ++n)
      bb[n] = *(const bfrag8*)(WB + (n * 16 + l16) * 512 + kk + lk * 8);
#pragma unroll
    for (int m = 0; m < 8; ++m)
#pragma unroll
      for (int n = 0; n < 4; ++n)
        mfma_bf16(acc[m][n], a[m], bb[n]);
  }
#pragma unroll
  for (int m = 0; m < 8; ++m)
#pragma unroll
    for (int n = 0; n < 4; ++n)
#pragma unroll
      for (int idx = 0; idx < 4; ++idx)
        RtS[(n * 16 + l16) * 520 + wv * 128 + m * 16 + lk * 4 + idx] =
            __float2bfloat16(acc[m][n][idx]);
  __syncthreads();

  // step B: S[64,64] = WA . Rt^T
  f32x4 acc2[4];
#pragma unroll
  for (int m = 0; m < 4; ++m) acc2[m] = f32x4{0.f, 0.f, 0.f, 0.f};
  for (int kk = 0; kk < 512; kk += 32) {
    bfrag8 a2[4];
#pragma unroll
    for (int m = 0; m < 4; ++m)
      a2[m] = *(const bfrag8*)(WA + (m * 16 + l16) * 512 + kk + lk * 8);
    const bfrag8 b2 = *(const bfrag8*)(&RtS[(wv * 16 + l16) * 520 + kk + lk * 8]);
#pragma unroll
    for (int m = 0; m < 4; ++m) mfma_bf16(acc2[m], a2[m], b2);
  }
  __syncthreads();
  float* S = (float*)RtS;  // [64][68]
#pragma unroll
  for (int m = 0; m < 4; ++m)
#pragma unroll
    for (int idx = 0; idx < 4; ++idx)
      S[(m * 16 + lk * 4 + idx) * 68 + wv * 16 + l16] = acc2[m][idx];
  __syncthreads();

  const int r = t >> 2, q = t & 3;   // r = d (query row), q*16+kq = e (key col)
  const float* bq_h = bq + i * 512 + h * 64;
  const float* bk_h = bk + i * 512 + h * 64;
  const float u_r = uv[r], bq_r = bq_h[r];
  float vals[16];
  float mx = -1e30f;
#pragma unroll
  for (int kq = 0; kq < 16; ++kq) {
    const int k = q * 16 + kq;
    float s = trans ? S[k * 68 + r] : S[r * 68 + k];
    s += u_r * bk_h[k] + bq_r * uv[64 + k] + 4096.0f * bq_r * bk_h[k];
    s *= 0.125f;
    vals[kq] = s;
    mx = fmaxf(mx, s);
  }
  mx = fmaxf(mx, __shfl_xor(mx, 1));
  mx = fmaxf(mx, __shfl_xor(mx, 2));
  float sum = 0.f;
#pragma unroll
  for (int kq = 0; kq < 16; ++kq) { vals[kq] = expf(vals[kq] - mx); sum += vals[kq]; }
  sum += __shfl_xor(sum, 1);
  sum += __shfl_xor(sum, 2);
  const float inv = 1.0f / sum;
#pragma unroll
  for (int kq = 0; kq < 16; ++kq)
    attT[q * 16 + kq][r] = __float2bfloat16(vals[kq] * inv);
  __syncthreads();
  const int er = t >> 2, c16 = (t & 3) * 16;
  bf16* op = attnT + (((long)(i * 8 + b) * 8 + h) * 64 + er) * 64 + c16;
  *(bfrag8*)(op) = *(const bfrag8*)(&attT[er][c16]);
  *(bfrag8*)(op + 8) = *(const bfrag8*)(&attT[er][c16 + 8]);
}

// =================== mfold: M[c,ef] = sum_d Wo[c, h*64+d] * attnT[e,d]; mvec += M.bv ===================
__global__ __launch_bounds__(256, 2) void mfold_kernel(
    const bf16* __restrict__ woB, const bf16* __restrict__ attnT,
    const float* __restrict__ bv, bf16* __restrict__ Mbuf, float* __restrict__ mvec)
{
  __shared__ __align__(16) bf16 As[128 * 32];
  __shared__ __align__(16) bf16 Bs[64 * 32];
  const int ib = blockIdx.z;          // i*8+b
  const int i = ib >> 3;
  const int h = blockIdx.y;
  const bf16* A = woB + (long)i * 262144 + h * 64;
  const bf16* Bt = attnT + ((long)ib * 8 + h) * 4096;
  f32x4 acc[4][2];
#pragma unroll
  for (int m = 0; m < 4; ++m)
#pragma unroll
    for (int n = 0; n < 2; ++n)
      acc[m][n] = f32x4{0.f, 0.f, 0.f, 0.f};
  const long m0 = (long)blockIdx.x * 128;
  gemm_core<128, 64>(A, 512, Bt, 64, 64, m0, 0, As, Bs, acc);

  const int t = threadIdx.x;
  const int lane = t & 63, wv = t >> 6;
  const int wr = wv >> 1, wc = wv & 1;
  const int l16 = lane & 15, lk = lane >> 4;
  bf16* C = Mbuf + (long)ib * 262144;
  const float* bvp = bv + i * 512 + h * 64;
  float mp[4][4];
#pragma unroll
  for (int m = 0; m < 4; ++m)
#pragma unroll
    for (int i2 = 0; i2 < 4; ++i2) mp[m][i2] = 0.f;
#pragma unroll
  for (int m = 0; m < 4; ++m) {
    const long gr0 = m0 + wr * 64 + m * 16 + lk * 4;
#pragma unroll
    for (int n = 0; n < 2; ++n) {
      const int gc = wc * 32 + n * 16 + l16;
      const float bvv = bvp[gc];
#pragma unroll
      for (int i2 = 0; i2 < 4; ++i2) {
        C[(gr0 + i2) * 512 + h * 64 + gc] = __float2bfloat16(acc[m][n][i2]);
        mp[m][i2] += acc[m][n][i2] * bvv;
      }
    }
  }
#pragma unroll
  for (int m = 0; m < 4; ++m)
#pragma unroll
    for (int i2 = 0; i2 < 4; ++i2) {
      float v = mp[m][i2];
      v += __shfl_xor(v, 1); v += __shfl_xor(v, 2);
      v += __shfl_xor(v, 4); v += __shfl_xor(v, 8);
      if (l16 == 0)
        atomicAdd(&mvec[(long)ib * 512 + m0 + wr * 64 + m * 16 + lk * 4 + i2], v);
    }
}

// =================== weff: W_eff[c,cin] = sum_ef M[c,ef] * wvT[cin,ef] ===================
__global__ __launch_bounds__(256, 2) void weff_gemm(
    const bf16* __restrict__ Mbuf, const bf16* __restrict__ wvT,
    bf16* __restrict__ Weff)
{
  __shared__ __align__(16) bf16 As[128 * 32];
  __shared__ __align__(16) bf16 Bs[128 * 32];
  const int ib = blockIdx.z;
  const int i = ib >> 3;
  f32x4 acc[4][4];
#pragma unroll
  for (int m = 0; m < 4; ++m)
#pragma unroll
    for (int n = 0; n < 4; ++n)
      acc[m][n] = f32x4{0.f, 0.f, 0.f, 0.f};
  const long m0 = (long)blockIdx.x * 128, n0 = (long)blockIdx.y * 128;
  gemm_core<128, 128>(Mbuf + (long)ib * 262144, 512, wvT + (long)i * 262144, 512,
                      512, m0, n0, As, Bs, acc);
  bf16* C = Weff + (long)ib * 262144;
  const int t = threadIdx.x;
  const int lane = t & 63, wv = t >> 6;
  const int wr = wv >> 1, wc = wv & 1;
  const int l16 = lane & 15, lk = lane >> 4;
#pragma unroll
  for (int m = 0; m < 4; ++m) {
    const long gr0 = m0 + wr * 64 + m * 16 + lk * 4;
#pragma unroll
    for (int n = 0; n < 4; ++n) {
      const long gc = n0 + wc * 64 + n * 16 + l16;
#pragma unroll
      for (int i2 = 0; i2 < 4; ++i2)
        C[(gr0 + i2) * 512 + gc] = __float2bfloat16(acc[m][n][i2]);
    }
  }
}

// =================== SE MLP ===================
__global__ __launch_bounds__(512) void se_mlp(
    const float* __restrict__ pooled,
    const float* __restrict__ W1, const float* __restrict__ b1,
    const float* __restrict__ W2, const float* __restrict__ b2,
    float* __restrict__ se)
{
  const int b = blockIdx.x, m = blockIdx.y;
  __shared__ float y[32];
  const int t = threadIdx.x;
  if (t < 32) {
    float s = b1[m * 32 + t];
    const float* w = W1 + (long)(m * 32 + t) * 512;
    const float* p = pooled + ((long)m * 8 + b) * 512;
    for (int c = 0; c < 512; ++c) s += w[c] * (p[c] * (1.0f / 4096.0f));
    y[t] = fmaxf(s, 0.0f);
  }
  __syncthreads();
  float s = b2[m * 512 + t];
  const float* w2 = W2 + (long)(m * 512 + t) * 32;
#pragma unroll
  for (int j = 0; j < 32; ++j) s += w2[j] * y[j];
  se[((long)m * 8 + b) * 512 + t] = 1.0f / (1.0f + expf(-s));
}

// ========= refined = l2norm_c(cross*se); alpha = sigmoid(gate); weighted out (fused) =========
__global__ __launch_bounds__(384) void refine_gate(
    const bf16* __restrict__ cr0, const bf16* __restrict__ cr1,
    const bf16* __restrict__ cr2, const float* __restrict__ se,
    const float* __restrict__ gw, const float* __restrict__ gb,
    const float* __restrict__ qacc, bf16* __restrict__ weighted)
{
  __shared__ float part[2][3][3];
  const int t = threadIdx.x, wv = t >> 6, lane = t & 63;
  const int px_i = (wv >= 3) ? 1 : 0;
  const int m = wv - px_i * 3;
  const int pix = blockIdx.x * 2 + px_i;
  const int b = pix >> 12;
  const bf16* cr = (m == 0) ? cr0 : (m == 1) ? cr1 : cr2;
  const int c0 = lane * 8;
  const bfrag8 v8 = *(const bfrag8*)(cr + (long)pix * 512 + c0);
  const float* sp = se + ((long)m * 8 + b) * 512 + c0;
  const float4 s0 = *(const float4*)(sp);
  const float4 s1 = *(const float4*)(sp + 4);
  float w[8] = {bf2f(v8[0]) * s0.x, bf2f(v8[1]) * s0.y,
                bf2f(v8[2]) * s0.z, bf2f(v8[3]) * s0.w,
                bf2f(v8[4]) * s1.x, bf2f(v8[5]) * s1.y,
                bf2f(v8[6]) * s1.z, bf2f(v8[7]) * s1.w};
  float ss = 0.f;
#pragma unroll
  for (int i = 0; i < 8; ++i) ss += w[i] * w[i];
  for (int o = 32; o; o >>= 1) ss += __shfl_xor(ss, o);
  const float inv = 1.0f / (sqrtf(ss) + 1e-6f);
  float rf[8];
#pragma unroll
  for (int i = 0; i < 8; ++i) rf[i] = w[i] * inv;

  float a0 = 0.f, a1 = 0.f, a2 = 0.f;
#pragma unroll
  for (int i = 0; i < 8; ++i) {
    const int c = m * 512 + c0 + i;
    a0 += gw[c] * rf[i];
    a1 += gw[1539 + c] * rf[i];
    a2 += gw[3078 + c] * rf[i];
  }
  for (int o = 32; o; o >>= 1) {
    a0 += __shfl_xor(a0, o); a1 += __shfl_xor(a1, o); a2 += __shfl_xor(a2, o);
  }
  if (lane == 0) {
    part[px_i][m][0] = a0; part[px_i][m][1] = a1; part[px_i][m][2] = a2;
  }
  __syncthreads();
  const float N = 2097152.0f;
  const float q0 = qacc[b * 4 + 0] / N;
  const float q1 = (qacc[b * 4 + 2] - qacc[b * 4 + 1] * qacc[b * 4 + 1] / N) / (N - 1.0f);
  const float q2 = qacc[b * 4 + 3] / N;
  const float sg = part[px_i][0][m] + part[px_i][1][m] + part[px_i][2][m] + gb[m] +
                   gw[m * 1539 + 1536] * q0 + gw[m * 1539 + 1537] * q1 +
                   gw[m * 1539 + 1538] * q2;
  const float al = 1.0f / (1.0f + expf(-sg));
  __align__(16) bf16 tmp[8];
#pragma unroll
  for (int i = 0; i < 8; ++i) tmp[i] = __float2bfloat16(rf[i] * al);
  *(bfrag8*)(weighted + (long)pix * 1536 + m * 512 + c0) = *(const bfrag8*)tmp;
}

// =================== host launch ===================
extern "C" void kernel_launch(void* const* d_in, const int* in_sizes, int n_in,
                              void* d_out, int out_size, void* d_ws, size_t ws_size,
                              hipStream_t stream)
{
  (void)in_sizes; (void)n_in; (void)out_size; (void)ws_size;
  const float* rgb   = (const float*)d_in[0];
  const float* depth = (const float*)d_in[1];
  const float* lidar = (const float*)d_in[2];
  const float* wq  = (const float*)d_in[3];
  const float* bq  = (const float*)d_in[4];
  const float* wk  = (const float*)d_in[5];
  const float* bk  = (const float*)d_in[6];
  const float* wvw = (const float*)d_in[7];
  const float* bv  = (const float*)d_in[8];
  const float* wo  = (const float*)d_in[9];
  const float* bo  = (const float*)d_in[10];
  const float* seW1 = (const float*)d_in[11];
  const float* seb1 = (const float*)d_in[12];
  const float* seW2 = (const float*)d_in[13];
  const float* seb2 = (const float*)d_in[14];
  const float* gw  = (const float*)d_in[15];
  const float* gb  = (const float*)d_in[16];
  const float* fw  = (const float*)d_in[17];
  const float* fb  = (const float*)d_in[18];

  char* ws = (char*)d_ws;
  bf16*  xT   = (bf16*)(ws + OFF_XT);
  bf16*  xC   = (bf16*)(ws + OFF_XC);
  bf16*  wqB  = (bf16*)(ws + OFF_WQ);
  bf16*  wkB  = (bf16*)(ws + OFF_WK);
  bf16*  wvT  = (bf16*)(ws + OFF_WVT);
  bf16*  woB  = (bf16*)(ws + OFF_WOB);
  bf16*  fwB  = (bf16*)(ws + OFF_FW);
  float* bo2  = (float*)(ws + OFF_BO2);
  float* pooled = (float*)(ws + OFF_POOL);
  float* seB  = (float*)(ws + OFF_SE);
  float* qacc = (float*)(ws + OFF_QACC);
  float* cs   = (float*)(ws + OFF_CS);
  bf16*  Gb   = (bf16*)(ws + OFF_GB);
  bf16*  attnT = (bf16*)(ws + OFF_ATT);
  float* qstage = (float*)(ws + OFF_QST);
  float* mvec = (float*)(ws + OFF_MVEC);
  bf16*  Mbuf = (bf16*)(ws + OFF_XC);              // alias, dead after weff
  bf16*  Weff = (bf16*)(ws + OFF_XC + 25165824L);  // alias, dead after cross
  bf16*  crossB = (bf16*)(ws + OFF_VST);

  // zero: pooled (+se, qacc harmlessly), colsum ; mvec
  (void)hipMemsetAsync(ws + OFF_POOL, 0, OFF_CS + 49152 - OFF_POOL, stream);
  (void)hipMemsetAsync(ws + OFF_MVEC, 0, 98304, stream);

  transpose_kernel<<<dim3(128, 16, 24), dim3(32, 8), 0, stream>>>(rgb, depth, lidar,
                                                                  xT, xC, cs, qstage);
  quality_reduce<<<24, 256, 0, stream>>>(qstage, qacc);
  prep_weights<<<2048, 256, 0, stream>>>(wq, wk, wvw, wo, fw, bo,
                                         wqB, wkB, wvT, woB, fwB, bo2);

  gram_kernel<<<dim3(4, 4, 24), 256, 0, stream>>>(xC, Gb);
  scores_kernel<<<dim3(8, 8, 6), 256, 0, stream>>>(wqB, wkB, Gb, cs, bq, bk, attnT);

  mfold_kernel<<<dim3(4, 8, 48), 256, 0, stream>>>(woB, attnT, bv, Mbuf, mvec);
  weff_gemm<<<dim3(4, 4, 48), 256, 0, stream>>>(Mbuf, wvT, Weff);

  cross_gemm<<<dim3(32, 4, 24), 256, 0, stream>>>(xT, Weff, crossB, bo2, mvec, pooled);
  se_mlp<<<dim3(8, 3), 512, 0, stream>>>(pooled, seW1, seb1, seW2, seb2, seB);

  bf16* cross0 = crossB;
  bf16* cross1 = (bf16*)(ws + OFF_VST + 33554432L);
  bf16* cross2 = (bf16*)(ws + OFF_VST + 67108864L);
  bf16* weighted = (bf16*)(ws + OFF_XC);
  refine_gate<<<16384, 384, 0, stream>>>(cross0, cross1, cross2, seB, gw, gb, qacc, weighted);

  fusion_gemm256<<<dim3(128, 6), 512, 0, stream>>>(weighted, fwB, (float*)d_out, fb);
}

// Round 9
// 807.387 us; speedup vs baseline: 1.8834x; 1.0936x over previous
//
#include <hip/hip_runtime.h>
#include <hip/hip_bf16.h>
#include <stdint.h>

using bf16 = __hip_bfloat16;
typedef short bfrag8 __attribute__((ext_vector_type(8)));
typedef float f32x4 __attribute__((ext_vector_type(4)));

// ---------------- workspace layout (bytes) ----------------
constexpr long OFF_XT   = 0L;           // 3 x [32768][512] bf16 NHWC (live until cross_gemm)
constexpr long OFF_XC   = 100663296L;   // 3 x [512][32768] bf16 channel-major (dead after gram)
constexpr long OFF_WQ   = 201326592L;   // 6 x [512][512] bf16
constexpr long OFF_WK   = 204472320L;
constexpr long OFF_WVT  = 207618048L;   // 6 x [cin 512][ef 512] bf16 (Wv transposed)
constexpr long OFF_WOB  = 210763776L;   // 6 x [512][512] bf16 (Wo plain)
constexpr long OFF_FW   = 213909504L;   // [1536][1536] bf16
constexpr long OFF_BO2  = 218628096L;   // [3][512] f32
constexpr long OFF_POOL = 218646528L;   // [3][8][512] f32   (memset from here)
constexpr long OFF_SE   = 218695680L;   // [3][8][512] f32
constexpr long OFF_QACC = 218744832L;   // [8][4] f32 (+pad to 1024)
constexpr long OFF_CS   = 218745856L;   // [3][8][512] f32 column sums (memset to here+49152)
constexpr long OFF_GB   = 218795008L;   // [3][8][512][512] bf16 Gram
constexpr long OFF_ATT  = 231377920L;   // attnT [6][8][8][64(e)][64(d)] bf16
constexpr long OFF_VST  = 234523648L;   // cross bf16 3 x [32768][512] (96 MB)
constexpr long OFF_QST  = 435850240L;   // [24][2048][2] f32 quality partials
constexpr long OFF_MVEC = 436243456L;   // [48][512] f32 (memset)
constexpr long OFF_IDB  = 436341760L;   // [512][512] bf16 identity
// aliases in XC region: Mbuf = OFF_XC, Weff = OFF_XC+25165824 ; weighted = OFF_XC after dead

__device__ __forceinline__ void mfma_bf16(f32x4& c, bfrag8 a, bfrag8 b) {
  asm("v_mfma_f32_16x16x32_bf16 %0, %1, %2, %0" : "+v"(c) : "v"(a), "v"(b));
}

__device__ __forceinline__ void gload16(const void* g, void* l) {
  __builtin_amdgcn_global_load_lds(
      (__attribute__((address_space(1))) void*)(g),
      (__attribute__((address_space(3))) void*)(l), 16, 0, 0);
}

__device__ __forceinline__ float bf2f(short s) {
  union { uint32_t u; float f; } cv;
  cv.u = ((uint32_t)(unsigned short)s) << 16;
  return cv.f;
}

// XCD-chunked bijective swizzle, n-fast logical order. Requires gx*gy % 8 == 0.
__device__ __forceinline__ void swz_mn(int gy, long& m0, long& n0) {
  const int gx = gridDim.x;
  const int orig = blockIdx.y * gx + blockIdx.x;
  const int q = (gx * gy) >> 3;
  const int wgid = (orig & 7) * q + (orig >> 3);
  m0 = (long)(wgid / gy) * 128;
  n0 = (long)(wgid % gy) * 128;
}

// ============================================================================
// 256x256 8-phase GEMM core (multi-segment K) with register-reuse phase order:
//   q0=(A0,B0) q1=(A0,B1) q2=(A1,B1) q3=(A1,B0)
// A-half loaded at q0/q2, B0 held q0->q3, B1 held q1->q2 -> 24 ds_read/K-tile.
// Stage ledger (verified r7/r8): per iter i (kt e=2i, o=2i+1):
//   p0:(o).A0 p1:(o).B0 p2:(e+2).B1 p3:(e+2).A1 +vmcnt(4)
//   p4:(e+2).A0 p5:(e+2).B0 p6:(o+2).B1 p7:(o+2).A1 +vmcnt(4)
// Wrapped (kt>=NT) stages land in a dummy 16KB slot: vmcnt exact, no race.
// ============================================================================
#define SWZ_OFF(r, kb) ((kb) ^ (((r) & 7) << 4))

__device__ __forceinline__ void bar256() {
  __builtin_amdgcn_sched_barrier(0);
  __builtin_amdgcn_s_barrier();
  __builtin_amdgcn_sched_barrier(0);
}

__device__ __forceinline__ void stage_half(const bf16* __restrict__ g, long ldg,
                                           char* slot, int t) {
#pragma unroll
  for (int j = 0; j < 2; ++j) {
    const int L = t * 16 + j * 8192;
    const int r = L >> 7;
    const int kb = (L & 127) ^ ((r & 7) << 4);   // inverse-swizzled source chunk
    gload16(g + (long)r * ldg + (kb >> 1), slot + L);
  }
}

template<int NSEG, int NTSEG>
__device__ __forceinline__ void gemm256_core(
    const bf16* const* Aseg, long lda,
    const bf16* const* Bseg, long ldb,
    long m0, long n0, char* sm, f32x4 (&acc)[4][4][2])
{
  constexpr int NT = NSEG * NTSEG;
  const int t = threadIdx.x;
  const int lane = t & 63, wid = t >> 6;
  const int wm = wid >> 2, wn = wid & 3;
  const int l16 = lane & 15, lk = lane >> 4;

  auto STAGE = [&](int mat, int hf, int kt) {
    const bool wrap = (kt >= NT);
    const int ktw = wrap ? kt - NT : kt;
    const int seg = ktw / NTSEG, ktt = ktw % NTSEG;
    const int kp = ktw & 1;
    char* slot = wrap ? (sm + 131072)
                      : (mat == 0 ? sm + (kp * 2 + hf) * 16384
                                  : sm + 65536 + (kp * 2 + hf) * 16384);
    if (mat == 0)
      stage_half(Aseg[seg] + (m0 + (long)hf * 128) * lda + ktt * 64, lda, slot, t);
    else
      stage_half(Bseg[seg] + (n0 + (long)hf * 128) * ldb + ktt * 64, ldb, slot, t);
  };

  // prologue: kt0 all 4 halves; kt1 B1+A1
  STAGE(0, 0, 0); STAGE(0, 1, 0); STAGE(1, 0, 0); STAGE(1, 1, 0);
  STAGE(1, 1, 1); STAGE(0, 1, 1);
  __builtin_amdgcn_sched_barrier(0);
  asm volatile("s_waitcnt vmcnt(4)" ::: "memory");
  bar256();

  constexpr int s_mat[8] = {0, 1, 1, 0, 0, 1, 1, 0};
  constexpr int s_hf[8]  = {0, 0, 1, 1, 0, 0, 1, 1};
  constexpr int s_dkt[8] = {1, 1, 2, 2, 2, 2, 3, 3};

  bfrag8 af[4][2], bfr0[2][2], bfr1[2][2];

  for (int i = 0; i < NT / 2; ++i) {
#pragma unroll
    for (int p = 0; p < 8; ++p) {
      const int q = p & 3, kp = p >> 2;
      const int ah = (q >= 2) ? 1 : 0;
      const int bh = (q == 1 || q == 2) ? 1 : 0;
      const char* Ab = sm + (kp * 2 + ah) * 16384;
      const char* Bb = sm + 65536 + (kp * 2 + bh) * 16384;
      if (q == 0 || q == 2) {
#pragma unroll
        for (int mf = 0; mf < 4; ++mf) {
          const int rowA = wm * 64 + mf * 16 + l16;
#pragma unroll
          for (int ks = 0; ks < 2; ++ks)
            af[mf][ks] = *(const bfrag8*)(Ab + rowA * 128 +
                                          SWZ_OFF(rowA, ks * 64 + lk * 16));
        }
      }
      if (q == 0) {
#pragma unroll
        for (int nf = 0; nf < 2; ++nf) {
          const int rowB = wn * 32 + nf * 16 + l16;
#pragma unroll
          for (int ks = 0; ks < 2; ++ks)
            bfr0[nf][ks] = *(const bfrag8*)(Bb + rowB * 128 +
                                            SWZ_OFF(rowB, ks * 64 + lk * 16));
        }
      }
      if (q == 1) {
#pragma unroll
        for (int nf = 0; nf < 2; ++nf) {
          const int rowB = wn * 32 + nf * 16 + l16;
#pragma unroll
          for (int ks = 0; ks < 2; ++ks)
            bfr1[nf][ks] = *(const bfrag8*)(Bb + rowB * 128 +
                                            SWZ_OFF(rowB, ks * 64 + lk * 16));
        }
      }
      STAGE(s_mat[p], s_hf[p], 2 * i + s_dkt[p]);
      bar256();
      __builtin_amdgcn_s_setprio(1);
      if (q == 0 || q == 3) {
#pragma unroll
        for (int ks = 0; ks < 2; ++ks)
#pragma unroll
          for (int mf = 0; mf < 4; ++mf)
#pragma unroll
            for (int nf = 0; nf < 2; ++nf)
              mfma_bf16(acc[q][mf][nf], af[mf][ks], bfr0[nf][ks]);
      } else {
#pragma unroll
        for (int ks = 0; ks < 2; ++ks)
#pragma unroll
          for (int mf = 0; mf < 4; ++mf)
#pragma unroll
            for (int nf = 0; nf < 2; ++nf)
              mfma_bf16(acc[q][mf][nf], af[mf][ks], bfr1[nf][ks]);
      }
      __builtin_amdgcn_s_setprio(0);
      if (p == 3 || p == 7) {
        __builtin_amdgcn_sched_barrier(0);
        asm volatile("s_waitcnt vmcnt(4)" ::: "memory");
      }
      bar256();
    }
  }
}

// =================== fusion GEMM (256² 8-phase): out f32 NCHW ===================
__global__ __launch_bounds__(512, 2) void fusion_gemm256(
    const bf16* __restrict__ A, const bf16* __restrict__ Bt,
    float* __restrict__ Cf, const float* __restrict__ bias)
{
  __shared__ __align__(16) char sm[147456];     // 128K slots + 16K dummy
  const int orig = blockIdx.y * 128 + blockIdx.x;     // grid (128, 6)
  const int wgid = (orig & 7) * 96 + (orig >> 3);
  const long m0 = (long)(wgid / 6) * 256;
  const long n0 = (long)(wgid % 6) * 256;
  f32x4 acc[4][4][2];
#pragma unroll
  for (int q = 0; q < 4; ++q)
#pragma unroll
    for (int mf = 0; mf < 4; ++mf)
#pragma unroll
      for (int nf = 0; nf < 2; ++nf)
        acc[q][mf][nf] = f32x4{0.f, 0.f, 0.f, 0.f};
  const bf16* Aseg[1] = {A};
  const bf16* Bseg[1] = {Bt};
  gemm256_core<1, 24>(Aseg, 1536, Bseg, 1536, m0, n0, sm, acc);

  const int t = threadIdx.x;
  const int lane = t & 63, wid = t >> 6;
  const int wm = wid >> 2, wn = wid & 3;
  const int l16 = lane & 15, lk = lane >> 4;
  constexpr int s_ah[4] = {0, 0, 1, 1};
  constexpr int s_bh[4] = {0, 1, 1, 0};
  const long b = m0 >> 12;
#pragma unroll
  for (int q = 0; q < 4; ++q) {
    const int ah = s_ah[q], bh = s_bh[q];
#pragma unroll
    for (int mf = 0; mf < 4; ++mf) {
      const long row = m0 + ah * 128 + wm * 64 + mf * 16 + lk * 4;
      const long p = row & 4095;
#pragma unroll
      for (int nf = 0; nf < 2; ++nf) {
        const long gc = n0 + bh * 128 + wn * 32 + nf * 16 + l16;
        const float bb = bias[gc];
        float4 o4;
        o4.x = acc[q][mf][nf][0] + bb; o4.y = acc[q][mf][nf][1] + bb;
        o4.z = acc[q][mf][nf][2] + bb; o4.w = acc[q][mf][nf][3] + bb;
        *(float4*)(Cf + b * 6291456L + gc * 4096L + p) = o4;
      }
    }
  }
}

// ====== cross GEMM (256² 8-phase, 3-segment K incl. identity-residual) ======
__global__ __launch_bounds__(512, 2) void cross_gemm256(
    const bf16* __restrict__ xT, const bf16* __restrict__ Weff,
    const bf16* __restrict__ idB,
    bf16* __restrict__ crossB, const float* __restrict__ bo2,
    const float* __restrict__ mvec, float* __restrict__ pooled)
{
  __shared__ __align__(16) char sm[147456];
  const int z = blockIdx.z;             // qm*8 + b
  const int qm = z >> 3, b = z & 7;
  const int KM0[3] = {1, 0, 0}, KM1[3] = {2, 2, 1};
  const bf16* Aseg[3] = {
      xT + (long)KM0[qm] * 16777216 + (long)b * 2097152,
      xT + (long)KM1[qm] * 16777216 + (long)b * 2097152,
      xT + (long)qm * 16777216 + (long)b * 2097152};       // residual via identity
  const bf16* Bseg[3] = {
      Weff + ((long)(2 * qm) * 8 + b) * 262144,
      Weff + ((long)(2 * qm + 1) * 8 + b) * 262144,
      idB};
  const int orig = blockIdx.y * 16 + blockIdx.x;   // grid (16, 2, 24)
  const int wgid = (orig & 7) * 4 + (orig >> 3);
  const long m0 = (long)(wgid >> 1) * 256;
  const long n0 = (long)(wgid & 1) * 256;
  f32x4 acc[4][4][2];
#pragma unroll
  for (int q = 0; q < 4; ++q)
#pragma unroll
    for (int mf = 0; mf < 4; ++mf)
#pragma unroll
      for (int nf = 0; nf < 2; ++nf)
        acc[q][mf][nf] = f32x4{0.f, 0.f, 0.f, 0.f};
  gemm256_core<3, 8>(Aseg, 512, Bseg, 512, m0, n0, sm, acc);

  const int t = threadIdx.x;
  const int lane = t & 63, wid = t >> 6;
  const int wm = wid >> 2, wn = wid & 3;
  const int l16 = lane & 15, lk = lane >> 4;
  constexpr int s_ah[4] = {0, 0, 1, 1};
  constexpr int s_bh[4] = {0, 1, 1, 0};
  bf16* Cb = crossB + (long)qm * 16777216;
  const float* mv0 = mvec + ((long)(2 * qm) * 8 + b) * 512;
  const float* mv1 = mvec + ((long)(2 * qm + 1) * 8 + b) * 512;
  float csum[2][2] = {{0.f, 0.f}, {0.f, 0.f}};
#pragma unroll
  for (int q = 0; q < 4; ++q) {
    const int ah = s_ah[q], bh = s_bh[q];
#pragma unroll
    for (int mf = 0; mf < 4; ++mf) {
      const long row = m0 + ah * 128 + wm * 64 + mf * 16 + lk * 4;
      const long gr0 = (long)b * 4096 + row;
#pragma unroll
      for (int nf = 0; nf < 2; ++nf) {
        const long gc = n0 + bh * 128 + wn * 32 + nf * 16 + l16;
        const float bb = bo2[qm * 512 + gc] + mv0[gc] + mv1[gc];
#pragma unroll
        for (int i2 = 0; i2 < 4; ++i2) {
          const float o = acc[q][mf][nf][i2] + bb;
          Cb[(gr0 + i2) * 512 + gc] = __float2bfloat16(o);
          csum[bh][nf] += o;
        }
      }
    }
  }
#pragma unroll
  for (int bh = 0; bh < 2; ++bh)
#pragma unroll
    for (int nf = 0; nf < 2; ++nf) {
      float s = csum[bh][nf];
      s += __shfl_xor(s, 16);
      s += __shfl_xor(s, 32);
      if (lk == 0) {
        const long gc = n0 + bh * 128 + wn * 32 + nf * 16 + l16;
        atomicAdd(&pooled[((long)qm * 8 + b) * 512 + gc], s);
      }
    }
}

// ============ transpose + stats: NCHW f32 -> NHWC + channel-major bf16, colsum, quality ============
__global__ __launch_bounds__(256) void transpose_kernel(
    const float* __restrict__ x0, const float* __restrict__ x1,
    const float* __restrict__ x2, bf16* __restrict__ xT, bf16* __restrict__ xC,
    float* __restrict__ cs, float* __restrict__ qstage)
{
  __shared__ float tile[32][33];
  __shared__ float qpart[4][2];
  const int zz = blockIdx.z;           // m*8 + b
  const int m = zz >> 3, b = zz & 7;
  const float* x = (m == 0) ? x0 : (m == 1) ? x1 : x2;
  bf16* y = xT + (long)m * 16777216;
  bf16* y2 = xC + (long)m * 16777216;
  const int p0 = blockIdx.x * 32, c0 = blockIdx.y * 32;
  const int tx = threadIdx.x, ty = threadIdx.y;
  float csp[4];
  float qa = 0.f, qb_ = 0.f;   // m==0 (rgb): sum,ssq ; else: zero-count in qa
#pragma unroll
  for (int j = 0; j < 4; ++j) {
    const float v = x[((long)b * 512 + c0 + ty + j * 8) * 4096 + p0 + tx];
    tile[ty + j * 8][tx] = v;
    y2[(long)(c0 + ty + j * 8) * 32768 + (long)b * 4096 + p0 + tx] = __float2bfloat16(v);
    csp[j] = v;
    if (m == 0) { qa += v; qb_ += v * v; }
    else qa += (v == 0.0f) ? 1.0f : 0.0f;
  }
  __syncthreads();
#pragma unroll
  for (int j = 0; j < 4; ++j)
    y[((long)b * 4096 + p0 + ty + j * 8) * 512 + c0 + tx] =
        __float2bfloat16(tile[tx][ty + j * 8]);
#pragma unroll
  for (int j = 0; j < 4; ++j) {
    float s = csp[j];
    for (int o = 16; o; o >>= 1) s += __shfl_xor(s, o);
    if (tx == 0) atomicAdd(&cs[(m * 8 + b) * 512 + c0 + ty + j * 8], s);
  }
  const int t = ty * 32 + tx;
  const int lane = t & 63;
  for (int o = 32; o; o >>= 1) { qa += __shfl_xor(qa, o); qb_ += __shfl_xor(qb_, o); }
  if (lane == 0) { qpart[t >> 6][0] = qa; qpart[t >> 6][1] = qb_; }
  __syncthreads();
  if (t == 0) {
    const float pa = qpart[0][0] + qpart[1][0] + qpart[2][0] + qpart[3][0];
    const float pb = qpart[0][1] + qpart[1][1] + qpart[2][1] + qpart[3][1];
    float* qs = qstage + ((long)zz * 2048 + blockIdx.y * 128 + blockIdx.x) * 2;
    qs[0] = pa; qs[1] = pb;
  }
}

// =================== quality partial reduce -> qacc ===================
__global__ __launch_bounds__(256) void quality_reduce(
    const float* __restrict__ qstage, float* __restrict__ qacc)
{
  __shared__ float pr[4][2];
  const int zz = blockIdx.x;  // m*8 + b
  const int m = zz >> 3, b = zz & 7;
  const int t = threadIdx.x;
  float sa = 0.f, sb = 0.f;
  for (int i = t; i < 2048; i += 256) {
    sa += qstage[((long)zz * 2048 + i) * 2];
    sb += qstage[((long)zz * 2048 + i) * 2 + 1];
  }
  for (int o = 32; o; o >>= 1) { sa += __shfl_xor(sa, o); sb += __shfl_xor(sb, o); }
  if ((t & 63) == 0) { pr[t >> 6][0] = sa; pr[t >> 6][1] = sb; }
  __syncthreads();
  if (t == 0) {
    sa = pr[0][0] + pr[1][0] + pr[2][0] + pr[3][0];
    sb = pr[0][1] + pr[1][1] + pr[2][1] + pr[3][1];
    if (m == 0) { qacc[b * 4 + 1] = sa; qacc[b * 4 + 2] = sb; }
    else if (m == 1) qacc[b * 4 + 0] = sa;
    else qacc[b * 4 + 3] = sa;
  }
}

// =================== weight conversion ===================
__global__ void prep_weights(
    const float* __restrict__ wq, const float* __restrict__ wk,
    const float* __restrict__ wv, const float* __restrict__ wo,
    const float* __restrict__ fw, const float* __restrict__ bo,
    bf16* __restrict__ wqB, bf16* __restrict__ wkB, bf16* __restrict__ wvT,
    bf16* __restrict__ woB, bf16* __restrict__ fwB, float* __restrict__ bo2,
    bf16* __restrict__ idB)
{
  const long stride = (long)gridDim.x * blockDim.x;
  for (long j = (long)blockIdx.x * blockDim.x + threadIdx.x; j < 2359296; j += stride) {
    fwB[j] = __float2bfloat16(fw[j]);
    if (j < 1572864) {
      wqB[j] = __float2bfloat16(wq[j]);
      wkB[j] = __float2bfloat16(wk[j]);
      woB[j] = __float2bfloat16(wo[j]);
      const long i = j >> 18, rem = j & 262143, cin = rem >> 9, ef = rem & 511;
      wvT[j] = __float2bfloat16(wv[(i << 18) + (ef << 9) + cin]);
    }
    if (j < 262144) {
      const long r = j >> 9, c = j & 511;
      idB[j] = __float2bfloat16((r == c) ? 1.0f : 0.0f);
    }
    if (j < 1536) {
      const long m2 = j >> 9, cc = j & 511;
      bo2[j] = bo[((m2 * 2) << 9) + cc] + bo[((m2 * 2 + 1) << 9) + cc];
    }
  }
}

// =================== 128² GEMM core (m97-style) ===================
template<int BM, int BN>
__device__ __forceinline__ void gemm_core(
    const bf16* __restrict__ A, long lda,
    const bf16* __restrict__ Bt, long ldb,
    int K, long m0, long n0,
    bf16* As, bf16* Bs, f32x4 (&acc)[BM / 32][BN / 32])
{
  constexpr int WM = BM / 2, WN = BN / 2, FM = BM / 32, FN = BN / 32;
  const int t = threadIdx.x;
  const int lane = t & 63, wv = t >> 6;
  const int wr = wv >> 1, wc = wv & 1;
  const int l16 = lane & 15, lk = lane >> 4;
  const int srow = t >> 2;
  const int scol = (t & 3) * 8;
  const bf16* Ag = A + (m0 + srow) * lda + scol;
  const bf16* Bg = Bt + (n0 + srow) * ldb + scol;
  char* AsB = (char*)As;
  char* BsB = (char*)Bs;
  const int aoff = wv * 1024;
  for (int kk = 0; kk < K; kk += 32) {
#pragma unroll
    for (int it = 0; it < BM / 64; ++it)
      gload16(Ag + (long)it * 64 * lda + kk, AsB + it * 4096 + aoff);
#pragma unroll
    for (int it = 0; it < BN / 64; ++it)
      gload16(Bg + (long)it * 64 * ldb + kk, BsB + it * 4096 + aoff);
    __syncthreads();
    bfrag8 af[FM], bfr[FN];
#pragma unroll
    for (int m = 0; m < FM; ++m)
      af[m] = *(const bfrag8*)(AsB + ((wr * WM + m * 16 + l16) * 32 + lk * 8) * 2);
#pragma unroll
    for (int n = 0; n < FN; ++n)
      bfr[n] = *(const bfrag8*)(BsB + ((wc * WN + n * 16 + l16) * 32 + lk * 8) * 2);
#pragma unroll
    for (int m = 0; m < FM; ++m)
#pragma unroll
      for (int n = 0; n < FN; ++n)
        mfma_bf16(acc[m][n], af[m], bfr[n]);
    __syncthreads();
  }
}

// =================== Gram: G[i,j] = sum_p xA[p,i] xB[p,j], bf16 out ===================
__global__ __launch_bounds__(256, 2) void gram_kernel(
    const bf16* __restrict__ xC, bf16* __restrict__ Gb)
{
  __shared__ __align__(16) bf16 As[128 * 32];
  __shared__ __align__(16) bf16 Bs[128 * 32];
  const int z = blockIdx.z;
  const int pair = z >> 3, b = z & 7;
  const int A1[3] = {0, 0, 1}, A2[3] = {1, 2, 2};
  const bf16* A = xC + (long)A1[pair] * 16777216 + b * 4096;
  const bf16* Bt = xC + (long)A2[pair] * 16777216 + b * 4096;
  f32x4 acc[4][4];
#pragma unroll
  for (int m = 0; m < 4; ++m)
#pragma unroll
    for (int n = 0; n < 4; ++n)
      acc[m][n] = f32x4{0.f, 0.f, 0.f, 0.f};
  const long m0 = (long)blockIdx.x * 128, n0 = (long)blockIdx.y * 128;
  gemm_core<128, 128>(A, 32768, Bt, 32768, 4096, m0, n0, As, Bs, acc);
  bf16* C = Gb + (long)z * 262144;
  const int t = threadIdx.x;
  const int lane = t & 63, wv = t >> 6;
  const int wr = wv >> 1, wc = wv & 1;
  const int l16 = lane & 15, lk = lane >> 4;
#pragma unroll
  for (int m = 0; m < 4; ++m) {
    const long gr0 = m0 + wr * 64 + m * 16 + lk * 4;
#pragma unroll
    for (int n = 0; n < 4; ++n) {
      const long gc = n0 + wc * 64 + n * 16 + l16;
#pragma unroll
      for (int i = 0; i < 4; ++i)
        C[(gr0 + i) * 512 + gc] = __float2bfloat16(acc[m][n][i]);
    }
  }
}

// =================== scores+softmax -> attnT[e][d] ===================
__global__ __launch_bounds__(256, 2) void scores_kernel(
    const bf16* __restrict__ wqB, const bf16* __restrict__ wkB,
    const bf16* __restrict__ Gb, const float* __restrict__ colsum,
    const float* __restrict__ bq, const float* __restrict__ bk,
    bf16* __restrict__ attnT)
{
  __shared__ __align__(16) bf16 RtS[64 * 520];  // R^T bf16 ; later aliased as S f32 [64][68]
  __shared__ float uv[128];
  __shared__ __align__(16) bf16 attT[64][64];
  const int h = blockIdx.x, b = blockIdx.y, i = blockIdx.z;
  const int qm = i >> 1, jj = i & 1;
  const int km = jj ? (qm == 2 ? 1 : 2) : (qm == 0 ? 1 : 0);
  const int lo = qm < km ? qm : km, hi = qm < km ? km : qm;
  const int pair = lo + hi - 1;
  const int trans = qm > km;
  const bf16* G = Gb + ((long)(pair * 8 + b)) * 262144;
  const bf16* Wq_h = wqB + (long)i * 262144 + h * 64 * 512;
  const bf16* Wk_h = wkB + (long)i * 262144 + h * 64 * 512;
  const bf16* WA = trans ? Wk_h : Wq_h;
  const bf16* WB = trans ? Wq_h : Wk_h;
  const int t = threadIdx.x, lane = t & 63, wv = t >> 6;
  const int l16 = lane & 15, lk = lane >> 4;

  if (t < 128) {
    const int d = t & 63;
    const bf16* wrow = ((t < 64) ? Wq_h : Wk_h) + d * 512;
    const float* sv = colsum + (((t < 64) ? qm : km) * 8 + b) * 512;
    float a = 0.f;
    for (int c = 0; c < 512; c += 8) {
      const bfrag8 w8 = *(const bfrag8*)(wrow + c);
#pragma unroll
      for (int e = 0; e < 8; ++e) a += bf2f(w8[e]) * sv[c + e];
    }
    uv[t] = a;
  }

  // step A: R[512,64] = G . WB^T ; wave wv owns rows [wv*128, +128)
  f32x4 acc[8][4];
#pragma unroll
  for (int m = 0; m < 8; ++m)
#pragma unroll
    for (int n = 0; n < 4; ++n)
      acc[m][n] = f32x4{0.f, 0.f, 0.f, 0.f};
  for (int kk = 0; kk < 512; kk += 32) {
    bfrag8 a[8], bb[4];
#pragma unroll
    for (int m = 0; m < 8; ++m)
      a[m] = *(const bfrag8*)(G + (wv * 128 + m * 16 + l16) * 512 + kk + lk * 8);
#pragma unroll
    for (int n = 0; n < 4; ++n)
      bb[n] = *(const bfrag8*)(WB + (n * 16 + l16) * 512 + kk + lk * 8);
#pragma unroll
    for (int m = 0; m < 8; ++m)
#pragma unroll
      for (int n = 0; n < 4; ++n)
        mfma_bf16(acc[m][n], a[m], bb[n]);
  }
#pragma unroll
  for (int m = 0; m < 8; ++m)
#pragma unroll
    for (int n = 0; n < 4; ++n)
#pragma unroll
      for (int idx = 0; idx < 4; ++idx)
        RtS[(n * 16 + l16) * 520 + wv * 128 + m * 16 + lk * 4 + idx] =
            __float2bfloat16(acc[m][n][idx]);
  __syncthreads();

  // step B: S[64,64] = WA . Rt^T
  f32x4 acc2[4];
#pragma unroll
  for (int m = 0; m < 4; ++m) acc2[m] = f32x4{0.f, 0.f, 0.f, 0.f};
  for (int kk = 0; kk < 512; kk += 32) {
    bfrag8 a2[4];
#pragma unroll
    for (int m = 0; m < 4; ++m)
      a2[m] = *(const bfrag8*)(WA + (m * 16 + l16) * 512 + kk + lk * 8);
    const bfrag8 b2 = *(const bfrag8*)(&RtS[(wv * 16 + l16) * 520 + kk + lk * 8]);
#pragma unroll
    for (int m = 0; m < 4; ++m) mfma_bf16(acc2[m], a2[m], b2);
  }
  __syncthreads();
  float* S = (float*)RtS;  // [64][68]
#pragma unroll
  for (int m = 0; m < 4; ++m)
#pragma unroll
    for (int idx = 0; idx < 4; ++idx)
      S[(m * 16 + lk * 4 + idx) * 68 + wv * 16 + l16] = acc2[m][idx];
  __syncthreads();

  const int r = t >> 2, q = t & 3;   // r = d (query row), q*16+kq = e (key col)
  const float* bq_h = bq + i * 512 + h * 64;
  const float* bk_h = bk + i * 512 + h * 64;
  const float u_r = uv[r], bq_r = bq_h[r];
  float vals[16];
  float mx = -1e30f;
#pragma unroll
  for (int kq = 0; kq < 16; ++kq) {
    const int k = q * 16 + kq;
    float s = trans ? S[k * 68 + r] : S[r * 68 + k];
    s += u_r * bk_h[k] + bq_r * uv[64 + k] + 4096.0f * bq_r * bk_h[k];
    s *= 0.125f;
    vals[kq] = s;
    mx = fmaxf(mx, s);
  }
  mx = fmaxf(mx, __shfl_xor(mx, 1));
  mx = fmaxf(mx, __shfl_xor(mx, 2));
  float sum = 0.f;
#pragma unroll
  for (int kq = 0; kq < 16; ++kq) { vals[kq] = expf(vals[kq] - mx); sum += vals[kq]; }
  sum += __shfl_xor(sum, 1);
  sum += __shfl_xor(sum, 2);
  const float inv = 1.0f / sum;
#pragma unroll
  for (int kq = 0; kq < 16; ++kq)
    attT[q * 16 + kq][r] = __float2bfloat16(vals[kq] * inv);
  __syncthreads();
  const int er = t >> 2, c16 = (t & 3) * 16;
  bf16* op = attnT + (((long)(i * 8 + b) * 8 + h) * 64 + er) * 64 + c16;
  *(bfrag8*)(op) = *(const bfrag8*)(&attT[er][c16]);
  *(bfrag8*)(op + 8) = *(const bfrag8*)(&attT[er][c16 + 8]);
}

// =================== mfold: M[c,ef] = sum_d Wo[c, h*64+d] * attnT[e,d]; mvec += M.bv ===================
__global__ __launch_bounds__(256, 2) void mfold_kernel(
    const bf16* __restrict__ woB, const bf16* __restrict__ attnT,
    const float* __restrict__ bv, bf16* __restrict__ Mbuf, float* __restrict__ mvec)
{
  __shared__ __align__(16) bf16 As[128 * 32];
  __shared__ __align__(16) bf16 Bs[64 * 32];
  const int ib = blockIdx.z;          // i*8+b
  const int i = ib >> 3;
  const int h = blockIdx.y;
  const bf16* A = woB + (long)i * 262144 + h * 64;
  const bf16* Bt = attnT + ((long)ib * 8 + h) * 4096;
  f32x4 acc[4][2];
#pragma unroll
  for (int m = 0; m < 4; ++m)
#pragma unroll
    for (int n = 0; n < 2; ++n)
      acc[m][n] = f32x4{0.f, 0.f, 0.f, 0.f};
  const long m0 = (long)blockIdx.x * 128;
  gemm_core<128, 64>(A, 512, Bt, 64, 64, m0, 0, As, Bs, acc);

  const int t = threadIdx.x;
  const int lane = t & 63, wv = t >> 6;
  const int wr = wv >> 1, wc = wv & 1;
  const int l16 = lane & 15, lk = lane >> 4;
  bf16* C = Mbuf + (long)ib * 262144;
  const float* bvp = bv + i * 512 + h * 64;
  float mp[4][4];
#pragma unroll
  for (int m = 0; m < 4; ++m)
#pragma unroll
    for (int i2 = 0; i2 < 4; ++i2) mp[m][i2] = 0.f;
#pragma unroll
  for (int m = 0; m < 4; ++m) {
    const long gr0 = m0 + wr * 64 + m * 16 + lk * 4;
#pragma unroll
    for (int n = 0; n < 2; ++n) {
      const int gc = wc * 32 + n * 16 + l16;
      const float bvv = bvp[gc];
#pragma unroll
      for (int i2 = 0; i2 < 4; ++i2) {
        C[(gr0 + i2) * 512 + h * 64 + gc] = __float2bfloat16(acc[m][n][i2]);
        mp[m][i2] += acc[m][n][i2] * bvv;
      }
    }
  }
#pragma unroll
  for (int m = 0; m < 4; ++m)
#pragma unroll
    for (int i2 = 0; i2 < 4; ++i2) {
      float v = mp[m][i2];
      v += __shfl_xor(v, 1); v += __shfl_xor(v, 2);
      v += __shfl_xor(v, 4); v += __shfl_xor(v, 8);
      if (l16 == 0)
        atomicAdd(&mvec[(long)ib * 512 + m0 + wr * 64 + m * 16 + lk * 4 + i2], v);
    }
}

// =================== weff: W_eff[c,cin] = sum_ef M[c,ef] * wvT[cin,ef] ===================
__global__ __launch_bounds__(256, 2) void weff_gemm(
    const bf16* __restrict__ Mbuf, const bf16* __restrict__ wvT,
    bf16* __restrict__ Weff)
{
  __shared__ __align__(16) bf16 As[128 * 32];
  __shared__ __align__(16) bf16 Bs[128 * 32];
  const int ib = blockIdx.z;
  const int i = ib >> 3;
  f32x4 acc[4][4];
#pragma unroll
  for (int m = 0; m < 4; ++m)
#pragma unroll
    for (int n = 0; n < 4; ++n)
      acc[m][n] = f32x4{0.f, 0.f, 0.f, 0.f};
  const long m0 = (long)blockIdx.x * 128, n0 = (long)blockIdx.y * 128;
  gemm_core<128, 128>(Mbuf + (long)ib * 262144, 512, wvT + (long)i * 262144, 512,
                      512, m0, n0, As, Bs, acc);
  bf16* C = Weff + (long)ib * 262144;
  const int t = threadIdx.x;
  const int lane = t & 63, wv = t >> 6;
  const int wr = wv >> 1, wc = wv & 1;
  const int l16 = lane & 15, lk = lane >> 4;
#pragma unroll
  for (int m = 0; m < 4; ++m) {
    const long gr0 = m0 + wr * 64 + m * 16 + lk * 4;
#pragma unroll
    for (int n = 0; n < 4; ++n) {
      const long gc = n0 + wc * 64 + n * 16 + l16;
#pragma unroll
      for (int i2 = 0; i2 < 4; ++i2)
        C[(gr0 + i2) * 512 + gc] = __float2bfloat16(acc[m][n][i2]);
    }
  }
}

// =================== SE MLP ===================
__global__ __launch_bounds__(512) void se_mlp(
    const float* __restrict__ pooled,
    const float* __restrict__ W1, const float* __restrict__ b1,
    const float* __restrict__ W2, const float* __restrict__ b2,
    float* __restrict__ se)
{
  const int b = blockIdx.x, m = blockIdx.y;
  __shared__ float y[32];
  const int t = threadIdx.x;
  if (t < 32) {
    float s = b1[m * 32 + t];
    const float* w = W1 + (long)(m * 32 + t) * 512;
    const float* p = pooled + ((long)m * 8 + b) * 512;
    for (int c = 0; c < 512; ++c) s += w[c] * (p[c] * (1.0f / 4096.0f));
    y[t] = fmaxf(s, 0.0f);
  }
  __syncthreads();
  float s = b2[m * 512 + t];
  const float* w2 = W2 + (long)(m * 512 + t) * 32;
#pragma unroll
  for (int j = 0; j < 32; ++j) s += w2[j] * y[j];
  se[((long)m * 8 + b) * 512 + t] = 1.0f / (1.0f + expf(-s));
}

// ========= refined = l2norm_c(cross*se); alpha = sigmoid(gate); weighted out (fused) =========
__global__ __launch_bounds__(384) void refine_gate(
    const bf16* __restrict__ cr0, const bf16* __restrict__ cr1,
    const bf16* __restrict__ cr2, const float* __restrict__ se,
    const float* __restrict__ gw, const float* __restrict__ gb,
    const float* __restrict__ qacc, bf16* __restrict__ weighted)
{
  __shared__ float part[2][3][3];
  const int t = threadIdx.x, wv = t >> 6, lane = t & 63;
  const int px_i = (wv >= 3) ? 1 : 0;
  const int m = wv - px_i * 3;
  const int pix = blockIdx.x * 2 + px_i;
  const int b = pix >> 12;
  const bf16* cr = (m == 0) ? cr0 : (m == 1) ? cr1 : cr2;
  const int c0 = lane * 8;
  const bfrag8 v8 = *(const bfrag8*)(cr + (long)pix * 512 + c0);
  const float* sp = se + ((long)m * 8 + b) * 512 + c0;
  const float4 s0 = *(const float4*)(sp);
  const float4 s1 = *(const float4*)(sp + 4);
  float w[8] = {bf2f(v8[0]) * s0.x, bf2f(v8[1]) * s0.y,
                bf2f(v8[2]) * s0.z, bf2f(v8[3]) * s0.w,
                bf2f(v8[4]) * s1.x, bf2f(v8[5]) * s1.y,
                bf2f(v8[6]) * s1.z, bf2f(v8[7]) * s1.w};
  float ss = 0.f;
#pragma unroll
  for (int i = 0; i < 8; ++i) ss += w[i] * w[i];
  for (int o = 32; o; o >>= 1) ss += __shfl_xor(ss, o);
  const float inv = 1.0f / (sqrtf(ss) + 1e-6f);
  float rf[8];
#pragma unroll
  for (int i = 0; i < 8; ++i) rf[i] = w[i] * inv;

  float a0 = 0.f, a1 = 0.f, a2 = 0.f;
#pragma unroll
  for (int i = 0; i < 8; ++i) {
    const int c = m * 512 + c0 + i;
    a0 += gw[c] * rf[i];
    a1 += gw[1539 + c] * rf[i];
    a2 += gw[3078 + c] * rf[i];
  }
  for (int o = 32; o; o >>= 1) {
    a0 += __shfl_xor(a0, o); a1 += __shfl_xor(a1, o); a2 += __shfl_xor(a2, o);
  }
  if (lane == 0) {
    part[px_i][m][0] = a0; part[px_i][m][1] = a1; part[px_i][m][2] = a2;
  }
  __syncthreads();
  const float N = 2097152.0f;
  const float q0 = qacc[b * 4 + 0] / N;
  const float q1 = (qacc[b * 4 + 2] - qacc[b * 4 + 1] * qacc[b * 4 + 1] / N) / (N - 1.0f);
  const float q2 = qacc[b * 4 + 3] / N;
  const float sg = part[px_i][0][m] + part[px_i][1][m] + part[px_i][2][m] + gb[m] +
                   gw[m * 1539 + 1536] * q0 + gw[m * 1539 + 1537] * q1 +
                   gw[m * 1539 + 1538] * q2;
  const float al = 1.0f / (1.0f + expf(-sg));
  __align__(16) bf16 tmp[8];
#pragma unroll
  for (int i = 0; i < 8; ++i) tmp[i] = __float2bfloat16(rf[i] * al);
  *(bfrag8*)(weighted + (long)pix * 1536 + m * 512 + c0) = *(const bfrag8*)tmp;
}

// =================== host launch ===================
extern "C" void kernel_launch(void* const* d_in, const int* in_sizes, int n_in,
                              void* d_out, int out_size, void* d_ws, size_t ws_size,
                              hipStream_t stream)
{
  (void)in_sizes; (void)n_in; (void)out_size; (void)ws_size;
  const float* rgb   = (const float*)d_in[0];
  const float* depth = (const float*)d_in[1];
  const float* lidar = (const float*)d_in[2];
  const float* wq  = (const float*)d_in[3];
  const float* bq  = (const float*)d_in[4];
  const float* wk  = (const float*)d_in[5];
  const float* bk  = (const float*)d_in[6];
  const float* wvw = (const float*)d_in[7];
  const float* bv  = (const float*)d_in[8];
  const float* wo  = (const float*)d_in[9];
  const float* bo  = (const float*)d_in[10];
  const float* seW1 = (const float*)d_in[11];
  const float* seb1 = (const float*)d_in[12];
  const float* seW2 = (const float*)d_in[13];
  const float* seb2 = (const float*)d_in[14];
  const float* gw  = (const float*)d_in[15];
  const float* gb  = (const float*)d_in[16];
  const float* fw  = (const float*)d_in[17];
  const float* fb  = (const float*)d_in[18];

  char* ws = (char*)d_ws;
  bf16*  xT   = (bf16*)(ws + OFF_XT);
  bf16*  xC   = (bf16*)(ws + OFF_XC);
  bf16*  wqB  = (bf16*)(ws + OFF_WQ);
  bf16*  wkB  = (bf16*)(ws + OFF_WK);
  bf16*  wvT  = (bf16*)(ws + OFF_WVT);
  bf16*  woB  = (bf16*)(ws + OFF_WOB);
  bf16*  fwB  = (bf16*)(ws + OFF_FW);
  float* bo2  = (float*)(ws + OFF_BO2);
  float* pooled = (float*)(ws + OFF_POOL);
  float* seB  = (float*)(ws + OFF_SE);
  float* qacc = (float*)(ws + OFF_QACC);
  float* cs   = (float*)(ws + OFF_CS);
  bf16*  Gb   = (bf16*)(ws + OFF_GB);
  bf16*  attnT = (bf16*)(ws + OFF_ATT);
  float* qstage = (float*)(ws + OFF_QST);
  float* mvec = (float*)(ws + OFF_MVEC);
  bf16*  idB  = (bf16*)(ws + OFF_IDB);
  bf16*  Mbuf = (bf16*)(ws + OFF_XC);              // alias, dead after weff
  bf16*  Weff = (bf16*)(ws + OFF_XC + 25165824L);  // alias, dead after cross
  bf16*  crossB = (bf16*)(ws + OFF_VST);

  // zero: pooled (+se, qacc harmlessly), colsum ; mvec
  (void)hipMemsetAsync(ws + OFF_POOL, 0, OFF_CS + 49152 - OFF_POOL, stream);
  (void)hipMemsetAsync(ws + OFF_MVEC, 0, 98304, stream);

  transpose_kernel<<<dim3(128, 16, 24), dim3(32, 8), 0, stream>>>(rgb, depth, lidar,
                                                                  xT, xC, cs, qstage);
  quality_reduce<<<24, 256, 0, stream>>>(qstage, qacc);
  prep_weights<<<2048, 256, 0, stream>>>(wq, wk, wvw, wo, fw, bo,
                                         wqB, wkB, wvT, woB, fwB, bo2, idB);

  gram_kernel<<<dim3(4, 4, 24), 256, 0, stream>>>(xC, Gb);
  scores_kernel<<<dim3(8, 8, 6), 256, 0, stream>>>(wqB, wkB, Gb, cs, bq, bk, attnT);

  mfold_kernel<<<dim3(4, 8, 48), 256, 0, stream>>>(woB, attnT, bv, Mbuf, mvec);
  weff_gemm<<<dim3(4, 4, 48), 256, 0, stream>>>(Mbuf, wvT, Weff);

  cross_gemm256<<<dim3(16, 2, 24), 512, 0, stream>>>(xT, Weff, idB, crossB, bo2,
                                                     mvec, pooled);
  se_mlp<<<dim3(8, 3), 512, 0, stream>>>(pooled, seW1, seb1, seW2, seb2, seB);

  bf16* cross0 = crossB;
  bf16* cross1 = (bf16*)(ws + OFF_VST + 33554432L);
  bf16* cross2 = (bf16*)(ws + OFF_VST + 67108864L);
  bf16* weighted = (bf16*)(ws + OFF_XC);
  refine_gate<<<16384, 384, 0, stream>>>(cross0, cross1, cross2, seB, gw, gb, qacc, weighted);

  fusion_gemm256<<<dim3(128, 6), 512, 0, stream>>>(weighted, fwB, (float*)d_out, fb);
}

// Round 10
// 723.692 us; speedup vs baseline: 2.1012x; 1.1156x over previous
//
#include <hip/hip_runtime.h>
#include <hip/hip_bf16.h>
#include <stdint.h>

using bf16 = __hip_bfloat16;
typedef short bfrag8 __attribute__((ext_vector_type(8)));
typedef short bfrag4 __attribute__((ext_vector_type(4)));
typedef float f32x4 __attribute__((ext_vector_type(4)));

// ---------------- workspace layout (bytes) ----------------
constexpr long OFF_XT   = 0L;           // 3 x [32768][512] bf16 NHWC (live until cross_gemm)
constexpr long OFF_XC   = 100663296L;   // 3 x [512][32768] bf16 channel-major (dead after gram)
constexpr long OFF_WQ   = 201326592L;   // 6 x [512][512] bf16
constexpr long OFF_WK   = 204472320L;
constexpr long OFF_WVT  = 207618048L;   // 6 x [cin 512][ef 512] bf16 (Wv transposed)
constexpr long OFF_WOB  = 210763776L;   // 6 x [512][512] bf16 (Wo plain)
constexpr long OFF_FW   = 213909504L;   // [1536][1536] bf16
constexpr long OFF_BO2  = 218628096L;   // [3][512] f32
constexpr long OFF_POOL = 218646528L;   // [3][8][512] f32   (memset from here)
constexpr long OFF_SE   = 218695680L;   // [3][8][512] f32
constexpr long OFF_QACC = 218744832L;   // [8][4] f32 (+pad to 1024)
constexpr long OFF_CS   = 218745856L;   // [3][8][512] f32 column sums (memset to here+49152)
constexpr long OFF_GB   = 218795008L;   // [3][8][512][512] bf16 Gram
constexpr long OFF_ATT  = 231377920L;   // attnT [6][8][8][64(e)][64(d)] bf16
constexpr long OFF_VST  = 234523648L;   // cross bf16 3 x [32768][512] (96 MB)
constexpr long OFF_QST  = 435850240L;   // [24][512][2] f32 quality partials
constexpr long OFF_MVEC = 436243456L;   // [48][512] f32 (memset)
constexpr long OFF_IDB  = 436341760L;   // [512][512] bf16 identity
// aliases in XC region: Mbuf = OFF_XC, Weff = OFF_XC+25165824 ; weighted = OFF_XC after dead

__device__ __forceinline__ void mfma_bf16(f32x4& c, bfrag8 a, bfrag8 b) {
  asm("v_mfma_f32_16x16x32_bf16 %0, %1, %2, %0" : "+v"(c) : "v"(a), "v"(b));
}

__device__ __forceinline__ void gload16(const void* g, void* l) {
  __builtin_amdgcn_global_load_lds(
      (__attribute__((address_space(1))) void*)(g),
      (__attribute__((address_space(3))) void*)(l), 16, 0, 0);
}

__device__ __forceinline__ float bf2f(short s) {
  union { uint32_t u; float f; } cv;
  cv.u = ((uint32_t)(unsigned short)s) << 16;
  return cv.f;
}

// XCD-chunked bijective swizzle, n-fast logical order. Requires gx*gy % 8 == 0.
__device__ __forceinline__ void swz_mn(int gy, long& m0, long& n0) {
  const int gx = gridDim.x;
  const int orig = blockIdx.y * gx + blockIdx.x;
  const int q = (gx * gy) >> 3;
  const int wgid = (orig & 7) * q + (orig >> 3);
  m0 = (long)(wgid / gy) * 128;
  n0 = (long)(wgid % gy) * 128;
}

// ============================================================================
// 256x256 8-phase GEMM core (multi-segment K) with register-reuse phase order:
//   q0=(A0,B0) q1=(A0,B1) q2=(A1,B1) q3=(A1,B0)
// Stage ledger (verified r7/r8): per iter i (kt e=2i, o=2i+1):
//   p0:(o).A0 p1:(o).B0 p2:(e+2).B1 p3:(e+2).A1 +vmcnt(4)
//   p4:(e+2).A0 p5:(e+2).B0 p6:(o+2).B1 p7:(o+2).A1 +vmcnt(4)
// Wrapped (kt>=NT) stages land in a dummy 16KB slot: vmcnt exact, no race.
// ============================================================================
#define SWZ_OFF(r, kb) ((kb) ^ (((r) & 7) << 4))

__device__ __forceinline__ void bar256() {
  __builtin_amdgcn_sched_barrier(0);
  __builtin_amdgcn_s_barrier();
  __builtin_amdgcn_sched_barrier(0);
}

__device__ __forceinline__ void stage_half(const bf16* __restrict__ g, long ldg,
                                           char* slot, int t) {
#pragma unroll
  for (int j = 0; j < 2; ++j) {
    const int L = t * 16 + j * 8192;
    const int r = L >> 7;
    const int kb = (L & 127) ^ ((r & 7) << 4);   // inverse-swizzled source chunk
    gload16(g + (long)r * ldg + (kb >> 1), slot + L);
  }
}

template<int NSEG, int NTSEG>
__device__ __forceinline__ void gemm256_core(
    const bf16* const* Aseg, long lda,
    const bf16* const* Bseg, long ldb,
    long m0, long n0, char* sm, f32x4 (&acc)[4][4][2])
{
  constexpr int NT = NSEG * NTSEG;
  const int t = threadIdx.x;
  const int lane = t & 63, wid = t >> 6;
  const int wm = wid >> 2, wn = wid & 3;
  const int l16 = lane & 15, lk = lane >> 4;

  auto STAGE = [&](int mat, int hf, int kt) {
    const bool wrap = (kt >= NT);
    const int ktw = wrap ? kt - NT : kt;
    const int seg = ktw / NTSEG, ktt = ktw % NTSEG;
    const int kp = ktw & 1;
    char* slot = wrap ? (sm + 131072)
                      : (mat == 0 ? sm + (kp * 2 + hf) * 16384
                                  : sm + 65536 + (kp * 2 + hf) * 16384);
    if (mat == 0)
      stage_half(Aseg[seg] + (m0 + (long)hf * 128) * lda + ktt * 64, lda, slot, t);
    else
      stage_half(Bseg[seg] + (n0 + (long)hf * 128) * ldb + ktt * 64, ldb, slot, t);
  };

  // prologue: kt0 all 4 halves; kt1 B1+A1
  STAGE(0, 0, 0); STAGE(0, 1, 0); STAGE(1, 0, 0); STAGE(1, 1, 0);
  STAGE(1, 1, 1); STAGE(0, 1, 1);
  __builtin_amdgcn_sched_barrier(0);
  asm volatile("s_waitcnt vmcnt(4)" ::: "memory");
  bar256();

  constexpr int s_mat[8] = {0, 1, 1, 0, 0, 1, 1, 0};
  constexpr int s_hf[8]  = {0, 0, 1, 1, 0, 0, 1, 1};
  constexpr int s_dkt[8] = {1, 1, 2, 2, 2, 2, 3, 3};

  bfrag8 af[4][2], bfr0[2][2], bfr1[2][2];

  for (int i = 0; i < NT / 2; ++i) {
#pragma unroll
    for (int p = 0; p < 8; ++p) {
      const int q = p & 3, kp = p >> 2;
      const int ah = (q >= 2) ? 1 : 0;
      const int bh = (q == 1 || q == 2) ? 1 : 0;
      const char* Ab = sm + (kp * 2 + ah) * 16384;
      const char* Bb = sm + 65536 + (kp * 2 + bh) * 16384;
      if (q == 0 || q == 2) {
#pragma unroll
        for (int mf = 0; mf < 4; ++mf) {
          const int rowA = wm * 64 + mf * 16 + l16;
#pragma unroll
          for (int ks = 0; ks < 2; ++ks)
            af[mf][ks] = *(const bfrag8*)(Ab + rowA * 128 +
                                          SWZ_OFF(rowA, ks * 64 + lk * 16));
        }
      }
      if (q == 0) {
#pragma unroll
        for (int nf = 0; nf < 2; ++nf) {
          const int rowB = wn * 32 + nf * 16 + l16;
#pragma unroll
          for (int ks = 0; ks < 2; ++ks)
            bfr0[nf][ks] = *(const bfrag8*)(Bb + rowB * 128 +
                                            SWZ_OFF(rowB, ks * 64 + lk * 16));
        }
      }
      if (q == 1) {
#pragma unroll
        for (int nf = 0; nf < 2; ++nf) {
          const int rowB = wn * 32 + nf * 16 + l16;
#pragma unroll
          for (int ks = 0; ks < 2; ++ks)
            bfr1[nf][ks] = *(const bfrag8*)(Bb + rowB * 128 +
                                            SWZ_OFF(rowB, ks * 64 + lk * 16));
        }
      }
      STAGE(s_mat[p], s_hf[p], 2 * i + s_dkt[p]);
      bar256();
      __builtin_amdgcn_s_setprio(1);
      if (q == 0 || q == 3) {
#pragma unroll
        for (int ks = 0; ks < 2; ++ks)
#pragma unroll
          for (int mf = 0; mf < 4; ++mf)
#pragma unroll
            for (int nf = 0; nf < 2; ++nf)
              mfma_bf16(acc[q][mf][nf], af[mf][ks], bfr0[nf][ks]);
      } else {
#pragma unroll
        for (int ks = 0; ks < 2; ++ks)
#pragma unroll
          for (int mf = 0; mf < 4; ++mf)
#pragma unroll
            for (int nf = 0; nf < 2; ++nf)
              mfma_bf16(acc[q][mf][nf], af[mf][ks], bfr1[nf][ks]);
      }
      __builtin_amdgcn_s_setprio(0);
      if (p == 3 || p == 7) {
        __builtin_amdgcn_sched_barrier(0);
        asm volatile("s_waitcnt vmcnt(4)" ::: "memory");
      }
      bar256();
    }
  }
}

// =================== fusion GEMM (256² 8-phase): out f32 NCHW ===================
__global__ __launch_bounds__(512, 2) void fusion_gemm256(
    const bf16* __restrict__ A, const bf16* __restrict__ Bt,
    float* __restrict__ Cf, const float* __restrict__ bias)
{
  __shared__ __align__(16) char sm[147456];     // 128K slots + 16K dummy
  const int orig = blockIdx.y * 128 + blockIdx.x;     // grid (128, 6)
  const int wgid = (orig & 7) * 96 + (orig >> 3);
  const long m0 = (long)(wgid / 6) * 256;
  const long n0 = (long)(wgid % 6) * 256;
  f32x4 acc[4][4][2];
#pragma unroll
  for (int q = 0; q < 4; ++q)
#pragma unroll
    for (int mf = 0; mf < 4; ++mf)
#pragma unroll
      for (int nf = 0; nf < 2; ++nf)
        acc[q][mf][nf] = f32x4{0.f, 0.f, 0.f, 0.f};
  const bf16* Aseg[1] = {A};
  const bf16* Bseg[1] = {Bt};
  gemm256_core<1, 24>(Aseg, 1536, Bseg, 1536, m0, n0, sm, acc);

  const int t = threadIdx.x;
  const int lane = t & 63, wid = t >> 6;
  const int wm = wid >> 2, wn = wid & 3;
  const int l16 = lane & 15, lk = lane >> 4;
  constexpr int s_ah[4] = {0, 0, 1, 1};
  constexpr int s_bh[4] = {0, 1, 1, 0};
  const long b = m0 >> 12;
#pragma unroll
  for (int q = 0; q < 4; ++q) {
    const int ah = s_ah[q], bh = s_bh[q];
#pragma unroll
    for (int mf = 0; mf < 4; ++mf) {
      const long row = m0 + ah * 128 + wm * 64 + mf * 16 + lk * 4;
      const long p = row & 4095;
#pragma unroll
      for (int nf = 0; nf < 2; ++nf) {
        const long gc = n0 + bh * 128 + wn * 32 + nf * 16 + l16;
        const float bb = bias[gc];
        float4 o4;
        o4.x = acc[q][mf][nf][0] + bb; o4.y = acc[q][mf][nf][1] + bb;
        o4.z = acc[q][mf][nf][2] + bb; o4.w = acc[q][mf][nf][3] + bb;
        *(float4*)(Cf + b * 6291456L + gc * 4096L + p) = o4;
      }
    }
  }
}

// ====== cross GEMM (256² 8-phase, 3-segment K incl. identity-residual) ======
__global__ __launch_bounds__(512, 2) void cross_gemm256(
    const bf16* __restrict__ xT, const bf16* __restrict__ Weff,
    const bf16* __restrict__ idB,
    bf16* __restrict__ crossB, const float* __restrict__ bo2,
    const float* __restrict__ mvec, float* __restrict__ pooled)
{
  __shared__ __align__(16) char sm[147456];
  const int z = blockIdx.z;             // qm*8 + b
  const int qm = z >> 3, b = z & 7;
  const int KM0[3] = {1, 0, 0}, KM1[3] = {2, 2, 1};
  const bf16* Aseg[3] = {
      xT + (long)KM0[qm] * 16777216 + (long)b * 2097152,
      xT + (long)KM1[qm] * 16777216 + (long)b * 2097152,
      xT + (long)qm * 16777216 + (long)b * 2097152};       // residual via identity
  const bf16* Bseg[3] = {
      Weff + ((long)(2 * qm) * 8 + b) * 262144,
      Weff + ((long)(2 * qm + 1) * 8 + b) * 262144,
      idB};
  const int orig = blockIdx.y * 16 + blockIdx.x;   // grid (16, 2, 24)
  const int wgid = (orig & 7) * 4 + (orig >> 3);
  const long m0 = (long)(wgid >> 1) * 256;
  const long n0 = (long)(wgid & 1) * 256;
  f32x4 acc[4][4][2];
#pragma unroll
  for (int q = 0; q < 4; ++q)
#pragma unroll
    for (int mf = 0; mf < 4; ++mf)
#pragma unroll
      for (int nf = 0; nf < 2; ++nf)
        acc[q][mf][nf] = f32x4{0.f, 0.f, 0.f, 0.f};
  gemm256_core<3, 8>(Aseg, 512, Bseg, 512, m0, n0, sm, acc);

  const int t = threadIdx.x;
  const int lane = t & 63, wid = t >> 6;
  const int wm = wid >> 2, wn = wid & 3;
  const int l16 = lane & 15, lk = lane >> 4;
  constexpr int s_ah[4] = {0, 0, 1, 1};
  constexpr int s_bh[4] = {0, 1, 1, 0};
  bf16* Cb = crossB + (long)qm * 16777216;
  const float* mv0 = mvec + ((long)(2 * qm) * 8 + b) * 512;
  const float* mv1 = mvec + ((long)(2 * qm + 1) * 8 + b) * 512;
  float csum[2][2] = {{0.f, 0.f}, {0.f, 0.f}};
#pragma unroll
  for (int q = 0; q < 4; ++q) {
    const int ah = s_ah[q], bh = s_bh[q];
#pragma unroll
    for (int mf = 0; mf < 4; ++mf) {
      const long row = m0 + ah * 128 + wm * 64 + mf * 16 + lk * 4;
      const long gr0 = (long)b * 4096 + row;
#pragma unroll
      for (int nf = 0; nf < 2; ++nf) {
        const long gc = n0 + bh * 128 + wn * 32 + nf * 16 + l16;
        const float bb = bo2[qm * 512 + gc] + mv0[gc] + mv1[gc];
#pragma unroll
        for (int i2 = 0; i2 < 4; ++i2) {
          const float o = acc[q][mf][nf][i2] + bb;
          Cb[(gr0 + i2) * 512 + gc] = __float2bfloat16(o);
          csum[bh][nf] += o;
        }
      }
    }
  }
#pragma unroll
  for (int bh = 0; bh < 2; ++bh)
#pragma unroll
    for (int nf = 0; nf < 2; ++nf) {
      float s = csum[bh][nf];
      s += __shfl_xor(s, 16);
      s += __shfl_xor(s, 32);
      if (lk == 0) {
        const long gc = n0 + bh * 128 + wn * 32 + nf * 16 + l16;
        atomicAdd(&pooled[((long)qm * 8 + b) * 512 + gc], s);
      }
    }
}

// ============ transpose + stats (vectorized): NCHW f32 -> NHWC + channel-major bf16 ============
// block 256, tile 128p x 32c ; LDS tile [c 32][p 128] bf16 pitch 132
__global__ __launch_bounds__(256) void transpose_kernel(
    const float* __restrict__ x0, const float* __restrict__ x1,
    const float* __restrict__ x2, bf16* __restrict__ xT, bf16* __restrict__ xC,
    float* __restrict__ cs, float* __restrict__ qstage)
{
  __shared__ __align__(16) bf16 tile[32 * 132];
  __shared__ float qpart[4][2];
  const int zz = blockIdx.z;           // m*8 + b
  const int m = zz >> 3, b = zz & 7;
  const float* x = (m == 0) ? x0 : (m == 1) ? x1 : x2;
  const int p0 = blockIdx.x * 128, c0 = blockIdx.y * 32;
  const int t = threadIdx.x;
  const int tx = t & 31, cy = t >> 5;
  bf16* y2 = xC + (long)m * 16777216;
  float qa = 0.f, qb_ = 0.f;
#pragma unroll
  for (int jc = 0; jc < 4; ++jc) {
    const int cl = jc * 8 + cy;
    const int c = c0 + cl;
    const float4 v = *(const float4*)(x + ((long)(b * 512 + c)) * 4096 + p0 + tx * 4);
    if (m == 0) {
      qa += v.x + v.y + v.z + v.w;
      qb_ += v.x * v.x + v.y * v.y + v.z * v.z + v.w * v.w;
    } else {
      qa += ((v.x == 0.0f) ? 1.f : 0.f) + ((v.y == 0.0f) ? 1.f : 0.f) +
            ((v.z == 0.0f) ? 1.f : 0.f) + ((v.w == 0.0f) ? 1.f : 0.f);
    }
    float s = v.x + v.y + v.z + v.w;
    for (int o = 1; o < 32; o <<= 1) s += __shfl_xor(s, o);
    if (tx == 0) atomicAdd(&cs[(m * 8 + b) * 512 + c], s);
    __align__(8) bf16 h[4];
    h[0] = __float2bfloat16(v.x); h[1] = __float2bfloat16(v.y);
    h[2] = __float2bfloat16(v.z); h[3] = __float2bfloat16(v.w);
    *(bfrag4*)(y2 + (long)c * 32768 + b * 4096 + p0 + tx * 4) = *(const bfrag4*)h;
    *(bfrag4*)(tile + cl * 132 + tx * 4) = *(const bfrag4*)h;
  }
  // quality: wave reduce + staged write
  const int lane = t & 63;
  float qaw = qa, qbw = qb_;
  for (int o = 32; o; o >>= 1) { qaw += __shfl_xor(qaw, o); qbw += __shfl_xor(qbw, o); }
  if (lane == 0) { qpart[t >> 6][0] = qaw; qpart[t >> 6][1] = qbw; }
  __syncthreads();
  if (t == 0) {
    float* qs = qstage + ((long)zz * 512 + blockIdx.y * 32 + blockIdx.x) * 2;
    qs[0] = qpart[0][0] + qpart[1][0] + qpart[2][0] + qpart[3][0];
    qs[1] = qpart[0][1] + qpart[1][1] + qpart[2][1] + qpart[3][1];
  }
  // phase B: xT[p][c] from tile columns, short8 stores
  bf16* y = xT + (long)m * 16777216;
#pragma unroll
  for (int jp = 0; jp < 2; ++jp) {
    const int pl = jp * 64 + (t >> 2);
    const int cg = (t & 3) * 8;
    __align__(16) bf16 o8[8];
#pragma unroll
    for (int i = 0; i < 8; ++i) o8[i] = tile[(cg + i) * 132 + pl];
    *(bfrag8*)(y + ((long)(b * 4096 + p0 + pl)) * 512 + c0 + cg) = *(const bfrag8*)o8;
  }
}

// =================== quality partial reduce -> qacc ===================
__global__ __launch_bounds__(256) void quality_reduce(
    const float* __restrict__ qstage, float* __restrict__ qacc)
{
  __shared__ float pr[4][2];
  const int zz = blockIdx.x;  // m*8 + b
  const int m = zz >> 3, b = zz & 7;
  const int t = threadIdx.x;
  float sa = 0.f, sb = 0.f;
  for (int i = t; i < 512; i += 256) {
    sa += qstage[((long)zz * 512 + i) * 2];
    sb += qstage[((long)zz * 512 + i) * 2 + 1];
  }
  for (int o = 32; o; o >>= 1) { sa += __shfl_xor(sa, o); sb += __shfl_xor(sb, o); }
  if ((t & 63) == 0) { pr[t >> 6][0] = sa; pr[t >> 6][1] = sb; }
  __syncthreads();
  if (t == 0) {
    sa = pr[0][0] + pr[1][0] + pr[2][0] + pr[3][0];
    sb = pr[0][1] + pr[1][1] + pr[2][1] + pr[3][1];
    if (m == 0) { qacc[b * 4 + 1] = sa; qacc[b * 4 + 2] = sb; }
    else if (m == 1) qacc[b * 4 + 0] = sa;
    else qacc[b * 4 + 3] = sa;
  }
}

// =================== weight conversion ===================
__global__ void prep_weights(
    const float* __restrict__ wq, const float* __restrict__ wk,
    const float* __restrict__ wv, const float* __restrict__ wo,
    const float* __restrict__ fw, const float* __restrict__ bo,
    bf16* __restrict__ wqB, bf16* __restrict__ wkB, bf16* __restrict__ wvT,
    bf16* __restrict__ woB, bf16* __restrict__ fwB, float* __restrict__ bo2,
    bf16* __restrict__ idB)
{
  const long stride = (long)gridDim.x * blockDim.x;
  for (long j = (long)blockIdx.x * blockDim.x + threadIdx.x; j < 2359296; j += stride) {
    fwB[j] = __float2bfloat16(fw[j]);
    if (j < 1572864) {
      wqB[j] = __float2bfloat16(wq[j]);
      wkB[j] = __float2bfloat16(wk[j]);
      woB[j] = __float2bfloat16(wo[j]);
      const long i = j >> 18, rem = j & 262143, cin = rem >> 9, ef = rem & 511;
      wvT[j] = __float2bfloat16(wv[(i << 18) + (ef << 9) + cin]);
    }
    if (j < 262144) {
      const long r = j >> 9, c = j & 511;
      idB[j] = __float2bfloat16((r == c) ? 1.0f : 0.0f);
    }
    if (j < 1536) {
      const long m2 = j >> 9, cc = j & 511;
      bo2[j] = bo[((m2 * 2) << 9) + cc] + bo[((m2 * 2 + 1) << 9) + cc];
    }
  }
}

// =================== 128² GEMM core (m97-style) ===================
template<int BM, int BN>
__device__ __forceinline__ void gemm_core(
    const bf16* __restrict__ A, long lda,
    const bf16* __restrict__ Bt, long ldb,
    int K, long m0, long n0,
    bf16* As, bf16* Bs, f32x4 (&acc)[BM / 32][BN / 32])
{
  constexpr int WM = BM / 2, WN = BN / 2, FM = BM / 32, FN = BN / 32;
  const int t = threadIdx.x;
  const int lane = t & 63, wv = t >> 6;
  const int wr = wv >> 1, wc = wv & 1;
  const int l16 = lane & 15, lk = lane >> 4;
  const int srow = t >> 2;
  const int scol = (t & 3) * 8;
  const bf16* Ag = A + (m0 + srow) * lda + scol;
  const bf16* Bg = Bt + (n0 + srow) * ldb + scol;
  char* AsB = (char*)As;
  char* BsB = (char*)Bs;
  const int aoff = wv * 1024;
  for (int kk = 0; kk < K; kk += 32) {
#pragma unroll
    for (int it = 0; it < BM / 64; ++it)
      gload16(Ag + (long)it * 64 * lda + kk, AsB + it * 4096 + aoff);
#pragma unroll
    for (int it = 0; it < BN / 64; ++it)
      gload16(Bg + (long)it * 64 * ldb + kk, BsB + it * 4096 + aoff);
    __syncthreads();
    bfrag8 af[FM], bfr[FN];
#pragma unroll
    for (int m = 0; m < FM; ++m)
      af[m] = *(const bfrag8*)(AsB + ((wr * WM + m * 16 + l16) * 32 + lk * 8) * 2);
#pragma unroll
    for (int n = 0; n < FN; ++n)
      bfr[n] = *(const bfrag8*)(BsB + ((wc * WN + n * 16 + l16) * 32 + lk * 8) * 2);
#pragma unroll
    for (int m = 0; m < FM; ++m)
#pragma unroll
      for (int n = 0; n < FN; ++n)
        mfma_bf16(acc[m][n], af[m], bfr[n]);
    __syncthreads();
  }
}

// =================== Gram: G[i,j] = sum_p xA[p,i] xB[p,j], bf16 out ===================
__global__ __launch_bounds__(256, 2) void gram_kernel(
    const bf16* __restrict__ xC, bf16* __restrict__ Gb)
{
  __shared__ __align__(16) bf16 As[128 * 32];
  __shared__ __align__(16) bf16 Bs[128 * 32];
  const int z = blockIdx.z;
  const int pair = z >> 3, b = z & 7;
  const int A1[3] = {0, 0, 1}, A2[3] = {1, 2, 2};
  const bf16* A = xC + (long)A1[pair] * 16777216 + b * 4096;
  const bf16* Bt = xC + (long)A2[pair] * 16777216 + b * 4096;
  f32x4 acc[4][4];
#pragma unroll
  for (int m = 0; m < 4; ++m)
#pragma unroll
    for (int n = 0; n < 4; ++n)
      acc[m][n] = f32x4{0.f, 0.f, 0.f, 0.f};
  const long m0 = (long)blockIdx.x * 128, n0 = (long)blockIdx.y * 128;
  gemm_core<128, 128>(A, 32768, Bt, 32768, 4096, m0, n0, As, Bs, acc);
  bf16* C = Gb + (long)z * 262144;
  const int t = threadIdx.x;
  const int lane = t & 63, wv = t >> 6;
  const int wr = wv >> 1, wc = wv & 1;
  const int l16 = lane & 15, lk = lane >> 4;
#pragma unroll
  for (int m = 0; m < 4; ++m) {
    const long gr0 = m0 + wr * 64 + m * 16 + lk * 4;
#pragma unroll
    for (int n = 0; n < 4; ++n) {
      const long gc = n0 + wc * 64 + n * 16 + l16;
#pragma unroll
      for (int i = 0; i < 4; ++i)
        C[(gr0 + i) * 512 + gc] = __float2bfloat16(acc[m][n][i]);
    }
  }
}

// =================== scores+softmax -> attnT[e][d] ===================
__global__ __launch_bounds__(256, 2) void scores_kernel(
    const bf16* __restrict__ wqB, const bf16* __restrict__ wkB,
    const bf16* __restrict__ Gb, const float* __restrict__ colsum,
    const float* __restrict__ bq, const float* __restrict__ bk,
    bf16* __restrict__ attnT)
{
  __shared__ __align__(16) bf16 RtS[64 * 520];  // R^T bf16 ; later aliased as S f32 [64][68]
  __shared__ float uv[128];
  __shared__ __align__(16) bf16 attT[64][64];
  const int h = blockIdx.x, b = blockIdx.y, i = blockIdx.z;
  const int qm = i >> 1, jj = i & 1;
  const int km = jj ? (qm == 2 ? 1 : 2) : (qm == 0 ? 1 : 0);
  const int lo = qm < km ? qm : km, hi = qm < km ? km : qm;
  const int pair = lo + hi - 1;
  const int trans = qm > km;
  const bf16* G = Gb + ((long)(pair * 8 + b)) * 262144;
  const bf16* Wq_h = wqB + (long)i * 262144 + h * 64 * 512;
  const bf16* Wk_h = wkB + (long)i * 262144 + h * 64 * 512;
  const bf16* WA = trans ? Wk_h : Wq_h;
  const bf16* WB = trans ? Wq_h : Wk_h;
  const int t = threadIdx.x, lane = t & 63, wv = t >> 6;
  const int l16 = lane & 15, lk = lane >> 4;

  if (t < 128) {
    const int d = t & 63;
    const bf16* wrow = ((t < 64) ? Wq_h : Wk_h) + d * 512;
    const float* sv = colsum + (((t < 64) ? qm : km) * 8 + b) * 512;
    float a = 0.f;
    for (int c = 0; c < 512; c += 8) {
      const bfrag8 w8 = *(const bfrag8*)(wrow + c);
#pragma unroll
      for (int e = 0; e < 8; ++e) a += bf2f(w8[e]) * sv[c + e];
    }
    uv[t] = a;
  }

  // step A: R[512,64] = G . WB^T ; wave wv owns rows [wv*128, +128)
  f32x4 acc[8][4];
#pragma unroll
  for (int m = 0; m < 8; ++m)
#pragma unroll
    for (int n = 0; n < 4; ++n)
      acc[m][n] = f32x4{0.f, 0.f, 0.f, 0.f};
  for (int kk = 0; kk < 512; kk += 32) {
    bfrag8 a[8], bb[4];
#pragma unroll
    for (int m = 0; m < 8; ++m)
      a[m] = *(const bfrag8*)(G + (wv * 128 + m * 16 + l16) * 512 + kk + lk * 8);
#pragma unroll
    for (int n = 0; n < 4; ++n)
      bb[n] = *(const bfrag8*)(WB + (n * 16 + l16) * 512 + kk + lk * 8);
#pragma unroll
    for (int m = 0; m < 8; ++m)
#pragma unroll
      for (int n = 0; n < 4; ++n)
        mfma_bf16(acc[m][n], a[m], bb[n]);
  }
#pragma unroll
  for (int m = 0; m < 8; ++m)
#pragma unroll
    for (int n = 0; n < 4; ++n)
#pragma unroll
      for (int idx = 0; idx < 4; ++idx)
        RtS[(n * 16 + l16) * 520 + wv * 128 + m * 16 + lk * 4 + idx] =
            __float2bfloat16(acc[m][n][idx]);
  __syncthreads();

  // step B: S[64,64] = WA . Rt^T
  f32x4 acc2[4];
#pragma unroll
  for (int m = 0; m < 4; ++m) acc2[m] = f32x4{0.f, 0.f, 0.f, 0.f};
  for (int kk = 0; kk < 512; kk += 32) {
    bfrag8 a2[4];
#pragma unroll
    for (int m = 0; m < 4; ++m)
      a2[m] = *(const bfrag8*)(WA + (m * 16 + l16) * 512 + kk + lk * 8);
    const bfrag8 b2 = *(const bfrag8*)(&RtS[(wv * 16 + l16) * 520 + kk + lk * 8]);
#pragma unroll
    for (int m = 0; m < 4; ++m) mfma_bf16(acc2[m], a2[m], b2);
  }
  __syncthreads();
  float* S = (float*)RtS;  // [64][68]
#pragma unroll
  for (int m = 0; m < 4; ++m)
#pragma unroll
    for (int idx = 0; idx < 4; ++idx)
      S[(m * 16 + lk * 4 + idx) * 68 + wv * 16 + l16] = acc2[m][idx];
  __syncthreads();

  const int r = t >> 2, q = t & 3;   // r = d (query row), q*16+kq = e (key col)
  const float* bq_h = bq + i * 512 + h * 64;
  const float* bk_h = bk + i * 512 + h * 64;
  const float u_r = uv[r], bq_r = bq_h[r];
  float vals[16];
  float mx = -1e30f;
#pragma unroll
  for (int kq = 0; kq < 16; ++kq) {
    const int k = q * 16 + kq;
    float s = trans ? S[k * 68 + r] : S[r * 68 + k];
    s += u_r * bk_h[k] + bq_r * uv[64 + k] + 4096.0f * bq_r * bk_h[k];
    s *= 0.125f;
    vals[kq] = s;
    mx = fmaxf(mx, s);
  }
  mx = fmaxf(mx, __shfl_xor(mx, 1));
  mx = fmaxf(mx, __shfl_xor(mx, 2));
  float sum = 0.f;
#pragma unroll
  for (int kq = 0; kq < 16; ++kq) { vals[kq] = expf(vals[kq] - mx); sum += vals[kq]; }
  sum += __shfl_xor(sum, 1);
  sum += __shfl_xor(sum, 2);
  const float inv = 1.0f / sum;
#pragma unroll
  for (int kq = 0; kq < 16; ++kq)
    attT[q * 16 + kq][r] = __float2bfloat16(vals[kq] * inv);
  __syncthreads();
  const int er = t >> 2, c16 = (t & 3) * 16;
  bf16* op = attnT + (((long)(i * 8 + b) * 8 + h) * 64 + er) * 64 + c16;
  *(bfrag8*)(op) = *(const bfrag8*)(&attT[er][c16]);
  *(bfrag8*)(op + 8) = *(const bfrag8*)(&attT[er][c16 + 8]);
}

// =================== mfold: M[c,ef] = sum_d Wo[c, h*64+d] * attnT[e,d]; mvec += M.bv ===================
__global__ __launch_bounds__(256, 2) void mfold_kernel(
    const bf16* __restrict__ woB, const bf16* __restrict__ attnT,
    const float* __restrict__ bv, bf16* __restrict__ Mbuf, float* __restrict__ mvec)
{
  __shared__ __align__(16) bf16 As[128 * 32];
  __shared__ __align__(16) bf16 Bs[64 * 32];
  const int ib = blockIdx.z;          // i*8+b
  const int i = ib >> 3;
  const int h = blockIdx.y;
  const bf16* A = woB + (long)i * 262144 + h * 64;
  const bf16* Bt = attnT + ((long)ib * 8 + h) * 4096;
  f32x4 acc[4][2];
#pragma unroll
  for (int m = 0; m < 4; ++m)
#pragma unroll
    for (int n = 0; n < 2; ++n)
      acc[m][n] = f32x4{0.f, 0.f, 0.f, 0.f};
  const long m0 = (long)blockIdx.x * 128;
  gemm_core<128, 64>(A, 512, Bt, 64, 64, m0, 0, As, Bs, acc);

  const int t = threadIdx.x;
  const int lane = t & 63, wv = t >> 6;
  const int wr = wv >> 1, wc = wv & 1;
  const int l16 = lane & 15, lk = lane >> 4;
  bf16* C = Mbuf + (long)ib * 262144;
  const float* bvp = bv + i * 512 + h * 64;
  float mp[4][4];
#pragma unroll
  for (int m = 0; m < 4; ++m)
#pragma unroll
    for (int i2 = 0; i2 < 4; ++i2) mp[m][i2] = 0.f;
#pragma unroll
  for (int m = 0; m < 4; ++m) {
    const long gr0 = m0 + wr * 64 + m * 16 + lk * 4;
#pragma unroll
    for (int n = 0; n < 2; ++n) {
      const int gc = wc * 32 + n * 16 + l16;
      const float bvv = bvp[gc];
#pragma unroll
      for (int i2 = 0; i2 < 4; ++i2) {
        C[(gr0 + i2) * 512 + h * 64 + gc] = __float2bfloat16(acc[m][n][i2]);
        mp[m][i2] += acc[m][n][i2] * bvv;
      }
    }
  }
#pragma unroll
  for (int m = 0; m < 4; ++m)
#pragma unroll
    for (int i2 = 0; i2 < 4; ++i2) {
      float v = mp[m][i2];
      v += __shfl_xor(v, 1); v += __shfl_xor(v, 2);
      v += __shfl_xor(v, 4); v += __shfl_xor(v, 8);
      if (l16 == 0)
        atomicAdd(&mvec[(long)ib * 512 + m0 + wr * 64 + m * 16 + lk * 4 + i2], v);
    }
}

// =================== weff: W_eff[c,cin] = sum_ef M[c,ef] * wvT[cin,ef] ===================
__global__ __launch_bounds__(256, 2) void weff_gemm(
    const bf16* __restrict__ Mbuf, const bf16* __restrict__ wvT,
    bf16* __restrict__ Weff)
{
  __shared__ __align__(16) bf16 As[128 * 32];
  __shared__ __align__(16) bf16 Bs[128 * 32];
  const int ib = blockIdx.z;
  const int i = ib >> 3;
  f32x4 acc[4][4];
#pragma unroll
  for (int m = 0; m < 4; ++m)
#pragma unroll
    for (int n = 0; n < 4; ++n)
      acc[m][n] = f32x4{0.f, 0.f, 0.f, 0.f};
  const long m0 = (long)blockIdx.x * 128, n0 = (long)blockIdx.y * 128;
  gemm_core<128, 128>(Mbuf + (long)ib * 262144, 512, wvT + (long)i * 262144, 512,
                      512, m0, n0, As, Bs, acc);
  bf16* C = Weff + (long)ib * 262144;
  const int t = threadIdx.x;
  const int lane = t & 63, wv = t >> 6;
  const int wr = wv >> 1, wc = wv & 1;
  const int l16 = lane & 15, lk = lane >> 4;
#pragma unroll
  for (int m = 0; m < 4; ++m) {
    const long gr0 = m0 + wr * 64 + m * 16 + lk * 4;
#pragma unroll
    for (int n = 0; n < 4; ++n) {
      const long gc = n0 + wc * 64 + n * 16 + l16;
#pragma unroll
      for (int i2 = 0; i2 < 4; ++i2)
        C[(gr0 + i2) * 512 + gc] = __float2bfloat16(acc[m][n][i2]);
    }
  }
}

// =================== SE MLP ===================
__global__ __launch_bounds__(512) void se_mlp(
    const float* __restrict__ pooled,
    const float* __restrict__ W1, const float* __restrict__ b1,
    const float* __restrict__ W2, const float* __restrict__ b2,
    float* __restrict__ se)
{
  const int b = blockIdx.x, m = blockIdx.y;
  __shared__ float y[32];
  const int t = threadIdx.x;
  if (t < 32) {
    float s = b1[m * 32 + t];
    const float* w = W1 + (long)(m * 32 + t) * 512;
    const float* p = pooled + ((long)m * 8 + b) * 512;
    for (int c = 0; c < 512; ++c) s += w[c] * (p[c] * (1.0f / 4096.0f));
    y[t] = fmaxf(s, 0.0f);
  }
  __syncthreads();
  float s = b2[m * 512 + t];
  const float* w2 = W2 + (long)(m * 512 + t) * 32;
#pragma unroll
  for (int j = 0; j < 32; ++j) s += w2[j] * y[j];
  se[((long)m * 8 + b) * 512 + t] = 1.0f / (1.0f + expf(-s));
}

// ========= refined = l2norm_c(cross*se); alpha = sigmoid(gate); weighted out (fused) =========
__global__ __launch_bounds__(384) void refine_gate(
    const bf16* __restrict__ cr0, const bf16* __restrict__ cr1,
    const bf16* __restrict__ cr2, const float* __restrict__ se,
    const float* __restrict__ gw, const float* __restrict__ gb,
    const float* __restrict__ qacc, bf16* __restrict__ weighted)
{
  __shared__ float part[2][3][3];
  const int t = threadIdx.x, wv = t >> 6, lane = t & 63;
  const int px_i = (wv >= 3) ? 1 : 0;
  const int m = wv - px_i * 3;
  const int pix = blockIdx.x * 2 + px_i;
  const int b = pix >> 12;
  const bf16* cr = (m == 0) ? cr0 : (m == 1) ? cr1 : cr2;
  const int c0 = lane * 8;
  const bfrag8 v8 = *(const bfrag8*)(cr + (long)pix * 512 + c0);
  const float* sp = se + ((long)m * 8 + b) * 512 + c0;
  const float4 s0 = *(const float4*)(sp);
  const float4 s1 = *(const float4*)(sp + 4);
  float w[8] = {bf2f(v8[0]) * s0.x, bf2f(v8[1]) * s0.y,
                bf2f(v8[2]) * s0.z, bf2f(v8[3]) * s0.w,
                bf2f(v8[4]) * s1.x, bf2f(v8[5]) * s1.y,
                bf2f(v8[6]) * s1.z, bf2f(v8[7]) * s1.w};
  float ss = 0.f;
#pragma unroll
  for (int i = 0; i < 8; ++i) ss += w[i] * w[i];
  for (int o = 32; o; o >>= 1) ss += __shfl_xor(ss, o);
  const float inv = 1.0f / (sqrtf(ss) + 1e-6f);
  float rf[8];
#pragma unroll
  for (int i = 0; i < 8; ++i) rf[i] = w[i] * inv;

  float a0 = 0.f, a1 = 0.f, a2 = 0.f;
#pragma unroll
  for (int i = 0; i < 8; ++i) {
    const int c = m * 512 + c0 + i;
    a0 += gw[c] * rf[i];
    a1 += gw[1539 + c] * rf[i];
    a2 += gw[3078 + c] * rf[i];
  }
  for (int o = 32; o; o >>= 1) {
    a0 += __shfl_xor(a0, o); a1 += __shfl_xor(a1, o); a2 += __shfl_xor(a2, o);
  }
  if (lane == 0) {
    part[px_i][m][0] = a0; part[px_i][m][1] = a1; part[px_i][m][2] = a2;
  }
  __syncthreads();
  const float N = 2097152.0f;
  const float q0 = qacc[b * 4 + 0] / N;
  const float q1 = (qacc[b * 4 + 2] - qacc[b * 4 + 1] * qacc[b * 4 + 1] / N) / (N - 1.0f);
  const float q2 = qacc[b * 4 + 3] / N;
  const float sg = part[px_i][0][m] + part[px_i][1][m] + part[px_i][2][m] + gb[m] +
                   gw[m * 1539 + 1536] * q0 + gw[m * 1539 + 1537] * q1 +
                   gw[m * 1539 + 1538] * q2;
  const float al = 1.0f / (1.0f + expf(-sg));
  __align__(16) bf16 tmp[8];
#pragma unroll
  for (int i = 0; i < 8; ++i) tmp[i] = __float2bfloat16(rf[i] * al);
  *(bfrag8*)(weighted + (long)pix * 1536 + m * 512 + c0) = *(const bfrag8*)tmp;
}

// =================== host launch ===================
extern "C" void kernel_launch(void* const* d_in, const int* in_sizes, int n_in,
                              void* d_out, int out_size, void* d_ws, size_t ws_size,
                              hipStream_t stream)
{
  (void)in_sizes; (void)n_in; (void)out_size; (void)ws_size;
  const float* rgb   = (const float*)d_in[0];
  const float* depth = (const float*)d_in[1];
  const float* lidar = (const float*)d_in[2];
  const float* wq  = (const float*)d_in[3];
  const float* bq  = (const float*)d_in[4];
  const float* wk  = (const float*)d_in[5];
  const float* bk  = (const float*)d_in[6];
  const float* wvw = (const float*)d_in[7];
  const float* bv  = (const float*)d_in[8];
  const float* wo  = (const float*)d_in[9];
  const float* bo  = (const float*)d_in[10];
  const float* seW1 = (const float*)d_in[11];
  const float* seb1 = (const float*)d_in[12];
  const float* seW2 = (const float*)d_in[13];
  const float* seb2 = (const float*)d_in[14];
  const float* gw  = (const float*)d_in[15];
  const float* gb  = (const float*)d_in[16];
  const float* fw  = (const float*)d_in[17];
  const float* fb  = (const float*)d_in[18];

  char* ws = (char*)d_ws;
  bf16*  xT   = (bf16*)(ws + OFF_XT);
  bf16*  xC   = (bf16*)(ws + OFF_XC);
  bf16*  wqB  = (bf16*)(ws + OFF_WQ);
  bf16*  wkB  = (bf16*)(ws + OFF_WK);
  bf16*  wvT  = (bf16*)(ws + OFF_WVT);
  bf16*  woB  = (bf16*)(ws + OFF_WOB);
  bf16*  fwB  = (bf16*)(ws + OFF_FW);
  float* bo2  = (float*)(ws + OFF_BO2);
  float* pooled = (float*)(ws + OFF_POOL);
  float* seB  = (float*)(ws + OFF_SE);
  float* qacc = (float*)(ws + OFF_QACC);
  float* cs   = (float*)(ws + OFF_CS);
  bf16*  Gb   = (bf16*)(ws + OFF_GB);
  bf16*  attnT = (bf16*)(ws + OFF_ATT);
  float* qstage = (float*)(ws + OFF_QST);
  float* mvec = (float*)(ws + OFF_MVEC);
  bf16*  idB  = (bf16*)(ws + OFF_IDB);
  bf16*  Mbuf = (bf16*)(ws + OFF_XC);              // alias, dead after weff
  bf16*  Weff = (bf16*)(ws + OFF_XC + 25165824L);  // alias, dead after cross
  bf16*  crossB = (bf16*)(ws + OFF_VST);

  // zero: pooled (+se, qacc harmlessly), colsum ; mvec
  (void)hipMemsetAsync(ws + OFF_POOL, 0, OFF_CS + 49152 - OFF_POOL, stream);
  (void)hipMemsetAsync(ws + OFF_MVEC, 0, 98304, stream);

  transpose_kernel<<<dim3(32, 16, 24), 256, 0, stream>>>(rgb, depth, lidar,
                                                         xT, xC, cs, qstage);
  quality_reduce<<<24, 256, 0, stream>>>(qstage, qacc);
  prep_weights<<<2048, 256, 0, stream>>>(wq, wk, wvw, wo, fw, bo,
                                         wqB, wkB, wvT, woB, fwB, bo2, idB);

  gram_kernel<<<dim3(4, 4, 24), 256, 0, stream>>>(xC, Gb);
  scores_kernel<<<dim3(8, 8, 6), 256, 0, stream>>>(wqB, wkB, Gb, cs, bq, bk, attnT);

  mfold_kernel<<<dim3(4, 8, 48), 256, 0, stream>>>(woB, attnT, bv, Mbuf, mvec);
  weff_gemm<<<dim3(4, 4, 48), 256, 0, stream>>>(Mbuf, wvT, Weff);

  cross_gemm256<<<dim3(16, 2, 24), 512, 0, stream>>>(xT, Weff, idB, crossB, bo2,
                                                     mvec, pooled);
  se_mlp<<<dim3(8, 3), 512, 0, stream>>>(pooled, seW1, seb1, seW2, seb2, seB);

  bf16* cross0 = crossB;
  bf16* cross1 = (bf16*)(ws + OFF_VST + 33554432L);
  bf16* cross2 = (bf16*)(ws + OFF_VST + 67108864L);
  bf16* weighted = (bf16*)(ws + OFF_XC);
  refine_gate<<<16384, 384, 0, stream>>>(cross0, cross1, cross2, seB, gw, gb, qacc, weighted);

  fusion_gemm256<<<dim3(128, 6), 512, 0, stream>>>(weighted, fwB, (float*)d_out, fb);
}

// Round 11
// 722.657 us; speedup vs baseline: 2.1042x; 1.0014x over previous
//
#include <hip/hip_runtime.h>
#include <hip/hip_bf16.h>
#include <stdint.h>

using bf16 = __hip_bfloat16;
typedef short bfrag8 __attribute__((ext_vector_type(8)));
typedef short bfrag4 __attribute__((ext_vector_type(4)));
typedef float f32x4 __attribute__((ext_vector_type(4)));

// ---------------- workspace layout (bytes) ----------------
constexpr long OFF_XT   = 0L;           // 3 x [32768][512] bf16 NHWC (live until cross_gemm)
constexpr long OFF_XC   = 100663296L;   // 3 x [512][32768] bf16 channel-major (dead after gram)
constexpr long OFF_WQ   = 201326592L;   // 6 x [512][512] bf16
constexpr long OFF_WK   = 204472320L;
constexpr long OFF_WVT  = 207618048L;   // 6 x [cin 512][ef 512] bf16 (Wv transposed)
constexpr long OFF_WOB  = 210763776L;   // 6 x [512][512] bf16 (Wo plain)
constexpr long OFF_FW   = 213909504L;   // [1536][1536] bf16
constexpr long OFF_BO2  = 218628096L;   // [3][512] f32
constexpr long OFF_POOL = 218646528L;   // [3][8][512] f32   (memset from here)
constexpr long OFF_SE   = 218695680L;   // [3][8][512] f32
constexpr long OFF_QACC = 218744832L;   // [8][4] f32 (+pad to 1024)
constexpr long OFF_CS   = 218745856L;   // [3][8][512] f32 column sums (memset to here+49152)
constexpr long OFF_GB   = 218795008L;   // [3][8][512][512] bf16 Gram
constexpr long OFF_ATT  = 231377920L;   // attnT [6][8][8][64(e)][64(d)] bf16
constexpr long OFF_VST  = 234523648L;   // cross bf16 3 x [32768][512] (96 MB)
constexpr long OFF_QST  = 435850240L;   // [24][512][2] f32 quality partials
constexpr long OFF_MVEC = 436243456L;   // [48][512] f32 (memset)
constexpr long OFF_IDB  = 436341760L;   // [512][512] bf16 identity
// aliases in XC region: Mbuf = OFF_XC, Weff = OFF_XC+25165824 ; weighted = OFF_XC after dead

__device__ __forceinline__ void mfma_bf16(f32x4& c, bfrag8 a, bfrag8 b) {
  asm("v_mfma_f32_16x16x32_bf16 %0, %1, %2, %0" : "+v"(c) : "v"(a), "v"(b));
}

__device__ __forceinline__ void gload16(const void* g, void* l) {
  __builtin_amdgcn_global_load_lds(
      (__attribute__((address_space(1))) void*)(g),
      (__attribute__((address_space(3))) void*)(l), 16, 0, 0);
}

__device__ __forceinline__ float bf2f(short s) {
  union { uint32_t u; float f; } cv;
  cv.u = ((uint32_t)(unsigned short)s) << 16;
  return cv.f;
}

// XCD-chunked bijective swizzle, n-fast logical order. Requires gx*gy % 8 == 0.
__device__ __forceinline__ void swz_mn(int gy, long& m0, long& n0) {
  const int gx = gridDim.x;
  const int orig = blockIdx.y * gx + blockIdx.x;
  const int q = (gx * gy) >> 3;
  const int wgid = (orig & 7) * q + (orig >> 3);
  m0 = (long)(wgid / gy) * 128;
  n0 = (long)(wgid % gy) * 128;
}

// ============================================================================
// 256x256 8-phase GEMM core (multi-segment K), register-reuse quadrant order
//   q0=(A0,B0) q1=(A0,B1) q2=(A1,B1) q3=(A1,B0)
// CORRECTED stage ledger (r11): every half staged 5-6 phases before use;
// per iter i (kt e=2i, o=2i+1):
//   p0:(o).B1  p1:(o).A1  p2:(e+2).A0  p3:(e+2).B0  +vmcnt(4) [retires kt o]
//   p4:(e+2).B1 p5:(e+2).A1 p6:(o+2).A0 p7:(o+2).B0 +vmcnt(4) [retires kt e+2]
// At each wait, exactly the 4 oldest halves (=the K-tile consumed in the next
// 4 phases) retire; 2 halves stay in flight. Slot-free distances verified.
// Wrapped (kt>=NT) stages land in a dummy 16KB slot: vmcnt exact, no race.
// ============================================================================
#define SWZ_OFF(r, kb) ((kb) ^ (((r) & 7) << 4))

__device__ __forceinline__ void bar256() {
  __builtin_amdgcn_sched_barrier(0);
  __builtin_amdgcn_s_barrier();
  __builtin_amdgcn_sched_barrier(0);
}

__device__ __forceinline__ void stage_half(const bf16* __restrict__ g, long ldg,
                                           char* slot, int t) {
#pragma unroll
  for (int j = 0; j < 2; ++j) {
    const int L = t * 16 + j * 8192;
    const int r = L >> 7;
    const int kb = (L & 127) ^ ((r & 7) << 4);   // inverse-swizzled source chunk
    gload16(g + (long)r * ldg + (kb >> 1), slot + L);
  }
}

template<int NSEG, int NTSEG>
__device__ __forceinline__ void gemm256_core(
    const bf16* const* Aseg, long lda,
    const bf16* const* Bseg, long ldb,
    long m0, long n0, char* sm, f32x4 (&acc)[4][4][2])
{
  constexpr int NT = NSEG * NTSEG;
  const int t = threadIdx.x;
  const int lane = t & 63, wid = t >> 6;
  const int wm = wid >> 2, wn = wid & 3;
  const int l16 = lane & 15, lk = lane >> 4;

  auto STAGE = [&](int mat, int hf, int kt) {
    const bool wrap = (kt >= NT);
    const int ktw = wrap ? kt - NT : kt;
    const int seg = ktw / NTSEG, ktt = ktw % NTSEG;
    const int kp = ktw & 1;
    char* slot = wrap ? (sm + 131072)
                      : (mat == 0 ? sm + (kp * 2 + hf) * 16384
                                  : sm + 65536 + (kp * 2 + hf) * 16384);
    if (mat == 0)
      stage_half(Aseg[seg] + (m0 + (long)hf * 128) * lda + ktt * 64, lda, slot, t);
    else
      stage_half(Bseg[seg] + (n0 + (long)hf * 128) * ldb + ktt * 64, ldb, slot, t);
  };

  // prologue: kt0 all 4 halves (A0,B0,B1,A1) then kt1 A0,B0 ; retire kt0
  STAGE(0, 0, 0); STAGE(1, 0, 0); STAGE(1, 1, 0); STAGE(0, 1, 0);
  STAGE(0, 0, 1); STAGE(1, 0, 1);
  __builtin_amdgcn_sched_barrier(0);
  asm volatile("s_waitcnt vmcnt(4)" ::: "memory");
  bar256();

  constexpr int s_mat[8] = {1, 0, 0, 1, 1, 0, 0, 1};
  constexpr int s_hf[8]  = {1, 1, 0, 0, 1, 1, 0, 0};
  constexpr int s_dkt[8] = {1, 1, 2, 2, 2, 2, 3, 3};

  bfrag8 af[4][2], bfr0[2][2], bfr1[2][2];

  for (int i = 0; i < NT / 2; ++i) {
#pragma unroll
    for (int p = 0; p < 8; ++p) {
      const int q = p & 3, kp = p >> 2;
      const int ah = (q >= 2) ? 1 : 0;
      const int bh = (q == 1 || q == 2) ? 1 : 0;
      const char* Ab = sm + (kp * 2 + ah) * 16384;
      const char* Bb = sm + 65536 + (kp * 2 + bh) * 16384;
      if (q == 0 || q == 2) {
#pragma unroll
        for (int mf = 0; mf < 4; ++mf) {
          const int rowA = wm * 64 + mf * 16 + l16;
#pragma unroll
          for (int ks = 0; ks < 2; ++ks)
            af[mf][ks] = *(const bfrag8*)(Ab + rowA * 128 +
                                          SWZ_OFF(rowA, ks * 64 + lk * 16));
        }
      }
      if (q == 0) {
#pragma unroll
        for (int nf = 0; nf < 2; ++nf) {
          const int rowB = wn * 32 + nf * 16 + l16;
#pragma unroll
          for (int ks = 0; ks < 2; ++ks)
            bfr0[nf][ks] = *(const bfrag8*)(Bb + rowB * 128 +
                                            SWZ_OFF(rowB, ks * 64 + lk * 16));
        }
      }
      if (q == 1) {
#pragma unroll
        for (int nf = 0; nf < 2; ++nf) {
          const int rowB = wn * 32 + nf * 16 + l16;
#pragma unroll
          for (int ks = 0; ks < 2; ++ks)
            bfr1[nf][ks] = *(const bfrag8*)(Bb + rowB * 128 +
                                            SWZ_OFF(rowB, ks * 64 + lk * 16));
        }
      }
      STAGE(s_mat[p], s_hf[p], 2 * i + s_dkt[p]);
      bar256();
      __builtin_amdgcn_s_setprio(1);
      if (q == 0 || q == 3) {
#pragma unroll
        for (int ks = 0; ks < 2; ++ks)
#pragma unroll
          for (int mf = 0; mf < 4; ++mf)
#pragma unroll
            for (int nf = 0; nf < 2; ++nf)
              mfma_bf16(acc[q][mf][nf], af[mf][ks], bfr0[nf][ks]);
      } else {
#pragma unroll
        for (int ks = 0; ks < 2; ++ks)
#pragma unroll
          for (int mf = 0; mf < 4; ++mf)
#pragma unroll
            for (int nf = 0; nf < 2; ++nf)
              mfma_bf16(acc[q][mf][nf], af[mf][ks], bfr1[nf][ks]);
      }
      __builtin_amdgcn_s_setprio(0);
      if (p == 3 || p == 7) {
        __builtin_amdgcn_sched_barrier(0);
        asm volatile("s_waitcnt vmcnt(4)" ::: "memory");
      }
      bar256();
    }
  }
}

// =================== fusion GEMM (256² 8-phase): out f32 NCHW ===================
__global__ __launch_bounds__(512, 2) void fusion_gemm256(
    const bf16* __restrict__ A, const bf16* __restrict__ Bt,
    float* __restrict__ Cf, const float* __restrict__ bias)
{
  __shared__ __align__(16) char sm[147456];     // 128K slots + 16K dummy
  const int orig = blockIdx.y * 128 + blockIdx.x;     // grid (128, 6)
  const int wgid = (orig & 7) * 96 + (orig >> 3);
  const long m0 = (long)(wgid / 6) * 256;
  const long n0 = (long)(wgid % 6) * 256;
  f32x4 acc[4][4][2];
#pragma unroll
  for (int q = 0; q < 4; ++q)
#pragma unroll
    for (int mf = 0; mf < 4; ++mf)
#pragma unroll
      for (int nf = 0; nf < 2; ++nf)
        acc[q][mf][nf] = f32x4{0.f, 0.f, 0.f, 0.f};
  const bf16* Aseg[1] = {A};
  const bf16* Bseg[1] = {Bt};
  gemm256_core<1, 24>(Aseg, 1536, Bseg, 1536, m0, n0, sm, acc);

  const int t = threadIdx.x;
  const int lane = t & 63, wid = t >> 6;
  const int wm = wid >> 2, wn = wid & 3;
  const int l16 = lane & 15, lk = lane >> 4;
  constexpr int s_ah[4] = {0, 0, 1, 1};
  constexpr int s_bh[4] = {0, 1, 1, 0};
  const long b = m0 >> 12;
#pragma unroll
  for (int q = 0; q < 4; ++q) {
    const int ah = s_ah[q], bh = s_bh[q];
#pragma unroll
    for (int mf = 0; mf < 4; ++mf) {
      const long row = m0 + ah * 128 + wm * 64 + mf * 16 + lk * 4;
      const long p = row & 4095;
#pragma unroll
      for (int nf = 0; nf < 2; ++nf) {
        const long gc = n0 + bh * 128 + wn * 32 + nf * 16 + l16;
        const float bb = bias[gc];
        float4 o4;
        o4.x = acc[q][mf][nf][0] + bb; o4.y = acc[q][mf][nf][1] + bb;
        o4.z = acc[q][mf][nf][2] + bb; o4.w = acc[q][mf][nf][3] + bb;
        *(float4*)(Cf + b * 6291456L + gc * 4096L + p) = o4;
      }
    }
  }
}

// ====== cross GEMM (256² 8-phase, 3-segment K incl. identity-residual) ======
__global__ __launch_bounds__(512, 2) void cross_gemm256(
    const bf16* __restrict__ xT, const bf16* __restrict__ Weff,
    const bf16* __restrict__ idB,
    bf16* __restrict__ crossB, const float* __restrict__ bo2,
    const float* __restrict__ mvec, float* __restrict__ pooled)
{
  __shared__ __align__(16) char sm[147456];
  const int z = blockIdx.z;             // qm*8 + b
  const int qm = z >> 3, b = z & 7;
  const int KM0[3] = {1, 0, 0}, KM1[3] = {2, 2, 1};
  const bf16* Aseg[3] = {
      xT + (long)KM0[qm] * 16777216 + (long)b * 2097152,
      xT + (long)KM1[qm] * 16777216 + (long)b * 2097152,
      xT + (long)qm * 16777216 + (long)b * 2097152};       // residual via identity
  const bf16* Bseg[3] = {
      Weff + ((long)(2 * qm) * 8 + b) * 262144,
      Weff + ((long)(2 * qm + 1) * 8 + b) * 262144,
      idB};
  const int orig = blockIdx.y * 16 + blockIdx.x;   // grid (16, 2, 24)
  const int wgid = (orig & 7) * 4 + (orig >> 3);
  const long m0 = (long)(wgid >> 1) * 256;
  const long n0 = (long)(wgid & 1) * 256;
  f32x4 acc[4][4][2];
#pragma unroll
  for (int q = 0; q < 4; ++q)
#pragma unroll
    for (int mf = 0; mf < 4; ++mf)
#pragma unroll
      for (int nf = 0; nf < 2; ++nf)
        acc[q][mf][nf] = f32x4{0.f, 0.f, 0.f, 0.f};
  gemm256_core<3, 8>(Aseg, 512, Bseg, 512, m0, n0, sm, acc);

  const int t = threadIdx.x;
  const int lane = t & 63, wid = t >> 6;
  const int wm = wid >> 2, wn = wid & 3;
  const int l16 = lane & 15, lk = lane >> 4;
  constexpr int s_ah[4] = {0, 0, 1, 1};
  constexpr int s_bh[4] = {0, 1, 1, 0};
  bf16* Cb = crossB + (long)qm * 16777216;
  const float* mv0 = mvec + ((long)(2 * qm) * 8 + b) * 512;
  const float* mv1 = mvec + ((long)(2 * qm + 1) * 8 + b) * 512;
  float csum[2][2] = {{0.f, 0.f}, {0.f, 0.f}};
#pragma unroll
  for (int q = 0; q < 4; ++q) {
    const int ah = s_ah[q], bh = s_bh[q];
#pragma unroll
    for (int mf = 0; mf < 4; ++mf) {
      const long row = m0 + ah * 128 + wm * 64 + mf * 16 + lk * 4;
      const long gr0 = (long)b * 4096 + row;
#pragma unroll
      for (int nf = 0; nf < 2; ++nf) {
        const long gc = n0 + bh * 128 + wn * 32 + nf * 16 + l16;
        const float bb = bo2[qm * 512 + gc] + mv0[gc] + mv1[gc];
#pragma unroll
        for (int i2 = 0; i2 < 4; ++i2) {
          const float o = acc[q][mf][nf][i2] + bb;
          Cb[(gr0 + i2) * 512 + gc] = __float2bfloat16(o);
          csum[bh][nf] += o;
        }
      }
    }
  }
#pragma unroll
  for (int bh = 0; bh < 2; ++bh)
#pragma unroll
    for (int nf = 0; nf < 2; ++nf) {
      float s = csum[bh][nf];
      s += __shfl_xor(s, 16);
      s += __shfl_xor(s, 32);
      if (lk == 0) {
        const long gc = n0 + bh * 128 + wn * 32 + nf * 16 + l16;
        atomicAdd(&pooled[((long)qm * 8 + b) * 512 + gc], s);
      }
    }
}

// ============ transpose + stats (vectorized): NCHW f32 -> NHWC + channel-major bf16 ============
// block 256, tile 128p x 32c ; LDS tile [c 32][p 128] bf16 pitch 132
__global__ __launch_bounds__(256) void transpose_kernel(
    const float* __restrict__ x0, const float* __restrict__ x1,
    const float* __restrict__ x2, bf16* __restrict__ xT, bf16* __restrict__ xC,
    float* __restrict__ cs, float* __restrict__ qstage)
{
  __shared__ __align__(16) bf16 tile[32 * 132];
  __shared__ float qpart[4][2];
  const int zz = blockIdx.z;           // m*8 + b
  const int m = zz >> 3, b = zz & 7;
  const float* x = (m == 0) ? x0 : (m == 1) ? x1 : x2;
  const int p0 = blockIdx.x * 128, c0 = blockIdx.y * 32;
  const int t = threadIdx.x;
  const int tx = t & 31, cy = t >> 5;
  bf16* y2 = xC + (long)m * 16777216;
  float qa = 0.f, qb_ = 0.f;
#pragma unroll
  for (int jc = 0; jc < 4; ++jc) {
    const int cl = jc * 8 + cy;
    const int c = c0 + cl;
    const float4 v = *(const float4*)(x + ((long)(b * 512 + c)) * 4096 + p0 + tx * 4);
    if (m == 0) {
      qa += v.x + v.y + v.z + v.w;
      qb_ += v.x * v.x + v.y * v.y + v.z * v.z + v.w * v.w;
    } else {
      qa += ((v.x == 0.0f) ? 1.f : 0.f) + ((v.y == 0.0f) ? 1.f : 0.f) +
            ((v.z == 0.0f) ? 1.f : 0.f) + ((v.w == 0.0f) ? 1.f : 0.f);
    }
    float s = v.x + v.y + v.z + v.w;
    for (int o = 1; o < 32; o <<= 1) s += __shfl_xor(s, o);
    if (tx == 0) atomicAdd(&cs[(m * 8 + b) * 512 + c], s);
    __align__(8) bf16 h[4];
    h[0] = __float2bfloat16(v.x); h[1] = __float2bfloat16(v.y);
    h[2] = __float2bfloat16(v.z); h[3] = __float2bfloat16(v.w);
    *(bfrag4*)(y2 + (long)c * 32768 + b * 4096 + p0 + tx * 4) = *(const bfrag4*)h;
    *(bfrag4*)(tile + cl * 132 + tx * 4) = *(const bfrag4*)h;
  }
  // quality: wave reduce + staged write
  const int lane = t & 63;
  float qaw = qa, qbw = qb_;
  for (int o = 32; o; o >>= 1) { qaw += __shfl_xor(qaw, o); qbw += __shfl_xor(qbw, o); }
  if (lane == 0) { qpart[t >> 6][0] = qaw; qpart[t >> 6][1] = qbw; }
  __syncthreads();
  if (t == 0) {
    float* qs = qstage + ((long)zz * 512 + blockIdx.y * 32 + blockIdx.x) * 2;
    qs[0] = qpart[0][0] + qpart[1][0] + qpart[2][0] + qpart[3][0];
    qs[1] = qpart[0][1] + qpart[1][1] + qpart[2][1] + qpart[3][1];
  }
  // phase B: xT[p][c] from tile columns, short8 stores
  bf16* y = xT + (long)m * 16777216;
#pragma unroll
  for (int jp = 0; jp < 2; ++jp) {
    const int pl = jp * 64 + (t >> 2);
    const int cg = (t & 3) * 8;
    __align__(16) bf16 o8[8];
#pragma unroll
    for (int i = 0; i < 8; ++i) o8[i] = tile[(cg + i) * 132 + pl];
    *(bfrag8*)(y + ((long)(b * 4096 + p0 + pl)) * 512 + c0 + cg) = *(const bfrag8*)o8;
  }
}

// =================== quality partial reduce -> qacc ===================
__global__ __launch_bounds__(256) void quality_reduce(
    const float* __restrict__ qstage, float* __restrict__ qacc)
{
  __shared__ float pr[4][2];
  const int zz = blockIdx.x;  // m*8 + b
  const int m = zz >> 3, b = zz & 7;
  const int t = threadIdx.x;
  float sa = 0.f, sb = 0.f;
  for (int i = t; i < 512; i += 256) {
    sa += qstage[((long)zz * 512 + i) * 2];
    sb += qstage[((long)zz * 512 + i) * 2 + 1];
  }
  for (int o = 32; o; o >>= 1) { sa += __shfl_xor(sa, o); sb += __shfl_xor(sb, o); }
  if ((t & 63) == 0) { pr[t >> 6][0] = sa; pr[t >> 6][1] = sb; }
  __syncthreads();
  if (t == 0) {
    sa = pr[0][0] + pr[1][0] + pr[2][0] + pr[3][0];
    sb = pr[0][1] + pr[1][1] + pr[2][1] + pr[3][1];
    if (m == 0) { qacc[b * 4 + 1] = sa; qacc[b * 4 + 2] = sb; }
    else if (m == 1) qacc[b * 4 + 0] = sa;
    else qacc[b * 4 + 3] = sa;
  }
}

// =================== weight conversion ===================
__global__ void prep_weights(
    const float* __restrict__ wq, const float* __restrict__ wk,
    const float* __restrict__ wv, const float* __restrict__ wo,
    const float* __restrict__ fw, const float* __restrict__ bo,
    bf16* __restrict__ wqB, bf16* __restrict__ wkB, bf16* __restrict__ wvT,
    bf16* __restrict__ woB, bf16* __restrict__ fwB, float* __restrict__ bo2,
    bf16* __restrict__ idB)
{
  const long stride = (long)gridDim.x * blockDim.x;
  for (long j = (long)blockIdx.x * blockDim.x + threadIdx.x; j < 2359296; j += stride) {
    fwB[j] = __float2bfloat16(fw[j]);
    if (j < 1572864) {
      wqB[j] = __float2bfloat16(wq[j]);
      wkB[j] = __float2bfloat16(wk[j]);
      woB[j] = __float2bfloat16(wo[j]);
      const long i = j >> 18, rem = j & 262143, cin = rem >> 9, ef = rem & 511;
      wvT[j] = __float2bfloat16(wv[(i << 18) + (ef << 9) + cin]);
    }
    if (j < 262144) {
      const long r = j >> 9, c = j & 511;
      idB[j] = __float2bfloat16((r == c) ? 1.0f : 0.0f);
    }
    if (j < 1536) {
      const long m2 = j >> 9, cc = j & 511;
      bo2[j] = bo[((m2 * 2) << 9) + cc] + bo[((m2 * 2 + 1) << 9) + cc];
    }
  }
}

// =================== 128² GEMM core (m97-style) ===================
template<int BM, int BN>
__device__ __forceinline__ void gemm_core(
    const bf16* __restrict__ A, long lda,
    const bf16* __restrict__ Bt, long ldb,
    int K, long m0, long n0,
    bf16* As, bf16* Bs, f32x4 (&acc)[BM / 32][BN / 32])
{
  constexpr int WM = BM / 2, WN = BN / 2, FM = BM / 32, FN = BN / 32;
  const int t = threadIdx.x;
  const int lane = t & 63, wv = t >> 6;
  const int wr = wv >> 1, wc = wv & 1;
  const int l16 = lane & 15, lk = lane >> 4;
  const int srow = t >> 2;
  const int scol = (t & 3) * 8;
  const bf16* Ag = A + (m0 + srow) * lda + scol;
  const bf16* Bg = Bt + (n0 + srow) * ldb + scol;
  char* AsB = (char*)As;
  char* BsB = (char*)Bs;
  const int aoff = wv * 1024;
  for (int kk = 0; kk < K; kk += 32) {
#pragma unroll
    for (int it = 0; it < BM / 64; ++it)
      gload16(Ag + (long)it * 64 * lda + kk, AsB + it * 4096 + aoff);
#pragma unroll
    for (int it = 0; it < BN / 64; ++it)
      gload16(Bg + (long)it * 64 * ldb + kk, BsB + it * 4096 + aoff);
    __syncthreads();
    bfrag8 af[FM], bfr[FN];
#pragma unroll
    for (int m = 0; m < FM; ++m)
      af[m] = *(const bfrag8*)(AsB + ((wr * WM + m * 16 + l16) * 32 + lk * 8) * 2);
#pragma unroll
    for (int n = 0; n < FN; ++n)
      bfr[n] = *(const bfrag8*)(BsB + ((wc * WN + n * 16 + l16) * 32 + lk * 8) * 2);
#pragma unroll
    for (int m = 0; m < FM; ++m)
#pragma unroll
      for (int n = 0; n < FN; ++n)
        mfma_bf16(acc[m][n], af[m], bfr[n]);
    __syncthreads();
  }
}

// =================== Gram: G[i,j] = sum_p xA[p,i] xB[p,j], bf16 out ===================
__global__ __launch_bounds__(256, 2) void gram_kernel(
    const bf16* __restrict__ xC, bf16* __restrict__ Gb)
{
  __shared__ __align__(16) bf16 As[128 * 32];
  __shared__ __align__(16) bf16 Bs[128 * 32];
  const int z = blockIdx.z;
  const int pair = z >> 3, b = z & 7;
  const int A1[3] = {0, 0, 1}, A2[3] = {1, 2, 2};
  const bf16* A = xC + (long)A1[pair] * 16777216 + b * 4096;
  const bf16* Bt = xC + (long)A2[pair] * 16777216 + b * 4096;
  f32x4 acc[4][4];
#pragma unroll
  for (int m = 0; m < 4; ++m)
#pragma unroll
    for (int n = 0; n < 4; ++n)
      acc[m][n] = f32x4{0.f, 0.f, 0.f, 0.f};
  const long m0 = (long)blockIdx.x * 128, n0 = (long)blockIdx.y * 128;
  gemm_core<128, 128>(A, 32768, Bt, 32768, 4096, m0, n0, As, Bs, acc);
  bf16* C = Gb + (long)z * 262144;
  const int t = threadIdx.x;
  const int lane = t & 63, wv = t >> 6;
  const int wr = wv >> 1, wc = wv & 1;
  const int l16 = lane & 15, lk = lane >> 4;
#pragma unroll
  for (int m = 0; m < 4; ++m) {
    const long gr0 = m0 + wr * 64 + m * 16 + lk * 4;
#pragma unroll
    for (int n = 0; n < 4; ++n) {
      const long gc = n0 + wc * 64 + n * 16 + l16;
#pragma unroll
      for (int i = 0; i < 4; ++i)
        C[(gr0 + i) * 512 + gc] = __float2bfloat16(acc[m][n][i]);
    }
  }
}

// =================== scores+softmax -> attnT[e][d] ===================
__global__ __launch_bounds__(256, 2) void scores_kernel(
    const bf16* __restrict__ wqB, const bf16* __restrict__ wkB,
    const bf16* __restrict__ Gb, const float* __restrict__ colsum,
    const float* __restrict__ bq, const float* __restrict__ bk,
    bf16* __restrict__ attnT)
{
  __shared__ __align__(16) bf16 RtS[64 * 520];  // R^T bf16 ; later aliased as S f32 [64][68]
  __shared__ float uv[128];
  __shared__ __align__(16) bf16 attT[64][64];
  const int h = blockIdx.x, b = blockIdx.y, i = blockIdx.z;
  const int qm = i >> 1, jj = i & 1;
  const int km = jj ? (qm == 2 ? 1 : 2) : (qm == 0 ? 1 : 0);
  const int lo = qm < km ? qm : km, hi = qm < km ? km : qm;
  const int pair = lo + hi - 1;
  const int trans = qm > km;
  const bf16* G = Gb + ((long)(pair * 8 + b)) * 262144;
  const bf16* Wq_h = wqB + (long)i * 262144 + h * 64 * 512;
  const bf16* Wk_h = wkB + (long)i * 262144 + h * 64 * 512;
  const bf16* WA = trans ? Wk_h : Wq_h;
  const bf16* WB = trans ? Wq_h : Wk_h;
  const int t = threadIdx.x, lane = t & 63, wv = t >> 6;
  const int l16 = lane & 15, lk = lane >> 4;

  if (t < 128) {
    const int d = t & 63;
    const bf16* wrow = ((t < 64) ? Wq_h : Wk_h) + d * 512;
    const float* sv = colsum + (((t < 64) ? qm : km) * 8 + b) * 512;
    float a = 0.f;
    for (int c = 0; c < 512; c += 8) {
      const bfrag8 w8 = *(const bfrag8*)(wrow + c);
#pragma unroll
      for (int e = 0; e < 8; ++e) a += bf2f(w8[e]) * sv[c + e];
    }
    uv[t] = a;
  }

  // step A: R[512,64] = G . WB^T ; wave wv owns rows [wv*128, +128)
  f32x4 acc[8][4];
#pragma unroll
  for (int m = 0; m < 8; ++m)
#pragma unroll
    for (int n = 0; n < 4; ++n)
      acc[m][n] = f32x4{0.f, 0.f, 0.f, 0.f};
  for (int kk = 0; kk < 512; kk += 32) {
    bfrag8 a[8], bb[4];
#pragma unroll
    for (int m = 0; m < 8; ++m)
      a[m] = *(const bfrag8*)(G + (wv * 128 + m * 16 + l16) * 512 + kk + lk * 8);
#pragma unroll
    for (int n = 0; n < 4; ++n)
      bb[n] = *(const bfrag8*)(WB + (n * 16 + l16) * 512 + kk + lk * 8);
#pragma unroll
    for (int m = 0; m < 8; ++m)
#pragma unroll
      for (int n = 0; n < 4; ++n)
        mfma_bf16(acc[m][n], a[m], bb[n]);
  }
#pragma unroll
  for (int m = 0; m < 8; ++m)
#pragma unroll
    for (int n = 0; n < 4; ++n)
#pragma unroll
      for (int idx = 0; idx < 4; ++idx)
        RtS[(n * 16 + l16) * 520 + wv * 128 + m * 16 + lk * 4 + idx] =
            __float2bfloat16(acc[m][n][idx]);
  __syncthreads();

  // step B: S[64,64] = WA . Rt^T
  f32x4 acc2[4];
#pragma unroll
  for (int m = 0; m < 4; ++m) acc2[m] = f32x4{0.f, 0.f, 0.f, 0.f};
  for (int kk = 0; kk < 512; kk += 32) {
    bfrag8 a2[4];
#pragma unroll
    for (int m = 0; m < 4; ++m)
      a2[m] = *(const bfrag8*)(WA + (m * 16 + l16) * 512 + kk + lk * 8);
    const bfrag8 b2 = *(const bfrag8*)(&RtS[(wv * 16 + l16) * 520 + kk + lk * 8]);
#pragma unroll
    for (int m = 0; m < 4; ++m) mfma_bf16(acc2[m], a2[m], b2);
  }
  __syncthreads();
  float* S = (float*)RtS;  // [64][68]
#pragma unroll
  for (int m = 0; m < 4; ++m)
#pragma unroll
    for (int idx = 0; idx < 4; ++idx)
      S[(m * 16 + lk * 4 + idx) * 68 + wv * 16 + l16] = acc2[m][idx];
  __syncthreads();

  const int r = t >> 2, q = t & 3;   // r = d (query row), q*16+kq = e (key col)
  const float* bq_h = bq + i * 512 + h * 64;
  const float* bk_h = bk + i * 512 + h * 64;
  const float u_r = uv[r], bq_r = bq_h[r];
  float vals[16];
  float mx = -1e30f;
#pragma unroll
  for (int kq = 0; kq < 16; ++kq) {
    const int k = q * 16 + kq;
    float s = trans ? S[k * 68 + r] : S[r * 68 + k];
    s += u_r * bk_h[k] + bq_r * uv[64 + k] + 4096.0f * bq_r * bk_h[k];
    s *= 0.125f;
    vals[kq] = s;
    mx = fmaxf(mx, s);
  }
  mx = fmaxf(mx, __shfl_xor(mx, 1));
  mx = fmaxf(mx, __shfl_xor(mx, 2));
  float sum = 0.f;
#pragma unroll
  for (int kq = 0; kq < 16; ++kq) { vals[kq] = expf(vals[kq] - mx); sum += vals[kq]; }
  sum += __shfl_xor(sum, 1);
  sum += __shfl_xor(sum, 2);
  const float inv = 1.0f / sum;
#pragma unroll
  for (int kq = 0; kq < 16; ++kq)
    attT[q * 16 + kq][r] = __float2bfloat16(vals[kq] * inv);
  __syncthreads();
  const int er = t >> 2, c16 = (t & 3) * 16;
  bf16* op = attnT + (((long)(i * 8 + b) * 8 + h) * 64 + er) * 64 + c16;
  *(bfrag8*)(op) = *(const bfrag8*)(&attT[er][c16]);
  *(bfrag8*)(op + 8) = *(const bfrag8*)(&attT[er][c16 + 8]);
}

// =================== mfold: M[c,ef] = sum_d Wo[c, h*64+d] * attnT[e,d]; mvec += M.bv ===================
__global__ __launch_bounds__(256, 2) void mfold_kernel(
    const bf16* __restrict__ woB, const bf16* __restrict__ attnT,
    const float* __restrict__ bv, bf16* __restrict__ Mbuf, float* __restrict__ mvec)
{
  __shared__ __align__(16) bf16 As[128 * 32];
  __shared__ __align__(16) bf16 Bs[64 * 32];
  const int ib = blockIdx.z;          // i*8+b
  const int i = ib >> 3;
  const int h = blockIdx.y;
  const bf16* A = woB + (long)i * 262144 + h * 64;
  const bf16* Bt = attnT + ((long)ib * 8 + h) * 4096;
  f32x4 acc[4][2];
#pragma unroll
  for (int m = 0; m < 4; ++m)
#pragma unroll
    for (int n = 0; n < 2; ++n)
      acc[m][n] = f32x4{0.f, 0.f, 0.f, 0.f};
  const long m0 = (long)blockIdx.x * 128;
  gemm_core<128, 64>(A, 512, Bt, 64, 64, m0, 0, As, Bs, acc);

  const int t = threadIdx.x;
  const int lane = t & 63, wv = t >> 6;
  const int wr = wv >> 1, wc = wv & 1;
  const int l16 = lane & 15, lk = lane >> 4;
  bf16* C = Mbuf + (long)ib * 262144;
  const float* bvp = bv + i * 512 + h * 64;
  float mp[4][4];
#pragma unroll
  for (int m = 0; m < 4; ++m)
#pragma unroll
    for (int i2 = 0; i2 < 4; ++i2) mp[m][i2] = 0.f;
#pragma unroll
  for (int m = 0; m < 4; ++m) {
    const long gr0 = m0 + wr * 64 + m * 16 + lk * 4;
#pragma unroll
    for (int n = 0; n < 2; ++n) {
      const int gc = wc * 32 + n * 16 + l16;
      const float bvv = bvp[gc];
#pragma unroll
      for (int i2 = 0; i2 < 4; ++i2) {
        C[(gr0 + i2) * 512 + h * 64 + gc] = __float2bfloat16(acc[m][n][i2]);
        mp[m][i2] += acc[m][n][i2] * bvv;
      }
    }
  }
#pragma unroll
  for (int m = 0; m < 4; ++m)
#pragma unroll
    for (int i2 = 0; i2 < 4; ++i2) {
      float v = mp[m][i2];
      v += __shfl_xor(v, 1); v += __shfl_xor(v, 2);
      v += __shfl_xor(v, 4); v += __shfl_xor(v, 8);
      if (l16 == 0)
        atomicAdd(&mvec[(long)ib * 512 + m0 + wr * 64 + m * 16 + lk * 4 + i2], v);
    }
}

// =================== weff: W_eff[c,cin] = sum_ef M[c,ef] * wvT[cin,ef] ===================
__global__ __launch_bounds__(256, 2) void weff_gemm(
    const bf16* __restrict__ Mbuf, const bf16* __restrict__ wvT,
    bf16* __restrict__ Weff)
{
  __shared__ __align__(16) bf16 As[128 * 32];
  __shared__ __align__(16) bf16 Bs[128 * 32];
  const int ib = blockIdx.z;
  const int i = ib >> 3;
  f32x4 acc[4][4];
#pragma unroll
  for (int m = 0; m < 4; ++m)
#pragma unroll
    for (int n = 0; n < 4; ++n)
      acc[m][n] = f32x4{0.f, 0.f, 0.f, 0.f};
  const long m0 = (long)blockIdx.x * 128, n0 = (long)blockIdx.y * 128;
  gemm_core<128, 128>(Mbuf + (long)ib * 262144, 512, wvT + (long)i * 262144, 512,
                      512, m0, n0, As, Bs, acc);
  bf16* C = Weff + (long)ib * 262144;
  const int t = threadIdx.x;
  const int lane = t & 63, wv = t >> 6;
  const int wr = wv >> 1, wc = wv & 1;
  const int l16 = lane & 15, lk = lane >> 4;
#pragma unroll
  for (int m = 0; m < 4; ++m) {
    const long gr0 = m0 + wr * 64 + m * 16 + lk * 4;
#pragma unroll
    for (int n = 0; n < 4; ++n) {
      const long gc = n0 + wc * 64 + n * 16 + l16;
#pragma unroll
      for (int i2 = 0; i2 < 4; ++i2)
        C[(gr0 + i2) * 512 + gc] = __float2bfloat16(acc[m][n][i2]);
    }
  }
}

// =================== SE MLP ===================
__global__ __launch_bounds__(512) void se_mlp(
    const float* __restrict__ pooled,
    const float* __restrict__ W1, const float* __restrict__ b1,
    const float* __restrict__ W2, const float* __restrict__ b2,
    float* __restrict__ se)
{
  const int b = blockIdx.x, m = blockIdx.y;
  __shared__ float y[32];
  const int t = threadIdx.x;
  if (t < 32) {
    float s = b1[m * 32 + t];
    const float* w = W1 + (long)(m * 32 + t) * 512;
    const float* p = pooled + ((long)m * 8 + b) * 512;
    for (int c = 0; c < 512; ++c) s += w[c] * (p[c] * (1.0f / 4096.0f));
    y[t] = fmaxf(s, 0.0f);
  }
  __syncthreads();
  float s = b2[m * 512 + t];
  const float* w2 = W2 + (long)(m * 512 + t) * 32;
#pragma unroll
  for (int j = 0; j < 32; ++j) s += w2[j] * y[j];
  se[((long)m * 8 + b) * 512 + t] = 1.0f / (1.0f + expf(-s));
}

// ========= refined = l2norm_c(cross*se); alpha = sigmoid(gate); weighted out (fused) =========
__global__ __launch_bounds__(384) void refine_gate(
    const bf16* __restrict__ cr0, const bf16* __restrict__ cr1,
    const bf16* __restrict__ cr2, const float* __restrict__ se,
    const float* __restrict__ gw, const float* __restrict__ gb,
    const float* __restrict__ qacc, bf16* __restrict__ weighted)
{
  __shared__ float part[2][3][3];
  const int t = threadIdx.x, wv = t >> 6, lane = t & 63;
  const int px_i = (wv >= 3) ? 1 : 0;
  const int m = wv - px_i * 3;
  const int pix = blockIdx.x * 2 + px_i;
  const int b = pix >> 12;
  const bf16* cr = (m == 0) ? cr0 : (m == 1) ? cr1 : cr2;
  const int c0 = lane * 8;
  const bfrag8 v8 = *(const bfrag8*)(cr + (long)pix * 512 + c0);
  const float* sp = se + ((long)m * 8 + b) * 512 + c0;
  const float4 s0 = *(const float4*)(sp);
  const float4 s1 = *(const float4*)(sp + 4);
  float w[8] = {bf2f(v8[0]) * s0.x, bf2f(v8[1]) * s0.y,
                bf2f(v8[2]) * s0.z, bf2f(v8[3]) * s0.w,
                bf2f(v8[4]) * s1.x, bf2f(v8[5]) * s1.y,
                bf2f(v8[6]) * s1.z, bf2f(v8[7]) * s1.w};
  float ss = 0.f;
#pragma unroll
  for (int i = 0; i < 8; ++i) ss += w[i] * w[i];
  for (int o = 32; o; o >>= 1) ss += __shfl_xor(ss, o);
  const float inv = 1.0f / (sqrtf(ss) + 1e-6f);
  float rf[8];
#pragma unroll
  for (int i = 0; i < 8; ++i) rf[i] = w[i] * inv;

  float a0 = 0.f, a1 = 0.f, a2 = 0.f;
#pragma unroll
  for (int i = 0; i < 8; ++i) {
    const int c = m * 512 + c0 + i;
    a0 += gw[c] * rf[i];
    a1 += gw[1539 + c] * rf[i];
    a2 += gw[3078 + c] * rf[i];
  }
  for (int o = 32; o; o >>= 1) {
    a0 += __shfl_xor(a0, o); a1 += __shfl_xor(a1, o); a2 += __shfl_xor(a2, o);
  }
  if (lane == 0) {
    part[px_i][m][0] = a0; part[px_i][m][1] = a1; part[px_i][m][2] = a2;
  }
  __syncthreads();
  const float N = 2097152.0f;
  const float q0 = qacc[b * 4 + 0] / N;
  const float q1 = (qacc[b * 4 + 2] - qacc[b * 4 + 1] * qacc[b * 4 + 1] / N) / (N - 1.0f);
  const float q2 = qacc[b * 4 + 3] / N;
  const float sg = part[px_i][0][m] + part[px_i][1][m] + part[px_i][2][m] + gb[m] +
                   gw[m * 1539 + 1536] * q0 + gw[m * 1539 + 1537] * q1 +
                   gw[m * 1539 + 1538] * q2;
  const float al = 1.0f / (1.0f + expf(-sg));
  __align__(16) bf16 tmp[8];
#pragma unroll
  for (int i = 0; i < 8; ++i) tmp[i] = __float2bfloat16(rf[i] * al);
  *(bfrag8*)(weighted + (long)pix * 1536 + m * 512 + c0) = *(const bfrag8*)tmp;
}

// =================== host launch ===================
extern "C" void kernel_launch(void* const* d_in, const int* in_sizes, int n_in,
                              void* d_out, int out_size, void* d_ws, size_t ws_size,
                              hipStream_t stream)
{
  (void)in_sizes; (void)n_in; (void)out_size; (void)ws_size;
  const float* rgb   = (const float*)d_in[0];
  const float* depth = (const float*)d_in[1];
  const float* lidar = (const float*)d_in[2];
  const float* wq  = (const float*)d_in[3];
  const float* bq  = (const float*)d_in[4];
  const float* wk  = (const float*)d_in[5];
  const float* bk  = (const float*)d_in[6];
  const float* wvw = (const float*)d_in[7];
  const float* bv  = (const float*)d_in[8];
  const float* wo  = (const float*)d_in[9];
  const float* bo  = (const float*)d_in[10];
  const float* seW1 = (const float*)d_in[11];
  const float* seb1 = (const float*)d_in[12];
  const float* seW2 = (const float*)d_in[13];
  const float* seb2 = (const float*)d_in[14];
  const float* gw  = (const float*)d_in[15];
  const float* gb  = (const float*)d_in[16];
  const float* fw  = (const float*)d_in[17];
  const float* fb  = (const float*)d_in[18];

  char* ws = (char*)d_ws;
  bf16*  xT   = (bf16*)(ws + OFF_XT);
  bf16*  xC   = (bf16*)(ws + OFF_XC);
  bf16*  wqB  = (bf16*)(ws + OFF_WQ);
  bf16*  wkB  = (bf16*)(ws + OFF_WK);
  bf16*  wvT  = (bf16*)(ws + OFF_WVT);
  bf16*  woB  = (bf16*)(ws + OFF_WOB);
  bf16*  fwB  = (bf16*)(ws + OFF_FW);
  float* bo2  = (float*)(ws + OFF_BO2);
  float* pooled = (float*)(ws + OFF_POOL);
  float* seB  = (float*)(ws + OFF_SE);
  float* qacc = (float*)(ws + OFF_QACC);
  float* cs   = (float*)(ws + OFF_CS);
  bf16*  Gb   = (bf16*)(ws + OFF_GB);
  bf16*  attnT = (bf16*)(ws + OFF_ATT);
  float* qstage = (float*)(ws + OFF_QST);
  float* mvec = (float*)(ws + OFF_MVEC);
  bf16*  idB  = (bf16*)(ws + OFF_IDB);
  bf16*  Mbuf = (bf16*)(ws + OFF_XC);              // alias, dead after weff
  bf16*  Weff = (bf16*)(ws + OFF_XC + 25165824L);  // alias, dead after cross
  bf16*  crossB = (bf16*)(ws + OFF_VST);

  // zero: pooled (+se, qacc harmlessly), colsum ; mvec
  (void)hipMemsetAsync(ws + OFF_POOL, 0, OFF_CS + 49152 - OFF_POOL, stream);
  (void)hipMemsetAsync(ws + OFF_MVEC, 0, 98304, stream);

  transpose_kernel<<<dim3(32, 16, 24), 256, 0, stream>>>(rgb, depth, lidar,
                                                         xT, xC, cs, qstage);
  quality_reduce<<<24, 256, 0, stream>>>(qstage, qacc);
  prep_weights<<<2048, 256, 0, stream>>>(wq, wk, wvw, wo, fw, bo,
                                         wqB, wkB, wvT, woB, fwB, bo2, idB);

  gram_kernel<<<dim3(4, 4, 24), 256, 0, stream>>>(xC, Gb);
  scores_kernel<<<dim3(8, 8, 6), 256, 0, stream>>>(wqB, wkB, Gb, cs, bq, bk, attnT);

  mfold_kernel<<<dim3(4, 8, 48), 256, 0, stream>>>(woB, attnT, bv, Mbuf, mvec);
  weff_gemm<<<dim3(4, 4, 48), 256, 0, stream>>>(Mbuf, wvT, Weff);

  cross_gemm256<<<dim3(16, 2, 24), 512, 0, stream>>>(xT, Weff, idB, crossB, bo2,
                                                     mvec, pooled);
  se_mlp<<<dim3(8, 3), 512, 0, stream>>>(pooled, seW1, seb1, seW2, seb2, seB);

  bf16* cross0 = crossB;
  bf16* cross1 = (bf16*)(ws + OFF_VST + 33554432L);
  bf16* cross2 = (bf16*)(ws + OFF_VST + 67108864L);
  bf16* weighted = (bf16*)(ws + OFF_XC);
  refine_gate<<<16384, 384, 0, stream>>>(cross0, cross1, cross2, seB, gw, gb, qacc, weighted);

  fusion_gemm256<<<dim3(128, 6), 512, 0, stream>>>(weighted, fwB, (float*)d_out, fb);
}

// Round 13
// 719.623 us; speedup vs baseline: 2.1131x; 1.0042x over previous
//
#include <hip/hip_runtime.h>
#include <hip/hip_bf16.h>
#include <stdint.h>

using bf16 = __hip_bfloat16;
typedef short bfrag8 __attribute__((ext_vector_type(8)));
typedef short bfrag4 __attribute__((ext_vector_type(4)));
typedef float f32x4 __attribute__((ext_vector_type(4)));

// ---------------- workspace layout (bytes) ----------------
constexpr long OFF_XT   = 0L;           // 3 x [32768][512] bf16 NHWC (live until cross_gemm)
constexpr long OFF_XC   = 100663296L;   // 3 x [512][32768] bf16 channel-major (dead after gram)
constexpr long OFF_WQ   = 201326592L;   // 6 x [512][512] bf16
constexpr long OFF_WK   = 204472320L;
constexpr long OFF_WVT  = 207618048L;   // 6 x [cin 512][ef 512] bf16 (Wv transposed)
constexpr long OFF_WOB  = 210763776L;   // 6 x [512][512] bf16 (Wo plain)
constexpr long OFF_FW   = 213909504L;   // [1536][1536] bf16
constexpr long OFF_BO2  = 218628096L;   // [3][512] f32
constexpr long OFF_POOL = 218646528L;   // [3][8][512] f32   (memset from here)
constexpr long OFF_SE   = 218695680L;   // [3][8][512] f32
constexpr long OFF_QACC = 218744832L;   // [8][4] f32 (+pad to 1024)
constexpr long OFF_CS   = 218745856L;   // [3][8][512] f32 column sums (memset to here+49152)
constexpr long OFF_GB   = 218795008L;   // [3][8][512][512] bf16 Gram
constexpr long OFF_ATT  = 231377920L;   // attnT [6][8][8][64(e)][64(d)] bf16
constexpr long OFF_VST  = 234523648L;   // cross bf16 3 x [32768][512] (96 MB)
constexpr long OFF_QST  = 435850240L;   // [24][512][2] f32 quality partials
constexpr long OFF_MVEC = 436243456L;   // [48][512] f32 (memset)
constexpr long OFF_IDB  = 436341760L;   // [512][512] bf16 identity
// aliases in XC region: Mbuf = OFF_XC, Weff = OFF_XC+25165824 ; weighted = OFF_XC after dead

__device__ __forceinline__ void mfma_bf16(f32x4& c, bfrag8 a, bfrag8 b) {
  asm("v_mfma_f32_16x16x32_bf16 %0, %1, %2, %0" : "+v"(c) : "v"(a), "v"(b));
}

__device__ __forceinline__ void gload16(const void* g, void* l) {
  __builtin_amdgcn_global_load_lds(
      (__attribute__((address_space(1))) void*)(g),
      (__attribute__((address_space(3))) void*)(l), 16, 0, 0);
}

__device__ __forceinline__ float bf2f(short s) {
  union { uint32_t u; float f; } cv;
  cv.u = ((uint32_t)(unsigned short)s) << 16;
  return cv.f;
}

// XCD-chunked bijective swizzle, n-fast logical order. Requires gx*gy % 8 == 0.
__device__ __forceinline__ void swz_mn(int gy, long& m0, long& n0) {
  const int gx = gridDim.x;
  const int orig = blockIdx.y * gx + blockIdx.x;
  const int q = (gx * gy) >> 3;
  const int wgid = (orig & 7) * q + (orig >> 3);
  m0 = (long)(wgid / gy) * 128;
  n0 = (long)(wgid % gy) * 128;
}

// ============================================================================
// 256x256 8-phase GEMM core (multi-segment K), register-reuse quadrant order
//   q0=(A0,B0) q1=(A0,B1) q2=(A1,B1) q3=(A1,B0)
// Stage ledger (r11, verified passing): per iter i (kt e=2i, o=2i+1):
//   p0:(o).B1  p1:(o).A1  p2:(e+2).A0  p3:(e+2).B0  +vmcnt(4) [retires kt o]
//   p4:(e+2).B1 p5:(e+2).A1 p6:(o+2).A0 p7:(o+2).B0 +vmcnt(4) [retires e+2]
// Wrapped (kt>=NT) stages land in a dummy 16KB slot: vmcnt exact, no race.
// ============================================================================
#define SWZ_OFF(r, kb) ((kb) ^ (((r) & 7) << 4))

__device__ __forceinline__ void bar256() {
  __builtin_amdgcn_sched_barrier(0);
  __builtin_amdgcn_s_barrier();
  __builtin_amdgcn_sched_barrier(0);
}

__device__ __forceinline__ void stage_half(const bf16* __restrict__ g, long ldg,
                                           char* slot, int t) {
#pragma unroll
  for (int j = 0; j < 2; ++j) {
    const int L = t * 16 + j * 8192;
    const int r = L >> 7;
    const int kb = (L & 127) ^ ((r & 7) << 4);   // inverse-swizzled source chunk
    gload16(g + (long)r * ldg + (kb >> 1), slot + L);
  }
}

template<int NSEG, int NTSEG>
__device__ __forceinline__ void gemm256_core(
    const bf16* const* Aseg, long lda,
    const bf16* const* Bseg, long ldb,
    long m0, long n0, char* sm, f32x4 (&acc)[4][4][2])
{
  constexpr int NT = NSEG * NTSEG;
  const int t = threadIdx.x;
  const int lane = t & 63, wid = t >> 6;
  const int wm = wid >> 2, wn = wid & 3;
  const int l16 = lane & 15, lk = lane >> 4;

  auto STAGE = [&](int mat, int hf, int kt) {
    const bool wrap = (kt >= NT);
    const int ktw = wrap ? kt - NT : kt;
    const int seg = ktw / NTSEG, ktt = ktw % NTSEG;
    const int kp = ktw & 1;
    char* slot = wrap ? (sm + 131072)
                      : (mat == 0 ? sm + (kp * 2 + hf) * 16384
                                  : sm + 65536 + (kp * 2 + hf) * 16384);
    if (mat == 0)
      stage_half(Aseg[seg] + (m0 + (long)hf * 128) * lda + ktt * 64, lda, slot, t);
    else
      stage_half(Bseg[seg] + (n0 + (long)hf * 128) * ldb + ktt * 64, ldb, slot, t);
  };

  // prologue: kt0 all 4 halves (A0,B0,B1,A1) then kt1 A0,B0 ; retire kt0
  STAGE(0, 0, 0); STAGE(1, 0, 0); STAGE(1, 1, 0); STAGE(0, 1, 0);
  STAGE(0, 0, 1); STAGE(1, 0, 1);
  __builtin_amdgcn_sched_barrier(0);
  asm volatile("s_waitcnt vmcnt(4)" ::: "memory");
  bar256();

  constexpr int s_mat[8] = {1, 0, 0, 1, 1, 0, 0, 1};
  constexpr int s_hf[8]  = {1, 1, 0, 0, 1, 1, 0, 0};
  constexpr int s_dkt[8] = {1, 1, 2, 2, 2, 2, 3, 3};

  bfrag8 af[4][2], bfr0[2][2], bfr1[2][2];

  for (int i = 0; i < NT / 2; ++i) {
#pragma unroll
    for (int p = 0; p < 8; ++p) {
      const int q = p & 3, kp = p >> 2;
      const int ah = (q >= 2) ? 1 : 0;
      const int bh = (q == 1 || q == 2) ? 1 : 0;
      const char* Ab = sm + (kp * 2 + ah) * 16384;
      const char* Bb = sm + 65536 + (kp * 2 + bh) * 16384;
      if (q == 0 || q == 2) {
#pragma unroll
        for (int mf = 0; mf < 4; ++mf) {
          const int rowA = wm * 64 + mf * 16 + l16;
#pragma unroll
          for (int ks = 0; ks < 2; ++ks)
            af[mf][ks] = *(const bfrag8*)(Ab + rowA * 128 +
                                          SWZ_OFF(rowA, ks * 64 + lk * 16));
        }
      }
      if (q == 0) {
#pragma unroll
        for (int nf = 0; nf < 2; ++nf) {
          const int rowB = wn * 32 + nf * 16 + l16;
#pragma unroll
          for (int ks = 0; ks < 2; ++ks)
            bfr0[nf][ks] = *(const bfrag8*)(Bb + rowB * 128 +
                                            SWZ_OFF(rowB, ks * 64 + lk * 16));
        }
      }
      if (q == 1) {
#pragma unroll
        for (int nf = 0; nf < 2; ++nf) {
          const int rowB = wn * 32 + nf * 16 + l16;
#pragma unroll
          for (int ks = 0; ks < 2; ++ks)
            bfr1[nf][ks] = *(const bfrag8*)(Bb + rowB * 128 +
                                            SWZ_OFF(rowB, ks * 64 + lk * 16));
        }
      }
      STAGE(s_mat[p], s_hf[p], 2 * i + s_dkt[p]);
      bar256();
      __builtin_amdgcn_s_setprio(1);
      if (q == 0 || q == 3) {
#pragma unroll
        for (int ks = 0; ks < 2; ++ks)
#pragma unroll
          for (int mf = 0; mf < 4; ++mf)
#pragma unroll
            for (int nf = 0; nf < 2; ++nf)
              mfma_bf16(acc[q][mf][nf], af[mf][ks], bfr0[nf][ks]);
      } else {
#pragma unroll
        for (int ks = 0; ks < 2; ++ks)
#pragma unroll
          for (int mf = 0; mf < 4; ++mf)
#pragma unroll
            for (int nf = 0; nf < 2; ++nf)
              mfma_bf16(acc[q][mf][nf], af[mf][ks], bfr1[nf][ks]);
      }
      __builtin_amdgcn_s_setprio(0);
      if (p == 3 || p == 7) {
        __builtin_amdgcn_sched_barrier(0);
        asm volatile("s_waitcnt vmcnt(4)" ::: "memory");
      }
      bar256();
    }
  }
}

// =================== fusion GEMM (256² 8-phase): out f32 NCHW ===================
__global__ __launch_bounds__(512, 2) void fusion_gemm256(
    const bf16* __restrict__ A, const bf16* __restrict__ Bt,
    float* __restrict__ Cf, const float* __restrict__ bias)
{
  __shared__ __align__(16) char sm[147456];     // 128K slots + 16K dummy
  const int orig = blockIdx.y * 128 + blockIdx.x;     // grid (128, 6)
  const int wgid = (orig & 7) * 96 + (orig >> 3);
  const long m0 = (long)(wgid / 6) * 256;
  const long n0 = (long)(wgid % 6) * 256;
  f32x4 acc[4][4][2];
#pragma unroll
  for (int q = 0; q < 4; ++q)
#pragma unroll
    for (int mf = 0; mf < 4; ++mf)
#pragma unroll
      for (int nf = 0; nf < 2; ++nf)
        acc[q][mf][nf] = f32x4{0.f, 0.f, 0.f, 0.f};
  const bf16* Aseg[1] = {A};
  const bf16* Bseg[1] = {Bt};
  gemm256_core<1, 24>(Aseg, 1536, Bseg, 1536, m0, n0, sm, acc);

  const int t = threadIdx.x;
  const int lane = t & 63, wid = t >> 6;
  const int wm = wid >> 2, wn = wid & 3;
  const int l16 = lane & 15, lk = lane >> 4;
  constexpr int s_ah[4] = {0, 0, 1, 1};
  constexpr int s_bh[4] = {0, 1, 1, 0};
  const long b = m0 >> 12;
#pragma unroll
  for (int q = 0; q < 4; ++q) {
    const int ah = s_ah[q], bh = s_bh[q];
#pragma unroll
    for (int mf = 0; mf < 4; ++mf) {
      const long row = m0 + ah * 128 + wm * 64 + mf * 16 + lk * 4;
      const long p = row & 4095;
#pragma unroll
      for (int nf = 0; nf < 2; ++nf) {
        const long gc = n0 + bh * 128 + wn * 32 + nf * 16 + l16;
        const float bb = bias[gc];
        float4 o4;
        o4.x = acc[q][mf][nf][0] + bb; o4.y = acc[q][mf][nf][1] + bb;
        o4.z = acc[q][mf][nf][2] + bb; o4.w = acc[q][mf][nf][3] + bb;
        *(float4*)(Cf + b * 6291456L + gc * 4096L + p) = o4;
      }
    }
  }
}

// ====== cross GEMM (256² 8-phase, 3-segment K incl. identity-residual) ======
__global__ __launch_bounds__(512, 2) void cross_gemm256(
    const bf16* __restrict__ xT, const bf16* __restrict__ Weff,
    const bf16* __restrict__ idB,
    bf16* __restrict__ crossB, const float* __restrict__ bo2,
    const float* __restrict__ mvec, float* __restrict__ pooled)
{
  __shared__ __align__(16) char sm[147456];
  const int z = blockIdx.z;             // qm*8 + b
  const int qm = z >> 3, b = z & 7;
  const int KM0[3] = {1, 0, 0}, KM1[3] = {2, 2, 1};
  const bf16* Aseg[3] = {
      xT + (long)KM0[qm] * 16777216 + (long)b * 2097152,
      xT + (long)KM1[qm] * 16777216 + (long)b * 2097152,
      xT + (long)qm * 16777216 + (long)b * 2097152};       // residual via identity
  const bf16* Bseg[3] = {
      Weff + ((long)(2 * qm) * 8 + b) * 262144,
      Weff + ((long)(2 * qm + 1) * 8 + b) * 262144,
      idB};
  const int orig = blockIdx.y * 16 + blockIdx.x;   // grid (16, 2, 24)
  const int wgid = (orig & 7) * 4 + (orig >> 3);
  const long m0 = (long)(wgid >> 1) * 256;
  const long n0 = (long)(wgid & 1) * 256;
  f32x4 acc[4][4][2];
#pragma unroll
  for (int q = 0; q < 4; ++q)
#pragma unroll
    for (int mf = 0; mf < 4; ++mf)
#pragma unroll
      for (int nf = 0; nf < 2; ++nf)
        acc[q][mf][nf] = f32x4{0.f, 0.f, 0.f, 0.f};
  gemm256_core<3, 8>(Aseg, 512, Bseg, 512, m0, n0, sm, acc);

  const int t = threadIdx.x;
  const int lane = t & 63, wid = t >> 6;
  const int wm = wid >> 2, wn = wid & 3;
  const int l16 = lane & 15, lk = lane >> 4;
  constexpr int s_ah[4] = {0, 0, 1, 1};
  constexpr int s_bh[4] = {0, 1, 1, 0};
  bf16* Cb = crossB + (long)qm * 16777216;
  const float* mv0 = mvec + ((long)(2 * qm) * 8 + b) * 512;
  const float* mv1 = mvec + ((long)(2 * qm + 1) * 8 + b) * 512;
  float csum[2][2] = {{0.f, 0.f}, {0.f, 0.f}};
#pragma unroll
  for (int q = 0; q < 4; ++q) {
    const int ah = s_ah[q], bh = s_bh[q];
#pragma unroll
    for (int mf = 0; mf < 4; ++mf) {
      const long row = m0 + ah * 128 + wm * 64 + mf * 16 + lk * 4;
      const long gr0 = (long)b * 4096 + row;
#pragma unroll
      for (int nf = 0; nf < 2; ++nf) {
        const long gc = n0 + bh * 128 + wn * 32 + nf * 16 + l16;
        const float bb = bo2[qm * 512 + gc] + mv0[gc] + mv1[gc];
#pragma unroll
        for (int i2 = 0; i2 < 4; ++i2) {
          const float o = acc[q][mf][nf][i2] + bb;
          Cb[(gr0 + i2) * 512 + gc] = __float2bfloat16(o);
          csum[bh][nf] += o;
        }
      }
    }
  }
#pragma unroll
  for (int bh = 0; bh < 2; ++bh)
#pragma unroll
    for (int nf = 0; nf < 2; ++nf) {
      float s = csum[bh][nf];
      s += __shfl_xor(s, 16);
      s += __shfl_xor(s, 32);
      if (lk == 0) {
        const long gc = n0 + bh * 128 + wn * 32 + nf * 16 + l16;
        atomicAdd(&pooled[((long)qm * 8 + b) * 512 + gc], s);
      }
    }
}

// ============ transpose + stats (vectorized): NCHW f32 -> NHWC + channel-major bf16 ============
// block 256, tile 128p x 32c ; LDS tile [c 32][p 128] bf16 pitch 132
__global__ __launch_bounds__(256) void transpose_kernel(
    const float* __restrict__ x0, const float* __restrict__ x1,
    const float* __restrict__ x2, bf16* __restrict__ xT, bf16* __restrict__ xC,
    float* __restrict__ cs, float* __restrict__ qstage)
{
  __shared__ __align__(16) bf16 tile[32 * 132];
  __shared__ float qpart[4][2];
  const int zz = blockIdx.z;           // m*8 + b
  const int m = zz >> 3, b = zz & 7;
  const float* x = (m == 0) ? x0 : (m == 1) ? x1 : x2;
  const int p0 = blockIdx.x * 128, c0 = blockIdx.y * 32;
  const int t = threadIdx.x;
  const int tx = t & 31, cy = t >> 5;
  bf16* y2 = xC + (long)m * 16777216;
  float qa = 0.f, qb_ = 0.f;
#pragma unroll
  for (int jc = 0; jc < 4; ++jc) {
    const int cl = jc * 8 + cy;
    const int c = c0 + cl;
    const float4 v = *(const float4*)(x + ((long)(b * 512 + c)) * 4096 + p0 + tx * 4);
    if (m == 0) {
      qa += v.x + v.y + v.z + v.w;
      qb_ += v.x * v.x + v.y * v.y + v.z * v.z + v.w * v.w;
    } else {
      qa += ((v.x == 0.0f) ? 1.f : 0.f) + ((v.y == 0.0f) ? 1.f : 0.f) +
            ((v.z == 0.0f) ? 1.f : 0.f) + ((v.w == 0.0f) ? 1.f : 0.f);
    }
    float s = v.x + v.y + v.z + v.w;
    for (int o = 1; o < 32; o <<= 1) s += __shfl_xor(s, o);
    if (tx == 0) atomicAdd(&cs[(m * 8 + b) * 512 + c], s);
    __align__(8) bf16 h[4];
    h[0] = __float2bfloat16(v.x); h[1] = __float2bfloat16(v.y);
    h[2] = __float2bfloat16(v.z); h[3] = __float2bfloat16(v.w);
    *(bfrag4*)(y2 + (long)c * 32768 + b * 4096 + p0 + tx * 4) = *(const bfrag4*)h;
    *(bfrag4*)(tile + cl * 132 + tx * 4) = *(const bfrag4*)h;
  }
  // quality: wave reduce + staged write
  const int lane = t & 63;
  float qaw = qa, qbw = qb_;
  for (int o = 32; o; o >>= 1) { qaw += __shfl_xor(qaw, o); qbw += __shfl_xor(qbw, o); }
  if (lane == 0) { qpart[t >> 6][0] = qaw; qpart[t >> 6][1] = qbw; }
  __syncthreads();
  if (t == 0) {
    float* qs = qstage + ((long)zz * 512 + blockIdx.y * 32 + blockIdx.x) * 2;
    qs[0] = qpart[0][0] + qpart[1][0] + qpart[2][0] + qpart[3][0];
    qs[1] = qpart[0][1] + qpart[1][1] + qpart[2][1] + qpart[3][1];
  }
  // phase B: xT[p][c] from tile columns, short8 stores
  bf16* y = xT + (long)m * 16777216;
#pragma unroll
  for (int jp = 0; jp < 2; ++jp) {
    const int pl = jp * 64 + (t >> 2);
    const int cg = (t & 3) * 8;
    __align__(16) bf16 o8[8];
#pragma unroll
    for (int i = 0; i < 8; ++i) o8[i] = tile[(cg + i) * 132 + pl];
    *(bfrag8*)(y + ((long)(b * 4096 + p0 + pl)) * 512 + c0 + cg) = *(const bfrag8*)o8;
  }
}

// =================== quality partial reduce -> qacc ===================
__global__ __launch_bounds__(256) void quality_reduce(
    const float* __restrict__ qstage, float* __restrict__ qacc)
{
  __shared__ float pr[4][2];
  const int zz = blockIdx.x;  // m*8 + b
  const int m = zz >> 3, b = zz & 7;
  const int t = threadIdx.x;
  float sa = 0.f, sb = 0.f;
  for (int i = t; i < 512; i += 256) {
    sa += qstage[((long)zz * 512 + i) * 2];
    sb += qstage[((long)zz * 512 + i) * 2 + 1];
  }
  for (int o = 32; o; o >>= 1) { sa += __shfl_xor(sa, o); sb += __shfl_xor(sb, o); }
  if ((t & 63) == 0) { pr[t >> 6][0] = sa; pr[t >> 6][1] = sb; }
  __syncthreads();
  if (t == 0) {
    sa = pr[0][0] + pr[1][0] + pr[2][0] + pr[3][0];
    sb = pr[0][1] + pr[1][1] + pr[2][1] + pr[3][1];
    if (m == 0) { qacc[b * 4 + 1] = sa; qacc[b * 4 + 2] = sb; }
    else if (m == 1) qacc[b * 4 + 0] = sa;
    else qacc[b * 4 + 3] = sa;
  }
}

// =================== weight conversion ===================
__global__ void prep_weights(
    const float* __restrict__ wq, const float* __restrict__ wk,
    const float* __restrict__ wv, const float* __restrict__ wo,
    const float* __restrict__ fw, const float* __restrict__ bo,
    bf16* __restrict__ wqB, bf16* __restrict__ wkB, bf16* __restrict__ wvT,
    bf16* __restrict__ woB, bf16* __restrict__ fwB, float* __restrict__ bo2,
    bf16* __restrict__ idB)
{
  const long stride = (long)gridDim.x * blockDim.x;
  for (long j = (long)blockIdx.x * blockDim.x + threadIdx.x; j < 2359296; j += stride) {
    fwB[j] = __float2bfloat16(fw[j]);
    if (j < 1572864) {
      wqB[j] = __float2bfloat16(wq[j]);
      wkB[j] = __float2bfloat16(wk[j]);
      woB[j] = __float2bfloat16(wo[j]);
      const long i = j >> 18, rem = j & 262143, cin = rem >> 9, ef = rem & 511;
      wvT[j] = __float2bfloat16(wv[(i << 18) + (ef << 9) + cin]);
    }
    if (j < 262144) {
      const long r = j >> 9, c = j & 511;
      idB[j] = __float2bfloat16((r == c) ? 1.0f : 0.0f);
    }
    if (j < 1536) {
      const long m2 = j >> 9, cc = j & 511;
      bo2[j] = bo[((m2 * 2) << 9) + cc] + bo[((m2 * 2 + 1) << 9) + cc];
    }
  }
}

// =================== 128² GEMM core (m97-style) ===================
template<int BM, int BN>
__device__ __forceinline__ void gemm_core(
    const bf16* __restrict__ A, long lda,
    const bf16* __restrict__ Bt, long ldb,
    int K, long m0, long n0,
    bf16* As, bf16* Bs, f32x4 (&acc)[BM / 32][BN / 32])
{
  constexpr int WM = BM / 2, WN = BN / 2, FM = BM / 32, FN = BN / 32;
  const int t = threadIdx.x;
  const int lane = t & 63, wv = t >> 6;
  const int wr = wv >> 1, wc = wv & 1;
  const int l16 = lane & 15, lk = lane >> 4;
  const int srow = t >> 2;
  const int scol = (t & 3) * 8;
  const bf16* Ag = A + (m0 + srow) * lda + scol;
  const bf16* Bg = Bt + (n0 + srow) * ldb + scol;
  char* AsB = (char*)As;
  char* BsB = (char*)Bs;
  const int aoff = wv * 1024;
  for (int kk = 0; kk < K; kk += 32) {
#pragma unroll
    for (int it = 0; it < BM / 64; ++it)
      gload16(Ag + (long)it * 64 * lda + kk, AsB + it * 4096 + aoff);
#pragma unroll
    for (int it = 0; it < BN / 64; ++it)
      gload16(Bg + (long)it * 64 * ldb + kk, BsB + it * 4096 + aoff);
    __syncthreads();
    bfrag8 af[FM], bfr[FN];
#pragma unroll
    for (int m = 0; m < FM; ++m)
      af[m] = *(const bfrag8*)(AsB + ((wr * WM + m * 16 + l16) * 32 + lk * 8) * 2);
#pragma unroll
    for (int n = 0; n < FN; ++n)
      bfr[n] = *(const bfrag8*)(BsB + ((wc * WN + n * 16 + l16) * 32 + lk * 8) * 2);
#pragma unroll
    for (int m = 0; m < FM; ++m)
#pragma unroll
      for (int n = 0; n < FN; ++n)
        mfma_bf16(acc[m][n], af[m], bfr[n]);
    __syncthreads();
  }
}

// =================== Gram: G[i,j] = sum_p xA[p,i] xB[p,j], bf16 out ===================
__global__ __launch_bounds__(256, 2) void gram_kernel(
    const bf16* __restrict__ xC, bf16* __restrict__ Gb)
{
  __shared__ __align__(16) bf16 As[128 * 32];
  __shared__ __align__(16) bf16 Bs[128 * 32];
  const int z = blockIdx.z;
  const int pair = z >> 3, b = z & 7;
  const int A1[3] = {0, 0, 1}, A2[3] = {1, 2, 2};
  const bf16* A = xC + (long)A1[pair] * 16777216 + b * 4096;
  const bf16* Bt = xC + (long)A2[pair] * 16777216 + b * 4096;
  f32x4 acc[4][4];
#pragma unroll
  for (int m = 0; m < 4; ++m)
#pragma unroll
    for (int n = 0; n < 4; ++n)
      acc[m][n] = f32x4{0.f, 0.f, 0.f, 0.f};
  const long m0 = (long)blockIdx.x * 128, n0 = (long)blockIdx.y * 128;
  gemm_core<128, 128>(A, 32768, Bt, 32768, 4096, m0, n0, As, Bs, acc);
  bf16* C = Gb + (long)z * 262144;
  const int t = threadIdx.x;
  const int lane = t & 63, wv = t >> 6;
  const int wr = wv >> 1, wc = wv & 1;
  const int l16 = lane & 15, lk = lane >> 4;
#pragma unroll
  for (int m = 0; m < 4; ++m) {
    const long gr0 = m0 + wr * 64 + m * 16 + lk * 4;
#pragma unroll
    for (int n = 0; n < 4; ++n) {
      const long gc = n0 + wc * 64 + n * 16 + l16;
#pragma unroll
      for (int i = 0; i < 4; ++i)
        C[(gr0 + i) * 512 + gc] = __float2bfloat16(acc[m][n][i]);
    }
  }
}

// =================== scores+softmax -> attnT[e][d] ===================
__global__ __launch_bounds__(256, 2) void scores_kernel(
    const bf16* __restrict__ wqB, const bf16* __restrict__ wkB,
    const bf16* __restrict__ Gb, const float* __restrict__ colsum,
    const float* __restrict__ bq, const float* __restrict__ bk,
    bf16* __restrict__ attnT)
{
  __shared__ __align__(16) bf16 RtS[64 * 520];  // R^T bf16 ; later aliased as S f32 [64][68]
  __shared__ float uv[128];
  __shared__ __align__(16) bf16 attT[64][64];
  const int h = blockIdx.x, b = blockIdx.y, i = blockIdx.z;
  const int qm = i >> 1, jj = i & 1;
  const int km = jj ? (qm == 2 ? 1 : 2) : (qm == 0 ? 1 : 0);
  const int lo = qm < km ? qm : km, hi = qm < km ? km : qm;
  const int pair = lo + hi - 1;
  const int trans = qm > km;
  const bf16* G = Gb + ((long)(pair * 8 + b)) * 262144;
  const bf16* Wq_h = wqB + (long)i * 262144 + h * 64 * 512;
  const bf16* Wk_h = wkB + (long)i * 262144 + h * 64 * 512;
  const bf16* WA = trans ? Wk_h : Wq_h;
  const bf16* WB = trans ? Wq_h : Wk_h;
  const int t = threadIdx.x, lane = t & 63, wv = t >> 6;
  const int l16 = lane & 15, lk = lane >> 4;

  if (t < 128) {
    const int d = t & 63;
    const bf16* wrow = ((t < 64) ? Wq_h : Wk_h) + d * 512;
    const float* sv = colsum + (((t < 64) ? qm : km) * 8 + b) * 512;
    float a = 0.f;
    for (int c = 0; c < 512; c += 8) {
      const bfrag8 w8 = *(const bfrag8*)(wrow + c);
#pragma unroll
      for (int e = 0; e < 8; ++e) a += bf2f(w8[e]) * sv[c + e];
    }
    uv[t] = a;
  }

  // step A: R[512,64] = G . WB^T ; wave wv owns rows [wv*128, +128)
  f32x4 acc[8][4];
#pragma unroll
  for (int m = 0; m < 8; ++m)
#pragma unroll
    for (int n = 0; n < 4; ++n)
      acc[m][n] = f32x4{0.f, 0.f, 0.f, 0.f};
  for (int kk = 0; kk < 512; kk += 32) {
    bfrag8 a[8], bb[4];
#pragma unroll
    for (int m = 0; m < 8; ++m)
      a[m] = *(const bfrag8*)(G + (wv * 128 + m * 16 + l16) * 512 + kk + lk * 8);
#pragma unroll
    for (int n = 0; n < 4; ++n)
      bb[n] = *(const bfrag8*)(WB + (n * 16 + l16) * 512 + kk + lk * 8);
#pragma unroll
    for (int m = 0; m < 8; ++m)
#pragma unroll
      for (int n = 0; n < 4; ++n)
        mfma_bf16(acc[m][n], a[m], bb[n]);
  }
#pragma unroll
  for (int m = 0; m < 8; ++m)
#pragma unroll
    for (int n = 0; n < 4; ++n)
#pragma unroll
      for (int idx = 0; idx < 4; ++idx)
        RtS[(n * 16 + l16) * 520 + wv * 128 + m * 16 + lk * 4 + idx] =
            __float2bfloat16(acc[m][n][idx]);
  __syncthreads();

  // step B: S[64,64] = WA . Rt^T
  f32x4 acc2[4];
#pragma unroll
  for (int m = 0; m < 4; ++m) acc2[m] = f32x4{0.f, 0.f, 0.f, 0.f};
  for (int kk = 0; kk < 512; kk += 32) {
    bfrag8 a2[4];
#pragma unroll
    for (int m = 0; m < 4; ++m)
      a2[m] = *(const bfrag8*)(WA + (m * 16 + l16) * 512 + kk + lk * 8);
    const bfrag8 b2 = *(const bfrag8*)(&RtS[(wv * 16 + l16) * 520 + kk + lk * 8]);
#pragma unroll
    for (int m = 0; m < 4; ++m) mfma_bf16(acc2[m], a2[m], b2);
  }
  __syncthreads();
  float* S = (float*)RtS;  // [64][68]
#pragma unroll
  for (int m = 0; m < 4; ++m)
#pragma unroll
    for (int idx = 0; idx < 4; ++idx)
      S[(m * 16 + lk * 4 + idx) * 68 + wv * 16 + l16] = acc2[m][idx];
  __syncthreads();

  const int r = t >> 2, q = t & 3;   // r = d (query row), q*16+kq = e (key col)
  const float* bq_h = bq + i * 512 + h * 64;
  const float* bk_h = bk + i * 512 + h * 64;
  const float u_r = uv[r], bq_r = bq_h[r];
  float vals[16];
  float mx = -1e30f;
#pragma unroll
  for (int kq = 0; kq < 16; ++kq) {
    const int k = q * 16 + kq;
    float s = trans ? S[k * 68 + r] : S[r * 68 + k];
    s += u_r * bk_h[k] + bq_r * uv[64 + k] + 4096.0f * bq_r * bk_h[k];
    s *= 0.125f;
    vals[kq] = s;
    mx = fmaxf(mx, s);
  }
  mx = fmaxf(mx, __shfl_xor(mx, 1));
  mx = fmaxf(mx, __shfl_xor(mx, 2));
  float sum = 0.f;
#pragma unroll
  for (int kq = 0; kq < 16; ++kq) { vals[kq] = expf(vals[kq] - mx); sum += vals[kq]; }
  sum += __shfl_xor(sum, 1);
  sum += __shfl_xor(sum, 2);
  const float inv = 1.0f / sum;
#pragma unroll
  for (int kq = 0; kq < 16; ++kq)
    attT[q * 16 + kq][r] = __float2bfloat16(vals[kq] * inv);
  __syncthreads();
  const int er = t >> 2, c16 = (t & 3) * 16;
  bf16* op = attnT + (((long)(i * 8 + b) * 8 + h) * 64 + er) * 64 + c16;
  *(bfrag8*)(op) = *(const bfrag8*)(&attT[er][c16]);
  *(bfrag8*)(op + 8) = *(const bfrag8*)(&attT[er][c16 + 8]);
}

// =================== mfold: M[c,ef] = sum_d Wo[c, h*64+d] * attnT[e,d]; mvec += M.bv ===================
__global__ __launch_bounds__(256, 2) void mfold_kernel(
    const bf16* __restrict__ woB, const bf16* __restrict__ attnT,
    const float* __restrict__ bv, bf16* __restrict__ Mbuf, float* __restrict__ mvec)
{
  __shared__ __align__(16) bf16 As[128 * 32];
  __shared__ __align__(16) bf16 Bs[64 * 32];
  const int ib = blockIdx.z;          // i*8+b
  const int i = ib >> 3;
  const int h = blockIdx.y;
  const bf16* A = woB + (long)i * 262144 + h * 64;
  const bf16* Bt = attnT + ((long)ib * 8 + h) * 4096;
  f32x4 acc[4][2];
#pragma unroll
  for (int m = 0; m < 4; ++m)
#pragma unroll
    for (int n = 0; n < 2; ++n)
      acc[m][n] = f32x4{0.f, 0.f, 0.f, 0.f};
  const long m0 = (long)blockIdx.x * 128;
  gemm_core<128, 64>(A, 512, Bt, 64, 64, m0, 0, As, Bs, acc);

  const int t = threadIdx.x;
  const int lane = t & 63, wv = t >> 6;
  const int wr = wv >> 1, wc = wv & 1;
  const int l16 = lane & 15, lk = lane >> 4;
  bf16* C = Mbuf + (long)ib * 262144;
  const float* bvp = bv + i * 512 + h * 64;
  float mp[4][4];
#pragma unroll
  for (int m = 0; m < 4; ++m)
#pragma unroll
    for (int i2 = 0; i2 < 4; ++i2) mp[m][i2] = 0.f;
#pragma unroll
  for (int m = 0; m < 4; ++m) {
    const long gr0 = m0 + wr * 64 + m * 16 + lk * 4;
#pragma unroll
    for (int n = 0; n < 2; ++n) {
      const int gc = wc * 32 + n * 16 + l16;
      const float bvv = bvp[gc];
#pragma unroll
      for (int i2 = 0; i2 < 4; ++i2) {
        C[(gr0 + i2) * 512 + h * 64 + gc] = __float2bfloat16(acc[m][n][i2]);
        mp[m][i2] += acc[m][n][i2] * bvv;
      }
    }
  }
#pragma unroll
  for (int m = 0; m < 4; ++m)
#pragma unroll
    for (int i2 = 0; i2 < 4; ++i2) {
      float v = mp[m][i2];
      v += __shfl_xor(v, 1); v += __shfl_xor(v, 2);
      v += __shfl_xor(v, 4); v += __shfl_xor(v, 8);
      if (l16 == 0)
        atomicAdd(&mvec[(long)ib * 512 + m0 + wr * 64 + m * 16 + lk * 4 + i2], v);
    }
}

// =================== weff: W_eff[c,cin] = sum_ef M[c,ef] * wvT[cin,ef] ===================
__global__ __launch_bounds__(256, 2) void weff_gemm(
    const bf16* __restrict__ Mbuf, const bf16* __restrict__ wvT,
    bf16* __restrict__ Weff)
{
  __shared__ __align__(16) bf16 As[128 * 32];
  __shared__ __align__(16) bf16 Bs[128 * 32];
  const int ib = blockIdx.z;
  const int i = ib >> 3;
  f32x4 acc[4][4];
#pragma unroll
  for (int m = 0; m < 4; ++m)
#pragma unroll
    for (int n = 0; n < 4; ++n)
      acc[m][n] = f32x4{0.f, 0.f, 0.f, 0.f};
  const long m0 = (long)blockIdx.x * 128, n0 = (long)blockIdx.y * 128;
  gemm_core<128, 128>(Mbuf + (long)ib * 262144, 512, wvT + (long)i * 262144, 512,
                      512, m0, n0, As, Bs, acc);
  bf16* C = Weff + (long)ib * 262144;
  const int t = threadIdx.x;
  const int lane = t & 63, wv = t >> 6;
  const int wr = wv >> 1, wc = wv & 1;
  const int l16 = lane & 15, lk = lane >> 4;
#pragma unroll
  for (int m = 0; m < 4; ++m) {
    const long gr0 = m0 + wr * 64 + m * 16 + lk * 4;
#pragma unroll
    for (int n = 0; n < 4; ++n) {
      const long gc = n0 + wc * 64 + n * 16 + l16;
#pragma unroll
      for (int i2 = 0; i2 < 4; ++i2)
        C[(gr0 + i2) * 512 + gc] = __float2bfloat16(acc[m][n][i2]);
    }
  }
}

// =================== SE MLP ===================
__global__ __launch_bounds__(512) void se_mlp(
    const float* __restrict__ pooled,
    const float* __restrict__ W1, const float* __restrict__ b1,
    const float* __restrict__ W2, const float* __restrict__ b2,
    float* __restrict__ se)
{
  const int b = blockIdx.x, m = blockIdx.y;
  __shared__ float y[32];
  const int t = threadIdx.x;
  if (t < 32) {
    float s = b1[m * 32 + t];
    const float* w = W1 + (long)(m * 32 + t) * 512;
    const float* p = pooled + ((long)m * 8 + b) * 512;
    for (int c = 0; c < 512; ++c) s += w[c] * (p[c] * (1.0f / 4096.0f));
    y[t] = fmaxf(s, 0.0f);
  }
  __syncthreads();
  float s = b2[m * 512 + t];
  const float* w2 = W2 + (long)(m * 512 + t) * 32;
#pragma unroll
  for (int j = 0; j < 32; ++j) s += w2[j] * y[j];
  se[((long)m * 8 + b) * 512 + t] = 1.0f / (1.0f + expf(-s));
}

// ========= refined = l2norm_c(cross*se); alpha = sigmoid(gate); weighted out (fused) =========
__global__ __launch_bounds__(384) void refine_gate(
    const bf16* __restrict__ cr0, const bf16* __restrict__ cr1,
    const bf16* __restrict__ cr2, const float* __restrict__ se,
    const float* __restrict__ gw, const float* __restrict__ gb,
    const float* __restrict__ qacc, bf16* __restrict__ weighted)
{
  __shared__ float part[2][3][3];
  const int t = threadIdx.x, wv = t >> 6, lane = t & 63;
  const int px_i = (wv >= 3) ? 1 : 0;
  const int m = wv - px_i * 3;
  const int pix = blockIdx.x * 2 + px_i;
  const int b = pix >> 12;
  const bf16* cr = (m == 0) ? cr0 : (m == 1) ? cr1 : cr2;
  const int c0 = lane * 8;
  const bfrag8 v8 = *(const bfrag8*)(cr + (long)pix * 512 + c0);
  const float* sp = se + ((long)m * 8 + b) * 512 + c0;
  const float4 s0 = *(const float4*)(sp);
  const float4 s1 = *(const float4*)(sp + 4);
  float w[8] = {bf2f(v8[0]) * s0.x, bf2f(v8[1]) * s0.y,
                bf2f(v8[2]) * s0.z, bf2f(v8[3]) * s0.w,
                bf2f(v8[4]) * s1.x, bf2f(v8[5]) * s1.y,
                bf2f(v8[6]) * s1.z, bf2f(v8[7]) * s1.w};
  float ss = 0.f;
#pragma unroll
  for (int i = 0; i < 8; ++i) ss += w[i] * w[i];
  for (int o = 32; o; o >>= 1) ss += __shfl_xor(ss, o);
  const float inv = 1.0f / (sqrtf(ss) + 1e-6f);
  float rf[8];
#pragma unroll
  for (int i = 0; i < 8; ++i) rf[i] = w[i] * inv;

  float a0 = 0.f, a1 = 0.f, a2 = 0.f;
#pragma unroll
  for (int i = 0; i < 8; ++i) {
    const int c = m * 512 + c0 + i;
    a0 += gw[c] * rf[i];
    a1 += gw[1539 + c] * rf[i];
    a2 += gw[3078 + c] * rf[i];
  }
  for (int o = 32; o; o >>= 1) {
    a0 += __shfl_xor(a0, o); a1 += __shfl_xor(a1, o); a2 += __shfl_xor(a2, o);
  }
  if (lane == 0) {
    part[px_i][m][0] = a0; part[px_i][m][1] = a1; part[px_i][m][2] = a2;
  }
  __syncthreads();
  const float N = 2097152.0f;
  const float q0 = qacc[b * 4 + 0] / N;
  const float q1 = (qacc[b * 4 + 2] - qacc[b * 4 + 1] * qacc[b * 4 + 1] / N) / (N - 1.0f);
  const float q2 = qacc[b * 4 + 3] / N;
  const float sg = part[px_i][0][m] + part[px_i][1][m] + part[px_i][2][m] + gb[m] +
                   gw[m * 1539 + 1536] * q0 + gw[m * 1539 + 1537] * q1 +
                   gw[m * 1539 + 1538] * q2;
  const float al = 1.0f / (1.0f + expf(-sg));
  __align__(16) bf16 tmp[8];
#pragma unroll
  for (int i = 0; i < 8; ++i) tmp[i] = __float2bfloat16(rf[i] * al);
  *(bfrag8*)(weighted + (long)pix * 1536 + m * 512 + c0) = *(const bfrag8*)tmp;
}

// =================== host launch ===================
extern "C" void kernel_launch(void* const* d_in, const int* in_sizes, int n_in,
                              void* d_out, int out_size, void* d_ws, size_t ws_size,
                              hipStream_t stream)
{
  (void)in_sizes; (void)n_in; (void)out_size; (void)ws_size;
  const float* rgb   = (const float*)d_in[0];
  const float* depth = (const float*)d_in[1];
  const float* lidar = (const float*)d_in[2];
  const float* wq  = (const float*)d_in[3];
  const float* bq  = (const float*)d_in[4];
  const float* wk  = (const float*)d_in[5];
  const float* bk  = (const float*)d_in[6];
  const float* wvw = (const float*)d_in[7];
  const float* bv  = (const float*)d_in[8];
  const float* wo  = (const float*)d_in[9];
  const float* bo  = (const float*)d_in[10];
  const float* seW1 = (const float*)d_in[11];
  const float* seb1 = (const float*)d_in[12];
  const float* seW2 = (const float*)d_in[13];
  const float* seb2 = (const float*)d_in[14];
  const float* gw  = (const float*)d_in[15];
  const float* gb  = (const float*)d_in[16];
  const float* fw  = (const float*)d_in[17];
  const float* fb  = (const float*)d_in[18];

  char* ws = (char*)d_ws;
  bf16*  xT   = (bf16*)(ws + OFF_XT);
  bf16*  xC   = (bf16*)(ws + OFF_XC);
  bf16*  wqB  = (bf16*)(ws + OFF_WQ);
  bf16*  wkB  = (bf16*)(ws + OFF_WK);
  bf16*  wvT  = (bf16*)(ws + OFF_WVT);
  bf16*  woB  = (bf16*)(ws + OFF_WOB);
  bf16*  fwB  = (bf16*)(ws + OFF_FW);
  float* bo2  = (float*)(ws + OFF_BO2);
  float* pooled = (float*)(ws + OFF_POOL);
  float* seB  = (float*)(ws + OFF_SE);
  float* qacc = (float*)(ws + OFF_QACC);
  float* cs   = (float*)(ws + OFF_CS);
  bf16*  Gb   = (bf16*)(ws + OFF_GB);
  bf16*  attnT = (bf16*)(ws + OFF_ATT);
  float* qstage = (float*)(ws + OFF_QST);
  float* mvec = (float*)(ws + OFF_MVEC);
  bf16*  idB  = (bf16*)(ws + OFF_IDB);
  bf16*  Mbuf = (bf16*)(ws + OFF_XC);              // alias, dead after weff
  bf16*  Weff = (bf16*)(ws + OFF_XC + 25165824L);  // alias, dead after cross
  bf16*  crossB = (bf16*)(ws + OFF_VST);

  // zero: pooled (+se, qacc harmlessly), colsum ; mvec
  (void)hipMemsetAsync(ws + OFF_POOL, 0, OFF_CS + 49152 - OFF_POOL, stream);
  (void)hipMemsetAsync(ws + OFF_MVEC, 0, 98304, stream);

  transpose_kernel<<<dim3(32, 16, 24), 256, 0, stream>>>(rgb, depth, lidar,
                                                         xT, xC, cs, qstage);
  quality_reduce<<<24, 256, 0, stream>>>(qstage, qacc);
  prep_weights<<<2048, 256, 0, stream>>>(wq, wk, wvw, wo, fw, bo,
                                         wqB, wkB, wvT, woB, fwB, bo2, idB);

  gram_kernel<<<dim3(4, 4, 24), 256, 0, stream>>>(xC, Gb);
  scores_kernel<<<dim3(8, 8, 6), 256, 0, stream>>>(wqB, wkB, Gb, cs, bq, bk, attnT);

  mfold_kernel<<<dim3(4, 8, 48), 256, 0, stream>>>(woB, attnT, bv, Mbuf, mvec);
  weff_gemm<<<dim3(4, 4, 48), 256, 0, stream>>>(Mbuf, wvT, Weff);

  cross_gemm256<<<dim3(16, 2, 24), 512, 0, stream>>>(xT, Weff, idB, crossB, bo2,
                                                     mvec, pooled);
  se_mlp<<<dim3(8, 3), 512, 0, stream>>>(pooled, seW1, seb1, seW2, seb2, seB);

  bf16* cross0 = crossB;
  bf16* cross1 = (bf16*)(ws + OFF_VST + 33554432L);
  bf16* cross2 = (bf16*)(ws + OFF_VST + 67108864L);
  bf16* weighted = (bf16*)(ws + OFF_XC);
  refine_gate<<<16384, 384, 0, stream>>>(cross0, cross1, cross2, seB, gw, gb, qacc, weighted);

  fusion_gemm256<<<dim3(128, 6), 512, 0, stream>>>(weighted, fwB, (float*)d_out, fb);
}